// Round 1
// baseline (400.774 us; speedup 1.0000x reference)
//
#include <hip/hip_runtime.h>

#define N_SEQ 2048
#define M_FFT 4096
#define D1    1536
#define NH    8
#define HD    192
#define ED    512

typedef __bf16 bf16;
typedef __bf16 bf16x4 __attribute__((ext_vector_type(4)));
typedef __bf16 bf16x8 __attribute__((ext_vector_type(8)));
typedef float  floatx4 __attribute__((ext_vector_type(4)));
typedef float  cx __attribute__((ext_vector_type(2)));   // complex as packed fp32

enum { MODE_PLAIN = 0, MODE_SILU_UV = 1, MODE_AT = 3, MODE_RPE = 4 };

__device__ __forceinline__ void gload16(const void* g, void* l) {
    __builtin_amdgcn_global_load_lds(
        (const __attribute__((address_space(1))) void*)g,
        (__attribute__((address_space(3))) void*)l, 16, 0, 0);
}

// ---------------------------------------------------------------------------
// bf16 MFMA GEMM (m97 structure): C = epilogue(A(MxK) @ Bw(NcxK)^T + bias)
// MODE_RPE: val = acc*scale_prev[row] + bias; atomic row sum-sq; relu; bf16.
// MODE_AT : val = acc*scale_prev[row] + bias; fp32 transposed store.
// ---------------------------------------------------------------------------
template<int MODE, typename OutT>
__global__ __launch_bounds__(256) void gemm_bf16(
    const bf16* __restrict__ A, const bf16* __restrict__ Bw,
    const float* __restrict__ bias, const float* __restrict__ bias2,
    OutT* __restrict__ C, OutT* __restrict__ C2,
    int M, int Nc, int K,
    const float* __restrict__ scale_in, float* __restrict__ sumsq_out)
{
    __shared__ __align__(16) bf16 As[128 * 32];
    __shared__ __align__(16) bf16 Bs[128 * 32];

    const int tid  = threadIdx.x;
    const int row0 = blockIdx.y * 128;
    const int col0 = blockIdx.x * 128;
    const int wid  = tid >> 6;
    const int lane = tid & 63;
    const int lm   = lane & 15;
    const int lk   = lane >> 4;
    const int wm   = wid >> 1;
    const int wn   = wid & 1;
    const int ldrow  = tid >> 2;
    const int ldcol8 = (tid & 3) * 8;

    floatx4 acc[4][4] = {};

    const bf16* Ag = A  + ((size_t)(row0 + ldrow)) * K + ldcol8;
    const bf16* Bg = Bw + ((size_t)(col0 + ldrow)) * K + ldcol8;
    bf16* AsW = As + (wid * 16) * 32;
    bf16* BsW = Bs + (wid * 16) * 32;

    for (int k0 = 0; k0 < K; k0 += 32) {
        gload16(Ag + k0, AsW);
        gload16(Ag + (size_t)64 * K + k0, AsW + 64 * 32);
        gload16(Bg + k0, BsW);
        gload16(Bg + (size_t)64 * K + k0, BsW + 64 * 32);
        __syncthreads();

        bf16x8 af[4], bfr[4];
        #pragma unroll
        for (int mi = 0; mi < 4; ++mi)
            af[mi] = *(const bf16x8*)&As[(wm * 64 + mi * 16 + lm) * 32 + lk * 8];
        #pragma unroll
        for (int nj = 0; nj < 4; ++nj)
            bfr[nj] = *(const bf16x8*)&Bs[(wn * 64 + nj * 16 + lm) * 32 + lk * 8];
        #pragma unroll
        for (int mi = 0; mi < 4; ++mi)
            #pragma unroll
            for (int nj = 0; nj < 4; ++nj)
                acc[mi][nj] = __builtin_amdgcn_mfma_f32_16x16x32_bf16(
                    af[mi], bfr[nj], acc[mi][nj], 0, 0, 0);
        __syncthreads();
    }

    const float* bs = bias;
    OutT* dst = C;
    int cadj = 0;
    if (MODE == MODE_SILU_UV && col0 >= D1) { bs = bias2; dst = C2; cadj = D1; }

    float bcol[4];
    #pragma unroll
    for (int nj = 0; nj < 4; ++nj)
        bcol[nj] = bs[col0 - cadj + wn * 64 + nj * 16 + lm];

    if (MODE == MODE_RPE) {
        #pragma unroll
        for (int mi = 0; mi < 4; ++mi) {
            #pragma unroll
            for (int r = 0; r < 4; ++r) {
                const int row = row0 + wm * 64 + mi * 16 + lk * 4 + r;
                float sc = 1.0f;
                if (scale_in)
                    sc = 1.0f / (sqrtf(scale_in[row]) * 0.04419417382415922f + 1e-8f);
                float ssq = 0.0f;
                #pragma unroll
                for (int nj = 0; nj < 4; ++nj) {
                    const int col = col0 + wn * 64 + nj * 16 + lm;
                    float val = acc[mi][nj][r] * sc + bcol[nj];
                    ssq += val * val;
                    ((bf16*)C)[(size_t)row * Nc + col] = (bf16)fmaxf(val, 0.0f);
                }
                ssq += __shfl_xor(ssq, 1, 64);
                ssq += __shfl_xor(ssq, 2, 64);
                ssq += __shfl_xor(ssq, 4, 64);
                ssq += __shfl_xor(ssq, 8, 64);
                if (lm == 0) atomicAdd(&sumsq_out[row], ssq);
            }
        }
        return;
    }

    #pragma unroll
    for (int mi = 0; mi < 4; ++mi) {
        const int rbase = row0 + wm * 64 + mi * 16 + lk * 4;
        float sc[4];
        #pragma unroll
        for (int r = 0; r < 4; ++r) {
            sc[r] = 1.0f;
            if (MODE == MODE_AT && scale_in)
                sc[r] = 1.0f / (sqrtf(scale_in[rbase + r]) * 0.04419417382415922f + 1e-8f);
        }
        #pragma unroll
        for (int nj = 0; nj < 4; ++nj) {
            const int col = col0 - cadj + wn * 64 + nj * 16 + lm;
            float vals[4];
            #pragma unroll
            for (int r = 0; r < 4; ++r) {
                float val = acc[mi][nj][r] * sc[r] + bcol[nj];
                if (MODE == MODE_SILU_UV)
                    val = val / (1.0f + __expf(-val));
                vals[r] = val;
            }
            if (MODE == MODE_SILU_UV) {
                int b = rbase >> 11, s = rbase & 2047;
                bf16x4 o;
                #pragma unroll
                for (int r = 0; r < 4; ++r) o[r] = (bf16)vals[r];
                *(bf16x4*)&((bf16*)dst)[((size_t)(b * D1 + col)) * N_SEQ + s] = o;
            } else if (MODE == MODE_AT) {
                float4 o = make_float4(vals[0], vals[1], vals[2], vals[3]);
                *(float4*)&((float*)C)[(size_t)col * M + rbase] = o;
            } else {
                #pragma unroll
                for (int r = 0; r < 4; ++r)
                    C[(size_t)(rbase + r) * Nc + col] = (OutT)vals[r];
            }
        }
    }
}

// ---------------------------------------------------------------------------
// mega-prologue: x convert (4096 blk) + 5 weight converts (3840 blk) +
// sumsq zero (12 blk) + RPE input layer w/ srms (4096 blk) +
// FFT twiddle table T[j][tau] = exp(-2*pi*i*j*tau/4096), j<256, tau<16 (16 blk)
// ---------------------------------------------------------------------------
__global__ __launch_bounds__(256) void f2b_all_kernel(
    const float* __restrict__ x,  const float* __restrict__ s0,
    const float* __restrict__ s1, const float* __restrict__ s2,
    const float* __restrict__ s3, const float* __restrict__ s4,
    const float* __restrict__ Wp, const float* __restrict__ bp,
    bf16* __restrict__ x_bf, bf16* __restrict__ w_bf,
    float* __restrict__ sumsq, bf16* __restrict__ g0,
    float* __restrict__ twd)
{
    const int bid = blockIdx.x;
    const int tid = threadIdx.x;
    __shared__ float red[4];

    if (bid < 7936) {
        const float* src;
        bf16* dst;
        size_t off;
        if (bid < 4096) {
            src = x; dst = x_bf; off = (size_t)bid * 1024;
        } else {
            int t = bid - 4096;
            int seg = t / 768;
            src = seg == 0 ? s0 : seg == 1 ? s1 : seg == 2 ? s2
                : seg == 3 ? s3 : s4;
            dst = w_bf + (size_t)seg * 786432;
            off = (size_t)(t % 768) * 1024;
        }
        size_t i = off + (size_t)tid * 4;
        float4 f = *(const float4*)(src + i);
        union { bf16 h[4]; short4 s; } u4;
        u4.h[0] = (bf16)f.x; u4.h[1] = (bf16)f.y;
        u4.h[2] = (bf16)f.z; u4.h[3] = (bf16)f.w;
        *(short4*)(dst + i) = u4.s;
    } else if (bid < 7948) {
        size_t i = (size_t)(bid - 7936) * 1024 + (size_t)tid * 4;
        *(float4*)(sumsq + i) = make_float4(0.f, 0.f, 0.f, 0.f);
    } else if (bid < 12044) {
        const int j = bid - 7948;
        float idxv = (j < N_SEQ) ? (float)j
                                 : (j == N_SEQ ? 0.0f : (float)(j - 2 * N_SEQ));
        float h1 = idxv * Wp[tid] + bp[tid];
        float h2 = idxv * Wp[tid + 256] + bp[tid + 256];
        float ss = h1 * h1 + h2 * h2;
        #pragma unroll
        for (int off = 32; off > 0; off >>= 1) ss += __shfl_down(ss, off, 64);
        if ((tid & 63) == 0) red[tid >> 6] = ss;
        __syncthreads();
        float tot = red[0] + red[1] + red[2] + red[3];
        float scale = 1.0f / (sqrtf(tot) * 0.04419417382415922f + 1e-8f);
        g0[(size_t)j * ED + tid]       = (bf16)fmaxf(h1 * scale, 0.0f);
        g0[(size_t)j * ED + tid + 256] = (bf16)fmaxf(h2 * scale, 0.0f);
    } else {
        const int idx = (bid - 12044) * 256 + tid;    // [0, 4096)
        const int j = idx >> 4, tau = idx & 15;
        float sA, cA;
        __sincosf(-6.283185307179586f * (float)(j * tau) * (1.0f / 4096.0f),
                  &sA, &cA);
        cx w; w.x = cA; w.y = sA;
        ((cx*)twd)[idx] = w;
    }
}

// ---------------------------------------------------------------------------
// Radix-16 FFT, radix-4 butterflies, packed-fp32 complex.
// All LDS addressing uses the affine identity:
//   fpad(base + s*t) = fpad(base) + s'*t   (s=256 -> s'=274, 16 -> 17, 1 -> 1)
// so each stage computes ONE base and uses literal ds offsets.
// Twiddles come from a precomputed table (inverse = conjugate).
// ---------------------------------------------------------------------------
#define FFT_LDS_SZ 4381

__device__ __forceinline__ int fpad(int i) { return i + (i >> 4) + 2 * (i >> 8); }

__device__ __forceinline__ cx mkcx(float a, float b) { cx r; r.x = a; r.y = b; return r; }
__device__ __forceinline__ cx cmul(cx a, cx b) {
    cx br = mkcx(-b.y, b.x);
    return a.xx * b + a.yy * br;
}
__device__ __forceinline__ cx cmul_cj(cx a, cx b) {      // a * conj(b)
    cx bc = mkcx(b.x, -b.y);
    cx br = mkcx(b.y, b.x);
    return a.xx * bc + a.yy * br;
}
__device__ __forceinline__ cx cneg_i(cx a) { return mkcx(a.y, -a.x); }   // a * (-i)
__device__ __forceinline__ cx cpos_i(cx a) { return mkcx(-a.y, a.x); }   // a * (+i)
__host__ __device__ constexpr int brev4(int t) {
    return ((t & 1) << 3) | ((t & 2) << 1) | ((t & 4) >> 1) | ((t & 8) >> 3);
}

#define CC1 0.9238795325112867f
#define SS1 0.3826834323650898f
#define RR2 0.7071067811865476f

template<bool HZ>
__device__ __forceinline__ void fft16_dif_r4(cx x[16]) {
    const cx W1 = mkcx( CC1, -SS1);
    const cx W2 = mkcx( RR2, -RR2);
    const cx W3 = mkcx( SS1, -CC1);
    const cx W6 = mkcx(-RR2, -RR2);
    const cx W9 = mkcx(-CC1,  SS1);
    #pragma unroll
    for (int n = 0; n < 4; ++n) {
        cx A, B, C, D;
        if (HZ) { A = x[n]; C = x[n]; B = x[n + 4]; D = x[n + 4]; }
        else {
            A = x[n] + x[n + 8];      C = x[n] - x[n + 8];
            B = x[n + 4] + x[n + 12]; D = x[n + 4] - x[n + 12];
        }
        cx s = A - B;
        cx nid = cneg_i(D);
        cx m = C + nid;
        cx p = C - nid;
        x[n] = A + B;
        if (n == 0)      { x[4] = s;            x[8]  = m;           x[12] = p; }
        else if (n == 1) { x[5] = cmul(s, W2);  x[9]  = cmul(m, W1); x[13] = cmul(p, W3); }
        else if (n == 2) { x[6] = cneg_i(s);    x[10] = cmul(m, W2); x[14] = cmul(p, W6); }
        else             { x[7] = cmul(s, W6);  x[11] = cmul(m, W3); x[15] = cmul(p, W9); }
    }
    #pragma unroll
    for (int q = 0; q < 16; q += 4) {
        cx a = x[q], b = x[q + 1], c = x[q + 2], d = x[q + 3];
        cx a1 = a + c, c1 = a - c;
        cx b1 = b + d, d1 = cneg_i(b - d);
        x[q]     = a1 + b1;
        x[q + 1] = a1 - b1;
        x[q + 2] = c1 + d1;
        x[q + 3] = c1 - d1;
    }
}

template<bool HALF_OUT>
__device__ __forceinline__ void fft16_dit_inv_r4(cx x[16]) {
    const cx V1 = mkcx( CC1, SS1);
    const cx V2 = mkcx( RR2, RR2);
    const cx V3 = mkcx( SS1, CC1);
    const cx V6 = mkcx(-RR2, RR2);
    #pragma unroll
    for (int q = 0; q < 16; q += 4) {
        cx a = x[q], b = x[q + 1], c = x[q + 2], d = x[q + 3];
        cx a1 = a + b, b1 = a - b;
        cx c1 = c + d, d1 = c - d;
        cx t = cpos_i(d1);
        x[q]     = a1 + c1;
        x[q + 2] = a1 - c1;
        x[q + 1] = b1 + t;
        x[q + 3] = b1 - t;
    }
    #pragma unroll
    for (int n = 0; n < 4; ++n) {
        cx t1, t2;
        if (n == 0)      { t1 = x[4];             t2 = x[12]; }
        else if (n == 1) { t1 = cmul(x[5],  V2);  t2 = cmul(x[13], V2); }
        else if (n == 2) { t1 = cpos_i(x[6]);     t2 = cpos_i(x[14]); }
        else             { t1 = cmul(x[7],  V6);  t2 = cmul(x[15], V6); }
        cx P = x[n] + t1, Q = x[n] - t1;
        cx R = x[n + 8] + t2, S = x[n + 8] - t2;
        cx t, u;
        if (n == 0)      { t = R;            u = S; }
        else if (n == 1) { t = cmul(R, V1);  u = cmul(S, V1); }
        else if (n == 2) { t = cmul(R, V2);  u = cmul(S, V2); }
        else             { t = cmul(R, V3);  u = cmul(S, V3); }
        cx iu = cpos_i(u);
        x[n]     = P + t;
        x[n + 4] = Q + iu;
        if (!HALF_OUT) {
            x[n + 8]  = P - t;
            x[n + 12] = Q - iu;
        }
    }
}

template<bool CONJ>
__device__ __forceinline__ void apply_tw(cx v[16], const cx tw[16]) {
    #pragma unroll
    for (int tau = 1; tau < 16; ++tau) {
        const int q = brev4(tau);
        v[q] = CONJ ? cmul_cj(v[q], tw[tau]) : cmul(v[q], tw[tau]);
    }
}

template<bool HALF_ZERO>
__device__ void fft4096_fwd(cx* d, int tid, const cx* __restrict__ Twd)
{
    cx v[16], tw[16];
    {
        cx* base = d + fpad(tid);                       // stride 256 -> 274
        const cx* Tr = Twd + (tid << 4);
        #pragma unroll
        for (int t = 1; t < 16; ++t) tw[t] = Tr[t];
        if (HALF_ZERO) {
            #pragma unroll
            for (int t = 0; t < 8; ++t) v[t] = base[274 * t];
            fft16_dif_r4<true>(v);
        } else {
            #pragma unroll
            for (int t = 0; t < 16; ++t) v[t] = base[274 * t];
            fft16_dif_r4<false>(v);
        }
        apply_tw<false>(v, tw);
        #pragma unroll
        for (int p = 0; p < 16; ++p) base[274 * p] = v[p];
    }
    __syncthreads();
    {
        cx* base = d + fpad(((tid >> 4) << 8) + (tid & 15));  // stride 16 -> 17
        const cx* Tr = Twd + ((tid & 15) << 8);         // row 16*(tid&15)
        #pragma unroll
        for (int t = 1; t < 16; ++t) tw[t] = Tr[t];
        #pragma unroll
        for (int t = 0; t < 16; ++t) v[t] = base[17 * t];
        fft16_dif_r4<false>(v);
        apply_tw<false>(v, tw);
        #pragma unroll
        for (int p = 0; p < 16; ++p) base[17 * p] = v[p];
    }
    __syncthreads();
    {
        cx* base = d + fpad(tid << 4);                  // stride 1
        #pragma unroll
        for (int t = 0; t < 16; ++t) v[t] = base[t];
        fft16_dif_r4<false>(v);
        #pragma unroll
        for (int p = 0; p < 16; ++p) base[p] = v[p];
    }
    __syncthreads();
}

// ---------------------------------------------------------------------------
// Forward FFT of packed (a_ch0, a_ch1) pair, then unpack the two real
// spectra IN DIF ORDER using the conjugate-partner identity
//   p2 = p ^ (2^floor(log2 p) - 1)   (p>=2; 0,1 self-paired)
// A0 = c*(Wk + conj(Wm)), A1 = c*(-i)*(Wk - conj(Wm)), c = 0.25/4096
// (the 0.5 unpack factors of BOTH spectra and the 1/M inverse scale are
//  folded here so fft_conv needs none of them).
// A0 -> old Wspec slot; A1 -> in-place over a_t (dead after this kernel;
// block r reads exactly rows 2r,2r+1 and writes the same bytes after sync).
// ---------------------------------------------------------------------------
__global__ __launch_bounds__(256, 4) void fft_a_kernel(
    const float* a_t, cx* __restrict__ A0s, cx* A1s,
    const cx* __restrict__ Twd)
{
    __shared__ cx data[FFT_LDS_SZ];
    const int tid = threadIdx.x;
    const int r = blockIdx.x;                      // pair index, ch = 2r

    const float* r0 = a_t + (size_t)(2 * r) * M_FFT;
    const float* r1 = r0 + M_FFT;
    {
        cx* base = data + fpad(tid);
        #pragma unroll
        for (int k = 0; k < 16; ++k)
            base[274 * k] = mkcx(r0[tid + 256 * k], r1[tid + 256 * k]);
    }
    __syncthreads();
    fft4096_fwd<false>(data, tid, Twd);

    const float c = 0.25f / 4096.0f;
    cx* A0row = A0s + (size_t)r * 4096;
    cx* A1row = A1s + (size_t)r * 4096;
    if (tid == 0) {
        #pragma unroll
        for (int i = 0; i < 16; ++i) {
            const int p2 = (i < 2) ? i : (i ^ ((1 << (31 - __clz(i))) - 1));
            cx Wk = data[fpad(i)];
            cx Wm = data[fpad(p2)];
            cx cjWm = mkcx(Wm.x, -Wm.y);
            A0row[i] = c * (Wk + cjWm);
            A1row[i] = c * cneg_i(Wk - cjWm);
        }
    } else {
        const int base = tid << 4;
        const int mask = (1 << (31 - __clz(base))) - 1;   // low 4 bits are 1111
        const cx* zb  = data + fpad(base);
        const cx* zb2 = data + fpad((base ^ mask) - 15);
        #pragma unroll
        for (int i = 0; i < 16; ++i) {
            cx Wk = zb[i];
            cx Wm = zb2[15 - i];
            cx cjWm = mkcx(Wm.x, -Wm.y);
            A0row[base + i] = c * (Wk + cjWm);
            A1row[base + i] = c * cneg_i(Wk - cjWm);
        }
    }
}

// ---------------------------------------------------------------------------
__global__ __launch_bounds__(256, 4) void fft_conv_kernel(
    const bf16* __restrict__ v_t, const cx* __restrict__ A0s,
    const cx* __restrict__ A1s, const bf16* __restrict__ u_t,
    bf16* __restrict__ gated_t, const cx* __restrict__ Twd)
{
    __shared__ cx data[FFT_LDS_SZ];
    const int tid = threadIdx.x;
    const int bx = blockIdx.x;
    const int b  = bx / 768;
    const int r  = bx - b * 768;
    const int ch = 2 * r;

    const bf16* z0 = v_t + ((size_t)(b * D1 + ch)) * N_SEQ;
    const bf16* z1 = z0 + N_SEQ;

    {
        const int s = tid * 8;
        cx* base = data + fpad(s);
        bf16x8 a0 = *(const bf16x8*)(z0 + s);
        bf16x8 a1 = *(const bf16x8*)(z1 + s);
        #pragma unroll
        for (int i = 0; i < 8; ++i)
            base[i] = mkcx((float)a0[i], (float)a1[i]);
    }
    __syncthreads();

    fft4096_fwd<true>(data, tid, Twd);

    // fused per-bin pointwise (pre-unpacked A spectra) + inverse stage 1
    cx v[16], tw[16];
    const cx* A0row = A0s + (size_t)r * 4096;
    const cx* A1row = A1s + (size_t)r * 4096;
    const int pbase = tid << 4;
    {
        if (tid == 0) {
            #pragma unroll
            for (int i = 0; i < 16; ++i) {
                const int p2 = (i < 2) ? i : (i ^ ((1 << (31 - __clz(i))) - 1));
                cx Zk = data[fpad(i)];
                cx Zm = data[fpad(p2)];
                cx cjZm = mkcx(Zm.x, -Zm.y);
                cx V0 = Zk + cjZm;
                cx V1 = cneg_i(Zk - cjZm);
                v[i] = cmul(V0, A0row[i]) + cpos_i(cmul(V1, A1row[i]));
            }
        } else {
            const int mask = (1 << (31 - __clz(pbase))) - 1;
            const cx* zb  = data + fpad(pbase);
            const cx* zb2 = data + fpad((pbase ^ mask) - 15);
            #pragma unroll
            for (int i = 0; i < 16; ++i) {
                cx Zk = zb[i];
                cx Zm = zb2[15 - i];
                cx a0 = A0row[pbase + i];
                cx a1 = A1row[pbase + i];
                cx cjZm = mkcx(Zm.x, -Zm.y);
                cx V0 = Zk + cjZm;
                cx V1 = cneg_i(Zk - cjZm);
                v[i] = cmul(V0, a0) + cpos_i(cmul(V1, a1));
            }
        }
        __syncthreads();
        fft16_dit_inv_r4<false>(v);
        cx* base = data + fpad(pbase);
        #pragma unroll
        for (int i = 0; i < 16; ++i) base[i] = v[i];
    }
    __syncthreads();
    {   // inverse stage 2
        cx* base = data + fpad(((tid >> 4) << 8) + (tid & 15));
        const cx* Tr = Twd + ((tid & 15) << 8);
        #pragma unroll
        for (int t = 1; t < 16; ++t) tw[t] = Tr[t];
        #pragma unroll
        for (int p = 0; p < 16; ++p) v[p] = base[17 * p];
        apply_tw<true>(v, tw);
        fft16_dit_inv_r4<false>(v);
        #pragma unroll
        for (int t = 0; t < 16; ++t) base[17 * t] = v[t];
    }
    __syncthreads();
    {   // inverse stage 3, lower half only
        cx* base = data + fpad(tid);
        const cx* Tr = Twd + (tid << 4);
        #pragma unroll
        for (int t = 1; t < 16; ++t) tw[t] = Tr[t];
        #pragma unroll
        for (int p = 0; p < 16; ++p) v[p] = base[274 * p];
        apply_tw<true>(v, tw);
        fft16_dit_inv_r4<true>(v);
        #pragma unroll
        for (int t = 0; t < 8; ++t) base[274 * t] = v[t];
    }
    __syncthreads();

    // gate with u (1/M already folded into the A spectra)
    const bf16* u0 = u_t + ((size_t)(b * D1 + ch)) * N_SEQ;
    const bf16* u1 = u0 + N_SEQ;
    bf16* g0 = gated_t + ((size_t)(b * D1 + ch)) * N_SEQ;
    bf16* g1 = g0 + N_SEQ;
    {
        const int t = tid * 8;
        const cx* base = data + fpad(t);
        bf16x8 ua = *(const bf16x8*)(u0 + t);
        bf16x8 ub = *(const bf16x8*)(u1 + t);
        bf16x8 oa, ob;
        #pragma unroll
        for (int i = 0; i < 8; ++i) {
            cx y = base[i];
            oa[i] = (bf16)(y.x * (float)ua[i]);
            ob[i] = (bf16)(y.y * (float)ub[i]);
        }
        *(bf16x8*)(g0 + t) = oa;
        *(bf16x8*)(g1 + t) = ob;
    }
}

// ---------------------------------------------------------------------------
__global__ __launch_bounds__(256) void transpose_cs_kernel(
    const bf16* __restrict__ in, bf16* __restrict__ outp)
{
    __shared__ bf16 tile[64 * 68];
    const int c0 = blockIdx.x * 64;
    const int m0 = blockIdx.y * 64;
    const int b  = m0 >> 11;
    const int s0 = m0 & 2047;
    const int tid = threadIdx.x;
    const int cl = tid >> 4;
    const int sc = (tid & 15) * 4;
    #pragma unroll
    for (int p = 0; p < 4; ++p) {
        int c = p * 16 + cl;
        bf16x4 v = *(const bf16x4*)&in[((size_t)(b * D1 + c0 + c)) * N_SEQ + s0 + sc];
        *(bf16x4*)&tile[c * 68 + sc] = v;
    }
    __syncthreads();
    const int sl = tid >> 4;
    const int cc = (tid & 15) * 4;
    #pragma unroll
    for (int p = 0; p < 4; ++p) {
        int s = p * 16 + sl;
        bf16x4 o;
        #pragma unroll
        for (int j = 0; j < 4; ++j) o[j] = tile[(cc + j) * 68 + s];
        *(bf16x4*)&outp[((size_t)(m0 + s)) * D1 + c0 + cc] = o;
    }
}

// ---------------------------------------------------------------------------
extern "C" void kernel_launch(void* const* d_in, const int* in_sizes, int n_in,
                              void* d_out, int out_size, void* d_ws, size_t ws_size,
                              hipStream_t stream)
{
    const float* x  = (const float*)d_in[0];
    const float* Wu = (const float*)d_in[1];
    const float* bu = (const float*)d_in[2];
    const float* Wv = (const float*)d_in[3];
    const float* bv = (const float*)d_in[4];
    const float* Wo = (const float*)d_in[5];
    const float* bo = (const float*)d_in[6];
    const float* Wp = (const float*)d_in[7];
    const float* bp = (const float*)d_in[8];
    const float* Wl = (const float*)d_in[9];
    const float* bl = (const float*)d_in[10];
    const float* Wr = (const float*)d_in[11];
    const float* br = (const float*)d_in[12];
    float* out = (float*)d_out;

    float* ws      = (float*)d_ws;
    float* a_t     = ws;                       // 1536*4096 fp32; A1spec after fft_a
    float* A0spec  = a_t   + 6291456;          // 768 x 4096 cx
    float* sumsq   = A0spec + 6291456;         // 3 x 4096 fp32
    float* twd     = sumsq + 12288;            // 256 x 16 cx twiddle table
    bf16*  bfws    = (bf16*)(twd + 8192);
    bf16*  x_bf    = bfws;                     // 8192*512
    bf16*  w_bf    = x_bf    + 4194304;        // 5 x 786432: Wu,Wv,Wo,Wl,Wr
    bf16*  Wuv_bf  = w_bf;                     // stacked [Wu;Wv] 3072 x 512
    bf16*  Wo_bf   = w_bf    + 2 * 786432;
    bf16*  Wl_bf   = Wo_bf   + 786432;
    bf16*  Wr_bf   = Wl_bf   + 786432;
    bf16*  gA      = Wr_bf   + 786432;         // 4096*512
    bf16*  gB      = gA      + 2097152;        // 4096*512
    bf16*  u_t     = gB      + 2097152;        // 8192*1536 [b][c][s]
    bf16*  v_t     = u_t     + 12582912;       // 8192*1536 [b][c][s]
    bf16*  gated_t = v_t     + 12582912;       // 8192*1536 [b][c][s]
    bf16*  gated   = gated_t + 12582912;       // 8192*1536 [m][c]

    dim3 blk(256);

    // x/w converts + sumsq zero + rpe input layer + twiddle table
    f2b_all_kernel<<<4096 + 5 * 768 + 12 + 4096 + 16, blk, 0, stream>>>(
        x, Wu, Wv, Wo, Wl, Wr, Wp, bp, x_bf, w_bf, sumsq, gA, twd);

    gemm_bf16<MODE_SILU_UV, bf16><<<dim3(24, 64), blk, 0, stream>>>(
        x_bf, Wuv_bf, bu, bv, u_t, v_t, 8192, 2 * D1, ED, nullptr, nullptr);

    // RPE MLP: srms folded into GEMM epilogues via row-scale commutation
    bf16* gin = gA;
    bf16* gout = gB;
    for (int i = 0; i < 3; ++i) {
        const float* sin_p = (i == 0) ? nullptr : sumsq + (size_t)(i - 1) * 4096;
        gemm_bf16<MODE_RPE, bf16><<<dim3(4, 32), blk, 0, stream>>>(
            gin, Wl_bf + (size_t)i * ED * ED, bl + (size_t)i * ED, nullptr,
            gout, nullptr, 4096, ED, ED, sin_p, sumsq + (size_t)i * 4096);
        bf16* t = gin; gin = gout; gout = t;
    }
    gemm_bf16<MODE_AT, float><<<dim3(12, 32), blk, 0, stream>>>(
        gin, Wr_bf, br, nullptr, a_t, nullptr, 4096, D1, ED,
        sumsq + 2 * 4096, nullptr);

    fft_a_kernel<<<768, blk, 0, stream>>>(
        a_t, (cx*)A0spec, (cx*)a_t, (const cx*)twd);
    fft_conv_kernel<<<3072, blk, 0, stream>>>(
        v_t, (const cx*)A0spec, (const cx*)a_t, u_t, gated_t, (const cx*)twd);

    transpose_cs_kernel<<<dim3(24, 128), blk, 0, stream>>>(gated_t, gated);

    gemm_bf16<MODE_PLAIN, float><<<dim3(4, 64), blk, 0, stream>>>(
        gated, Wo_bf, bo, nullptr, out, nullptr, 8192, ED, D1,
        nullptr, nullptr);
}

// Round 2
// 392.181 us; speedup vs baseline: 1.0219x; 1.0219x over previous
//
#include <hip/hip_runtime.h>

#define N_SEQ 2048
#define M_FFT 4096
#define D1    1536
#define NH    8
#define HD    192
#define ED    512

typedef __bf16 bf16;
typedef __bf16 bf16x4 __attribute__((ext_vector_type(4)));
typedef __bf16 bf16x8 __attribute__((ext_vector_type(8)));
typedef float  floatx4 __attribute__((ext_vector_type(4)));
typedef float  cx __attribute__((ext_vector_type(2)));   // complex as packed fp32

enum { MODE_PLAIN = 0, MODE_SILU_UV = 1, MODE_AT = 3, MODE_RPE = 4 };

__device__ __forceinline__ void gload16(const void* g, void* l) {
    __builtin_amdgcn_global_load_lds(
        (const __attribute__((address_space(1))) void*)g,
        (__attribute__((address_space(3))) void*)l, 16, 0, 0);
}

// ---------------------------------------------------------------------------
// bf16 MFMA GEMM (m97 structure): C = epilogue(A(MxK) @ Bw(NcxK)^T + bias)
// ---------------------------------------------------------------------------
template<int MODE, typename OutT>
__global__ __launch_bounds__(256) void gemm_bf16(
    const bf16* __restrict__ A, const bf16* __restrict__ Bw,
    const float* __restrict__ bias, const float* __restrict__ bias2,
    OutT* __restrict__ C, OutT* __restrict__ C2,
    int M, int Nc, int K,
    const float* __restrict__ scale_in, float* __restrict__ sumsq_out)
{
    __shared__ __align__(16) bf16 As[128 * 32];
    __shared__ __align__(16) bf16 Bs[128 * 32];

    const int tid  = threadIdx.x;
    const int row0 = blockIdx.y * 128;
    const int col0 = blockIdx.x * 128;
    const int wid  = tid >> 6;
    const int lane = tid & 63;
    const int lm   = lane & 15;
    const int lk   = lane >> 4;
    const int wm   = wid >> 1;
    const int wn   = wid & 1;
    const int ldrow  = tid >> 2;
    const int ldcol8 = (tid & 3) * 8;

    floatx4 acc[4][4] = {};

    const bf16* Ag = A  + ((size_t)(row0 + ldrow)) * K + ldcol8;
    const bf16* Bg = Bw + ((size_t)(col0 + ldrow)) * K + ldcol8;
    bf16* AsW = As + (wid * 16) * 32;
    bf16* BsW = Bs + (wid * 16) * 32;

    for (int k0 = 0; k0 < K; k0 += 32) {
        gload16(Ag + k0, AsW);
        gload16(Ag + (size_t)64 * K + k0, AsW + 64 * 32);
        gload16(Bg + k0, BsW);
        gload16(Bg + (size_t)64 * K + k0, BsW + 64 * 32);
        __syncthreads();

        bf16x8 af[4], bfr[4];
        #pragma unroll
        for (int mi = 0; mi < 4; ++mi)
            af[mi] = *(const bf16x8*)&As[(wm * 64 + mi * 16 + lm) * 32 + lk * 8];
        #pragma unroll
        for (int nj = 0; nj < 4; ++nj)
            bfr[nj] = *(const bf16x8*)&Bs[(wn * 64 + nj * 16 + lm) * 32 + lk * 8];
        #pragma unroll
        for (int mi = 0; mi < 4; ++mi)
            #pragma unroll
            for (int nj = 0; nj < 4; ++nj)
                acc[mi][nj] = __builtin_amdgcn_mfma_f32_16x16x32_bf16(
                    af[mi], bfr[nj], acc[mi][nj], 0, 0, 0);
        __syncthreads();
    }

    const float* bs = bias;
    OutT* dst = C;
    int cadj = 0;
    if (MODE == MODE_SILU_UV && col0 >= D1) { bs = bias2; dst = C2; cadj = D1; }

    float bcol[4];
    #pragma unroll
    for (int nj = 0; nj < 4; ++nj)
        bcol[nj] = bs[col0 - cadj + wn * 64 + nj * 16 + lm];

    if (MODE == MODE_RPE) {
        #pragma unroll
        for (int mi = 0; mi < 4; ++mi) {
            #pragma unroll
            for (int r = 0; r < 4; ++r) {
                const int row = row0 + wm * 64 + mi * 16 + lk * 4 + r;
                float sc = 1.0f;
                if (scale_in)
                    sc = 1.0f / (sqrtf(scale_in[row]) * 0.04419417382415922f + 1e-8f);
                float ssq = 0.0f;
                #pragma unroll
                for (int nj = 0; nj < 4; ++nj) {
                    const int col = col0 + wn * 64 + nj * 16 + lm;
                    float val = acc[mi][nj][r] * sc + bcol[nj];
                    ssq += val * val;
                    ((bf16*)C)[(size_t)row * Nc + col] = (bf16)fmaxf(val, 0.0f);
                }
                ssq += __shfl_xor(ssq, 1, 64);
                ssq += __shfl_xor(ssq, 2, 64);
                ssq += __shfl_xor(ssq, 4, 64);
                ssq += __shfl_xor(ssq, 8, 64);
                if (lm == 0) atomicAdd(&sumsq_out[row], ssq);
            }
        }
        return;
    }

    #pragma unroll
    for (int mi = 0; mi < 4; ++mi) {
        const int rbase = row0 + wm * 64 + mi * 16 + lk * 4;
        float sc[4];
        #pragma unroll
        for (int r = 0; r < 4; ++r) {
            sc[r] = 1.0f;
            if (MODE == MODE_AT && scale_in)
                sc[r] = 1.0f / (sqrtf(scale_in[rbase + r]) * 0.04419417382415922f + 1e-8f);
        }
        #pragma unroll
        for (int nj = 0; nj < 4; ++nj) {
            const int col = col0 - cadj + wn * 64 + nj * 16 + lm;
            float vals[4];
            #pragma unroll
            for (int r = 0; r < 4; ++r) {
                float val = acc[mi][nj][r] * sc[r] + bcol[nj];
                if (MODE == MODE_SILU_UV)
                    val = val / (1.0f + __expf(-val));
                vals[r] = val;
            }
            if (MODE == MODE_SILU_UV) {
                int b = rbase >> 11, s = rbase & 2047;
                bf16x4 o;
                #pragma unroll
                for (int r = 0; r < 4; ++r) o[r] = (bf16)vals[r];
                *(bf16x4*)&((bf16*)dst)[((size_t)(b * D1 + col)) * N_SEQ + s] = o;
            } else if (MODE == MODE_AT) {
                float4 o = make_float4(vals[0], vals[1], vals[2], vals[3]);
                *(float4*)&((float*)C)[(size_t)col * M + rbase] = o;
            } else {
                #pragma unroll
                for (int r = 0; r < 4; ++r)
                    C[(size_t)(rbase + r) * Nc + col] = (OutT)vals[r];
            }
        }
    }
}

// ---------------------------------------------------------------------------
// mega-prologue: x convert + 5 weight converts + sumsq zero +
// RPE input layer w/ srms + FFT twiddle table (256 x 16 cx)
// ---------------------------------------------------------------------------
__global__ __launch_bounds__(256) void f2b_all_kernel(
    const float* __restrict__ x,  const float* __restrict__ s0,
    const float* __restrict__ s1, const float* __restrict__ s2,
    const float* __restrict__ s3, const float* __restrict__ s4,
    const float* __restrict__ Wp, const float* __restrict__ bp,
    bf16* __restrict__ x_bf, bf16* __restrict__ w_bf,
    float* __restrict__ sumsq, bf16* __restrict__ g0,
    float* __restrict__ twd)
{
    const int bid = blockIdx.x;
    const int tid = threadIdx.x;
    __shared__ float red[4];

    if (bid < 7936) {
        const float* src;
        bf16* dst;
        size_t off;
        if (bid < 4096) {
            src = x; dst = x_bf; off = (size_t)bid * 1024;
        } else {
            int t = bid - 4096;
            int seg = t / 768;
            src = seg == 0 ? s0 : seg == 1 ? s1 : seg == 2 ? s2
                : seg == 3 ? s3 : s4;
            dst = w_bf + (size_t)seg * 786432;
            off = (size_t)(t % 768) * 1024;
        }
        size_t i = off + (size_t)tid * 4;
        float4 f = *(const float4*)(src + i);
        union { bf16 h[4]; short4 s; } u4;
        u4.h[0] = (bf16)f.x; u4.h[1] = (bf16)f.y;
        u4.h[2] = (bf16)f.z; u4.h[3] = (bf16)f.w;
        *(short4*)(dst + i) = u4.s;
    } else if (bid < 7948) {
        size_t i = (size_t)(bid - 7936) * 1024 + (size_t)tid * 4;
        *(float4*)(sumsq + i) = make_float4(0.f, 0.f, 0.f, 0.f);
    } else if (bid < 12044) {
        const int j = bid - 7948;
        float idxv = (j < N_SEQ) ? (float)j
                                 : (j == N_SEQ ? 0.0f : (float)(j - 2 * N_SEQ));
        float h1 = idxv * Wp[tid] + bp[tid];
        float h2 = idxv * Wp[tid + 256] + bp[tid + 256];
        float ss = h1 * h1 + h2 * h2;
        #pragma unroll
        for (int off = 32; off > 0; off >>= 1) ss += __shfl_down(ss, off, 64);
        if ((tid & 63) == 0) red[tid >> 6] = ss;
        __syncthreads();
        float tot = red[0] + red[1] + red[2] + red[3];
        float scale = 1.0f / (sqrtf(tot) * 0.04419417382415922f + 1e-8f);
        g0[(size_t)j * ED + tid]       = (bf16)fmaxf(h1 * scale, 0.0f);
        g0[(size_t)j * ED + tid + 256] = (bf16)fmaxf(h2 * scale, 0.0f);
    } else {
        const int idx = (bid - 12044) * 256 + tid;    // [0, 4096)
        const int j = idx >> 4, tau = idx & 15;
        float sA, cA;
        __sincosf(-6.283185307179586f * (float)(j * tau) * (1.0f / 4096.0f),
                  &sA, &cA);
        cx w; w.x = cA; w.y = sA;
        ((cx*)twd)[idx] = w;
    }
}

// ---------------------------------------------------------------------------
// Radix-16 FFT, radix-4 butterflies, packed-fp32 complex.
// LDS addressing: fpad(base + s*t) = fpad(base) + s'*t  (256->274, 16->17, 1->1)
// Twiddles from precomputed table (inverse = conjugate); both fwd-stage tw
// rows are hoisted to kernel start (they depend only on tid).
// ---------------------------------------------------------------------------
#define FFT_LDS_SZ 4381

__device__ __forceinline__ int fpad(int i) { return i + (i >> 4) + 2 * (i >> 8); }

__device__ __forceinline__ cx mkcx(float a, float b) { cx r; r.x = a; r.y = b; return r; }
__device__ __forceinline__ cx cmul(cx a, cx b) {
    cx br = mkcx(-b.y, b.x);
    return a.xx * b + a.yy * br;
}
__device__ __forceinline__ cx cmul_cj(cx a, cx b) {      // a * conj(b)
    cx bc = mkcx(b.x, -b.y);
    cx br = mkcx(b.y, b.x);
    return a.xx * bc + a.yy * br;
}
__device__ __forceinline__ cx cneg_i(cx a) { return mkcx(a.y, -a.x); }   // a * (-i)
__device__ __forceinline__ cx cpos_i(cx a) { return mkcx(-a.y, a.x); }   // a * (+i)
__host__ __device__ constexpr int brev4(int t) {
    return ((t & 1) << 3) | ((t & 2) << 1) | ((t & 4) >> 1) | ((t & 8) >> 3);
}

#define CC1 0.9238795325112867f
#define SS1 0.3826834323650898f
#define RR2 0.7071067811865476f

template<bool HZ>
__device__ __forceinline__ void fft16_dif_r4(cx x[16]) {
    const cx W1 = mkcx( CC1, -SS1);
    const cx W2 = mkcx( RR2, -RR2);
    const cx W3 = mkcx( SS1, -CC1);
    const cx W6 = mkcx(-RR2, -RR2);
    const cx W9 = mkcx(-CC1,  SS1);
    #pragma unroll
    for (int n = 0; n < 4; ++n) {
        cx A, B, C, D;
        if (HZ) { A = x[n]; C = x[n]; B = x[n + 4]; D = x[n + 4]; }
        else {
            A = x[n] + x[n + 8];      C = x[n] - x[n + 8];
            B = x[n + 4] + x[n + 12]; D = x[n + 4] - x[n + 12];
        }
        cx s = A - B;
        cx nid = cneg_i(D);
        cx m = C + nid;
        cx p = C - nid;
        x[n] = A + B;
        if (n == 0)      { x[4] = s;            x[8]  = m;           x[12] = p; }
        else if (n == 1) { x[5] = cmul(s, W2);  x[9]  = cmul(m, W1); x[13] = cmul(p, W3); }
        else if (n == 2) { x[6] = cneg_i(s);    x[10] = cmul(m, W2); x[14] = cmul(p, W6); }
        else             { x[7] = cmul(s, W6);  x[11] = cmul(m, W3); x[15] = cmul(p, W9); }
    }
    #pragma unroll
    for (int q = 0; q < 16; q += 4) {
        cx a = x[q], b = x[q + 1], c = x[q + 2], d = x[q + 3];
        cx a1 = a + c, c1 = a - c;
        cx b1 = b + d, d1 = cneg_i(b - d);
        x[q]     = a1 + b1;
        x[q + 1] = a1 - b1;
        x[q + 2] = c1 + d1;
        x[q + 3] = c1 - d1;
    }
}

template<bool HALF_OUT>
__device__ __forceinline__ void fft16_dit_inv_r4(cx x[16]) {
    const cx V1 = mkcx( CC1, SS1);
    const cx V2 = mkcx( RR2, RR2);
    const cx V3 = mkcx( SS1, CC1);
    const cx V6 = mkcx(-RR2, RR2);
    #pragma unroll
    for (int q = 0; q < 16; q += 4) {
        cx a = x[q], b = x[q + 1], c = x[q + 2], d = x[q + 3];
        cx a1 = a + b, b1 = a - b;
        cx c1 = c + d, d1 = c - d;
        cx t = cpos_i(d1);
        x[q]     = a1 + c1;
        x[q + 2] = a1 - c1;
        x[q + 1] = b1 + t;
        x[q + 3] = b1 - t;
    }
    #pragma unroll
    for (int n = 0; n < 4; ++n) {
        cx t1, t2;
        if (n == 0)      { t1 = x[4];             t2 = x[12]; }
        else if (n == 1) { t1 = cmul(x[5],  V2);  t2 = cmul(x[13], V2); }
        else if (n == 2) { t1 = cpos_i(x[6]);     t2 = cpos_i(x[14]); }
        else             { t1 = cmul(x[7],  V6);  t2 = cmul(x[15], V6); }
        cx P = x[n] + t1, Q = x[n] - t1;
        cx R = x[n + 8] + t2, S = x[n + 8] - t2;
        cx t, u;
        if (n == 0)      { t = R;            u = S; }
        else if (n == 1) { t = cmul(R, V1);  u = cmul(S, V1); }
        else if (n == 2) { t = cmul(R, V2);  u = cmul(S, V2); }
        else             { t = cmul(R, V3);  u = cmul(S, V3); }
        cx iu = cpos_i(u);
        x[n]     = P + t;
        x[n + 4] = Q + iu;
        if (!HALF_OUT) {
            x[n + 8]  = P - t;
            x[n + 12] = Q - iu;
        }
    }
}

template<bool CONJ>
__device__ __forceinline__ void apply_tw(cx v[16], const cx tw[16]) {
    #pragma unroll
    for (int tau = 1; tau < 16; ++tau) {
        const int q = brev4(tau);
        v[q] = CONJ ? cmul_cj(v[q], tw[tau]) : cmul(v[q], tw[tau]);
    }
}

// Forward 4096-FFT. If PF, issues the A0/A1 row prefetch between stages 2
// and 3 (pinned with sched_barrier) so the latency hides under stage 3.
template<bool HALF_ZERO, bool PF>
__device__ __forceinline__ void fft4096_fwd(
    cx* d, int tid, const cx* __restrict__ Twd,
    const float4* A0p, const float4* A1p,
    float4 a0pf[8], float4 a1pf[8])
{
    cx v[16], tw[16], tw2[16];
    {   // hoisted: both stage tw rows depend only on tid
        const cx* Tr1 = Twd + (tid << 4);
        const cx* Tr2 = Twd + ((tid & 15) << 8);
        #pragma unroll
        for (int t = 1; t < 16; ++t) tw[t] = Tr1[t];
        #pragma unroll
        for (int t = 1; t < 16; ++t) tw2[t] = Tr2[t];
    }
    {
        cx* base = d + fpad(tid);                       // stride 256 -> 274
        if (HALF_ZERO) {
            #pragma unroll
            for (int t = 0; t < 8; ++t) v[t] = base[274 * t];
            fft16_dif_r4<true>(v);
        } else {
            #pragma unroll
            for (int t = 0; t < 16; ++t) v[t] = base[274 * t];
            fft16_dif_r4<false>(v);
        }
        apply_tw<false>(v, tw);
        #pragma unroll
        for (int p = 0; p < 16; ++p) base[274 * p] = v[p];
    }
    __syncthreads();
    {
        cx* base = d + fpad(((tid >> 4) << 8) + (tid & 15));  // stride 16 -> 17
        #pragma unroll
        for (int t = 0; t < 16; ++t) v[t] = base[17 * t];
        fft16_dif_r4<false>(v);
        apply_tw<false>(v, tw2);
        #pragma unroll
        for (int p = 0; p < 16; ++p) base[17 * p] = v[p];
    }
    __syncthreads();
    if (PF) {
        #pragma unroll
        for (int i = 0; i < 8; ++i) { a0pf[i] = A0p[i]; a1pf[i] = A1p[i]; }
        __builtin_amdgcn_sched_barrier(0);   // don't let loads sink past here
    }
    {
        cx* base = d + fpad(tid << 4);                  // stride 1
        #pragma unroll
        for (int t = 0; t < 16; ++t) v[t] = base[t];
        fft16_dif_r4<false>(v);
        #pragma unroll
        for (int p = 0; p < 16; ++p) base[p] = v[p];
    }
    __syncthreads();
}

// ---------------------------------------------------------------------------
// Forward FFT of packed (a_ch0, a_ch1) pair, unpack both real spectra in
// DIF order (conjugate-partner: p2 = p ^ (2^floor(log2 p) - 1)).
// A0 = c*(Wk + conj(Wm)), A1 = c*(-i)*(Wk - conj(Wm)), c = 0.25/4096.
// ---------------------------------------------------------------------------
__global__ __launch_bounds__(256, 4) void fft_a_kernel(
    const float* a_t, cx* __restrict__ A0s, cx* A1s,
    const cx* __restrict__ Twd)
{
    __shared__ cx data[FFT_LDS_SZ];
    const int tid = threadIdx.x;
    const int r = blockIdx.x;                      // pair index, ch = 2r

    const float* r0 = a_t + (size_t)(2 * r) * M_FFT;
    const float* r1 = r0 + M_FFT;
    {
        cx* base = data + fpad(tid);
        #pragma unroll
        for (int k = 0; k < 16; ++k)
            base[274 * k] = mkcx(r0[tid + 256 * k], r1[tid + 256 * k]);
    }
    __syncthreads();
    fft4096_fwd<false, false>(data, tid, Twd, nullptr, nullptr, nullptr, nullptr);

    const float c = 0.25f / 4096.0f;
    cx* A0row = A0s + (size_t)r * 4096;
    cx* A1row = A1s + (size_t)r * 4096;
    if (tid == 0) {
        #pragma unroll
        for (int i = 0; i < 16; ++i) {
            const int p2 = (i < 2) ? i : (i ^ ((1 << (31 - __clz(i))) - 1));
            cx Wk = data[fpad(i)];
            cx Wm = data[fpad(p2)];
            cx cjWm = mkcx(Wm.x, -Wm.y);
            A0row[i] = c * (Wk + cjWm);
            A1row[i] = c * cneg_i(Wk - cjWm);
        }
    } else {
        const int base = tid << 4;
        const int mask = (1 << (31 - __clz(base))) - 1;
        const cx* zb  = data + fpad(base);
        const cx* zb2 = data + fpad((base ^ mask) - 15);
        #pragma unroll
        for (int i = 0; i < 16; ++i) {
            cx Wk = zb[i];
            cx Wm = zb2[15 - i];
            cx cjWm = mkcx(Wm.x, -Wm.y);
            A0row[base + i] = c * (Wk + cjWm);
            A1row[base + i] = c * cneg_i(Wk - cjWm);
        }
    }
}

// ---------------------------------------------------------------------------
// Conv kernel. Block remap groups the 4 batches sharing an A-row onto the
// same XCD at adjacent slots (bijective): xcd = r&7, slot = (r>>3)*4 + b.
// A rows prefetched to registers during fwd FFT; u prefetched during inverse.
// ---------------------------------------------------------------------------
__global__ __launch_bounds__(256, 4) void fft_conv_kernel(
    const bf16* __restrict__ v_t, const cx* __restrict__ A0s,
    const cx* __restrict__ A1s, const bf16* __restrict__ u_t,
    bf16* __restrict__ gated_t, const cx* __restrict__ Twd)
{
    __shared__ cx data[FFT_LDS_SZ];
    const int tid = threadIdx.x;
    const int bx = blockIdx.x;
    const int xcd  = bx & 7;
    const int slot = bx >> 3;
    const int b    = slot & 3;
    const int r    = (slot >> 2) * 8 + xcd;
    const int ch = 2 * r;

    const bf16* z0 = v_t + ((size_t)(b * D1 + ch)) * N_SEQ;
    const bf16* z1 = z0 + N_SEQ;

    {
        const int s = tid * 8;
        cx* base = data + fpad(s);
        bf16x8 a0 = *(const bf16x8*)(z0 + s);
        bf16x8 a1 = *(const bf16x8*)(z1 + s);
        #pragma unroll
        for (int i = 0; i < 8; ++i)
            base[i] = mkcx((float)a0[i], (float)a1[i]);
    }
    __syncthreads();

    const int pbase = tid << 4;
    const cx* A0row = A0s + (size_t)r * 4096;
    const cx* A1row = A1s + (size_t)r * 4096;
    float4 a0pf[8], a1pf[8];
    fft4096_fwd<true, true>(data, tid, Twd,
                            (const float4*)(A0row + pbase),
                            (const float4*)(A1row + pbase), a0pf, a1pf);

    // fused per-bin pointwise (prefetched A spectra) + inverse stage 1
    cx v[16], tw[16];
    {
        auto pf = [](const float4* p, int i) -> cx {
            return (i & 1) ? mkcx(p[i >> 1].z, p[i >> 1].w)
                           : mkcx(p[i >> 1].x, p[i >> 1].y);
        };
        if (tid == 0) {
            #pragma unroll
            for (int i = 0; i < 16; ++i) {
                const int p2 = (i < 2) ? i : (i ^ ((1 << (31 - __clz(i))) - 1));
                cx Zk = data[fpad(i)];
                cx Zm = data[fpad(p2)];
                cx cjZm = mkcx(Zm.x, -Zm.y);
                cx V0 = Zk + cjZm;
                cx V1 = cneg_i(Zk - cjZm);
                v[i] = cmul(V0, pf(a0pf, i)) + cpos_i(cmul(V1, pf(a1pf, i)));
            }
        } else {
            const int mask = (1 << (31 - __clz(pbase))) - 1;
            const cx* zb  = data + fpad(pbase);
            const cx* zb2 = data + fpad((pbase ^ mask) - 15);
            #pragma unroll
            for (int i = 0; i < 16; ++i) {
                cx Zk = zb[i];
                cx Zm = zb2[15 - i];
                cx cjZm = mkcx(Zm.x, -Zm.y);
                cx V0 = Zk + cjZm;
                cx V1 = cneg_i(Zk - cjZm);
                v[i] = cmul(V0, pf(a0pf, i)) + cpos_i(cmul(V1, pf(a1pf, i)));
            }
        }
        __syncthreads();
        fft16_dit_inv_r4<false>(v);
        cx* base = data + fpad(pbase);
        #pragma unroll
        for (int i = 0; i < 16; ++i) base[i] = v[i];
    }
    __syncthreads();

    // u prefetch: issue now, consume in the gate stage (hides under inverse)
    const bf16* u0 = u_t + ((size_t)(b * D1 + ch)) * N_SEQ;
    const bf16* u1 = u0 + N_SEQ;
    bf16x8 ua = *(const bf16x8*)(u0 + tid * 8);
    bf16x8 ub = *(const bf16x8*)(u1 + tid * 8);
    __builtin_amdgcn_sched_barrier(0);

    {   // inverse stage 2
        cx* base = data + fpad(((tid >> 4) << 8) + (tid & 15));
        const cx* Tr = Twd + ((tid & 15) << 8);
        #pragma unroll
        for (int t = 1; t < 16; ++t) tw[t] = Tr[t];
        #pragma unroll
        for (int p = 0; p < 16; ++p) v[p] = base[17 * p];
        apply_tw<true>(v, tw);
        fft16_dit_inv_r4<false>(v);
        #pragma unroll
        for (int t = 0; t < 16; ++t) base[17 * t] = v[t];
    }
    __syncthreads();
    {   // inverse stage 3, lower half only
        cx* base = data + fpad(tid);
        const cx* Tr = Twd + (tid << 4);
        #pragma unroll
        for (int t = 1; t < 16; ++t) tw[t] = Tr[t];
        #pragma unroll
        for (int p = 0; p < 16; ++p) v[p] = base[274 * p];
        apply_tw<true>(v, tw);
        fft16_dit_inv_r4<true>(v);
        #pragma unroll
        for (int t = 0; t < 8; ++t) base[274 * t] = v[t];
    }
    __syncthreads();

    // gate with u (1/M already folded into the A spectra)
    bf16* g0 = gated_t + ((size_t)(b * D1 + ch)) * N_SEQ;
    bf16* g1 = g0 + N_SEQ;
    {
        const int t = tid * 8;
        const cx* base = data + fpad(t);
        bf16x8 oa, ob;
        #pragma unroll
        for (int i = 0; i < 8; ++i) {
            cx y = base[i];
            oa[i] = (bf16)(y.x * (float)ua[i]);
            ob[i] = (bf16)(y.y * (float)ub[i]);
        }
        *(bf16x8*)(g0 + t) = oa;
        *(bf16x8*)(g1 + t) = ob;
    }
}

// ---------------------------------------------------------------------------
__global__ __launch_bounds__(256) void transpose_cs_kernel(
    const bf16* __restrict__ in, bf16* __restrict__ outp)
{
    __shared__ bf16 tile[64 * 68];
    const int c0 = blockIdx.x * 64;
    const int m0 = blockIdx.y * 64;
    const int b  = m0 >> 11;
    const int s0 = m0 & 2047;
    const int tid = threadIdx.x;
    const int cl = tid >> 4;
    const int sc = (tid & 15) * 4;
    #pragma unroll
    for (int p = 0; p < 4; ++p) {
        int c = p * 16 + cl;
        bf16x4 v = *(const bf16x4*)&in[((size_t)(b * D1 + c0 + c)) * N_SEQ + s0 + sc];
        *(bf16x4*)&tile[c * 68 + sc] = v;
    }
    __syncthreads();
    const int sl = tid >> 4;
    const int cc = (tid & 15) * 4;
    #pragma unroll
    for (int p = 0; p < 4; ++p) {
        int s = p * 16 + sl;
        bf16x4 o;
        #pragma unroll
        for (int j = 0; j < 4; ++j) o[j] = tile[(cc + j) * 68 + s];
        *(bf16x4*)&outp[((size_t)(m0 + s)) * D1 + c0 + cc] = o;
    }
}

// ---------------------------------------------------------------------------
extern "C" void kernel_launch(void* const* d_in, const int* in_sizes, int n_in,
                              void* d_out, int out_size, void* d_ws, size_t ws_size,
                              hipStream_t stream)
{
    const float* x  = (const float*)d_in[0];
    const float* Wu = (const float*)d_in[1];
    const float* bu = (const float*)d_in[2];
    const float* Wv = (const float*)d_in[3];
    const float* bv = (const float*)d_in[4];
    const float* Wo = (const float*)d_in[5];
    const float* bo = (const float*)d_in[6];
    const float* Wp = (const float*)d_in[7];
    const float* bp = (const float*)d_in[8];
    const float* Wl = (const float*)d_in[9];
    const float* bl = (const float*)d_in[10];
    const float* Wr = (const float*)d_in[11];
    const float* br = (const float*)d_in[12];
    float* out = (float*)d_out;

    float* ws      = (float*)d_ws;
    float* a_t     = ws;                       // 1536*4096 fp32; A1spec after fft_a
    float* A0spec  = a_t   + 6291456;          // 768 x 4096 cx
    float* sumsq   = A0spec + 6291456;         // 3 x 4096 fp32
    float* twd     = sumsq + 12288;            // 256 x 16 cx twiddle table
    bf16*  bfws    = (bf16*)(twd + 8192);
    bf16*  x_bf    = bfws;                     // 8192*512
    bf16*  w_bf    = x_bf    + 4194304;        // 5 x 786432: Wu,Wv,Wo,Wl,Wr
    bf16*  Wuv_bf  = w_bf;                     // stacked [Wu;Wv] 3072 x 512
    bf16*  Wo_bf   = w_bf    + 2 * 786432;
    bf16*  Wl_bf   = Wo_bf   + 786432;
    bf16*  Wr_bf   = Wl_bf   + 786432;
    bf16*  gA      = Wr_bf   + 786432;         // 4096*512
    bf16*  gB      = gA      + 2097152;        // 4096*512
    bf16*  u_t     = gB      + 2097152;        // 8192*1536 [b][c][s]
    bf16*  v_t     = u_t     + 12582912;       // 8192*1536 [b][c][s]
    bf16*  gated_t = v_t     + 12582912;       // 8192*1536 [b][c][s]
    bf16*  gated   = gated_t + 12582912;       // 8192*1536 [m][c]

    dim3 blk(256);

    // x/w converts + sumsq zero + rpe input layer + twiddle table
    f2b_all_kernel<<<4096 + 5 * 768 + 12 + 4096 + 16, blk, 0, stream>>>(
        x, Wu, Wv, Wo, Wl, Wr, Wp, bp, x_bf, w_bf, sumsq, gA, twd);

    gemm_bf16<MODE_SILU_UV, bf16><<<dim3(24, 64), blk, 0, stream>>>(
        x_bf, Wuv_bf, bu, bv, u_t, v_t, 8192, 2 * D1, ED, nullptr, nullptr);

    // RPE MLP: srms folded into GEMM epilogues via row-scale commutation
    bf16* gin = gA;
    bf16* gout = gB;
    for (int i = 0; i < 3; ++i) {
        const float* sin_p = (i == 0) ? nullptr : sumsq + (size_t)(i - 1) * 4096;
        gemm_bf16<MODE_RPE, bf16><<<dim3(4, 32), blk, 0, stream>>>(
            gin, Wl_bf + (size_t)i * ED * ED, bl + (size_t)i * ED, nullptr,
            gout, nullptr, 4096, ED, ED, sin_p, sumsq + (size_t)i * 4096);
        bf16* t = gin; gin = gout; gout = t;
    }
    gemm_bf16<MODE_AT, float><<<dim3(12, 32), blk, 0, stream>>>(
        gin, Wr_bf, br, nullptr, a_t, nullptr, 4096, D1, ED,
        sumsq + 2 * 4096, nullptr);

    fft_a_kernel<<<768, blk, 0, stream>>>(
        a_t, (cx*)A0spec, (cx*)a_t, (const cx*)twd);
    fft_conv_kernel<<<3072, blk, 0, stream>>>(
        v_t, (const cx*)A0spec, (const cx*)a_t, u_t, gated_t, (const cx*)twd);

    transpose_cs_kernel<<<dim3(24, 128), blk, 0, stream>>>(gated_t, gated);

    gemm_bf16<MODE_PLAIN, float><<<dim3(4, 64), blk, 0, stream>>>(
        gated, Wo_bf, bo, nullptr, out, nullptr, 8192, ED, D1,
        nullptr, nullptr);
}

// Round 3
// 370.249 us; speedup vs baseline: 1.0824x; 1.0592x over previous
//
#include <hip/hip_runtime.h>

#define N_SEQ 2048
#define M_FFT 4096
#define D1    1536
#define NH    8
#define HD    192
#define ED    512

typedef __bf16 bf16;
typedef __bf16 bf16x4 __attribute__((ext_vector_type(4)));
typedef __bf16 bf16x8 __attribute__((ext_vector_type(8)));
typedef float  floatx4 __attribute__((ext_vector_type(4)));
typedef float  cx __attribute__((ext_vector_type(2)));   // complex as packed fp32

enum { MODE_PLAIN = 0, MODE_SILU_UV = 1, MODE_AT = 3, MODE_RPE = 4 };

__device__ __forceinline__ void gload16(const void* g, void* l) {
    __builtin_amdgcn_global_load_lds(
        (const __attribute__((address_space(1))) void*)g,
        (__attribute__((address_space(3))) void*)l, 16, 0, 0);
}

// ---------------------------------------------------------------------------
// bf16 MFMA GEMM (m97 structure): C = epilogue(A(MxK) @ Bw(NcxK)^T + bias)
// ---------------------------------------------------------------------------
template<int MODE, typename OutT>
__global__ __launch_bounds__(256) void gemm_bf16(
    const bf16* __restrict__ A, const bf16* __restrict__ Bw,
    const float* __restrict__ bias, const float* __restrict__ bias2,
    OutT* __restrict__ C, OutT* __restrict__ C2,
    int M, int Nc, int K,
    const float* __restrict__ scale_in, float* __restrict__ sumsq_out)
{
    __shared__ __align__(16) bf16 As[128 * 32];
    __shared__ __align__(16) bf16 Bs[128 * 32];

    const int tid  = threadIdx.x;
    const int row0 = blockIdx.y * 128;
    const int col0 = blockIdx.x * 128;
    const int wid  = tid >> 6;
    const int lane = tid & 63;
    const int lm   = lane & 15;
    const int lk   = lane >> 4;
    const int wm   = wid >> 1;
    const int wn   = wid & 1;
    const int ldrow  = tid >> 2;
    const int ldcol8 = (tid & 3) * 8;

    floatx4 acc[4][4] = {};

    const bf16* Ag = A  + ((size_t)(row0 + ldrow)) * K + ldcol8;
    const bf16* Bg = Bw + ((size_t)(col0 + ldrow)) * K + ldcol8;
    bf16* AsW = As + (wid * 16) * 32;
    bf16* BsW = Bs + (wid * 16) * 32;

    for (int k0 = 0; k0 < K; k0 += 32) {
        gload16(Ag + k0, AsW);
        gload16(Ag + (size_t)64 * K + k0, AsW + 64 * 32);
        gload16(Bg + k0, BsW);
        gload16(Bg + (size_t)64 * K + k0, BsW + 64 * 32);
        __syncthreads();

        bf16x8 af[4], bfr[4];
        #pragma unroll
        for (int mi = 0; mi < 4; ++mi)
            af[mi] = *(const bf16x8*)&As[(wm * 64 + mi * 16 + lm) * 32 + lk * 8];
        #pragma unroll
        for (int nj = 0; nj < 4; ++nj)
            bfr[nj] = *(const bf16x8*)&Bs[(wn * 64 + nj * 16 + lm) * 32 + lk * 8];
        #pragma unroll
        for (int mi = 0; mi < 4; ++mi)
            #pragma unroll
            for (int nj = 0; nj < 4; ++nj)
                acc[mi][nj] = __builtin_amdgcn_mfma_f32_16x16x32_bf16(
                    af[mi], bfr[nj], acc[mi][nj], 0, 0, 0);
        __syncthreads();
    }

    const float* bs = bias;
    OutT* dst = C;
    int cadj = 0;
    if (MODE == MODE_SILU_UV && col0 >= D1) { bs = bias2; dst = C2; cadj = D1; }

    float bcol[4];
    #pragma unroll
    for (int nj = 0; nj < 4; ++nj)
        bcol[nj] = bs[col0 - cadj + wn * 64 + nj * 16 + lm];

    if (MODE == MODE_RPE) {
        #pragma unroll
        for (int mi = 0; mi < 4; ++mi) {
            #pragma unroll
            for (int r = 0; r < 4; ++r) {
                const int row = row0 + wm * 64 + mi * 16 + lk * 4 + r;
                float sc = 1.0f;
                if (scale_in)
                    sc = 1.0f / (sqrtf(scale_in[row]) * 0.04419417382415922f + 1e-8f);
                float ssq = 0.0f;
                #pragma unroll
                for (int nj = 0; nj < 4; ++nj) {
                    const int col = col0 + wn * 64 + nj * 16 + lm;
                    float val = acc[mi][nj][r] * sc + bcol[nj];
                    ssq += val * val;
                    ((bf16*)C)[(size_t)row * Nc + col] = (bf16)fmaxf(val, 0.0f);
                }
                ssq += __shfl_xor(ssq, 1, 64);
                ssq += __shfl_xor(ssq, 2, 64);
                ssq += __shfl_xor(ssq, 4, 64);
                ssq += __shfl_xor(ssq, 8, 64);
                if (lm == 0) atomicAdd(&sumsq_out[row], ssq);
            }
        }
        return;
    }

    #pragma unroll
    for (int mi = 0; mi < 4; ++mi) {
        const int rbase = row0 + wm * 64 + mi * 16 + lk * 4;
        float sc[4];
        #pragma unroll
        for (int r = 0; r < 4; ++r) {
            sc[r] = 1.0f;
            if (MODE == MODE_AT && scale_in)
                sc[r] = 1.0f / (sqrtf(scale_in[rbase + r]) * 0.04419417382415922f + 1e-8f);
        }
        #pragma unroll
        for (int nj = 0; nj < 4; ++nj) {
            const int col = col0 - cadj + wn * 64 + nj * 16 + lm;
            float vals[4];
            #pragma unroll
            for (int r = 0; r < 4; ++r) {
                float val = acc[mi][nj][r] * sc[r] + bcol[nj];
                if (MODE == MODE_SILU_UV)
                    val = val / (1.0f + __expf(-val));
                vals[r] = val;
            }
            if (MODE == MODE_SILU_UV) {
                int b = rbase >> 11, s = rbase & 2047;
                bf16x4 o;
                #pragma unroll
                for (int r = 0; r < 4; ++r) o[r] = (bf16)vals[r];
                *(bf16x4*)&((bf16*)dst)[((size_t)(b * D1 + col)) * N_SEQ + s] = o;
            } else if (MODE == MODE_AT) {
                float4 o = make_float4(vals[0], vals[1], vals[2], vals[3]);
                *(float4*)&((float*)C)[(size_t)col * M + rbase] = o;
            } else {
                #pragma unroll
                for (int r = 0; r < 4; ++r)
                    C[(size_t)(rbase + r) * Nc + col] = (OutT)vals[r];
            }
        }
    }
}

// ---------------------------------------------------------------------------
// mega-prologue: x convert + 5 weight converts + sumsq zero +
// RPE input layer w/ srms + FFT twiddle table (256 x 16 cx)
// ---------------------------------------------------------------------------
__global__ __launch_bounds__(256) void f2b_all_kernel(
    const float* __restrict__ x,  const float* __restrict__ s0,
    const float* __restrict__ s1, const float* __restrict__ s2,
    const float* __restrict__ s3, const float* __restrict__ s4,
    const float* __restrict__ Wp, const float* __restrict__ bp,
    bf16* __restrict__ x_bf, bf16* __restrict__ w_bf,
    float* __restrict__ sumsq, bf16* __restrict__ g0,
    float* __restrict__ twd)
{
    const int bid = blockIdx.x;
    const int tid = threadIdx.x;
    __shared__ float red[4];

    if (bid < 7936) {
        const float* src;
        bf16* dst;
        size_t off;
        if (bid < 4096) {
            src = x; dst = x_bf; off = (size_t)bid * 1024;
        } else {
            int t = bid - 4096;
            int seg = t / 768;
            src = seg == 0 ? s0 : seg == 1 ? s1 : seg == 2 ? s2
                : seg == 3 ? s3 : s4;
            dst = w_bf + (size_t)seg * 786432;
            off = (size_t)(t % 768) * 1024;
        }
        size_t i = off + (size_t)tid * 4;
        float4 f = *(const float4*)(src + i);
        union { bf16 h[4]; short4 s; } u4;
        u4.h[0] = (bf16)f.x; u4.h[1] = (bf16)f.y;
        u4.h[2] = (bf16)f.z; u4.h[3] = (bf16)f.w;
        *(short4*)(dst + i) = u4.s;
    } else if (bid < 7948) {
        size_t i = (size_t)(bid - 7936) * 1024 + (size_t)tid * 4;
        *(float4*)(sumsq + i) = make_float4(0.f, 0.f, 0.f, 0.f);
    } else if (bid < 12044) {
        const int j = bid - 7948;
        float idxv = (j < N_SEQ) ? (float)j
                                 : (j == N_SEQ ? 0.0f : (float)(j - 2 * N_SEQ));
        float h1 = idxv * Wp[tid] + bp[tid];
        float h2 = idxv * Wp[tid + 256] + bp[tid + 256];
        float ss = h1 * h1 + h2 * h2;
        #pragma unroll
        for (int off = 32; off > 0; off >>= 1) ss += __shfl_down(ss, off, 64);
        if ((tid & 63) == 0) red[tid >> 6] = ss;
        __syncthreads();
        float tot = red[0] + red[1] + red[2] + red[3];
        float scale = 1.0f / (sqrtf(tot) * 0.04419417382415922f + 1e-8f);
        g0[(size_t)j * ED + tid]       = (bf16)fmaxf(h1 * scale, 0.0f);
        g0[(size_t)j * ED + tid + 256] = (bf16)fmaxf(h2 * scale, 0.0f);
    } else {
        const int idx = (bid - 12044) * 256 + tid;    // [0, 4096)
        const int j = idx >> 4, tau = idx & 15;
        float sA, cA;
        __sincosf(-6.283185307179586f * (float)(j * tau) * (1.0f / 4096.0f),
                  &sA, &cA);
        cx w; w.x = cA; w.y = sA;
        ((cx*)twd)[idx] = w;
    }
}

// ---------------------------------------------------------------------------
// Radix-16 FFT, radix-4 butterflies, packed-fp32 complex.
// LDS addressing: fpad(base + s*t) = fpad(base) + s'*t  (256->274, 16->17, 1->1)
// Stage-1/inv-3 twiddle row (tid<<4) lives in REGISTERS for the whole kernel
// (inverse = conjugate). Stage-2/inv-2 rows (only 16 distinct) live in a 2 KB
// LDS table laid out [tau][row16] -> broadcast, conflict-free reads.
// ---------------------------------------------------------------------------
#define FFT_LDS_SZ 4381

__device__ __forceinline__ int fpad(int i) { return i + (i >> 4) + 2 * (i >> 8); }

__device__ __forceinline__ cx mkcx(float a, float b) { cx r; r.x = a; r.y = b; return r; }
__device__ __forceinline__ cx cmul(cx a, cx b) {
    cx br = mkcx(-b.y, b.x);
    return a.xx * b + a.yy * br;
}
__device__ __forceinline__ cx cmul_cj(cx a, cx b) {      // a * conj(b)
    cx bc = mkcx(b.x, -b.y);
    cx br = mkcx(b.y, b.x);
    return a.xx * bc + a.yy * br;
}
__device__ __forceinline__ cx cneg_i(cx a) { return mkcx(a.y, -a.x); }   // a * (-i)
__device__ __forceinline__ cx cpos_i(cx a) { return mkcx(-a.y, a.x); }   // a * (+i)
__host__ __device__ constexpr int brev4(int t) {
    return ((t & 1) << 3) | ((t & 2) << 1) | ((t & 4) >> 1) | ((t & 8) >> 3);
}

#define CC1 0.9238795325112867f
#define SS1 0.3826834323650898f
#define RR2 0.7071067811865476f

template<bool HZ>
__device__ __forceinline__ void fft16_dif_r4(cx x[16]) {
    const cx W1 = mkcx( CC1, -SS1);
    const cx W2 = mkcx( RR2, -RR2);
    const cx W3 = mkcx( SS1, -CC1);
    const cx W6 = mkcx(-RR2, -RR2);
    const cx W9 = mkcx(-CC1,  SS1);
    #pragma unroll
    for (int n = 0; n < 4; ++n) {
        cx A, B, C, D;
        if (HZ) { A = x[n]; C = x[n]; B = x[n + 4]; D = x[n + 4]; }
        else {
            A = x[n] + x[n + 8];      C = x[n] - x[n + 8];
            B = x[n + 4] + x[n + 12]; D = x[n + 4] - x[n + 12];
        }
        cx s = A - B;
        cx nid = cneg_i(D);
        cx m = C + nid;
        cx p = C - nid;
        x[n] = A + B;
        if (n == 0)      { x[4] = s;            x[8]  = m;           x[12] = p; }
        else if (n == 1) { x[5] = cmul(s, W2);  x[9]  = cmul(m, W1); x[13] = cmul(p, W3); }
        else if (n == 2) { x[6] = cneg_i(s);    x[10] = cmul(m, W2); x[14] = cmul(p, W6); }
        else             { x[7] = cmul(s, W6);  x[11] = cmul(m, W3); x[15] = cmul(p, W9); }
    }
    #pragma unroll
    for (int q = 0; q < 16; q += 4) {
        cx a = x[q], b = x[q + 1], c = x[q + 2], d = x[q + 3];
        cx a1 = a + c, c1 = a - c;
        cx b1 = b + d, d1 = cneg_i(b - d);
        x[q]     = a1 + b1;
        x[q + 1] = a1 - b1;
        x[q + 2] = c1 + d1;
        x[q + 3] = c1 - d1;
    }
}

template<bool HALF_OUT>
__device__ __forceinline__ void fft16_dit_inv_r4(cx x[16]) {
    const cx V1 = mkcx( CC1, SS1);
    const cx V2 = mkcx( RR2, RR2);
    const cx V3 = mkcx( SS1, CC1);
    const cx V6 = mkcx(-RR2, RR2);
    #pragma unroll
    for (int q = 0; q < 16; q += 4) {
        cx a = x[q], b = x[q + 1], c = x[q + 2], d = x[q + 3];
        cx a1 = a + b, b1 = a - b;
        cx c1 = c + d, d1 = c - d;
        cx t = cpos_i(d1);
        x[q]     = a1 + c1;
        x[q + 2] = a1 - c1;
        x[q + 1] = b1 + t;
        x[q + 3] = b1 - t;
    }
    #pragma unroll
    for (int n = 0; n < 4; ++n) {
        cx t1, t2;
        if (n == 0)      { t1 = x[4];             t2 = x[12]; }
        else if (n == 1) { t1 = cmul(x[5],  V2);  t2 = cmul(x[13], V2); }
        else if (n == 2) { t1 = cpos_i(x[6]);     t2 = cpos_i(x[14]); }
        else             { t1 = cmul(x[7],  V6);  t2 = cmul(x[15], V6); }
        cx P = x[n] + t1, Q = x[n] - t1;
        cx R = x[n + 8] + t2, S = x[n + 8] - t2;
        cx t, u;
        if (n == 0)      { t = R;            u = S; }
        else if (n == 1) { t = cmul(R, V1);  u = cmul(S, V1); }
        else if (n == 2) { t = cmul(R, V2);  u = cmul(S, V2); }
        else             { t = cmul(R, V3);  u = cmul(S, V3); }
        cx iu = cpos_i(u);
        x[n]     = P + t;
        x[n + 4] = Q + iu;
        if (!HALF_OUT) {
            x[n + 8]  = P - t;
            x[n + 12] = Q - iu;
        }
    }
}

template<bool CONJ>
__device__ __forceinline__ void apply_tw(cx v[16], const cx tw[16]) {
    #pragma unroll
    for (int tau = 1; tau < 16; ++tau) {
        const int q = brev4(tau);
        v[q] = CONJ ? cmul_cj(v[q], tw[tau]) : cmul(v[q], tw[tau]);
    }
}

// twrow points at tw2lds + (tid&15); stride 16 per tau. Broadcast reads.
template<bool CONJ>
__device__ __forceinline__ void apply_tw_lds(cx v[16], const cx* twrow) {
    #pragma unroll
    for (int tau = 1; tau < 16; ++tau) {
        cx w = twrow[tau * 16];
        const int q = brev4(tau);
        v[q] = CONJ ? cmul_cj(v[q], w) : cmul(v[q], w);
    }
}

// Forward 4096-FFT; stage-1 inputs pre-loaded in v by the caller
// (only v[0..7] if HALF_ZERO). tw = reg row (tid<<4); tw2lds = LDS table.
template<bool HALF_ZERO>
__device__ __forceinline__ void fft4096_fwd_core(
    cx* d, int tid, const cx tw[16], const cx* tw2lds, cx v[16])
{
    {   // stage 1 (stride 256 -> 274): direct from registers
        fft16_dif_r4<HALF_ZERO>(v);
        apply_tw<false>(v, tw);
        cx* base = d + fpad(tid);
        #pragma unroll
        for (int p = 0; p < 16; ++p) base[274 * p] = v[p];
    }
    __syncthreads();
    {   // stage 2 (stride 16 -> 17)
        cx* base = d + fpad(((tid >> 4) << 8) + (tid & 15));
        #pragma unroll
        for (int t = 0; t < 16; ++t) v[t] = base[17 * t];
        fft16_dif_r4<false>(v);
        apply_tw_lds<false>(v, tw2lds + (tid & 15));
        #pragma unroll
        for (int p = 0; p < 16; ++p) base[17 * p] = v[p];
    }
    __syncthreads();
    {   // stage 3 (stride 1)
        cx* base = d + fpad(tid << 4);
        #pragma unroll
        for (int t = 0; t < 16; ++t) v[t] = base[t];
        fft16_dif_r4<false>(v);
        #pragma unroll
        for (int p = 0; p < 16; ++p) base[p] = v[p];
    }
    __syncthreads();
}

// ---------------------------------------------------------------------------
// Forward FFT of packed (a_ch0, a_ch1) pair, unpack both real spectra in
// DIF order (conjugate-partner: p2 = p ^ (2^floor(log2 p) - 1)).
// A0 = c*(Wk + conj(Wm)), A1 = c*(-i)*(Wk - conj(Wm)), c = 0.25/4096.
// ---------------------------------------------------------------------------
__global__ __launch_bounds__(256, 4) void fft_a_kernel(
    const float* a_t, cx* __restrict__ A0s, cx* A1s,
    const cx* __restrict__ Twd)
{
    __shared__ cx data[FFT_LDS_SZ];
    __shared__ cx tw2lds[256];
    const int tid = threadIdx.x;
    const int r = blockIdx.x;                      // pair index, ch = 2r

    cx tw[16];
    {
        const cx* Tr1 = Twd + (tid << 4);
        #pragma unroll
        for (int t = 1; t < 16; ++t) tw[t] = Tr1[t];
        tw2lds[(tid >> 4) * 16 + (tid & 15)] = Twd[(tid & 15) * 256 + (tid >> 4)];
    }

    const float* r0 = a_t + (size_t)(2 * r) * M_FFT;
    const float* r1 = r0 + M_FFT;
    cx v[16];
    #pragma unroll
    for (int t = 0; t < 16; ++t)
        v[t] = mkcx(r0[tid + 256 * t], r1[tid + 256 * t]);

    fft4096_fwd_core<false>(data, tid, tw, tw2lds, v);

    const float c = 0.25f / 4096.0f;
    cx* A0row = A0s + (size_t)r * 4096;
    cx* A1row = A1s + (size_t)r * 4096;
    if (tid == 0) {
        #pragma unroll
        for (int i = 0; i < 16; ++i) {
            const int p2 = (i < 2) ? i : (i ^ ((1 << (31 - __clz(i))) - 1));
            cx Wk = data[fpad(i)];
            cx Wm = data[fpad(p2)];
            cx cjWm = mkcx(Wm.x, -Wm.y);
            A0row[i] = c * (Wk + cjWm);
            A1row[i] = c * cneg_i(Wk - cjWm);
        }
    } else {
        const int base = tid << 4;
        const int mask = (1 << (31 - __clz(base))) - 1;
        const cx* zb  = data + fpad(base);
        const cx* zb2 = data + fpad((base ^ mask) - 15);
        #pragma unroll
        for (int i = 0; i < 16; ++i) {
            cx Wk = zb[i];
            cx Wm = zb2[15 - i];
            cx cjWm = mkcx(Wm.x, -Wm.y);
            A0row[base + i] = c * (Wk + cjWm);
            A1row[base + i] = c * cneg_i(Wk - cjWm);
        }
    }
}

// ---------------------------------------------------------------------------
// Conv kernel. XCD remap (bijective) keeps the 4 batches sharing an A-row
// temporally adjacent on one XCD: xcd = r&7, slot = (r>>3)*4 + b.
// Stage-1 inputs loaded straight from global (no staging phase); A0/A1 read
// as plain float4 at pointwise (L2-warm); u read in the gate stage.
// ---------------------------------------------------------------------------
__global__ __launch_bounds__(256, 4) void fft_conv_kernel(
    const bf16* __restrict__ v_t, const cx* __restrict__ A0s,
    const cx* __restrict__ A1s, const bf16* __restrict__ u_t,
    bf16* __restrict__ gated_t, const cx* __restrict__ Twd)
{
    __shared__ cx data[FFT_LDS_SZ];
    __shared__ cx tw2lds[256];
    const int tid = threadIdx.x;
    const int bx = blockIdx.x;
    const int xcd  = bx & 7;
    const int slot = bx >> 3;
    const int b    = slot & 3;
    const int r    = (slot >> 2) * 8 + xcd;
    const int ch = 2 * r;

    cx tw[16];
    {
        const cx* Tr1 = Twd + (tid << 4);
        #pragma unroll
        for (int t = 1; t < 16; ++t) tw[t] = Tr1[t];
        tw2lds[(tid >> 4) * 16 + (tid & 15)] = Twd[(tid & 15) * 256 + (tid >> 4)];
    }

    const bf16* z0 = v_t + ((size_t)(b * D1 + ch)) * N_SEQ;
    const bf16* z1 = z0 + N_SEQ;
    cx v[16];
    #pragma unroll
    for (int t = 0; t < 8; ++t)
        v[t] = mkcx((float)z0[tid + 256 * t], (float)z1[tid + 256 * t]);

    fft4096_fwd_core<true>(data, tid, tw, tw2lds, v);

    // fused per-bin pointwise (A spectra from L2) + inverse stage 1
    const cx* A0row = A0s + (size_t)r * 4096;
    const cx* A1row = A1s + (size_t)r * 4096;
    const int pbase = tid << 4;
    {
        float4 a0pf[8], a1pf[8];
        {
            const float4* A0p = (const float4*)(A0row + pbase);
            const float4* A1p = (const float4*)(A1row + pbase);
            #pragma unroll
            for (int i = 0; i < 8; ++i) { a0pf[i] = A0p[i]; a1pf[i] = A1p[i]; }
        }
        auto pf = [](const float4* p, int i) -> cx {
            return (i & 1) ? mkcx(p[i >> 1].z, p[i >> 1].w)
                           : mkcx(p[i >> 1].x, p[i >> 1].y);
        };
        if (tid == 0) {
            #pragma unroll
            for (int i = 0; i < 16; ++i) {
                const int p2 = (i < 2) ? i : (i ^ ((1 << (31 - __clz(i))) - 1));
                cx Zk = data[fpad(i)];
                cx Zm = data[fpad(p2)];
                cx cjZm = mkcx(Zm.x, -Zm.y);
                cx V0 = Zk + cjZm;
                cx V1 = cneg_i(Zk - cjZm);
                v[i] = cmul(V0, pf(a0pf, i)) + cpos_i(cmul(V1, pf(a1pf, i)));
            }
        } else {
            const int mask = (1 << (31 - __clz(pbase))) - 1;
            const cx* zb  = data + fpad(pbase);
            const cx* zb2 = data + fpad((pbase ^ mask) - 15);
            #pragma unroll
            for (int i = 0; i < 16; ++i) {
                cx Zk = zb[i];
                cx Zm = zb2[15 - i];
                cx cjZm = mkcx(Zm.x, -Zm.y);
                cx V0 = Zk + cjZm;
                cx V1 = cneg_i(Zk - cjZm);
                v[i] = cmul(V0, pf(a0pf, i)) + cpos_i(cmul(V1, pf(a1pf, i)));
            }
        }
        __syncthreads();
        fft16_dit_inv_r4<false>(v);
        cx* base = data + fpad(pbase);
        #pragma unroll
        for (int i = 0; i < 16; ++i) base[i] = v[i];
    }
    __syncthreads();
    {   // inverse stage 2 (tw2 from LDS, conjugated)
        cx* base = data + fpad(((tid >> 4) << 8) + (tid & 15));
        #pragma unroll
        for (int p = 0; p < 16; ++p) v[p] = base[17 * p];
        apply_tw_lds<true>(v, tw2lds + (tid & 15));
        fft16_dit_inv_r4<false>(v);
        #pragma unroll
        for (int t = 0; t < 16; ++t) base[17 * t] = v[t];
    }
    __syncthreads();
    {   // inverse stage 3, lower half only (tw regs, conjugated)
        cx* base = data + fpad(tid);
        #pragma unroll
        for (int p = 0; p < 16; ++p) v[p] = base[274 * p];
        apply_tw<true>(v, tw);
        fft16_dit_inv_r4<true>(v);
        #pragma unroll
        for (int t = 0; t < 8; ++t) base[274 * t] = v[t];
    }
    __syncthreads();

    // gate with u (1/M already folded into the A spectra)
    const bf16* u0 = u_t + ((size_t)(b * D1 + ch)) * N_SEQ;
    const bf16* u1 = u0 + N_SEQ;
    bf16* g0 = gated_t + ((size_t)(b * D1 + ch)) * N_SEQ;
    bf16* g1 = g0 + N_SEQ;
    {
        const int t = tid * 8;
        const cx* base = data + fpad(t);
        bf16x8 ua = *(const bf16x8*)(u0 + t);
        bf16x8 ub = *(const bf16x8*)(u1 + t);
        bf16x8 oa, ob;
        #pragma unroll
        for (int i = 0; i < 8; ++i) {
            cx y = base[i];
            oa[i] = (bf16)(y.x * (float)ua[i]);
            ob[i] = (bf16)(y.y * (float)ub[i]);
        }
        *(bf16x8*)(g0 + t) = oa;
        *(bf16x8*)(g1 + t) = ob;
    }
}

// ---------------------------------------------------------------------------
__global__ __launch_bounds__(256) void transpose_cs_kernel(
    const bf16* __restrict__ in, bf16* __restrict__ outp)
{
    __shared__ bf16 tile[64 * 68];
    const int c0 = blockIdx.x * 64;
    const int m0 = blockIdx.y * 64;
    const int b  = m0 >> 11;
    const int s0 = m0 & 2047;
    const int tid = threadIdx.x;
    const int cl = tid >> 4;
    const int sc = (tid & 15) * 4;
    #pragma unroll
    for (int p = 0; p < 4; ++p) {
        int c = p * 16 + cl;
        bf16x4 v = *(const bf16x4*)&in[((size_t)(b * D1 + c0 + c)) * N_SEQ + s0 + sc];
        *(bf16x4*)&tile[c * 68 + sc] = v;
    }
    __syncthreads();
    const int sl = tid >> 4;
    const int cc = (tid & 15) * 4;
    #pragma unroll
    for (int p = 0; p < 4; ++p) {
        int s = p * 16 + sl;
        bf16x4 o;
        #pragma unroll
        for (int j = 0; j < 4; ++j) o[j] = tile[(cc + j) * 68 + s];
        *(bf16x4*)&outp[((size_t)(m0 + s)) * D1 + c0 + cc] = o;
    }
}

// ---------------------------------------------------------------------------
extern "C" void kernel_launch(void* const* d_in, const int* in_sizes, int n_in,
                              void* d_out, int out_size, void* d_ws, size_t ws_size,
                              hipStream_t stream)
{
    const float* x  = (const float*)d_in[0];
    const float* Wu = (const float*)d_in[1];
    const float* bu = (const float*)d_in[2];
    const float* Wv = (const float*)d_in[3];
    const float* bv = (const float*)d_in[4];
    const float* Wo = (const float*)d_in[5];
    const float* bo = (const float*)d_in[6];
    const float* Wp = (const float*)d_in[7];
    const float* bp = (const float*)d_in[8];
    const float* Wl = (const float*)d_in[9];
    const float* bl = (const float*)d_in[10];
    const float* Wr = (const float*)d_in[11];
    const float* br = (const float*)d_in[12];
    float* out = (float*)d_out;

    float* ws      = (float*)d_ws;
    float* a_t     = ws;                       // 1536*4096 fp32; A1spec after fft_a
    float* A0spec  = a_t   + 6291456;          // 768 x 4096 cx
    float* sumsq   = A0spec + 6291456;         // 3 x 4096 fp32
    float* twd     = sumsq + 12288;            // 256 x 16 cx twiddle table
    bf16*  bfws    = (bf16*)(twd + 8192);
    bf16*  x_bf    = bfws;                     // 8192*512
    bf16*  w_bf    = x_bf    + 4194304;        // 5 x 786432: Wu,Wv,Wo,Wl,Wr
    bf16*  Wuv_bf  = w_bf;                     // stacked [Wu;Wv] 3072 x 512
    bf16*  Wo_bf   = w_bf    + 2 * 786432;
    bf16*  Wl_bf   = Wo_bf   + 786432;
    bf16*  Wr_bf   = Wl_bf   + 786432;
    bf16*  gA      = Wr_bf   + 786432;         // 4096*512
    bf16*  gB      = gA      + 2097152;        // 4096*512
    bf16*  u_t     = gB      + 2097152;        // 8192*1536 [b][c][s]
    bf16*  v_t     = u_t     + 12582912;       // 8192*1536 [b][c][s]
    bf16*  gated_t = v_t     + 12582912;       // 8192*1536 [b][c][s]
    bf16*  gated   = gated_t + 12582912;       // 8192*1536 [m][c]

    dim3 blk(256);

    // x/w converts + sumsq zero + rpe input layer + twiddle table
    f2b_all_kernel<<<4096 + 5 * 768 + 12 + 4096 + 16, blk, 0, stream>>>(
        x, Wu, Wv, Wo, Wl, Wr, Wp, bp, x_bf, w_bf, sumsq, gA, twd);

    gemm_bf16<MODE_SILU_UV, bf16><<<dim3(24, 64), blk, 0, stream>>>(
        x_bf, Wuv_bf, bu, bv, u_t, v_t, 8192, 2 * D1, ED, nullptr, nullptr);

    // RPE MLP: srms folded into GEMM epilogues via row-scale commutation
    bf16* gin = gA;
    bf16* gout = gB;
    for (int i = 0; i < 3; ++i) {
        const float* sin_p = (i == 0) ? nullptr : sumsq + (size_t)(i - 1) * 4096;
        gemm_bf16<MODE_RPE, bf16><<<dim3(4, 32), blk, 0, stream>>>(
            gin, Wl_bf + (size_t)i * ED * ED, bl + (size_t)i * ED, nullptr,
            gout, nullptr, 4096, ED, ED, sin_p, sumsq + (size_t)i * 4096);
        bf16* t = gin; gin = gout; gout = t;
    }
    gemm_bf16<MODE_AT, float><<<dim3(12, 32), blk, 0, stream>>>(
        gin, Wr_bf, br, nullptr, a_t, nullptr, 4096, D1, ED,
        sumsq + 2 * 4096, nullptr);

    fft_a_kernel<<<768, blk, 0, stream>>>(
        a_t, (cx*)A0spec, (cx*)a_t, (const cx*)twd);
    fft_conv_kernel<<<3072, blk, 0, stream>>>(
        v_t, (const cx*)A0spec, (const cx*)a_t, u_t, gated_t, (const cx*)twd);

    transpose_cs_kernel<<<dim3(24, 128), blk, 0, stream>>>(gated_t, gated);

    gemm_bf16<MODE_PLAIN, float><<<dim3(4, 64), blk, 0, stream>>>(
        gated, Wo_bf, bo, nullptr, out, nullptr, 8192, ED, D1,
        nullptr, nullptr);
}

// Round 4
// 357.224 us; speedup vs baseline: 1.1219x; 1.0365x over previous
//
#include <hip/hip_runtime.h>

#define N_SEQ 2048
#define M_FFT 4096
#define D1    1536
#define NH    8
#define HD    192
#define ED    512

typedef __bf16 bf16;
typedef __bf16 bf16x4 __attribute__((ext_vector_type(4)));
typedef __bf16 bf16x8 __attribute__((ext_vector_type(8)));
typedef float  floatx4 __attribute__((ext_vector_type(4)));
typedef float  cx __attribute__((ext_vector_type(2)));   // complex as packed fp32

enum { MODE_PLAIN = 0, MODE_SILU_UV = 1, MODE_AT = 3, MODE_RPE = 4 };

__device__ __forceinline__ void gload16(const void* g, void* l) {
    __builtin_amdgcn_global_load_lds(
        (const __attribute__((address_space(1))) void*)g,
        (__attribute__((address_space(3))) void*)l, 16, 0, 0);
}

// ---------------------------------------------------------------------------
// bf16 MFMA GEMM, 2-phase double-buffered: the NEXT K-tile's
// global_load_lds is issued BEFORE the current tile's ds_read+MFMA, so the
// single __syncthreads per step (vmcnt(0)+barrier) waits on loads that have
// been in flight for the whole compute phase. K/32 is even for all shapes,
// so a by-2 unrolled loop keeps the buffer index compile-time static.
// ---------------------------------------------------------------------------
template<int MODE, typename OutT>
__global__ __launch_bounds__(256) void gemm_bf16(
    const bf16* __restrict__ A, const bf16* __restrict__ Bw,
    const float* __restrict__ bias, const float* __restrict__ bias2,
    OutT* __restrict__ C, OutT* __restrict__ C2,
    int M, int Nc, int K,
    const float* __restrict__ scale_in, float* __restrict__ sumsq_out)
{
    __shared__ __align__(16) bf16 As[2][128 * 32];
    __shared__ __align__(16) bf16 Bs[2][128 * 32];

    const int tid  = threadIdx.x;
    const int row0 = blockIdx.y * 128;
    const int col0 = blockIdx.x * 128;
    const int wid  = tid >> 6;
    const int lane = tid & 63;
    const int lm   = lane & 15;
    const int lk   = lane >> 4;
    const int wm   = wid >> 1;
    const int wn   = wid & 1;
    const int ldrow  = tid >> 2;
    const int ldcol8 = (tid & 3) * 8;

    floatx4 acc[4][4] = {};

    const bf16* Ag = A  + ((size_t)(row0 + ldrow)) * K + ldcol8;
    const bf16* Bg = Bw + ((size_t)(col0 + ldrow)) * K + ldcol8;
    const int woff = (wid * 16) * 32;

    auto stage = [&](int k0, int buf) {
        gload16(Ag + k0, &As[buf][woff]);
        gload16(Ag + (size_t)64 * K + k0, &As[buf][woff + 64 * 32]);
        gload16(Bg + k0, &Bs[buf][woff]);
        gload16(Bg + (size_t)64 * K + k0, &Bs[buf][woff + 64 * 32]);
    };
    auto compute = [&](int buf) {
        bf16x8 af[4], bfr[4];
        #pragma unroll
        for (int mi = 0; mi < 4; ++mi)
            af[mi] = *(const bf16x8*)&As[buf][(wm * 64 + mi * 16 + lm) * 32 + lk * 8];
        #pragma unroll
        for (int nj = 0; nj < 4; ++nj)
            bfr[nj] = *(const bf16x8*)&Bs[buf][(wn * 64 + nj * 16 + lm) * 32 + lk * 8];
        #pragma unroll
        for (int mi = 0; mi < 4; ++mi)
            #pragma unroll
            for (int nj = 0; nj < 4; ++nj)
                acc[mi][nj] = __builtin_amdgcn_mfma_f32_16x16x32_bf16(
                    af[mi], bfr[nj], acc[mi][nj], 0, 0, 0);
    };

    const int nt = K >> 5;           // # of 32-wide K tiles (always even here)
    stage(0, 0);
    __syncthreads();                 // drains vmcnt(0): tile 0 ready
    for (int t = 0; t < nt; t += 2) {
        stage((t + 1) << 5, 1);      // in flight during compute of buf0
        compute(0);
        __syncthreads();             // vmcnt(0)+barrier: buf1 ready, buf0 free
        if (t + 2 < nt) stage((t + 2) << 5, 0);
        compute(1);
        __syncthreads();             // buf0 ready (or final drain)
    }

    const float* bs = bias;
    OutT* dst = C;
    int cadj = 0;
    if (MODE == MODE_SILU_UV && col0 >= D1) { bs = bias2; dst = C2; cadj = D1; }

    float bcol[4];
    #pragma unroll
    for (int nj = 0; nj < 4; ++nj)
        bcol[nj] = bs[col0 - cadj + wn * 64 + nj * 16 + lm];

    if (MODE == MODE_RPE) {
        #pragma unroll
        for (int mi = 0; mi < 4; ++mi) {
            #pragma unroll
            for (int r = 0; r < 4; ++r) {
                const int row = row0 + wm * 64 + mi * 16 + lk * 4 + r;
                float sc = 1.0f;
                if (scale_in)
                    sc = 1.0f / (sqrtf(scale_in[row]) * 0.04419417382415922f + 1e-8f);
                float ssq = 0.0f;
                #pragma unroll
                for (int nj = 0; nj < 4; ++nj) {
                    const int col = col0 + wn * 64 + nj * 16 + lm;
                    float val = acc[mi][nj][r] * sc + bcol[nj];
                    ssq += val * val;
                    ((bf16*)C)[(size_t)row * Nc + col] = (bf16)fmaxf(val, 0.0f);
                }
                ssq += __shfl_xor(ssq, 1, 64);
                ssq += __shfl_xor(ssq, 2, 64);
                ssq += __shfl_xor(ssq, 4, 64);
                ssq += __shfl_xor(ssq, 8, 64);
                if (lm == 0) atomicAdd(&sumsq_out[row], ssq);
            }
        }
        return;
    }

    #pragma unroll
    for (int mi = 0; mi < 4; ++mi) {
        const int rbase = row0 + wm * 64 + mi * 16 + lk * 4;
        float sc[4];
        #pragma unroll
        for (int r = 0; r < 4; ++r) {
            sc[r] = 1.0f;
            if (MODE == MODE_AT && scale_in)
                sc[r] = 1.0f / (sqrtf(scale_in[rbase + r]) * 0.04419417382415922f + 1e-8f);
        }
        #pragma unroll
        for (int nj = 0; nj < 4; ++nj) {
            const int col = col0 - cadj + wn * 64 + nj * 16 + lm;
            float vals[4];
            #pragma unroll
            for (int r = 0; r < 4; ++r) {
                float val = acc[mi][nj][r] * sc[r] + bcol[nj];
                if (MODE == MODE_SILU_UV)
                    val = val / (1.0f + __expf(-val));
                vals[r] = val;
            }
            if (MODE == MODE_SILU_UV) {
                int b = rbase >> 11, s = rbase & 2047;
                bf16x4 o;
                #pragma unroll
                for (int r = 0; r < 4; ++r) o[r] = (bf16)vals[r];
                *(bf16x4*)&((bf16*)dst)[((size_t)(b * D1 + col)) * N_SEQ + s] = o;
            } else if (MODE == MODE_AT) {
                float4 o = make_float4(vals[0], vals[1], vals[2], vals[3]);
                *(float4*)&((float*)C)[(size_t)col * M + rbase] = o;
            } else {
                #pragma unroll
                for (int r = 0; r < 4; ++r)
                    C[(size_t)(rbase + r) * Nc + col] = (OutT)vals[r];
            }
        }
    }
}

// ---------------------------------------------------------------------------
// mega-prologue: x convert + 5 weight converts + sumsq zero +
// RPE input layer w/ srms + FFT twiddle table (256 x 16 cx)
// ---------------------------------------------------------------------------
__global__ __launch_bounds__(256) void f2b_all_kernel(
    const float* __restrict__ x,  const float* __restrict__ s0,
    const float* __restrict__ s1, const float* __restrict__ s2,
    const float* __restrict__ s3, const float* __restrict__ s4,
    const float* __restrict__ Wp, const float* __restrict__ bp,
    bf16* __restrict__ x_bf, bf16* __restrict__ w_bf,
    float* __restrict__ sumsq, bf16* __restrict__ g0,
    float* __restrict__ twd)
{
    const int bid = blockIdx.x;
    const int tid = threadIdx.x;
    __shared__ float red[4];

    if (bid < 7936) {
        const float* src;
        bf16* dst;
        size_t off;
        if (bid < 4096) {
            src = x; dst = x_bf; off = (size_t)bid * 1024;
        } else {
            int t = bid - 4096;
            int seg = t / 768;
            src = seg == 0 ? s0 : seg == 1 ? s1 : seg == 2 ? s2
                : seg == 3 ? s3 : s4;
            dst = w_bf + (size_t)seg * 786432;
            off = (size_t)(t % 768) * 1024;
        }
        size_t i = off + (size_t)tid * 4;
        float4 f = *(const float4*)(src + i);
        union { bf16 h[4]; short4 s; } u4;
        u4.h[0] = (bf16)f.x; u4.h[1] = (bf16)f.y;
        u4.h[2] = (bf16)f.z; u4.h[3] = (bf16)f.w;
        *(short4*)(dst + i) = u4.s;
    } else if (bid < 7948) {
        size_t i = (size_t)(bid - 7936) * 1024 + (size_t)tid * 4;
        *(float4*)(sumsq + i) = make_float4(0.f, 0.f, 0.f, 0.f);
    } else if (bid < 12044) {
        const int j = bid - 7948;
        float idxv = (j < N_SEQ) ? (float)j
                                 : (j == N_SEQ ? 0.0f : (float)(j - 2 * N_SEQ));
        float h1 = idxv * Wp[tid] + bp[tid];
        float h2 = idxv * Wp[tid + 256] + bp[tid + 256];
        float ss = h1 * h1 + h2 * h2;
        #pragma unroll
        for (int off = 32; off > 0; off >>= 1) ss += __shfl_down(ss, off, 64);
        if ((tid & 63) == 0) red[tid >> 6] = ss;
        __syncthreads();
        float tot = red[0] + red[1] + red[2] + red[3];
        float scale = 1.0f / (sqrtf(tot) * 0.04419417382415922f + 1e-8f);
        g0[(size_t)j * ED + tid]       = (bf16)fmaxf(h1 * scale, 0.0f);
        g0[(size_t)j * ED + tid + 256] = (bf16)fmaxf(h2 * scale, 0.0f);
    } else {
        const int idx = (bid - 12044) * 256 + tid;    // [0, 4096)
        const int j = idx >> 4, tau = idx & 15;
        float sA, cA;
        __sincosf(-6.283185307179586f * (float)(j * tau) * (1.0f / 4096.0f),
                  &sA, &cA);
        cx w; w.x = cA; w.y = sA;
        ((cx*)twd)[idx] = w;
    }
}

// ---------------------------------------------------------------------------
// Radix-16 FFT, radix-4 butterflies, packed-fp32 complex.
// LDS addressing: fpad(base + s*t) = fpad(base) + s'*t  (256->274, 16->17, 1->1)
// Stage-1/inv-3 twiddle row (tid<<4) lives in REGISTERS for the whole kernel
// (inverse = conjugate). Stage-2/inv-2 rows (only 16 distinct) live in a 2 KB
// LDS table laid out [tau][row16] -> broadcast, conflict-free reads.
// ---------------------------------------------------------------------------
#define FFT_LDS_SZ 4381

__device__ __forceinline__ int fpad(int i) { return i + (i >> 4) + 2 * (i >> 8); }

__device__ __forceinline__ cx mkcx(float a, float b) { cx r; r.x = a; r.y = b; return r; }
__device__ __forceinline__ cx cmul(cx a, cx b) {
    cx br = mkcx(-b.y, b.x);
    return a.xx * b + a.yy * br;
}
__device__ __forceinline__ cx cmul_cj(cx a, cx b) {      // a * conj(b)
    cx bc = mkcx(b.x, -b.y);
    cx br = mkcx(b.y, b.x);
    return a.xx * bc + a.yy * br;
}
__device__ __forceinline__ cx cneg_i(cx a) { return mkcx(a.y, -a.x); }   // a * (-i)
__device__ __forceinline__ cx cpos_i(cx a) { return mkcx(-a.y, a.x); }   // a * (+i)
__host__ __device__ constexpr int brev4(int t) {
    return ((t & 1) << 3) | ((t & 2) << 1) | ((t & 4) >> 1) | ((t & 8) >> 3);
}

#define CC1 0.9238795325112867f
#define SS1 0.3826834323650898f
#define RR2 0.7071067811865476f

template<bool HZ>
__device__ __forceinline__ void fft16_dif_r4(cx x[16]) {
    const cx W1 = mkcx( CC1, -SS1);
    const cx W2 = mkcx( RR2, -RR2);
    const cx W3 = mkcx( SS1, -CC1);
    const cx W6 = mkcx(-RR2, -RR2);
    const cx W9 = mkcx(-CC1,  SS1);
    #pragma unroll
    for (int n = 0; n < 4; ++n) {
        cx A, B, C, D;
        if (HZ) { A = x[n]; C = x[n]; B = x[n + 4]; D = x[n + 4]; }
        else {
            A = x[n] + x[n + 8];      C = x[n] - x[n + 8];
            B = x[n + 4] + x[n + 12]; D = x[n + 4] - x[n + 12];
        }
        cx s = A - B;
        cx nid = cneg_i(D);
        cx m = C + nid;
        cx p = C - nid;
        x[n] = A + B;
        if (n == 0)      { x[4] = s;            x[8]  = m;           x[12] = p; }
        else if (n == 1) { x[5] = cmul(s, W2);  x[9]  = cmul(m, W1); x[13] = cmul(p, W3); }
        else if (n == 2) { x[6] = cneg_i(s);    x[10] = cmul(m, W2); x[14] = cmul(p, W6); }
        else             { x[7] = cmul(s, W6);  x[11] = cmul(m, W3); x[15] = cmul(p, W9); }
    }
    #pragma unroll
    for (int q = 0; q < 16; q += 4) {
        cx a = x[q], b = x[q + 1], c = x[q + 2], d = x[q + 3];
        cx a1 = a + c, c1 = a - c;
        cx b1 = b + d, d1 = cneg_i(b - d);
        x[q]     = a1 + b1;
        x[q + 1] = a1 - b1;
        x[q + 2] = c1 + d1;
        x[q + 3] = c1 - d1;
    }
}

template<bool HALF_OUT>
__device__ __forceinline__ void fft16_dit_inv_r4(cx x[16]) {
    const cx V1 = mkcx( CC1, SS1);
    const cx V2 = mkcx( RR2, RR2);
    const cx V3 = mkcx( SS1, CC1);
    const cx V6 = mkcx(-RR2, RR2);
    #pragma unroll
    for (int q = 0; q < 16; q += 4) {
        cx a = x[q], b = x[q + 1], c = x[q + 2], d = x[q + 3];
        cx a1 = a + b, b1 = a - b;
        cx c1 = c + d, d1 = c - d;
        cx t = cpos_i(d1);
        x[q]     = a1 + c1;
        x[q + 2] = a1 - c1;
        x[q + 1] = b1 + t;
        x[q + 3] = b1 - t;
    }
    #pragma unroll
    for (int n = 0; n < 4; ++n) {
        cx t1, t2;
        if (n == 0)      { t1 = x[4];             t2 = x[12]; }
        else if (n == 1) { t1 = cmul(x[5],  V2);  t2 = cmul(x[13], V2); }
        else if (n == 2) { t1 = cpos_i(x[6]);     t2 = cpos_i(x[14]); }
        else             { t1 = cmul(x[7],  V6);  t2 = cmul(x[15], V6); }
        cx P = x[n] + t1, Q = x[n] - t1;
        cx R = x[n + 8] + t2, S = x[n + 8] - t2;
        cx t, u;
        if (n == 0)      { t = R;            u = S; }
        else if (n == 1) { t = cmul(R, V1);  u = cmul(S, V1); }
        else if (n == 2) { t = cmul(R, V2);  u = cmul(S, V2); }
        else             { t = cmul(R, V3);  u = cmul(S, V3); }
        cx iu = cpos_i(u);
        x[n]     = P + t;
        x[n + 4] = Q + iu;
        if (!HALF_OUT) {
            x[n + 8]  = P - t;
            x[n + 12] = Q - iu;
        }
    }
}

template<bool CONJ>
__device__ __forceinline__ void apply_tw(cx v[16], const cx tw[16]) {
    #pragma unroll
    for (int tau = 1; tau < 16; ++tau) {
        const int q = brev4(tau);
        v[q] = CONJ ? cmul_cj(v[q], tw[tau]) : cmul(v[q], tw[tau]);
    }
}

// twrow points at tw2lds + (tid&15); stride 16 per tau. Broadcast reads.
template<bool CONJ>
__device__ __forceinline__ void apply_tw_lds(cx v[16], const cx* twrow) {
    #pragma unroll
    for (int tau = 1; tau < 16; ++tau) {
        cx w = twrow[tau * 16];
        const int q = brev4(tau);
        v[q] = CONJ ? cmul_cj(v[q], w) : cmul(v[q], w);
    }
}

// Forward 4096-FFT; stage-1 inputs pre-loaded in v by the caller
// (only v[0..7] if HALF_ZERO). tw = reg row (tid<<4); tw2lds = LDS table.
template<bool HALF_ZERO>
__device__ __forceinline__ void fft4096_fwd_core(
    cx* d, int tid, const cx tw[16], const cx* tw2lds, cx v[16])
{
    {   // stage 1 (stride 256 -> 274): direct from registers
        fft16_dif_r4<HALF_ZERO>(v);
        apply_tw<false>(v, tw);
        cx* base = d + fpad(tid);
        #pragma unroll
        for (int p = 0; p < 16; ++p) base[274 * p] = v[p];
    }
    __syncthreads();
    {   // stage 2 (stride 16 -> 17)
        cx* base = d + fpad(((tid >> 4) << 8) + (tid & 15));
        #pragma unroll
        for (int t = 0; t < 16; ++t) v[t] = base[17 * t];
        fft16_dif_r4<false>(v);
        apply_tw_lds<false>(v, tw2lds + (tid & 15));
        #pragma unroll
        for (int p = 0; p < 16; ++p) base[17 * p] = v[p];
    }
    __syncthreads();
    {   // stage 3 (stride 1)
        cx* base = d + fpad(tid << 4);
        #pragma unroll
        for (int t = 0; t < 16; ++t) v[t] = base[t];
        fft16_dif_r4<false>(v);
        #pragma unroll
        for (int p = 0; p < 16; ++p) base[p] = v[p];
    }
    __syncthreads();
}

// ---------------------------------------------------------------------------
// Forward FFT of packed (a_ch0, a_ch1) pair, unpack both real spectra in
// DIF order (conjugate-partner: p2 = p ^ (2^floor(log2 p) - 1)).
// A0 = c*(Wk + conj(Wm)), A1 = c*(-i)*(Wk - conj(Wm)), c = 0.25/4096.
// ---------------------------------------------------------------------------
__global__ __launch_bounds__(256, 4) void fft_a_kernel(
    const float* a_t, cx* __restrict__ A0s, cx* A1s,
    const cx* __restrict__ Twd)
{
    __shared__ cx data[FFT_LDS_SZ];
    __shared__ cx tw2lds[256];
    const int tid = threadIdx.x;
    const int r = blockIdx.x;                      // pair index, ch = 2r

    cx tw[16];
    {
        const cx* Tr1 = Twd + (tid << 4);
        #pragma unroll
        for (int t = 1; t < 16; ++t) tw[t] = Tr1[t];
        tw2lds[(tid >> 4) * 16 + (tid & 15)] = Twd[(tid & 15) * 256 + (tid >> 4)];
    }

    const float* r0 = a_t + (size_t)(2 * r) * M_FFT;
    const float* r1 = r0 + M_FFT;
    cx v[16];
    #pragma unroll
    for (int t = 0; t < 16; ++t)
        v[t] = mkcx(r0[tid + 256 * t], r1[tid + 256 * t]);

    fft4096_fwd_core<false>(data, tid, tw, tw2lds, v);

    const float c = 0.25f / 4096.0f;
    cx* A0row = A0s + (size_t)r * 4096;
    cx* A1row = A1s + (size_t)r * 4096;
    if (tid == 0) {
        #pragma unroll
        for (int i = 0; i < 16; ++i) {
            const int p2 = (i < 2) ? i : (i ^ ((1 << (31 - __clz(i))) - 1));
            cx Wk = data[fpad(i)];
            cx Wm = data[fpad(p2)];
            cx cjWm = mkcx(Wm.x, -Wm.y);
            A0row[i] = c * (Wk + cjWm);
            A1row[i] = c * cneg_i(Wk - cjWm);
        }
    } else {
        const int base = tid << 4;
        const int mask = (1 << (31 - __clz(base))) - 1;
        const cx* zb  = data + fpad(base);
        const cx* zb2 = data + fpad((base ^ mask) - 15);
        #pragma unroll
        for (int i = 0; i < 16; ++i) {
            cx Wk = zb[i];
            cx Wm = zb2[15 - i];
            cx cjWm = mkcx(Wm.x, -Wm.y);
            A0row[base + i] = c * (Wk + cjWm);
            A1row[base + i] = c * cneg_i(Wk - cjWm);
        }
    }
}

// ---------------------------------------------------------------------------
// Conv kernel. XCD remap (bijective) keeps the 4 batches sharing an A-row
// temporally adjacent on one XCD: xcd = r&7, slot = (r>>3)*4 + b.
// Stage-1 inputs loaded straight from global (no staging phase); A0/A1 read
// as plain float4 at pointwise (L2-warm); u read in the gate stage.
// ---------------------------------------------------------------------------
__global__ __launch_bounds__(256, 4) void fft_conv_kernel(
    const bf16* __restrict__ v_t, const cx* __restrict__ A0s,
    const cx* __restrict__ A1s, const bf16* __restrict__ u_t,
    bf16* __restrict__ gated_t, const cx* __restrict__ Twd)
{
    __shared__ cx data[FFT_LDS_SZ];
    __shared__ cx tw2lds[256];
    const int tid = threadIdx.x;
    const int bx = blockIdx.x;
    const int xcd  = bx & 7;
    const int slot = bx >> 3;
    const int b    = slot & 3;
    const int r    = (slot >> 2) * 8 + xcd;
    const int ch = 2 * r;

    cx tw[16];
    {
        const cx* Tr1 = Twd + (tid << 4);
        #pragma unroll
        for (int t = 1; t < 16; ++t) tw[t] = Tr1[t];
        tw2lds[(tid >> 4) * 16 + (tid & 15)] = Twd[(tid & 15) * 256 + (tid >> 4)];
    }

    const bf16* z0 = v_t + ((size_t)(b * D1 + ch)) * N_SEQ;
    const bf16* z1 = z0 + N_SEQ;
    cx v[16];
    #pragma unroll
    for (int t = 0; t < 8; ++t)
        v[t] = mkcx((float)z0[tid + 256 * t], (float)z1[tid + 256 * t]);

    fft4096_fwd_core<true>(data, tid, tw, tw2lds, v);

    // fused per-bin pointwise (A spectra from L2) + inverse stage 1
    const cx* A0row = A0s + (size_t)r * 4096;
    const cx* A1row = A1s + (size_t)r * 4096;
    const int pbase = tid << 4;
    {
        float4 a0pf[8], a1pf[8];
        {
            const float4* A0p = (const float4*)(A0row + pbase);
            const float4* A1p = (const float4*)(A1row + pbase);
            #pragma unroll
            for (int i = 0; i < 8; ++i) { a0pf[i] = A0p[i]; a1pf[i] = A1p[i]; }
        }
        auto pf = [](const float4* p, int i) -> cx {
            return (i & 1) ? mkcx(p[i >> 1].z, p[i >> 1].w)
                           : mkcx(p[i >> 1].x, p[i >> 1].y);
        };
        if (tid == 0) {
            #pragma unroll
            for (int i = 0; i < 16; ++i) {
                const int p2 = (i < 2) ? i : (i ^ ((1 << (31 - __clz(i))) - 1));
                cx Zk = data[fpad(i)];
                cx Zm = data[fpad(p2)];
                cx cjZm = mkcx(Zm.x, -Zm.y);
                cx V0 = Zk + cjZm;
                cx V1 = cneg_i(Zk - cjZm);
                v[i] = cmul(V0, pf(a0pf, i)) + cpos_i(cmul(V1, pf(a1pf, i)));
            }
        } else {
            const int mask = (1 << (31 - __clz(pbase))) - 1;
            const cx* zb  = data + fpad(pbase);
            const cx* zb2 = data + fpad((pbase ^ mask) - 15);
            #pragma unroll
            for (int i = 0; i < 16; ++i) {
                cx Zk = zb[i];
                cx Zm = zb2[15 - i];
                cx cjZm = mkcx(Zm.x, -Zm.y);
                cx V0 = Zk + cjZm;
                cx V1 = cneg_i(Zk - cjZm);
                v[i] = cmul(V0, pf(a0pf, i)) + cpos_i(cmul(V1, pf(a1pf, i)));
            }
        }
        __syncthreads();
        fft16_dit_inv_r4<false>(v);
        cx* base = data + fpad(pbase);
        #pragma unroll
        for (int i = 0; i < 16; ++i) base[i] = v[i];
    }
    __syncthreads();
    {   // inverse stage 2 (tw2 from LDS, conjugated)
        cx* base = data + fpad(((tid >> 4) << 8) + (tid & 15));
        #pragma unroll
        for (int p = 0; p < 16; ++p) v[p] = base[17 * p];
        apply_tw_lds<true>(v, tw2lds + (tid & 15));
        fft16_dit_inv_r4<false>(v);
        #pragma unroll
        for (int t = 0; t < 16; ++t) base[17 * t] = v[t];
    }
    __syncthreads();
    {   // inverse stage 3, lower half only (tw regs, conjugated)
        cx* base = data + fpad(tid);
        #pragma unroll
        for (int p = 0; p < 16; ++p) v[p] = base[274 * p];
        apply_tw<true>(v, tw);
        fft16_dit_inv_r4<true>(v);
        #pragma unroll
        for (int t = 0; t < 8; ++t) base[274 * t] = v[t];
    }
    __syncthreads();

    // gate with u (1/M already folded into the A spectra)
    const bf16* u0 = u_t + ((size_t)(b * D1 + ch)) * N_SEQ;
    const bf16* u1 = u0 + N_SEQ;
    bf16* g0 = gated_t + ((size_t)(b * D1 + ch)) * N_SEQ;
    bf16* g1 = g0 + N_SEQ;
    {
        const int t = tid * 8;
        const cx* base = data + fpad(t);
        bf16x8 ua = *(const bf16x8*)(u0 + t);
        bf16x8 ub = *(const bf16x8*)(u1 + t);
        bf16x8 oa, ob;
        #pragma unroll
        for (int i = 0; i < 8; ++i) {
            cx y = base[i];
            oa[i] = (bf16)(y.x * (float)ua[i]);
            ob[i] = (bf16)(y.y * (float)ub[i]);
        }
        *(bf16x8*)(g0 + t) = oa;
        *(bf16x8*)(g1 + t) = ob;
    }
}

// ---------------------------------------------------------------------------
__global__ __launch_bounds__(256) void transpose_cs_kernel(
    const bf16* __restrict__ in, bf16* __restrict__ outp)
{
    __shared__ bf16 tile[64 * 68];
    const int c0 = blockIdx.x * 64;
    const int m0 = blockIdx.y * 64;
    const int b  = m0 >> 11;
    const int s0 = m0 & 2047;
    const int tid = threadIdx.x;
    const int cl = tid >> 4;
    const int sc = (tid & 15) * 4;
    #pragma unroll
    for (int p = 0; p < 4; ++p) {
        int c = p * 16 + cl;
        bf16x4 v = *(const bf16x4*)&in[((size_t)(b * D1 + c0 + c)) * N_SEQ + s0 + sc];
        *(bf16x4*)&tile[c * 68 + sc] = v;
    }
    __syncthreads();
    const int sl = tid >> 4;
    const int cc = (tid & 15) * 4;
    #pragma unroll
    for (int p = 0; p < 4; ++p) {
        int s = p * 16 + sl;
        bf16x4 o;
        #pragma unroll
        for (int j = 0; j < 4; ++j) o[j] = tile[(cc + j) * 68 + s];
        *(bf16x4*)&outp[((size_t)(m0 + s)) * D1 + c0 + cc] = o;
    }
}

// ---------------------------------------------------------------------------
extern "C" void kernel_launch(void* const* d_in, const int* in_sizes, int n_in,
                              void* d_out, int out_size, void* d_ws, size_t ws_size,
                              hipStream_t stream)
{
    const float* x  = (const float*)d_in[0];
    const float* Wu = (const float*)d_in[1];
    const float* bu = (const float*)d_in[2];
    const float* Wv = (const float*)d_in[3];
    const float* bv = (const float*)d_in[4];
    const float* Wo = (const float*)d_in[5];
    const float* bo = (const float*)d_in[6];
    const float* Wp = (const float*)d_in[7];
    const float* bp = (const float*)d_in[8];
    const float* Wl = (const float*)d_in[9];
    const float* bl = (const float*)d_in[10];
    const float* Wr = (const float*)d_in[11];
    const float* br = (const float*)d_in[12];
    float* out = (float*)d_out;

    float* ws      = (float*)d_ws;
    float* a_t     = ws;                       // 1536*4096 fp32; A1spec after fft_a
    float* A0spec  = a_t   + 6291456;          // 768 x 4096 cx
    float* sumsq   = A0spec + 6291456;         // 3 x 4096 fp32
    float* twd     = sumsq + 12288;            // 256 x 16 cx twiddle table
    bf16*  bfws    = (bf16*)(twd + 8192);
    bf16*  x_bf    = bfws;                     // 8192*512
    bf16*  w_bf    = x_bf    + 4194304;        // 5 x 786432: Wu,Wv,Wo,Wl,Wr
    bf16*  Wuv_bf  = w_bf;                     // stacked [Wu;Wv] 3072 x 512
    bf16*  Wo_bf   = w_bf    + 2 * 786432;
    bf16*  Wl_bf   = Wo_bf   + 786432;
    bf16*  Wr_bf   = Wl_bf   + 786432;
    bf16*  gA      = Wr_bf   + 786432;         // 4096*512
    bf16*  gB      = gA      + 2097152;        // 4096*512
    bf16*  u_t     = gB      + 2097152;        // 8192*1536 [b][c][s]
    bf16*  v_t     = u_t     + 12582912;       // 8192*1536 [b][c][s]
    bf16*  gated_t = v_t     + 12582912;       // 8192*1536 [b][c][s]
    bf16*  gated   = gated_t + 12582912;       // 8192*1536 [m][c]

    dim3 blk(256);

    // x/w converts + sumsq zero + rpe input layer + twiddle table
    f2b_all_kernel<<<4096 + 5 * 768 + 12 + 4096 + 16, blk, 0, stream>>>(
        x, Wu, Wv, Wo, Wl, Wr, Wp, bp, x_bf, w_bf, sumsq, gA, twd);

    gemm_bf16<MODE_SILU_UV, bf16><<<dim3(24, 64), blk, 0, stream>>>(
        x_bf, Wuv_bf, bu, bv, u_t, v_t, 8192, 2 * D1, ED, nullptr, nullptr);

    // RPE MLP: srms folded into GEMM epilogues via row-scale commutation
    bf16* gin = gA;
    bf16* gout = gB;
    for (int i = 0; i < 3; ++i) {
        const float* sin_p = (i == 0) ? nullptr : sumsq + (size_t)(i - 1) * 4096;
        gemm_bf16<MODE_RPE, bf16><<<dim3(4, 32), blk, 0, stream>>>(
            gin, Wl_bf + (size_t)i * ED * ED, bl + (size_t)i * ED, nullptr,
            gout, nullptr, 4096, ED, ED, sin_p, sumsq + (size_t)i * 4096);
        bf16* t = gin; gin = gout; gout = t;
    }
    gemm_bf16<MODE_AT, float><<<dim3(12, 32), blk, 0, stream>>>(
        gin, Wr_bf, br, nullptr, a_t, nullptr, 4096, D1, ED,
        sumsq + 2 * 4096, nullptr);

    fft_a_kernel<<<768, blk, 0, stream>>>(
        a_t, (cx*)A0spec, (cx*)a_t, (const cx*)twd);
    fft_conv_kernel<<<3072, blk, 0, stream>>>(
        v_t, (const cx*)A0spec, (const cx*)a_t, u_t, gated_t, (const cx*)twd);

    transpose_cs_kernel<<<dim3(24, 128), blk, 0, stream>>>(gated_t, gated);

    gemm_bf16<MODE_PLAIN, float><<<dim3(4, 64), blk, 0, stream>>>(
        gated, Wo_bf, bo, nullptr, out, nullptr, 8192, ED, D1,
        nullptr, nullptr);
}

// Round 5
// 352.445 us; speedup vs baseline: 1.1371x; 1.0136x over previous
//
#include <hip/hip_runtime.h>

#define N_SEQ 2048
#define M_FFT 4096
#define D1    1536
#define NH    8
#define HD    192
#define ED    512

typedef __bf16 bf16;
typedef __bf16 bf16x4 __attribute__((ext_vector_type(4)));
typedef __bf16 bf16x8 __attribute__((ext_vector_type(8)));
typedef float  floatx4 __attribute__((ext_vector_type(4)));
typedef float  cx __attribute__((ext_vector_type(2)));   // complex as packed fp32

enum { MODE_PLAIN = 0, MODE_SILU_UV = 1, MODE_AT = 3, MODE_RPE = 4 };

__device__ __forceinline__ void gload16(const void* g, void* l) {
    __builtin_amdgcn_global_load_lds(
        (const __attribute__((address_space(1))) void*)g,
        (__attribute__((address_space(3))) void*)l, 16, 0, 0);
}

// ---------------------------------------------------------------------------
// bf16 MFMA GEMM, 2-phase double-buffered (round-3 structure, verified).
// ---------------------------------------------------------------------------
template<int MODE, typename OutT>
__global__ __launch_bounds__(256) void gemm_bf16(
    const bf16* __restrict__ A, const bf16* __restrict__ Bw,
    const float* __restrict__ bias, const float* __restrict__ bias2,
    OutT* __restrict__ C, OutT* __restrict__ C2,
    int M, int Nc, int K,
    const float* __restrict__ scale_in, float* __restrict__ sumsq_out)
{
    __shared__ __align__(16) bf16 As[2][128 * 32];
    __shared__ __align__(16) bf16 Bs[2][128 * 32];

    const int tid  = threadIdx.x;
    const int row0 = blockIdx.y * 128;
    const int col0 = blockIdx.x * 128;
    const int wid  = tid >> 6;
    const int lane = tid & 63;
    const int lm   = lane & 15;
    const int lk   = lane >> 4;
    const int wm   = wid >> 1;
    const int wn   = wid & 1;
    const int ldrow  = tid >> 2;
    const int ldcol8 = (tid & 3) * 8;

    floatx4 acc[4][4] = {};

    const bf16* Ag = A  + ((size_t)(row0 + ldrow)) * K + ldcol8;
    const bf16* Bg = Bw + ((size_t)(col0 + ldrow)) * K + ldcol8;
    const int woff = (wid * 16) * 32;

    auto stage = [&](int k0, int buf) {
        gload16(Ag + k0, &As[buf][woff]);
        gload16(Ag + (size_t)64 * K + k0, &As[buf][woff + 64 * 32]);
        gload16(Bg + k0, &Bs[buf][woff]);
        gload16(Bg + (size_t)64 * K + k0, &Bs[buf][woff + 64 * 32]);
    };
    auto compute = [&](int buf) {
        bf16x8 af[4], bfr[4];
        #pragma unroll
        for (int mi = 0; mi < 4; ++mi)
            af[mi] = *(const bf16x8*)&As[buf][(wm * 64 + mi * 16 + lm) * 32 + lk * 8];
        #pragma unroll
        for (int nj = 0; nj < 4; ++nj)
            bfr[nj] = *(const bf16x8*)&Bs[buf][(wn * 64 + nj * 16 + lm) * 32 + lk * 8];
        #pragma unroll
        for (int mi = 0; mi < 4; ++mi)
            #pragma unroll
            for (int nj = 0; nj < 4; ++nj)
                acc[mi][nj] = __builtin_amdgcn_mfma_f32_16x16x32_bf16(
                    af[mi], bfr[nj], acc[mi][nj], 0, 0, 0);
    };

    const int nt = K >> 5;           // # of 32-wide K tiles (always even here)
    stage(0, 0);
    __syncthreads();                 // drains vmcnt(0): tile 0 ready
    for (int t = 0; t < nt; t += 2) {
        stage((t + 1) << 5, 1);      // in flight during compute of buf0
        compute(0);
        __syncthreads();             // vmcnt(0)+barrier: buf1 ready, buf0 free
        if (t + 2 < nt) stage((t + 2) << 5, 0);
        compute(1);
        __syncthreads();             // buf0 ready (or final drain)
    }

    const float* bs = bias;
    OutT* dst = C;
    int cadj = 0;
    if (MODE == MODE_SILU_UV && col0 >= D1) { bs = bias2; dst = C2; cadj = D1; }

    float bcol[4];
    #pragma unroll
    for (int nj = 0; nj < 4; ++nj)
        bcol[nj] = bs[col0 - cadj + wn * 64 + nj * 16 + lm];

    if (MODE == MODE_RPE) {
        #pragma unroll
        for (int mi = 0; mi < 4; ++mi) {
            #pragma unroll
            for (int r = 0; r < 4; ++r) {
                const int row = row0 + wm * 64 + mi * 16 + lk * 4 + r;
                float sc = 1.0f;
                if (scale_in)
                    sc = 1.0f / (sqrtf(scale_in[row]) * 0.04419417382415922f + 1e-8f);
                float ssq = 0.0f;
                #pragma unroll
                for (int nj = 0; nj < 4; ++nj) {
                    const int col = col0 + wn * 64 + nj * 16 + lm;
                    float val = acc[mi][nj][r] * sc + bcol[nj];
                    ssq += val * val;
                    ((bf16*)C)[(size_t)row * Nc + col] = (bf16)fmaxf(val, 0.0f);
                }
                ssq += __shfl_xor(ssq, 1, 64);
                ssq += __shfl_xor(ssq, 2, 64);
                ssq += __shfl_xor(ssq, 4, 64);
                ssq += __shfl_xor(ssq, 8, 64);
                if (lm == 0) atomicAdd(&sumsq_out[row], ssq);
            }
        }
        return;
    }

    #pragma unroll
    for (int mi = 0; mi < 4; ++mi) {
        const int rbase = row0 + wm * 64 + mi * 16 + lk * 4;
        float sc[4];
        #pragma unroll
        for (int r = 0; r < 4; ++r) {
            sc[r] = 1.0f;
            if (MODE == MODE_AT && scale_in)
                sc[r] = 1.0f / (sqrtf(scale_in[rbase + r]) * 0.04419417382415922f + 1e-8f);
        }
        #pragma unroll
        for (int nj = 0; nj < 4; ++nj) {
            const int col = col0 - cadj + wn * 64 + nj * 16 + lm;
            float vals[4];
            #pragma unroll
            for (int r = 0; r < 4; ++r) {
                float val = acc[mi][nj][r] * sc[r] + bcol[nj];
                if (MODE == MODE_SILU_UV)
                    val = val / (1.0f + __expf(-val));
                vals[r] = val;
            }
            if (MODE == MODE_SILU_UV) {
                int b = rbase >> 11, s = rbase & 2047;
                bf16x4 o;
                #pragma unroll
                for (int r = 0; r < 4; ++r) o[r] = (bf16)vals[r];
                *(bf16x4*)&((bf16*)dst)[((size_t)(b * D1 + col)) * N_SEQ + s] = o;
            } else if (MODE == MODE_AT) {
                float4 o = make_float4(vals[0], vals[1], vals[2], vals[3]);
                *(float4*)&((float*)C)[(size_t)col * M + rbase] = o;
            } else {
                #pragma unroll
                for (int r = 0; r < 4; ++r)
                    C[(size_t)(rbase + r) * Nc + col] = (OutT)vals[r];
            }
        }
    }
}

// ---------------------------------------------------------------------------
// mega-prologue: x convert + 5 weight converts + sumsq zero +
// RPE input layer w/ srms + FFT twiddle table (256 x 16 cx)
// ---------------------------------------------------------------------------
__global__ __launch_bounds__(256) void f2b_all_kernel(
    const float* __restrict__ x,  const float* __restrict__ s0,
    const float* __restrict__ s1, const float* __restrict__ s2,
    const float* __restrict__ s3, const float* __restrict__ s4,
    const float* __restrict__ Wp, const float* __restrict__ bp,
    bf16* __restrict__ x_bf, bf16* __restrict__ w_bf,
    float* __restrict__ sumsq, bf16* __restrict__ g0,
    float* __restrict__ twd)
{
    const int bid = blockIdx.x;
    const int tid = threadIdx.x;
    __shared__ float red[4];

    if (bid < 7936) {
        const float* src;
        bf16* dst;
        size_t off;
        if (bid < 4096) {
            src = x; dst = x_bf; off = (size_t)bid * 1024;
        } else {
            int t = bid - 4096;
            int seg = t / 768;
            src = seg == 0 ? s0 : seg == 1 ? s1 : seg == 2 ? s2
                : seg == 3 ? s3 : s4;
            dst = w_bf + (size_t)seg * 786432;
            off = (size_t)(t % 768) * 1024;
        }
        size_t i = off + (size_t)tid * 4;
        float4 f = *(const float4*)(src + i);
        union { bf16 h[4]; short4 s; } u4;
        u4.h[0] = (bf16)f.x; u4.h[1] = (bf16)f.y;
        u4.h[2] = (bf16)f.z; u4.h[3] = (bf16)f.w;
        *(short4*)(dst + i) = u4.s;
    } else if (bid < 7948) {
        size_t i = (size_t)(bid - 7936) * 1024 + (size_t)tid * 4;
        *(float4*)(sumsq + i) = make_float4(0.f, 0.f, 0.f, 0.f);
    } else if (bid < 12044) {
        const int j = bid - 7948;
        float idxv = (j < N_SEQ) ? (float)j
                                 : (j == N_SEQ ? 0.0f : (float)(j - 2 * N_SEQ));
        float h1 = idxv * Wp[tid] + bp[tid];
        float h2 = idxv * Wp[tid + 256] + bp[tid + 256];
        float ss = h1 * h1 + h2 * h2;
        #pragma unroll
        for (int off = 32; off > 0; off >>= 1) ss += __shfl_down(ss, off, 64);
        if ((tid & 63) == 0) red[tid >> 6] = ss;
        __syncthreads();
        float tot = red[0] + red[1] + red[2] + red[3];
        float scale = 1.0f / (sqrtf(tot) * 0.04419417382415922f + 1e-8f);
        g0[(size_t)j * ED + tid]       = (bf16)fmaxf(h1 * scale, 0.0f);
        g0[(size_t)j * ED + tid + 256] = (bf16)fmaxf(h2 * scale, 0.0f);
    } else {
        const int idx = (bid - 12044) * 256 + tid;    // [0, 4096)
        const int j = idx >> 4, tau = idx & 15;
        float sA, cA;
        __sincosf(-6.283185307179586f * (float)(j * tau) * (1.0f / 4096.0f),
                  &sA, &cA);
        cx w; w.x = cA; w.y = sA;
        ((cx*)twd)[idx] = w;
    }
}

// ---------------------------------------------------------------------------
// Radix-16 FFT, radix-4 butterflies, packed-fp32 complex.
// LDS addressing: fpad(base + s*t) = fpad(base) + s'*t  (256->274, 16->17, 1->1)
// Stage-1/inv-3 twiddle row (tid<<4) in REGISTERS (inverse = conjugate);
// stage-2/inv-2 rows (16 distinct) in a 2 KB LDS broadcast table.
// ---------------------------------------------------------------------------
#define FFT_LDS_SZ 4381

__device__ __forceinline__ int fpad(int i) { return i + (i >> 4) + 2 * (i >> 8); }

__device__ __forceinline__ cx mkcx(float a, float b) { cx r; r.x = a; r.y = b; return r; }
__device__ __forceinline__ cx cmul(cx a, cx b) {
    cx br = mkcx(-b.y, b.x);
    return a.xx * b + a.yy * br;
}
__device__ __forceinline__ cx cmul_cj(cx a, cx b) {      // a * conj(b)
    cx bc = mkcx(b.x, -b.y);
    cx br = mkcx(b.y, b.x);
    return a.xx * bc + a.yy * br;
}
__device__ __forceinline__ cx cneg_i(cx a) { return mkcx(a.y, -a.x); }   // a * (-i)
__device__ __forceinline__ cx cpos_i(cx a) { return mkcx(-a.y, a.x); }   // a * (+i)
__host__ __device__ constexpr int brev4(int t) {
    return ((t & 1) << 3) | ((t & 2) << 1) | ((t & 4) >> 1) | ((t & 8) >> 3);
}

#define CC1 0.9238795325112867f
#define SS1 0.3826834323650898f
#define RR2 0.7071067811865476f

template<bool HZ>
__device__ __forceinline__ void fft16_dif_r4(cx x[16]) {
    const cx W1 = mkcx( CC1, -SS1);
    const cx W2 = mkcx( RR2, -RR2);
    const cx W3 = mkcx( SS1, -CC1);
    const cx W6 = mkcx(-RR2, -RR2);
    const cx W9 = mkcx(-CC1,  SS1);
    #pragma unroll
    for (int n = 0; n < 4; ++n) {
        cx A, B, C, D;
        if (HZ) { A = x[n]; C = x[n]; B = x[n + 4]; D = x[n + 4]; }
        else {
            A = x[n] + x[n + 8];      C = x[n] - x[n + 8];
            B = x[n + 4] + x[n + 12]; D = x[n + 4] - x[n + 12];
        }
        cx s = A - B;
        cx nid = cneg_i(D);
        cx m = C + nid;
        cx p = C - nid;
        x[n] = A + B;
        if (n == 0)      { x[4] = s;            x[8]  = m;           x[12] = p; }
        else if (n == 1) { x[5] = cmul(s, W2);  x[9]  = cmul(m, W1); x[13] = cmul(p, W3); }
        else if (n == 2) { x[6] = cneg_i(s);    x[10] = cmul(m, W2); x[14] = cmul(p, W6); }
        else             { x[7] = cmul(s, W6);  x[11] = cmul(m, W3); x[15] = cmul(p, W9); }
    }
    #pragma unroll
    for (int q = 0; q < 16; q += 4) {
        cx a = x[q], b = x[q + 1], c = x[q + 2], d = x[q + 3];
        cx a1 = a + c, c1 = a - c;
        cx b1 = b + d, d1 = cneg_i(b - d);
        x[q]     = a1 + b1;
        x[q + 1] = a1 - b1;
        x[q + 2] = c1 + d1;
        x[q + 3] = c1 - d1;
    }
}

template<bool HALF_OUT>
__device__ __forceinline__ void fft16_dit_inv_r4(cx x[16]) {
    const cx V1 = mkcx( CC1, SS1);
    const cx V2 = mkcx( RR2, RR2);
    const cx V3 = mkcx( SS1, CC1);
    const cx V6 = mkcx(-RR2, RR2);
    #pragma unroll
    for (int q = 0; q < 16; q += 4) {
        cx a = x[q], b = x[q + 1], c = x[q + 2], d = x[q + 3];
        cx a1 = a + b, b1 = a - b;
        cx c1 = c + d, d1 = c - d;
        cx t = cpos_i(d1);
        x[q]     = a1 + c1;
        x[q + 2] = a1 - c1;
        x[q + 1] = b1 + t;
        x[q + 3] = b1 - t;
    }
    #pragma unroll
    for (int n = 0; n < 4; ++n) {
        cx t1, t2;
        if (n == 0)      { t1 = x[4];             t2 = x[12]; }
        else if (n == 1) { t1 = cmul(x[5],  V2);  t2 = cmul(x[13], V2); }
        else if (n == 2) { t1 = cpos_i(x[6]);     t2 = cpos_i(x[14]); }
        else             { t1 = cmul(x[7],  V6);  t2 = cmul(x[15], V6); }
        cx P = x[n] + t1, Q = x[n] - t1;
        cx R = x[n + 8] + t2, S = x[n + 8] - t2;
        cx t, u;
        if (n == 0)      { t = R;            u = S; }
        else if (n == 1) { t = cmul(R, V1);  u = cmul(S, V1); }
        else if (n == 2) { t = cmul(R, V2);  u = cmul(S, V2); }
        else             { t = cmul(R, V3);  u = cmul(S, V3); }
        cx iu = cpos_i(u);
        x[n]     = P + t;
        x[n + 4] = Q + iu;
        if (!HALF_OUT) {
            x[n + 8]  = P - t;
            x[n + 12] = Q - iu;
        }
    }
}

template<bool CONJ>
__device__ __forceinline__ void apply_tw(cx v[16], const cx tw[16]) {
    #pragma unroll
    for (int tau = 1; tau < 16; ++tau) {
        const int q = brev4(tau);
        v[q] = CONJ ? cmul_cj(v[q], tw[tau]) : cmul(v[q], tw[tau]);
    }
}

// twrow points at tw2lds + (tid&15); stride 16 per tau. Broadcast reads.
template<bool CONJ>
__device__ __forceinline__ void apply_tw_lds(cx v[16], const cx* twrow) {
    #pragma unroll
    for (int tau = 1; tau < 16; ++tau) {
        cx w = twrow[tau * 16];
        const int q = brev4(tau);
        v[q] = CONJ ? cmul_cj(v[q], w) : cmul(v[q], w);
    }
}

// ---- per-stage helpers (in-place per-thread; caller places barriers) ------
__device__ __forceinline__ void fwd_s1_store_hz(
    const cx vin[8], const cx tw[16], cx* d, int tid)
{
    cx x[16];
    #pragma unroll
    for (int t = 0; t < 8; ++t) x[t] = vin[t];
    fft16_dif_r4<true>(x);
    apply_tw<false>(x, tw);
    cx* base = d + fpad(tid);
    #pragma unroll
    for (int p = 0; p < 16; ++p) base[274 * p] = x[p];
}

__device__ __forceinline__ void fwd_s2(cx* d, int tid, const cx* tw2lds)
{
    cx v[16];
    cx* base = d + fpad(((tid >> 4) << 8) + (tid & 15));
    #pragma unroll
    for (int t = 0; t < 16; ++t) v[t] = base[17 * t];
    fft16_dif_r4<false>(v);
    apply_tw_lds<false>(v, tw2lds + (tid & 15));
    #pragma unroll
    for (int p = 0; p < 16; ++p) base[17 * p] = v[p];
}

__device__ __forceinline__ void fwd_s3(cx* d, int tid)
{
    cx v[16];
    cx* base = d + fpad(tid << 4);
    #pragma unroll
    for (int t = 0; t < 16; ++t) v[t] = base[t];
    fft16_dif_r4<false>(v);
    #pragma unroll
    for (int p = 0; p < 16; ++p) base[p] = v[p];
}

__device__ __forceinline__ void inv_s2(cx* d, int tid, const cx* tw2lds)
{
    cx v[16];
    cx* base = d + fpad(((tid >> 4) << 8) + (tid & 15));
    #pragma unroll
    for (int p = 0; p < 16; ++p) v[p] = base[17 * p];
    apply_tw_lds<true>(v, tw2lds + (tid & 15));
    fft16_dit_inv_r4<false>(v);
    #pragma unroll
    for (int t = 0; t < 16; ++t) base[17 * t] = v[t];
}

__device__ __forceinline__ void inv_s3_half(cx* d, int tid, const cx tw[16])
{
    cx v[16];
    cx* base = d + fpad(tid);
    #pragma unroll
    for (int p = 0; p < 16; ++p) v[p] = base[274 * p];
    apply_tw<true>(v, tw);
    fft16_dit_inv_r4<true>(v);
    #pragma unroll
    for (int t = 0; t < 8; ++t) base[274 * t] = v[t];
}

// pointwise: read Z partners from d, multiply with A spectra (regs), -> v
__device__ __forceinline__ void pointwise_read(
    const cx* d, int tid, const float4 a0pf[8], const float4 a1pf[8],
    cx v[16])
{
    auto pf = [](const float4* p, int i) -> cx {
        return (i & 1) ? mkcx(p[i >> 1].z, p[i >> 1].w)
                       : mkcx(p[i >> 1].x, p[i >> 1].y);
    };
    const int pbase = tid << 4;
    if (tid == 0) {
        #pragma unroll
        for (int i = 0; i < 16; ++i) {
            const int p2 = (i < 2) ? i : (i ^ ((1 << (31 - __clz(i))) - 1));
            cx Zk = d[fpad(i)];
            cx Zm = d[fpad(p2)];
            cx cjZm = mkcx(Zm.x, -Zm.y);
            cx V0 = Zk + cjZm;
            cx V1 = cneg_i(Zk - cjZm);
            v[i] = cmul(V0, pf(a0pf, i)) + cpos_i(cmul(V1, pf(a1pf, i)));
        }
    } else {
        const int mask = (1 << (31 - __clz(pbase))) - 1;
        const cx* zb  = d + fpad(pbase);
        const cx* zb2 = d + fpad((pbase ^ mask) - 15);
        #pragma unroll
        for (int i = 0; i < 16; ++i) {
            cx Zk = zb[i];
            cx Zm = zb2[15 - i];
            cx cjZm = mkcx(Zm.x, -Zm.y);
            cx V0 = Zk + cjZm;
            cx V1 = cneg_i(Zk - cjZm);
            v[i] = cmul(V0, pf(a0pf, i)) + cpos_i(cmul(V1, pf(a1pf, i)));
        }
    }
}

// Forward 4096-FFT (single-chunk path, used by fft_a).
template<bool HALF_ZERO>
__device__ __forceinline__ void fft4096_fwd_core(
    cx* d, int tid, const cx tw[16], const cx* tw2lds, cx v[16])
{
    {
        fft16_dif_r4<HALF_ZERO>(v);
        apply_tw<false>(v, tw);
        cx* base = d + fpad(tid);
        #pragma unroll
        for (int p = 0; p < 16; ++p) base[274 * p] = v[p];
    }
    __syncthreads();
    fwd_s2(d, tid, tw2lds);
    __syncthreads();
    fwd_s3(d, tid);
    __syncthreads();
}

// ---------------------------------------------------------------------------
// Forward FFT of packed (a_ch0, a_ch1) pair, unpack both real spectra in
// DIF order (conjugate-partner: p2 = p ^ (2^floor(log2 p) - 1)).
// A0 = c*(Wk + conj(Wm)), A1 = c*(-i)*(Wk - conj(Wm)), c = 0.25/4096.
// ---------------------------------------------------------------------------
__global__ __launch_bounds__(256, 4) void fft_a_kernel(
    const float* a_t, cx* __restrict__ A0s, cx* A1s,
    const cx* __restrict__ Twd)
{
    __shared__ cx data[FFT_LDS_SZ];
    __shared__ cx tw2lds[256];
    const int tid = threadIdx.x;
    const int r = blockIdx.x;                      // pair index, ch = 2r

    cx tw[16];
    {
        const cx* Tr1 = Twd + (tid << 4);
        #pragma unroll
        for (int t = 1; t < 16; ++t) tw[t] = Tr1[t];
        tw2lds[(tid >> 4) * 16 + (tid & 15)] = Twd[(tid & 15) * 256 + (tid >> 4)];
    }

    const float* r0 = a_t + (size_t)(2 * r) * M_FFT;
    const float* r1 = r0 + M_FFT;
    cx v[16];
    #pragma unroll
    for (int t = 0; t < 16; ++t)
        v[t] = mkcx(r0[tid + 256 * t], r1[tid + 256 * t]);

    fft4096_fwd_core<false>(data, tid, tw, tw2lds, v);

    const float c = 0.25f / 4096.0f;
    cx* A0row = A0s + (size_t)r * 4096;
    cx* A1row = A1s + (size_t)r * 4096;
    if (tid == 0) {
        #pragma unroll
        for (int i = 0; i < 16; ++i) {
            const int p2 = (i < 2) ? i : (i ^ ((1 << (31 - __clz(i))) - 1));
            cx Wk = data[fpad(i)];
            cx Wm = data[fpad(p2)];
            cx cjWm = mkcx(Wm.x, -Wm.y);
            A0row[i] = c * (Wk + cjWm);
            A1row[i] = c * cneg_i(Wk - cjWm);
        }
    } else {
        const int base = tid << 4;
        const int mask = (1 << (31 - __clz(base))) - 1;
        const cx* zb  = data + fpad(base);
        const cx* zb2 = data + fpad((base ^ mask) - 15);
        #pragma unroll
        for (int i = 0; i < 16; ++i) {
            cx Wk = zb[i];
            cx Wm = zb2[15 - i];
            cx cjWm = mkcx(Wm.x, -Wm.y);
            A0row[base + i] = c * (Wk + cjWm);
            A1row[base + i] = c * cneg_i(Wk - cjWm);
        }
    }
}

// ---------------------------------------------------------------------------
// Conv kernel: TWO channel-pairs per block (batches 2bp and 2bp+1 of the
// SAME r) -> 2x work per barrier region, A rows loaded once for both.
// Bijective XCD remap: xcd = r&7; slots pair (r,bp=0),(r,bp=1) adjacent.
// ---------------------------------------------------------------------------
__global__ __launch_bounds__(256, 2) void fft_conv_kernel(
    const bf16* __restrict__ v_t, const cx* __restrict__ A0s,
    const cx* __restrict__ A1s, const bf16* __restrict__ u_t,
    bf16* __restrict__ gated_t, const cx* __restrict__ Twd)
{
    __shared__ cx data[2][FFT_LDS_SZ];
    __shared__ cx tw2lds[256];
    const int tid = threadIdx.x;
    const int bx = blockIdx.x;
    const int xcd  = bx & 7;
    const int slot = bx >> 3;                 // [0,192)
    const int bp   = slot & 1;
    const int r    = (slot >> 1) * 8 + xcd;   // [0,768), bijective
    const int ch   = 2 * r;
    const int b0   = 2 * bp;
    const int b1   = 2 * bp + 1;

    cx tw[16];
    {
        const cx* Tr1 = Twd + (tid << 4);
        #pragma unroll
        for (int t = 1; t < 16; ++t) tw[t] = Tr1[t];
        tw2lds[(tid >> 4) * 16 + (tid & 15)] = Twd[(tid & 15) * 256 + (tid >> 4)];
    }

    // ---- forward stage 1: both chunks straight from global ----
    const bf16* z00 = v_t + ((size_t)(b0 * D1 + ch)) * N_SEQ;
    const bf16* z01 = z00 + N_SEQ;
    const bf16* z10 = v_t + ((size_t)(b1 * D1 + ch)) * N_SEQ;
    const bf16* z11 = z10 + N_SEQ;
    {
        cx w0[8], w1[8];
        #pragma unroll
        for (int t = 0; t < 8; ++t)
            w0[t] = mkcx((float)z00[tid + 256 * t], (float)z01[tid + 256 * t]);
        #pragma unroll
        for (int t = 0; t < 8; ++t)
            w1[t] = mkcx((float)z10[tid + 256 * t], (float)z11[tid + 256 * t]);
        fwd_s1_store_hz(w0, tw, data[0], tid);
        fwd_s1_store_hz(w1, tw, data[1], tid);
    }
    __syncthreads();

    fwd_s2(data[0], tid, tw2lds);
    fwd_s2(data[1], tid, tw2lds);
    __syncthreads();

    // A rows (shared by both chunks): issue before stage-3 compute so the
    // pre-barrier vmcnt drain overlaps both chunks' stage 3.
    const int pbase = tid << 4;
    float4 a0pf[8], a1pf[8];
    {
        const float4* A0p = (const float4*)(A0s + (size_t)r * 4096 + pbase);
        const float4* A1p = (const float4*)(A1s + (size_t)r * 4096 + pbase);
        #pragma unroll
        for (int i = 0; i < 8; ++i) { a0pf[i] = A0p[i]; a1pf[i] = A1p[i]; }
    }
    fwd_s3(data[0], tid);
    fwd_s3(data[1], tid);
    __syncthreads();

    // ---- pointwise (A in regs, used twice) + inverse stage 1 ----
    cx vA[16], vB[16];
    pointwise_read(data[0], tid, a0pf, a1pf, vA);
    pointwise_read(data[1], tid, a0pf, a1pf, vB);
    __syncthreads();                       // all scattered Z reads done
    fft16_dit_inv_r4<false>(vA);
    fft16_dit_inv_r4<false>(vB);
    {
        cx* baseA = data[0] + fpad(pbase);
        cx* baseB = data[1] + fpad(pbase);
        #pragma unroll
        for (int i = 0; i < 16; ++i) baseA[i] = vA[i];
        #pragma unroll
        for (int i = 0; i < 16; ++i) baseB[i] = vB[i];
    }
    __syncthreads();

    // u rows: issue before inv stage 2 so drain overlaps it
    const bf16* u00 = u_t + ((size_t)(b0 * D1 + ch)) * N_SEQ;
    const bf16* u01 = u00 + N_SEQ;
    const bf16* u10 = u_t + ((size_t)(b1 * D1 + ch)) * N_SEQ;
    const bf16* u11 = u10 + N_SEQ;
    bf16x8 ua0 = *(const bf16x8*)(u00 + tid * 8);
    bf16x8 ub0 = *(const bf16x8*)(u01 + tid * 8);
    bf16x8 ua1 = *(const bf16x8*)(u10 + tid * 8);
    bf16x8 ub1 = *(const bf16x8*)(u11 + tid * 8);

    inv_s2(data[0], tid, tw2lds);
    inv_s2(data[1], tid, tw2lds);
    __syncthreads();

    inv_s3_half(data[0], tid, tw);
    inv_s3_half(data[1], tid, tw);
    __syncthreads();

    // ---- gate with u (1/M folded into A spectra) ----
    {
        const int t = tid * 8;
        bf16* g00 = gated_t + ((size_t)(b0 * D1 + ch)) * N_SEQ;
        bf16* g01 = g00 + N_SEQ;
        bf16* g10 = gated_t + ((size_t)(b1 * D1 + ch)) * N_SEQ;
        bf16* g11 = g10 + N_SEQ;
        const cx* baseA = data[0] + fpad(t);
        const cx* baseB = data[1] + fpad(t);
        bf16x8 oa, ob, oc, od;
        #pragma unroll
        for (int i = 0; i < 8; ++i) {
            cx ya = baseA[i];
            cx yb = baseB[i];
            oa[i] = (bf16)(ya.x * (float)ua0[i]);
            ob[i] = (bf16)(ya.y * (float)ub0[i]);
            oc[i] = (bf16)(yb.x * (float)ua1[i]);
            od[i] = (bf16)(yb.y * (float)ub1[i]);
        }
        *(bf16x8*)(g00 + t) = oa;
        *(bf16x8*)(g01 + t) = ob;
        *(bf16x8*)(g10 + t) = oc;
        *(bf16x8*)(g11 + t) = od;
    }
}

// ---------------------------------------------------------------------------
__global__ __launch_bounds__(256) void transpose_cs_kernel(
    const bf16* __restrict__ in, bf16* __restrict__ outp)
{
    __shared__ bf16 tile[64 * 68];
    const int c0 = blockIdx.x * 64;
    const int m0 = blockIdx.y * 64;
    const int b  = m0 >> 11;
    const int s0 = m0 & 2047;
    const int tid = threadIdx.x;
    const int cl = tid >> 4;
    const int sc = (tid & 15) * 4;
    #pragma unroll
    for (int p = 0; p < 4; ++p) {
        int c = p * 16 + cl;
        bf16x4 v = *(const bf16x4*)&in[((size_t)(b * D1 + c0 + c)) * N_SEQ + s0 + sc];
        *(bf16x4*)&tile[c * 68 + sc] = v;
    }
    __syncthreads();
    const int sl = tid >> 4;
    const int cc = (tid & 15) * 4;
    #pragma unroll
    for (int p = 0; p < 4; ++p) {
        int s = p * 16 + sl;
        bf16x4 o;
        #pragma unroll
        for (int j = 0; j < 4; ++j) o[j] = tile[(cc + j) * 68 + s];
        *(bf16x4*)&outp[((size_t)(m0 + s)) * D1 + c0 + cc] = o;
    }
}

// ---------------------------------------------------------------------------
extern "C" void kernel_launch(void* const* d_in, const int* in_sizes, int n_in,
                              void* d_out, int out_size, void* d_ws, size_t ws_size,
                              hipStream_t stream)
{
    const float* x  = (const float*)d_in[0];
    const float* Wu = (const float*)d_in[1];
    const float* bu = (const float*)d_in[2];
    const float* Wv = (const float*)d_in[3];
    const float* bv = (const float*)d_in[4];
    const float* Wo = (const float*)d_in[5];
    const float* bo = (const float*)d_in[6];
    const float* Wp = (const float*)d_in[7];
    const float* bp = (const float*)d_in[8];
    const float* Wl = (const float*)d_in[9];
    const float* bl = (const float*)d_in[10];
    const float* Wr = (const float*)d_in[11];
    const float* br = (const float*)d_in[12];
    float* out = (float*)d_out;

    float* ws      = (float*)d_ws;
    float* a_t     = ws;                       // 1536*4096 fp32; A1spec after fft_a
    float* A0spec  = a_t   + 6291456;          // 768 x 4096 cx
    float* sumsq   = A0spec + 6291456;         // 3 x 4096 fp32
    float* twd     = sumsq + 12288;            // 256 x 16 cx twiddle table
    bf16*  bfws    = (bf16*)(twd + 8192);
    bf16*  x_bf    = bfws;                     // 8192*512
    bf16*  w_bf    = x_bf    + 4194304;        // 5 x 786432: Wu,Wv,Wo,Wl,Wr
    bf16*  Wuv_bf  = w_bf;                     // stacked [Wu;Wv] 3072 x 512
    bf16*  Wo_bf   = w_bf    + 2 * 786432;
    bf16*  Wl_bf   = Wo_bf   + 786432;
    bf16*  Wr_bf   = Wl_bf   + 786432;
    bf16*  gA      = Wr_bf   + 786432;         // 4096*512
    bf16*  gB      = gA      + 2097152;        // 4096*512
    bf16*  u_t     = gB      + 2097152;        // 8192*1536 [b][c][s]
    bf16*  v_t     = u_t     + 12582912;       // 8192*1536 [b][c][s]
    bf16*  gated_t = v_t     + 12582912;       // 8192*1536 [b][c][s]
    bf16*  gated   = gated_t + 12582912;       // 8192*1536 [m][c]

    dim3 blk(256);

    // x/w converts + sumsq zero + rpe input layer + twiddle table
    f2b_all_kernel<<<4096 + 5 * 768 + 12 + 4096 + 16, blk, 0, stream>>>(
        x, Wu, Wv, Wo, Wl, Wr, Wp, bp, x_bf, w_bf, sumsq, gA, twd);

    gemm_bf16<MODE_SILU_UV, bf16><<<dim3(24, 64), blk, 0, stream>>>(
        x_bf, Wuv_bf, bu, bv, u_t, v_t, 8192, 2 * D1, ED, nullptr, nullptr);

    // RPE MLP: srms folded into GEMM epilogues via row-scale commutation
    bf16* gin = gA;
    bf16* gout = gB;
    for (int i = 0; i < 3; ++i) {
        const float* sin_p = (i == 0) ? nullptr : sumsq + (size_t)(i - 1) * 4096;
        gemm_bf16<MODE_RPE, bf16><<<dim3(4, 32), blk, 0, stream>>>(
            gin, Wl_bf + (size_t)i * ED * ED, bl + (size_t)i * ED, nullptr,
            gout, nullptr, 4096, ED, ED, sin_p, sumsq + (size_t)i * 4096);
        bf16* t = gin; gin = gout; gout = t;
    }
    gemm_bf16<MODE_AT, float><<<dim3(12, 32), blk, 0, stream>>>(
        gin, Wr_bf, br, nullptr, a_t, nullptr, 4096, D1, ED,
        sumsq + 2 * 4096, nullptr);

    fft_a_kernel<<<768, blk, 0, stream>>>(
        a_t, (cx*)A0spec, (cx*)a_t, (const cx*)twd);
    fft_conv_kernel<<<1536, blk, 0, stream>>>(
        v_t, (const cx*)A0spec, (const cx*)a_t, u_t, gated_t, (const cx*)twd);

    transpose_cs_kernel<<<dim3(24, 128), blk, 0, stream>>>(gated_t, gated);

    gemm_bf16<MODE_PLAIN, float><<<dim3(4, 64), blk, 0, stream>>>(
        gated, Wo_bf, bo, nullptr, out, nullptr, 8192, ED, D1,
        nullptr, nullptr);
}

// Round 6
// 341.868 us; speedup vs baseline: 1.1723x; 1.0309x over previous
//
#include <hip/hip_runtime.h>

#define N_SEQ 2048
#define M_FFT 4096
#define D1    1536
#define NH    8
#define HD    192
#define ED    512

typedef __bf16 bf16;
typedef __bf16 bf16x4 __attribute__((ext_vector_type(4)));
typedef __bf16 bf16x8 __attribute__((ext_vector_type(8)));
typedef float  floatx4 __attribute__((ext_vector_type(4)));
typedef float  cx __attribute__((ext_vector_type(2)));   // complex as packed fp32

enum { MODE_PLAIN = 0, MODE_SILU_UV = 1, MODE_AT = 3, MODE_RPE = 4 };

__device__ __forceinline__ void gload16(const void* g, void* l) {
    __builtin_amdgcn_global_load_lds(
        (const __attribute__((address_space(1))) void*)g,
        (__attribute__((address_space(3))) void*)l, 16, 0, 0);
}

// ---------------------------------------------------------------------------
// bf16 MFMA GEMM, depth-4 pipeline with COUNTED vmcnt (T4): 4 LDS buffers,
// 3 tiles always in flight, per step:
//   barrier(A)  : all waves done compute(t-1) -> buf[(t+3)&3] overwrite-safe
//   stage(t+3)
//   vmcnt(12)   : MY tile-t loads done (before barrier B for cross-wave vis)
//   barrier(B)  : ALL waves' tile-t loads done
//   compute(t)
// Raw s_barrier (no implicit vmcnt(0) drain). Requires K%128==0 (nt%4==0):
// K=512 -> nt=16, K=1536 -> nt=48.
// ---------------------------------------------------------------------------
template<int MODE, typename OutT>
__global__ __launch_bounds__(256) void gemm_bf16(
    const bf16* __restrict__ A, const bf16* __restrict__ Bw,
    const float* __restrict__ bias, const float* __restrict__ bias2,
    OutT* __restrict__ C, OutT* __restrict__ C2,
    int M, int Nc, int K,
    const float* __restrict__ scale_in, float* __restrict__ sumsq_out)
{
    __shared__ __align__(16) bf16 As[4][128 * 32];
    __shared__ __align__(16) bf16 Bs[4][128 * 32];

    const int tid  = threadIdx.x;
    const int row0 = blockIdx.y * 128;
    const int col0 = blockIdx.x * 128;
    const int wid  = tid >> 6;
    const int lane = tid & 63;
    const int lm   = lane & 15;
    const int lk   = lane >> 4;
    const int wm   = wid >> 1;
    const int wn   = wid & 1;
    const int ldrow  = tid >> 2;
    const int ldcol8 = (tid & 3) * 8;

    floatx4 acc[4][4] = {};

    const bf16* Ag = A  + ((size_t)(row0 + ldrow)) * K + ldcol8;
    const bf16* Bg = Bw + ((size_t)(col0 + ldrow)) * K + ldcol8;
    const int woff = (wid * 16) * 32;

    auto stage = [&](int t, int buf) {
        const int k0 = t << 5;
        gload16(Ag + k0, &As[buf][woff]);
        gload16(Ag + (size_t)64 * K + k0, &As[buf][woff + 64 * 32]);
        gload16(Bg + k0, &Bs[buf][woff]);
        gload16(Bg + (size_t)64 * K + k0, &Bs[buf][woff + 64 * 32]);
    };
    auto compute = [&](int buf) {
        bf16x8 af[4], bfr[4];
        #pragma unroll
        for (int mi = 0; mi < 4; ++mi)
            af[mi] = *(const bf16x8*)&As[buf][(wm * 64 + mi * 16 + lm) * 32 + lk * 8];
        #pragma unroll
        for (int nj = 0; nj < 4; ++nj)
            bfr[nj] = *(const bf16x8*)&Bs[buf][(wn * 64 + nj * 16 + lm) * 32 + lk * 8];
        #pragma unroll
        for (int mi = 0; mi < 4; ++mi)
            #pragma unroll
            for (int nj = 0; nj < 4; ++nj)
                acc[mi][nj] = __builtin_amdgcn_mfma_f32_16x16x32_bf16(
                    af[mi], bfr[nj], acc[mi][nj], 0, 0, 0);
    };

#define GEMM_STEP(T, BUF, DOSTAGE, VM)                                  \
    do {                                                                \
        __builtin_amdgcn_s_barrier();          /* A: compute(t-1) done */\
        __builtin_amdgcn_sched_barrier(0);                              \
        if (DOSTAGE) stage((T) + 3, ((T) + 3) & 3);                     \
        asm volatile("s_waitcnt vmcnt(" #VM ")" ::: "memory");          \
        __builtin_amdgcn_s_barrier();          /* B: tile T fully in LDS */\
        __builtin_amdgcn_sched_barrier(0);                              \
        compute(BUF);                                                   \
    } while (0)

    const int nt = K >> 5;           // 16 or 48; nt % 4 == 0
    stage(0, 0);
    stage(1, 1);
    stage(2, 2);
    for (int t4 = 0; t4 < nt - 4; t4 += 4) {
        GEMM_STEP(t4 + 0, 0, true, 12);
        GEMM_STEP(t4 + 1, 1, true, 12);
        GEMM_STEP(t4 + 2, 2, true, 12);
        GEMM_STEP(t4 + 3, 3, true, 12);
    }
    GEMM_STEP(nt - 4, 0, true, 12);  // stages tile nt-1 into buf 3
    GEMM_STEP(nt - 3, 1, false, 8);
    GEMM_STEP(nt - 2, 2, false, 4);
    GEMM_STEP(nt - 1, 3, false, 0);
#undef GEMM_STEP

    const float* bs = bias;
    OutT* dst = C;
    int cadj = 0;
    if (MODE == MODE_SILU_UV && col0 >= D1) { bs = bias2; dst = C2; cadj = D1; }

    float bcol[4];
    #pragma unroll
    for (int nj = 0; nj < 4; ++nj)
        bcol[nj] = bs[col0 - cadj + wn * 64 + nj * 16 + lm];

    if (MODE == MODE_RPE) {
        #pragma unroll
        for (int mi = 0; mi < 4; ++mi) {
            #pragma unroll
            for (int r = 0; r < 4; ++r) {
                const int row = row0 + wm * 64 + mi * 16 + lk * 4 + r;
                float sc = 1.0f;
                if (scale_in)
                    sc = 1.0f / (sqrtf(scale_in[row]) * 0.04419417382415922f + 1e-8f);
                float ssq = 0.0f;
                #pragma unroll
                for (int nj = 0; nj < 4; ++nj) {
                    const int col = col0 + wn * 64 + nj * 16 + lm;
                    float val = acc[mi][nj][r] * sc + bcol[nj];
                    ssq += val * val;
                    ((bf16*)C)[(size_t)row * Nc + col] = (bf16)fmaxf(val, 0.0f);
                }
                ssq += __shfl_xor(ssq, 1, 64);
                ssq += __shfl_xor(ssq, 2, 64);
                ssq += __shfl_xor(ssq, 4, 64);
                ssq += __shfl_xor(ssq, 8, 64);
                if (lm == 0) atomicAdd(&sumsq_out[row], ssq);
            }
        }
        return;
    }

    #pragma unroll
    for (int mi = 0; mi < 4; ++mi) {
        const int rbase = row0 + wm * 64 + mi * 16 + lk * 4;
        float sc[4];
        #pragma unroll
        for (int r = 0; r < 4; ++r) {
            sc[r] = 1.0f;
            if (MODE == MODE_AT && scale_in)
                sc[r] = 1.0f / (sqrtf(scale_in[rbase + r]) * 0.04419417382415922f + 1e-8f);
        }
        #pragma unroll
        for (int nj = 0; nj < 4; ++nj) {
            const int col = col0 - cadj + wn * 64 + nj * 16 + lm;
            float vals[4];
            #pragma unroll
            for (int r = 0; r < 4; ++r) {
                float val = acc[mi][nj][r] * sc[r] + bcol[nj];
                if (MODE == MODE_SILU_UV)
                    val = val * __fdividef(1.0f, 1.0f + __expf(-val));
                vals[r] = val;
            }
            if (MODE == MODE_SILU_UV) {
                int b = rbase >> 11, s = rbase & 2047;
                bf16x4 o;
                #pragma unroll
                for (int r = 0; r < 4; ++r) o[r] = (bf16)vals[r];
                *(bf16x4*)&((bf16*)dst)[((size_t)(b * D1 + col)) * N_SEQ + s] = o;
            } else if (MODE == MODE_AT) {
                float4 o = make_float4(vals[0], vals[1], vals[2], vals[3]);
                *(float4*)&((float*)C)[(size_t)col * M + rbase] = o;
            } else {
                #pragma unroll
                for (int r = 0; r < 4; ++r)
                    C[(size_t)(rbase + r) * Nc + col] = (OutT)vals[r];
            }
        }
    }
}

// ---------------------------------------------------------------------------
// mega-prologue: x convert + 5 weight converts + sumsq zero +
// RPE input layer w/ srms + FFT twiddle table (256 x 16 cx)
// ---------------------------------------------------------------------------
__global__ __launch_bounds__(256) void f2b_all_kernel(
    const float* __restrict__ x,  const float* __restrict__ s0,
    const float* __restrict__ s1, const float* __restrict__ s2,
    const float* __restrict__ s3, const float* __restrict__ s4,
    const float* __restrict__ Wp, const float* __restrict__ bp,
    bf16* __restrict__ x_bf, bf16* __restrict__ w_bf,
    float* __restrict__ sumsq, bf16* __restrict__ g0,
    float* __restrict__ twd)
{
    const int bid = blockIdx.x;
    const int tid = threadIdx.x;
    __shared__ float red[4];

    if (bid < 7936) {
        const float* src;
        bf16* dst;
        size_t off;
        if (bid < 4096) {
            src = x; dst = x_bf; off = (size_t)bid * 1024;
        } else {
            int t = bid - 4096;
            int seg = t / 768;
            src = seg == 0 ? s0 : seg == 1 ? s1 : seg == 2 ? s2
                : seg == 3 ? s3 : s4;
            dst = w_bf + (size_t)seg * 786432;
            off = (size_t)(t % 768) * 1024;
        }
        size_t i = off + (size_t)tid * 4;
        float4 f = *(const float4*)(src + i);
        union { bf16 h[4]; short4 s; } u4;
        u4.h[0] = (bf16)f.x; u4.h[1] = (bf16)f.y;
        u4.h[2] = (bf16)f.z; u4.h[3] = (bf16)f.w;
        *(short4*)(dst + i) = u4.s;
    } else if (bid < 7948) {
        size_t i = (size_t)(bid - 7936) * 1024 + (size_t)tid * 4;
        *(float4*)(sumsq + i) = make_float4(0.f, 0.f, 0.f, 0.f);
    } else if (bid < 12044) {
        const int j = bid - 7948;
        float idxv = (j < N_SEQ) ? (float)j
                                 : (j == N_SEQ ? 0.0f : (float)(j - 2 * N_SEQ));
        float h1 = idxv * Wp[tid] + bp[tid];
        float h2 = idxv * Wp[tid + 256] + bp[tid + 256];
        float ss = h1 * h1 + h2 * h2;
        #pragma unroll
        for (int off = 32; off > 0; off >>= 1) ss += __shfl_down(ss, off, 64);
        if ((tid & 63) == 0) red[tid >> 6] = ss;
        __syncthreads();
        float tot = red[0] + red[1] + red[2] + red[3];
        float scale = 1.0f / (sqrtf(tot) * 0.04419417382415922f + 1e-8f);
        g0[(size_t)j * ED + tid]       = (bf16)fmaxf(h1 * scale, 0.0f);
        g0[(size_t)j * ED + tid + 256] = (bf16)fmaxf(h2 * scale, 0.0f);
    } else {
        const int idx = (bid - 12044) * 256 + tid;    // [0, 4096)
        const int j = idx >> 4, tau = idx & 15;
        float sA, cA;
        __sincosf(-6.283185307179586f * (float)(j * tau) * (1.0f / 4096.0f),
                  &sA, &cA);
        cx w; w.x = cA; w.y = sA;
        ((cx*)twd)[idx] = w;
    }
}

// ---------------------------------------------------------------------------
// Radix-16 FFT, radix-4 butterflies, packed-fp32 complex.
// LDS addressing: fpad(base + s*t) = fpad(base) + s'*t  (256->274, 16->17, 1->1)
// Stage-1/inv-3 twiddle row (tid<<4) in REGISTERS (inverse = conjugate);
// stage-2/inv-2 rows (16 distinct) in a 2 KB LDS broadcast table.
// ---------------------------------------------------------------------------
#define FFT_LDS_SZ 4381

__device__ __forceinline__ int fpad(int i) { return i + (i >> 4) + 2 * (i >> 8); }

__device__ __forceinline__ cx mkcx(float a, float b) { cx r; r.x = a; r.y = b; return r; }
__device__ __forceinline__ cx cmul(cx a, cx b) {
    cx br = mkcx(-b.y, b.x);
    return a.xx * b + a.yy * br;
}
__device__ __forceinline__ cx cmul_cj(cx a, cx b) {      // a * conj(b)
    cx bc = mkcx(b.x, -b.y);
    cx br = mkcx(b.y, b.x);
    return a.xx * bc + a.yy * br;
}
__device__ __forceinline__ cx cneg_i(cx a) { return mkcx(a.y, -a.x); }   // a * (-i)
__device__ __forceinline__ cx cpos_i(cx a) { return mkcx(-a.y, a.x); }   // a * (+i)
__host__ __device__ constexpr int brev4(int t) {
    return ((t & 1) << 3) | ((t & 2) << 1) | ((t & 4) >> 1) | ((t & 8) >> 3);
}

#define CC1 0.9238795325112867f
#define SS1 0.3826834323650898f
#define RR2 0.7071067811865476f

template<bool HZ>
__device__ __forceinline__ void fft16_dif_r4(cx x[16]) {
    const cx W1 = mkcx( CC1, -SS1);
    const cx W2 = mkcx( RR2, -RR2);
    const cx W3 = mkcx( SS1, -CC1);
    const cx W6 = mkcx(-RR2, -RR2);
    const cx W9 = mkcx(-CC1,  SS1);
    #pragma unroll
    for (int n = 0; n < 4; ++n) {
        cx A, B, C, D;
        if (HZ) { A = x[n]; C = x[n]; B = x[n + 4]; D = x[n + 4]; }
        else {
            A = x[n] + x[n + 8];      C = x[n] - x[n + 8];
            B = x[n + 4] + x[n + 12]; D = x[n + 4] - x[n + 12];
        }
        cx s = A - B;
        cx nid = cneg_i(D);
        cx m = C + nid;
        cx p = C - nid;
        x[n] = A + B;
        if (n == 0)      { x[4] = s;            x[8]  = m;           x[12] = p; }
        else if (n == 1) { x[5] = cmul(s, W2);  x[9]  = cmul(m, W1); x[13] = cmul(p, W3); }
        else if (n == 2) { x[6] = cneg_i(s);    x[10] = cmul(m, W2); x[14] = cmul(p, W6); }
        else             { x[7] = cmul(s, W6);  x[11] = cmul(m, W3); x[15] = cmul(p, W9); }
    }
    #pragma unroll
    for (int q = 0; q < 16; q += 4) {
        cx a = x[q], b = x[q + 1], c = x[q + 2], d = x[q + 3];
        cx a1 = a + c, c1 = a - c;
        cx b1 = b + d, d1 = cneg_i(b - d);
        x[q]     = a1 + b1;
        x[q + 1] = a1 - b1;
        x[q + 2] = c1 + d1;
        x[q + 3] = c1 - d1;
    }
}

template<bool HALF_OUT>
__device__ __forceinline__ void fft16_dit_inv_r4(cx x[16]) {
    const cx V1 = mkcx( CC1, SS1);
    const cx V2 = mkcx( RR2, RR2);
    const cx V3 = mkcx( SS1, CC1);
    const cx V6 = mkcx(-RR2, RR2);
    #pragma unroll
    for (int q = 0; q < 16; q += 4) {
        cx a = x[q], b = x[q + 1], c = x[q + 2], d = x[q + 3];
        cx a1 = a + b, b1 = a - b;
        cx c1 = c + d, d1 = c - d;
        cx t = cpos_i(d1);
        x[q]     = a1 + c1;
        x[q + 2] = a1 - c1;
        x[q + 1] = b1 + t;
        x[q + 3] = b1 - t;
    }
    #pragma unroll
    for (int n = 0; n < 4; ++n) {
        cx t1, t2;
        if (n == 0)      { t1 = x[4];             t2 = x[12]; }
        else if (n == 1) { t1 = cmul(x[5],  V2);  t2 = cmul(x[13], V2); }
        else if (n == 2) { t1 = cpos_i(x[6]);     t2 = cpos_i(x[14]); }
        else             { t1 = cmul(x[7],  V6);  t2 = cmul(x[15], V6); }
        cx P = x[n] + t1, Q = x[n] - t1;
        cx R = x[n + 8] + t2, S = x[n + 8] - t2;
        cx t, u;
        if (n == 0)      { t = R;            u = S; }
        else if (n == 1) { t = cmul(R, V1);  u = cmul(S, V1); }
        else if (n == 2) { t = cmul(R, V2);  u = cmul(S, V2); }
        else             { t = cmul(R, V3);  u = cmul(S, V3); }
        cx iu = cpos_i(u);
        x[n]     = P + t;
        x[n + 4] = Q + iu;
        if (!HALF_OUT) {
            x[n + 8]  = P - t;
            x[n + 12] = Q - iu;
        }
    }
}

template<bool CONJ>
__device__ __forceinline__ void apply_tw(cx v[16], const cx tw[16]) {
    #pragma unroll
    for (int tau = 1; tau < 16; ++tau) {
        const int q = brev4(tau);
        v[q] = CONJ ? cmul_cj(v[q], tw[tau]) : cmul(v[q], tw[tau]);
    }
}

// twrow points at tw2lds + (tid&15); stride 16 per tau. Broadcast reads.
template<bool CONJ>
__device__ __forceinline__ void apply_tw_lds(cx v[16], const cx* twrow) {
    #pragma unroll
    for (int tau = 1; tau < 16; ++tau) {
        cx w = twrow[tau * 16];
        const int q = brev4(tau);
        v[q] = CONJ ? cmul_cj(v[q], w) : cmul(v[q], w);
    }
}

// ---- per-stage helpers (in-place per-thread; caller places barriers) ------
__device__ __forceinline__ void fwd_s1_store_hz(
    const cx vin[8], const cx tw[16], cx* d, int tid)
{
    cx x[16];
    #pragma unroll
    for (int t = 0; t < 8; ++t) x[t] = vin[t];
    fft16_dif_r4<true>(x);
    apply_tw<false>(x, tw);
    cx* base = d + fpad(tid);
    #pragma unroll
    for (int p = 0; p < 16; ++p) base[274 * p] = x[p];
}

__device__ __forceinline__ void fwd_s2(cx* d, int tid, const cx* tw2lds)
{
    cx v[16];
    cx* base = d + fpad(((tid >> 4) << 8) + (tid & 15));
    #pragma unroll
    for (int t = 0; t < 16; ++t) v[t] = base[17 * t];
    fft16_dif_r4<false>(v);
    apply_tw_lds<false>(v, tw2lds + (tid & 15));
    #pragma unroll
    for (int p = 0; p < 16; ++p) base[17 * p] = v[p];
}

__device__ __forceinline__ void fwd_s3(cx* d, int tid)
{
    cx v[16];
    cx* base = d + fpad(tid << 4);
    #pragma unroll
    for (int t = 0; t < 16; ++t) v[t] = base[t];
    fft16_dif_r4<false>(v);
    #pragma unroll
    for (int p = 0; p < 16; ++p) base[p] = v[p];
}

__device__ __forceinline__ void inv_s2(cx* d, int tid, const cx* tw2lds)
{
    cx v[16];
    cx* base = d + fpad(((tid >> 4) << 8) + (tid & 15));
    #pragma unroll
    for (int p = 0; p < 16; ++p) v[p] = base[17 * p];
    apply_tw_lds<true>(v, tw2lds + (tid & 15));
    fft16_dit_inv_r4<false>(v);
    #pragma unroll
    for (int t = 0; t < 16; ++t) base[17 * t] = v[t];
}

__device__ __forceinline__ void inv_s3_half(cx* d, int tid, const cx tw[16])
{
    cx v[16];
    cx* base = d + fpad(tid);
    #pragma unroll
    for (int p = 0; p < 16; ++p) v[p] = base[274 * p];
    apply_tw<true>(v, tw);
    fft16_dit_inv_r4<true>(v);
    #pragma unroll
    for (int t = 0; t < 8; ++t) base[274 * t] = v[t];
}

// pointwise: read Z partners from d, multiply with A spectra (regs), -> v
__device__ __forceinline__ void pointwise_read(
    const cx* d, int tid, const float4 a0pf[8], const float4 a1pf[8],
    cx v[16])
{
    auto pf = [](const float4* p, int i) -> cx {
        return (i & 1) ? mkcx(p[i >> 1].z, p[i >> 1].w)
                       : mkcx(p[i >> 1].x, p[i >> 1].y);
    };
    const int pbase = tid << 4;
    if (tid == 0) {
        #pragma unroll
        for (int i = 0; i < 16; ++i) {
            const int p2 = (i < 2) ? i : (i ^ ((1 << (31 - __clz(i))) - 1));
            cx Zk = d[fpad(i)];
            cx Zm = d[fpad(p2)];
            cx cjZm = mkcx(Zm.x, -Zm.y);
            cx V0 = Zk + cjZm;
            cx V1 = cneg_i(Zk - cjZm);
            v[i] = cmul(V0, pf(a0pf, i)) + cpos_i(cmul(V1, pf(a1pf, i)));
        }
    } else {
        const int mask = (1 << (31 - __clz(pbase))) - 1;
        const cx* zb  = d + fpad(pbase);
        const cx* zb2 = d + fpad((pbase ^ mask) - 15);
        #pragma unroll
        for (int i = 0; i < 16; ++i) {
            cx Zk = zb[i];
            cx Zm = zb2[15 - i];
            cx cjZm = mkcx(Zm.x, -Zm.y);
            cx V0 = Zk + cjZm;
            cx V1 = cneg_i(Zk - cjZm);
            v[i] = cmul(V0, pf(a0pf, i)) + cpos_i(cmul(V1, pf(a1pf, i)));
        }
    }
}

// Forward 4096-FFT (single-chunk path, used by fft_a).
template<bool HALF_ZERO>
__device__ __forceinline__ void fft4096_fwd_core(
    cx* d, int tid, const cx tw[16], const cx* tw2lds, cx v[16])
{
    {
        fft16_dif_r4<HALF_ZERO>(v);
        apply_tw<false>(v, tw);
        cx* base = d + fpad(tid);
        #pragma unroll
        for (int p = 0; p < 16; ++p) base[274 * p] = v[p];
    }
    __syncthreads();
    fwd_s2(d, tid, tw2lds);
    __syncthreads();
    fwd_s3(d, tid);
    __syncthreads();
}

// ---------------------------------------------------------------------------
// Forward FFT of packed (a_ch0, a_ch1) pair, unpack both real spectra in
// DIF order (conjugate-partner: p2 = p ^ (2^floor(log2 p) - 1)).
// A0 = c*(Wk + conj(Wm)), A1 = c*(-i)*(Wk - conj(Wm)), c = 0.25/4096.
// ---------------------------------------------------------------------------
__global__ __launch_bounds__(256, 4) void fft_a_kernel(
    const float* a_t, cx* __restrict__ A0s, cx* A1s,
    const cx* __restrict__ Twd)
{
    __shared__ cx data[FFT_LDS_SZ];
    __shared__ cx tw2lds[256];
    const int tid = threadIdx.x;
    const int r = blockIdx.x;                      // pair index, ch = 2r

    cx tw[16];
    {
        const cx* Tr1 = Twd + (tid << 4);
        #pragma unroll
        for (int t = 1; t < 16; ++t) tw[t] = Tr1[t];
        tw2lds[(tid >> 4) * 16 + (tid & 15)] = Twd[(tid & 15) * 256 + (tid >> 4)];
    }

    const float* r0 = a_t + (size_t)(2 * r) * M_FFT;
    const float* r1 = r0 + M_FFT;
    cx v[16];
    #pragma unroll
    for (int t = 0; t < 16; ++t)
        v[t] = mkcx(r0[tid + 256 * t], r1[tid + 256 * t]);

    fft4096_fwd_core<false>(data, tid, tw, tw2lds, v);

    const float c = 0.25f / 4096.0f;
    cx* A0row = A0s + (size_t)r * 4096;
    cx* A1row = A1s + (size_t)r * 4096;
    if (tid == 0) {
        #pragma unroll
        for (int i = 0; i < 16; ++i) {
            const int p2 = (i < 2) ? i : (i ^ ((1 << (31 - __clz(i))) - 1));
            cx Wk = data[fpad(i)];
            cx Wm = data[fpad(p2)];
            cx cjWm = mkcx(Wm.x, -Wm.y);
            A0row[i] = c * (Wk + cjWm);
            A1row[i] = c * cneg_i(Wk - cjWm);
        }
    } else {
        const int base = tid << 4;
        const int mask = (1 << (31 - __clz(base))) - 1;
        const cx* zb  = data + fpad(base);
        const cx* zb2 = data + fpad((base ^ mask) - 15);
        #pragma unroll
        for (int i = 0; i < 16; ++i) {
            cx Wk = zb[i];
            cx Wm = zb2[15 - i];
            cx cjWm = mkcx(Wm.x, -Wm.y);
            A0row[base + i] = c * (Wk + cjWm);
            A1row[base + i] = c * cneg_i(Wk - cjWm);
        }
    }
}

// ---------------------------------------------------------------------------
// Conv kernel: TWO channel-pairs per block (batches 2bp and 2bp+1 of the
// SAME r) -> 2x work per barrier region, A rows loaded once for both.
// Bijective XCD remap: xcd = r&7; slots pair (r,bp=0),(r,bp=1) adjacent.
// ---------------------------------------------------------------------------
__global__ __launch_bounds__(256, 2) void fft_conv_kernel(
    const bf16* __restrict__ v_t, const cx* __restrict__ A0s,
    const cx* __restrict__ A1s, const bf16* __restrict__ u_t,
    bf16* __restrict__ gated_t, const cx* __restrict__ Twd)
{
    __shared__ cx data[2][FFT_LDS_SZ];
    __shared__ cx tw2lds[256];
    const int tid = threadIdx.x;
    const int bx = blockIdx.x;
    const int xcd  = bx & 7;
    const int slot = bx >> 3;                 // [0,192)
    const int bp   = slot & 1;
    const int r    = (slot >> 1) * 8 + xcd;   // [0,768), bijective
    const int ch   = 2 * r;
    const int b0   = 2 * bp;
    const int b1   = 2 * bp + 1;

    cx tw[16];
    {
        const cx* Tr1 = Twd + (tid << 4);
        #pragma unroll
        for (int t = 1; t < 16; ++t) tw[t] = Tr1[t];
        tw2lds[(tid >> 4) * 16 + (tid & 15)] = Twd[(tid & 15) * 256 + (tid >> 4)];
    }

    // ---- forward stage 1: both chunks straight from global ----
    const bf16* z00 = v_t + ((size_t)(b0 * D1 + ch)) * N_SEQ;
    const bf16* z01 = z00 + N_SEQ;
    const bf16* z10 = v_t + ((size_t)(b1 * D1 + ch)) * N_SEQ;
    const bf16* z11 = z10 + N_SEQ;
    {
        cx w0[8], w1[8];
        #pragma unroll
        for (int t = 0; t < 8; ++t)
            w0[t] = mkcx((float)z00[tid + 256 * t], (float)z01[tid + 256 * t]);
        #pragma unroll
        for (int t = 0; t < 8; ++t)
            w1[t] = mkcx((float)z10[tid + 256 * t], (float)z11[tid + 256 * t]);
        fwd_s1_store_hz(w0, tw, data[0], tid);
        fwd_s1_store_hz(w1, tw, data[1], tid);
    }
    __syncthreads();

    fwd_s2(data[0], tid, tw2lds);
    fwd_s2(data[1], tid, tw2lds);
    __syncthreads();

    // A rows (shared by both chunks): issue before stage-3 compute so the
    // pre-barrier vmcnt drain overlaps both chunks' stage 3.
    const int pbase = tid << 4;
    float4 a0pf[8], a1pf[8];
    {
        const float4* A0p = (const float4*)(A0s + (size_t)r * 4096 + pbase);
        const float4* A1p = (const float4*)(A1s + (size_t)r * 4096 + pbase);
        #pragma unroll
        for (int i = 0; i < 8; ++i) { a0pf[i] = A0p[i]; a1pf[i] = A1p[i]; }
    }
    fwd_s3(data[0], tid);
    fwd_s3(data[1], tid);
    __syncthreads();

    // ---- pointwise (A in regs, used twice) + inverse stage 1 ----
    cx vA[16], vB[16];
    pointwise_read(data[0], tid, a0pf, a1pf, vA);
    pointwise_read(data[1], tid, a0pf, a1pf, vB);
    __syncthreads();                       // all scattered Z reads done
    fft16_dit_inv_r4<false>(vA);
    fft16_dit_inv_r4<false>(vB);
    {
        cx* baseA = data[0] + fpad(pbase);
        cx* baseB = data[1] + fpad(pbase);
        #pragma unroll
        for (int i = 0; i < 16; ++i) baseA[i] = vA[i];
        #pragma unroll
        for (int i = 0; i < 16; ++i) baseB[i] = vB[i];
    }
    __syncthreads();

    // u rows: issue before inv stage 2 so drain overlaps it
    const bf16* u00 = u_t + ((size_t)(b0 * D1 + ch)) * N_SEQ;
    const bf16* u01 = u00 + N_SEQ;
    const bf16* u10 = u_t + ((size_t)(b1 * D1 + ch)) * N_SEQ;
    const bf16* u11 = u10 + N_SEQ;
    bf16x8 ua0 = *(const bf16x8*)(u00 + tid * 8);
    bf16x8 ub0 = *(const bf16x8*)(u01 + tid * 8);
    bf16x8 ua1 = *(const bf16x8*)(u10 + tid * 8);
    bf16x8 ub1 = *(const bf16x8*)(u11 + tid * 8);

    inv_s2(data[0], tid, tw2lds);
    inv_s2(data[1], tid, tw2lds);
    __syncthreads();

    inv_s3_half(data[0], tid, tw);
    inv_s3_half(data[1], tid, tw);
    __syncthreads();

    // ---- gate with u (1/M folded into A spectra) ----
    {
        const int t = tid * 8;
        bf16* g00 = gated_t + ((size_t)(b0 * D1 + ch)) * N_SEQ;
        bf16* g01 = g00 + N_SEQ;
        bf16* g10 = gated_t + ((size_t)(b1 * D1 + ch)) * N_SEQ;
        bf16* g11 = g10 + N_SEQ;
        const cx* baseA = data[0] + fpad(t);
        const cx* baseB = data[1] + fpad(t);
        bf16x8 oa, ob, oc, od;
        #pragma unroll
        for (int i = 0; i < 8; ++i) {
            cx ya = baseA[i];
            cx yb = baseB[i];
            oa[i] = (bf16)(ya.x * (float)ua0[i]);
            ob[i] = (bf16)(ya.y * (float)ub0[i]);
            oc[i] = (bf16)(yb.x * (float)ua1[i]);
            od[i] = (bf16)(yb.y * (float)ub1[i]);
        }
        *(bf16x8*)(g00 + t) = oa;
        *(bf16x8*)(g01 + t) = ob;
        *(bf16x8*)(g10 + t) = oc;
        *(bf16x8*)(g11 + t) = od;
    }
}

// ---------------------------------------------------------------------------
__global__ __launch_bounds__(256) void transpose_cs_kernel(
    const bf16* __restrict__ in, bf16* __restrict__ outp)
{
    __shared__ bf16 tile[64 * 68];
    const int c0 = blockIdx.x * 64;
    const int m0 = blockIdx.y * 64;
    const int b  = m0 >> 11;
    const int s0 = m0 & 2047;
    const int tid = threadIdx.x;
    const int cl = tid >> 4;
    const int sc = (tid & 15) * 4;
    #pragma unroll
    for (int p = 0; p < 4; ++p) {
        int c = p * 16 + cl;
        bf16x4 v = *(const bf16x4*)&in[((size_t)(b * D1 + c0 + c)) * N_SEQ + s0 + sc];
        *(bf16x4*)&tile[c * 68 + sc] = v;
    }
    __syncthreads();
    const int sl = tid >> 4;
    const int cc = (tid & 15) * 4;
    #pragma unroll
    for (int p = 0; p < 4; ++p) {
        int s = p * 16 + sl;
        bf16x4 o;
        #pragma unroll
        for (int j = 0; j < 4; ++j) o[j] = tile[(cc + j) * 68 + s];
        *(bf16x4*)&outp[((size_t)(m0 + s)) * D1 + c0 + cc] = o;
    }
}

// ---------------------------------------------------------------------------
extern "C" void kernel_launch(void* const* d_in, const int* in_sizes, int n_in,
                              void* d_out, int out_size, void* d_ws, size_t ws_size,
                              hipStream_t stream)
{
    const float* x  = (const float*)d_in[0];
    const float* Wu = (const float*)d_in[1];
    const float* bu = (const float*)d_in[2];
    const float* Wv = (const float*)d_in[3];
    const float* bv = (const float*)d_in[4];
    const float* Wo = (const float*)d_in[5];
    const float* bo = (const float*)d_in[6];
    const float* Wp = (const float*)d_in[7];
    const float* bp = (const float*)d_in[8];
    const float* Wl = (const float*)d_in[9];
    const float* bl = (const float*)d_in[10];
    const float* Wr = (const float*)d_in[11];
    const float* br = (const float*)d_in[12];
    float* out = (float*)d_out;

    float* ws      = (float*)d_ws;
    float* a_t     = ws;                       // 1536*4096 fp32; A1spec after fft_a
    float* A0spec  = a_t   + 6291456;          // 768 x 4096 cx
    float* sumsq   = A0spec + 6291456;         // 3 x 4096 fp32
    float* twd     = sumsq + 12288;            // 256 x 16 cx twiddle table
    bf16*  bfws    = (bf16*)(twd + 8192);
    bf16*  x_bf    = bfws;                     // 8192*512
    bf16*  w_bf    = x_bf    + 4194304;        // 5 x 786432: Wu,Wv,Wo,Wl,Wr
    bf16*  Wuv_bf  = w_bf;                     // stacked [Wu;Wv] 3072 x 512
    bf16*  Wo_bf   = w_bf    + 2 * 786432;
    bf16*  Wl_bf   = Wo_bf   + 786432;
    bf16*  Wr_bf   = Wl_bf   + 786432;
    bf16*  gA      = Wr_bf   + 786432;         // 4096*512
    bf16*  gB      = gA      + 2097152;        // 4096*512
    bf16*  u_t     = gB      + 2097152;        // 8192*1536 [b][c][s]
    bf16*  v_t     = u_t     + 12582912;       // 8192*1536 [b][c][s]
    bf16*  gated_t = v_t     + 12582912;       // 8192*1536 [b][c][s]
    bf16*  gated   = gated_t + 12582912;       // 8192*1536 [m][c]

    dim3 blk(256);

    // x/w converts + sumsq zero + rpe input layer + twiddle table
    f2b_all_kernel<<<4096 + 5 * 768 + 12 + 4096 + 16, blk, 0, stream>>>(
        x, Wu, Wv, Wo, Wl, Wr, Wp, bp, x_bf, w_bf, sumsq, gA, twd);

    gemm_bf16<MODE_SILU_UV, bf16><<<dim3(24, 64), blk, 0, stream>>>(
        x_bf, Wuv_bf, bu, bv, u_t, v_t, 8192, 2 * D1, ED, nullptr, nullptr);

    // RPE MLP: srms folded into GEMM epilogues via row-scale commutation
    bf16* gin = gA;
    bf16* gout = gB;
    for (int i = 0; i < 3; ++i) {
        const float* sin_p = (i == 0) ? nullptr : sumsq + (size_t)(i - 1) * 4096;
        gemm_bf16<MODE_RPE, bf16><<<dim3(4, 32), blk, 0, stream>>>(
            gin, Wl_bf + (size_t)i * ED * ED, bl + (size_t)i * ED, nullptr,
            gout, nullptr, 4096, ED, ED, sin_p, sumsq + (size_t)i * 4096);
        bf16* t = gin; gin = gout; gout = t;
    }
    gemm_bf16<MODE_AT, float><<<dim3(12, 32), blk, 0, stream>>>(
        gin, Wr_bf, br, nullptr, a_t, nullptr, 4096, D1, ED,
        sumsq + 2 * 4096, nullptr);

    fft_a_kernel<<<768, blk, 0, stream>>>(
        a_t, (cx*)A0spec, (cx*)a_t, (const cx*)twd);
    fft_conv_kernel<<<1536, blk, 0, stream>>>(
        v_t, (const cx*)A0spec, (const cx*)a_t, u_t, gated_t, (const cx*)twd);

    transpose_cs_kernel<<<dim3(24, 128), blk, 0, stream>>>(gated_t, gated);

    gemm_bf16<MODE_PLAIN, float><<<dim3(4, 64), blk, 0, stream>>>(
        gated, Wo_bf, bo, nullptr, out, nullptr, 8192, ED, D1,
        nullptr, nullptr);
}

// Round 7
// 334.602 us; speedup vs baseline: 1.1978x; 1.0217x over previous
//
#include <hip/hip_runtime.h>

#define N_SEQ 2048
#define M_FFT 4096
#define D1    1536
#define NH    8
#define HD    192
#define ED    512

typedef __bf16 bf16;
typedef __bf16 bf16x4 __attribute__((ext_vector_type(4)));
typedef __bf16 bf16x8 __attribute__((ext_vector_type(8)));
typedef float  floatx4 __attribute__((ext_vector_type(4)));
typedef float  cx __attribute__((ext_vector_type(2)));   // complex as packed fp32

enum { MODE_PLAIN = 0, MODE_SILU_UV = 1, MODE_AT = 3, MODE_RPE = 4 };

__device__ __forceinline__ void gload16(const void* g, void* l) {
    __builtin_amdgcn_global_load_lds(
        (const __attribute__((address_space(1))) void*)g,
        (__attribute__((address_space(3))) void*)l, 16, 0, 0);
}

// ---------------------------------------------------------------------------
// bf16 MFMA GEMM, depth-4 pipeline with COUNTED vmcnt (T4), BN-templated:
//   BN=128: 4 loads/stage, vmcnt 12/8/4/0   (SILU_UV, big grid)
//   BN=64 : 3 loads/stage, vmcnt  9/6/3/0   (PLAIN/AT/RPE: doubles grid size
//           for the small-N GEMMs -> fixes 0.5-1 block/CU occupancy holes)
// Per step: barrier(A) overwrite-safe -> stage(t+3) -> vmcnt(N) own loads of
// tile t done -> barrier(B) all waves' loads visible -> compute(t).
// Raw s_barrier (no vmcnt(0) drain). Requires nt % 4 == 0 (K=512/1536 ok).
// ---------------------------------------------------------------------------
template<int MODE, int BN, typename OutT>
__global__ __launch_bounds__(256) void gemm_bf16(
    const bf16* __restrict__ A, const bf16* __restrict__ Bw,
    const float* __restrict__ bias, const float* __restrict__ bias2,
    OutT* __restrict__ C, OutT* __restrict__ C2,
    int M, int Nc, int K,
    const float* __restrict__ scale_in, float* __restrict__ sumsq_out)
{
    constexpr int NJ = BN / 32;            // n-fragments per wave (4 or 2)
    __shared__ __align__(16) bf16 As[4][128 * 32];
    __shared__ __align__(16) bf16 Bs[4][BN * 32];

    const int tid  = threadIdx.x;
    const int row0 = blockIdx.y * 128;
    const int col0 = blockIdx.x * BN;
    const int wid  = tid >> 6;
    const int lane = tid & 63;
    const int lm   = lane & 15;
    const int lk   = lane >> 4;
    const int wm   = wid >> 1;
    const int wn   = wid & 1;
    const int ldrow  = tid >> 2;
    const int ldcol8 = (tid & 3) * 8;

    floatx4 acc[4][NJ] = {};

    const bf16* Ag = A  + ((size_t)(row0 + ldrow)) * K + ldcol8;
    const bf16* Bg = Bw + ((size_t)(col0 + ldrow)) * K + ldcol8;
    const int woff = (wid * 16) * 32;

    auto stage = [&](int t, int buf) {
        const int k0 = t << 5;
        gload16(Ag + k0, &As[buf][woff]);
        gload16(Ag + (size_t)64 * K + k0, &As[buf][woff + 64 * 32]);
        gload16(Bg + k0, &Bs[buf][woff]);
        if constexpr (BN == 128)
            gload16(Bg + (size_t)64 * K + k0, &Bs[buf][woff + 64 * 32]);
    };
    auto compute = [&](int buf) {
        bf16x8 af[4], bfr[NJ];
        #pragma unroll
        for (int mi = 0; mi < 4; ++mi)
            af[mi] = *(const bf16x8*)&As[buf][(wm * 64 + mi * 16 + lm) * 32 + lk * 8];
        #pragma unroll
        for (int nj = 0; nj < NJ; ++nj)
            bfr[nj] = *(const bf16x8*)&Bs[buf][(wn * (BN / 2) + nj * 16 + lm) * 32 + lk * 8];
        #pragma unroll
        for (int mi = 0; mi < 4; ++mi)
            #pragma unroll
            for (int nj = 0; nj < NJ; ++nj)
                acc[mi][nj] = __builtin_amdgcn_mfma_f32_16x16x32_bf16(
                    af[mi], bfr[nj], acc[mi][nj], 0, 0, 0);
    };

#define GEMM_STEP(T, BUF, DOSTAGE, VM)                                  \
    do {                                                                \
        __builtin_amdgcn_s_barrier();          /* A: compute(t-1) done */\
        __builtin_amdgcn_sched_barrier(0);                              \
        if (DOSTAGE) stage((T) + 3, ((T) + 3) & 3);                     \
        asm volatile("s_waitcnt vmcnt(" #VM ")" ::: "memory");          \
        __builtin_amdgcn_s_barrier();          /* B: tile T fully in LDS */\
        __builtin_amdgcn_sched_barrier(0);                              \
        compute(BUF);                                                   \
    } while (0)

    const int nt = K >> 5;           // 16 or 48; nt % 4 == 0
    stage(0, 0);
    stage(1, 1);
    stage(2, 2);
    if constexpr (BN == 128) {
        for (int t4 = 0; t4 < nt - 4; t4 += 4) {
            GEMM_STEP(t4 + 0, 0, true, 12);
            GEMM_STEP(t4 + 1, 1, true, 12);
            GEMM_STEP(t4 + 2, 2, true, 12);
            GEMM_STEP(t4 + 3, 3, true, 12);
        }
        GEMM_STEP(nt - 4, 0, true, 12);
        GEMM_STEP(nt - 3, 1, false, 8);
        GEMM_STEP(nt - 2, 2, false, 4);
        GEMM_STEP(nt - 1, 3, false, 0);
    } else {
        for (int t4 = 0; t4 < nt - 4; t4 += 4) {
            GEMM_STEP(t4 + 0, 0, true, 9);
            GEMM_STEP(t4 + 1, 1, true, 9);
            GEMM_STEP(t4 + 2, 2, true, 9);
            GEMM_STEP(t4 + 3, 3, true, 9);
        }
        GEMM_STEP(nt - 4, 0, true, 9);
        GEMM_STEP(nt - 3, 1, false, 6);
        GEMM_STEP(nt - 2, 2, false, 3);
        GEMM_STEP(nt - 1, 3, false, 0);
    }
#undef GEMM_STEP

    const float* bs = bias;
    OutT* dst = C;
    int cadj = 0;
    if (MODE == MODE_SILU_UV && col0 >= D1) { bs = bias2; dst = C2; cadj = D1; }

    float bcol[NJ];
    #pragma unroll
    for (int nj = 0; nj < NJ; ++nj)
        bcol[nj] = bs[col0 - cadj + wn * (BN / 2) + nj * 16 + lm];

    if (MODE == MODE_RPE) {
        #pragma unroll
        for (int mi = 0; mi < 4; ++mi) {
            #pragma unroll
            for (int r = 0; r < 4; ++r) {
                const int row = row0 + wm * 64 + mi * 16 + lk * 4 + r;
                float sc = 1.0f;
                if (scale_in)
                    sc = 1.0f / (sqrtf(scale_in[row]) * 0.04419417382415922f + 1e-8f);
                float ssq = 0.0f;
                #pragma unroll
                for (int nj = 0; nj < NJ; ++nj) {
                    const int col = col0 + wn * (BN / 2) + nj * 16 + lm;
                    float val = acc[mi][nj][r] * sc + bcol[nj];
                    ssq += val * val;
                    ((bf16*)C)[(size_t)row * Nc + col] = (bf16)fmaxf(val, 0.0f);
                }
                ssq += __shfl_xor(ssq, 1, 64);
                ssq += __shfl_xor(ssq, 2, 64);
                ssq += __shfl_xor(ssq, 4, 64);
                ssq += __shfl_xor(ssq, 8, 64);
                if (lm == 0) atomicAdd(&sumsq_out[row], ssq);
            }
        }
        return;
    }

    #pragma unroll
    for (int mi = 0; mi < 4; ++mi) {
        const int rbase = row0 + wm * 64 + mi * 16 + lk * 4;
        float sc[4];
        #pragma unroll
        for (int r = 0; r < 4; ++r) {
            sc[r] = 1.0f;
            if (MODE == MODE_AT && scale_in)
                sc[r] = 1.0f / (sqrtf(scale_in[rbase + r]) * 0.04419417382415922f + 1e-8f);
        }
        #pragma unroll
        for (int nj = 0; nj < NJ; ++nj) {
            const int col = col0 - cadj + wn * (BN / 2) + nj * 16 + lm;
            float vals[4];
            #pragma unroll
            for (int r = 0; r < 4; ++r) {
                float val = acc[mi][nj][r] * sc[r] + bcol[nj];
                if (MODE == MODE_SILU_UV)
                    val = val * __fdividef(1.0f, 1.0f + __expf(-val));
                vals[r] = val;
            }
            if (MODE == MODE_SILU_UV) {
                int b = rbase >> 11, s = rbase & 2047;
                bf16x4 o;
                #pragma unroll
                for (int r = 0; r < 4; ++r) o[r] = (bf16)vals[r];
                *(bf16x4*)&((bf16*)dst)[((size_t)(b * D1 + col)) * N_SEQ + s] = o;
            } else if (MODE == MODE_AT) {
                float4 o = make_float4(vals[0], vals[1], vals[2], vals[3]);
                *(float4*)&((float*)C)[(size_t)col * M + rbase] = o;
            } else {
                #pragma unroll
                for (int r = 0; r < 4; ++r)
                    C[(size_t)(rbase + r) * Nc + col] = (OutT)vals[r];
            }
        }
    }
}

// ---------------------------------------------------------------------------
// mega-prologue: x convert + 5 weight converts + sumsq zero +
// RPE input layer w/ srms + FFT twiddle table (256 x 16 cx)
// ---------------------------------------------------------------------------
__global__ __launch_bounds__(256) void f2b_all_kernel(
    const float* __restrict__ x,  const float* __restrict__ s0,
    const float* __restrict__ s1, const float* __restrict__ s2,
    const float* __restrict__ s3, const float* __restrict__ s4,
    const float* __restrict__ Wp, const float* __restrict__ bp,
    bf16* __restrict__ x_bf, bf16* __restrict__ w_bf,
    float* __restrict__ sumsq, bf16* __restrict__ g0,
    float* __restrict__ twd)
{
    const int bid = blockIdx.x;
    const int tid = threadIdx.x;
    __shared__ float red[4];

    if (bid < 7936) {
        const float* src;
        bf16* dst;
        size_t off;
        if (bid < 4096) {
            src = x; dst = x_bf; off = (size_t)bid * 1024;
        } else {
            int t = bid - 4096;
            int seg = t / 768;
            src = seg == 0 ? s0 : seg == 1 ? s1 : seg == 2 ? s2
                : seg == 3 ? s3 : s4;
            dst = w_bf + (size_t)seg * 786432;
            off = (size_t)(t % 768) * 1024;
        }
        size_t i = off + (size_t)tid * 4;
        float4 f = *(const float4*)(src + i);
        union { bf16 h[4]; short4 s; } u4;
        u4.h[0] = (bf16)f.x; u4.h[1] = (bf16)f.y;
        u4.h[2] = (bf16)f.z; u4.h[3] = (bf16)f.w;
        *(short4*)(dst + i) = u4.s;
    } else if (bid < 7948) {
        size_t i = (size_t)(bid - 7936) * 1024 + (size_t)tid * 4;
        *(float4*)(sumsq + i) = make_float4(0.f, 0.f, 0.f, 0.f);
    } else if (bid < 12044) {
        const int j = bid - 7948;
        float idxv = (j < N_SEQ) ? (float)j
                                 : (j == N_SEQ ? 0.0f : (float)(j - 2 * N_SEQ));
        float h1 = idxv * Wp[tid] + bp[tid];
        float h2 = idxv * Wp[tid + 256] + bp[tid + 256];
        float ss = h1 * h1 + h2 * h2;
        #pragma unroll
        for (int off = 32; off > 0; off >>= 1) ss += __shfl_down(ss, off, 64);
        if ((tid & 63) == 0) red[tid >> 6] = ss;
        __syncthreads();
        float tot = red[0] + red[1] + red[2] + red[3];
        float scale = 1.0f / (sqrtf(tot) * 0.04419417382415922f + 1e-8f);
        g0[(size_t)j * ED + tid]       = (bf16)fmaxf(h1 * scale, 0.0f);
        g0[(size_t)j * ED + tid + 256] = (bf16)fmaxf(h2 * scale, 0.0f);
    } else {
        const int idx = (bid - 12044) * 256 + tid;    // [0, 4096)
        const int j = idx >> 4, tau = idx & 15;
        float sA, cA;
        __sincosf(-6.283185307179586f * (float)(j * tau) * (1.0f / 4096.0f),
                  &sA, &cA);
        cx w; w.x = cA; w.y = sA;
        ((cx*)twd)[idx] = w;
    }
}

// ---------------------------------------------------------------------------
// Radix-16 FFT, radix-4 butterflies, packed-fp32 complex.
// LDS addressing: fpad(base + s*t) = fpad(base) + s'*t  (256->274, 16->17, 1->1)
// Stage-1/inv-3 twiddle row (tid<<4) in REGISTERS (inverse = conjugate);
// stage-2/inv-2 rows (16 distinct) in a 2 KB LDS broadcast table.
// ---------------------------------------------------------------------------
#define FFT_LDS_SZ 4381

__device__ __forceinline__ int fpad(int i) { return i + (i >> 4) + 2 * (i >> 8); }

__device__ __forceinline__ cx mkcx(float a, float b) { cx r; r.x = a; r.y = b; return r; }
__device__ __forceinline__ cx cmul(cx a, cx b) {
    cx br = mkcx(-b.y, b.x);
    return a.xx * b + a.yy * br;
}
__device__ __forceinline__ cx cmul_cj(cx a, cx b) {      // a * conj(b)
    cx bc = mkcx(b.x, -b.y);
    cx br = mkcx(b.y, b.x);
    return a.xx * bc + a.yy * br;
}
__device__ __forceinline__ cx cneg_i(cx a) { return mkcx(a.y, -a.x); }   // a * (-i)
__device__ __forceinline__ cx cpos_i(cx a) { return mkcx(-a.y, a.x); }   // a * (+i)
__host__ __device__ constexpr int brev4(int t) {
    return ((t & 1) << 3) | ((t & 2) << 1) | ((t & 4) >> 1) | ((t & 8) >> 3);
}

#define CC1 0.9238795325112867f
#define SS1 0.3826834323650898f
#define RR2 0.7071067811865476f

template<bool HZ>
__device__ __forceinline__ void fft16_dif_r4(cx x[16]) {
    const cx W1 = mkcx( CC1, -SS1);
    const cx W2 = mkcx( RR2, -RR2);
    const cx W3 = mkcx( SS1, -CC1);
    const cx W6 = mkcx(-RR2, -RR2);
    const cx W9 = mkcx(-CC1,  SS1);
    #pragma unroll
    for (int n = 0; n < 4; ++n) {
        cx A, B, C, D;
        if (HZ) { A = x[n]; C = x[n]; B = x[n + 4]; D = x[n + 4]; }
        else {
            A = x[n] + x[n + 8];      C = x[n] - x[n + 8];
            B = x[n + 4] + x[n + 12]; D = x[n + 4] - x[n + 12];
        }
        cx s = A - B;
        cx nid = cneg_i(D);
        cx m = C + nid;
        cx p = C - nid;
        x[n] = A + B;
        if (n == 0)      { x[4] = s;            x[8]  = m;           x[12] = p; }
        else if (n == 1) { x[5] = cmul(s, W2);  x[9]  = cmul(m, W1); x[13] = cmul(p, W3); }
        else if (n == 2) { x[6] = cneg_i(s);    x[10] = cmul(m, W2); x[14] = cmul(p, W6); }
        else             { x[7] = cmul(s, W6);  x[11] = cmul(m, W3); x[15] = cmul(p, W9); }
    }
    #pragma unroll
    for (int q = 0; q < 16; q += 4) {
        cx a = x[q], b = x[q + 1], c = x[q + 2], d = x[q + 3];
        cx a1 = a + c, c1 = a - c;
        cx b1 = b + d, d1 = cneg_i(b - d);
        x[q]     = a1 + b1;
        x[q + 1] = a1 - b1;
        x[q + 2] = c1 + d1;
        x[q + 3] = c1 - d1;
    }
}

template<bool HALF_OUT>
__device__ __forceinline__ void fft16_dit_inv_r4(cx x[16]) {
    const cx V1 = mkcx( CC1, SS1);
    const cx V2 = mkcx( RR2, RR2);
    const cx V3 = mkcx( SS1, CC1);
    const cx V6 = mkcx(-RR2, RR2);
    #pragma unroll
    for (int q = 0; q < 16; q += 4) {
        cx a = x[q], b = x[q + 1], c = x[q + 2], d = x[q + 3];
        cx a1 = a + b, b1 = a - b;
        cx c1 = c + d, d1 = c - d;
        cx t = cpos_i(d1);
        x[q]     = a1 + c1;
        x[q + 2] = a1 - c1;
        x[q + 1] = b1 + t;
        x[q + 3] = b1 - t;
    }
    #pragma unroll
    for (int n = 0; n < 4; ++n) {
        cx t1, t2;
        if (n == 0)      { t1 = x[4];             t2 = x[12]; }
        else if (n == 1) { t1 = cmul(x[5],  V2);  t2 = cmul(x[13], V2); }
        else if (n == 2) { t1 = cpos_i(x[6]);     t2 = cpos_i(x[14]); }
        else             { t1 = cmul(x[7],  V6);  t2 = cmul(x[15], V6); }
        cx P = x[n] + t1, Q = x[n] - t1;
        cx R = x[n + 8] + t2, S = x[n + 8] - t2;
        cx t, u;
        if (n == 0)      { t = R;            u = S; }
        else if (n == 1) { t = cmul(R, V1);  u = cmul(S, V1); }
        else if (n == 2) { t = cmul(R, V2);  u = cmul(S, V2); }
        else             { t = cmul(R, V3);  u = cmul(S, V3); }
        cx iu = cpos_i(u);
        x[n]     = P + t;
        x[n + 4] = Q + iu;
        if (!HALF_OUT) {
            x[n + 8]  = P - t;
            x[n + 12] = Q - iu;
        }
    }
}

template<bool CONJ>
__device__ __forceinline__ void apply_tw(cx v[16], const cx tw[16]) {
    #pragma unroll
    for (int tau = 1; tau < 16; ++tau) {
        const int q = brev4(tau);
        v[q] = CONJ ? cmul_cj(v[q], tw[tau]) : cmul(v[q], tw[tau]);
    }
}

// twrow points at tw2lds + (tid&15); stride 16 per tau. Broadcast reads.
template<bool CONJ>
__device__ __forceinline__ void apply_tw_lds(cx v[16], const cx* twrow) {
    #pragma unroll
    for (int tau = 1; tau < 16; ++tau) {
        cx w = twrow[tau * 16];
        const int q = brev4(tau);
        v[q] = CONJ ? cmul_cj(v[q], w) : cmul(v[q], w);
    }
}

// ---- per-stage helpers (in-place per-thread; caller places barriers) ------
__device__ __forceinline__ void fwd_s1_store_hz(
    const cx vin[8], const cx tw[16], cx* d, int tid)
{
    cx x[16];
    #pragma unroll
    for (int t = 0; t < 8; ++t) x[t] = vin[t];
    fft16_dif_r4<true>(x);
    apply_tw<false>(x, tw);
    cx* base = d + fpad(tid);
    #pragma unroll
    for (int p = 0; p < 16; ++p) base[274 * p] = x[p];
}

__device__ __forceinline__ void fwd_s2(cx* d, int tid, const cx* tw2lds)
{
    cx v[16];
    cx* base = d + fpad(((tid >> 4) << 8) + (tid & 15));
    #pragma unroll
    for (int t = 0; t < 16; ++t) v[t] = base[17 * t];
    fft16_dif_r4<false>(v);
    apply_tw_lds<false>(v, tw2lds + (tid & 15));
    #pragma unroll
    for (int p = 0; p < 16; ++p) base[17 * p] = v[p];
}

__device__ __forceinline__ void fwd_s3(cx* d, int tid)
{
    cx v[16];
    cx* base = d + fpad(tid << 4);
    #pragma unroll
    for (int t = 0; t < 16; ++t) v[t] = base[t];
    fft16_dif_r4<false>(v);
    #pragma unroll
    for (int p = 0; p < 16; ++p) base[p] = v[p];
}

__device__ __forceinline__ void inv_s2(cx* d, int tid, const cx* tw2lds)
{
    cx v[16];
    cx* base = d + fpad(((tid >> 4) << 8) + (tid & 15));
    #pragma unroll
    for (int p = 0; p < 16; ++p) v[p] = base[17 * p];
    apply_tw_lds<true>(v, tw2lds + (tid & 15));
    fft16_dit_inv_r4<false>(v);
    #pragma unroll
    for (int t = 0; t < 16; ++t) base[17 * t] = v[t];
}

__device__ __forceinline__ void inv_s3_half(cx* d, int tid, const cx tw[16])
{
    cx v[16];
    cx* base = d + fpad(tid);
    #pragma unroll
    for (int p = 0; p < 16; ++p) v[p] = base[274 * p];
    apply_tw<true>(v, tw);
    fft16_dit_inv_r4<true>(v);
    #pragma unroll
    for (int t = 0; t < 8; ++t) base[274 * t] = v[t];
}

// pointwise: read Z partners from d, multiply with A spectra (regs), -> v
__device__ __forceinline__ void pointwise_read(
    const cx* d, int tid, const float4 a0pf[8], const float4 a1pf[8],
    cx v[16])
{
    auto pf = [](const float4* p, int i) -> cx {
        return (i & 1) ? mkcx(p[i >> 1].z, p[i >> 1].w)
                       : mkcx(p[i >> 1].x, p[i >> 1].y);
    };
    const int pbase = tid << 4;
    if (tid == 0) {
        #pragma unroll
        for (int i = 0; i < 16; ++i) {
            const int p2 = (i < 2) ? i : (i ^ ((1 << (31 - __clz(i))) - 1));
            cx Zk = d[fpad(i)];
            cx Zm = d[fpad(p2)];
            cx cjZm = mkcx(Zm.x, -Zm.y);
            cx V0 = Zk + cjZm;
            cx V1 = cneg_i(Zk - cjZm);
            v[i] = cmul(V0, pf(a0pf, i)) + cpos_i(cmul(V1, pf(a1pf, i)));
        }
    } else {
        const int mask = (1 << (31 - __clz(pbase))) - 1;
        const cx* zb  = d + fpad(pbase);
        const cx* zb2 = d + fpad((pbase ^ mask) - 15);
        #pragma unroll
        for (int i = 0; i < 16; ++i) {
            cx Zk = zb[i];
            cx Zm = zb2[15 - i];
            cx cjZm = mkcx(Zm.x, -Zm.y);
            cx V0 = Zk + cjZm;
            cx V1 = cneg_i(Zk - cjZm);
            v[i] = cmul(V0, pf(a0pf, i)) + cpos_i(cmul(V1, pf(a1pf, i)));
        }
    }
}

// Forward 4096-FFT (single-chunk path, used by fft_a).
template<bool HALF_ZERO>
__device__ __forceinline__ void fft4096_fwd_core(
    cx* d, int tid, const cx tw[16], const cx* tw2lds, cx v[16])
{
    {
        fft16_dif_r4<HALF_ZERO>(v);
        apply_tw<false>(v, tw);
        cx* base = d + fpad(tid);
        #pragma unroll
        for (int p = 0; p < 16; ++p) base[274 * p] = v[p];
    }
    __syncthreads();
    fwd_s2(d, tid, tw2lds);
    __syncthreads();
    fwd_s3(d, tid);
    __syncthreads();
}

// ---------------------------------------------------------------------------
// Forward FFT of packed (a_ch0, a_ch1) pair, unpack both real spectra in
// DIF order (conjugate-partner: p2 = p ^ (2^floor(log2 p) - 1)).
// A0 = c*(Wk + conj(Wm)), A1 = c*(-i)*(Wk - conj(Wm)), c = 0.25/4096.
// ---------------------------------------------------------------------------
__global__ __launch_bounds__(256, 4) void fft_a_kernel(
    const float* a_t, cx* __restrict__ A0s, cx* A1s,
    const cx* __restrict__ Twd)
{
    __shared__ cx data[FFT_LDS_SZ];
    __shared__ cx tw2lds[256];
    const int tid = threadIdx.x;
    const int r = blockIdx.x;                      // pair index, ch = 2r

    cx tw[16];
    {
        const cx* Tr1 = Twd + (tid << 4);
        #pragma unroll
        for (int t = 1; t < 16; ++t) tw[t] = Tr1[t];
        tw2lds[(tid >> 4) * 16 + (tid & 15)] = Twd[(tid & 15) * 256 + (tid >> 4)];
    }

    const float* r0 = a_t + (size_t)(2 * r) * M_FFT;
    const float* r1 = r0 + M_FFT;
    cx v[16];
    #pragma unroll
    for (int t = 0; t < 16; ++t)
        v[t] = mkcx(r0[tid + 256 * t], r1[tid + 256 * t]);

    fft4096_fwd_core<false>(data, tid, tw, tw2lds, v);

    const float c = 0.25f / 4096.0f;
    cx* A0row = A0s + (size_t)r * 4096;
    cx* A1row = A1s + (size_t)r * 4096;
    if (tid == 0) {
        #pragma unroll
        for (int i = 0; i < 16; ++i) {
            const int p2 = (i < 2) ? i : (i ^ ((1 << (31 - __clz(i))) - 1));
            cx Wk = data[fpad(i)];
            cx Wm = data[fpad(p2)];
            cx cjWm = mkcx(Wm.x, -Wm.y);
            A0row[i] = c * (Wk + cjWm);
            A1row[i] = c * cneg_i(Wk - cjWm);
        }
    } else {
        const int base = tid << 4;
        const int mask = (1 << (31 - __clz(base))) - 1;
        const cx* zb  = data + fpad(base);
        const cx* zb2 = data + fpad((base ^ mask) - 15);
        #pragma unroll
        for (int i = 0; i < 16; ++i) {
            cx Wk = zb[i];
            cx Wm = zb2[15 - i];
            cx cjWm = mkcx(Wm.x, -Wm.y);
            A0row[base + i] = c * (Wk + cjWm);
            A1row[base + i] = c * cneg_i(Wk - cjWm);
        }
    }
}

// ---------------------------------------------------------------------------
// Conv kernel: TWO channel-pairs per block (batches 2bp and 2bp+1 of the
// SAME r) -> 2x work per barrier region, A rows loaded once for both.
// Bijective XCD remap: xcd = r&7; slots pair (r,bp=0),(r,bp=1) adjacent.
// ---------------------------------------------------------------------------
__global__ __launch_bounds__(256, 2) void fft_conv_kernel(
    const bf16* __restrict__ v_t, const cx* __restrict__ A0s,
    const cx* __restrict__ A1s, const bf16* __restrict__ u_t,
    bf16* __restrict__ gated_t, const cx* __restrict__ Twd)
{
    __shared__ cx data[2][FFT_LDS_SZ];
    __shared__ cx tw2lds[256];
    const int tid = threadIdx.x;
    const int bx = blockIdx.x;
    const int xcd  = bx & 7;
    const int slot = bx >> 3;                 // [0,192)
    const int bp   = slot & 1;
    const int r    = (slot >> 1) * 8 + xcd;   // [0,768), bijective
    const int ch   = 2 * r;
    const int b0   = 2 * bp;
    const int b1   = 2 * bp + 1;

    cx tw[16];
    {
        const cx* Tr1 = Twd + (tid << 4);
        #pragma unroll
        for (int t = 1; t < 16; ++t) tw[t] = Tr1[t];
        tw2lds[(tid >> 4) * 16 + (tid & 15)] = Twd[(tid & 15) * 256 + (tid >> 4)];
    }

    // ---- forward stage 1: both chunks straight from global ----
    const bf16* z00 = v_t + ((size_t)(b0 * D1 + ch)) * N_SEQ;
    const bf16* z01 = z00 + N_SEQ;
    const bf16* z10 = v_t + ((size_t)(b1 * D1 + ch)) * N_SEQ;
    const bf16* z11 = z10 + N_SEQ;
    {
        cx w0[8], w1[8];
        #pragma unroll
        for (int t = 0; t < 8; ++t)
            w0[t] = mkcx((float)z00[tid + 256 * t], (float)z01[tid + 256 * t]);
        #pragma unroll
        for (int t = 0; t < 8; ++t)
            w1[t] = mkcx((float)z10[tid + 256 * t], (float)z11[tid + 256 * t]);
        fwd_s1_store_hz(w0, tw, data[0], tid);
        fwd_s1_store_hz(w1, tw, data[1], tid);
    }
    __syncthreads();

    fwd_s2(data[0], tid, tw2lds);
    fwd_s2(data[1], tid, tw2lds);
    __syncthreads();

    // A rows (shared by both chunks): issue before stage-3 compute so the
    // pre-barrier vmcnt drain overlaps both chunks' stage 3.
    const int pbase = tid << 4;
    float4 a0pf[8], a1pf[8];
    {
        const float4* A0p = (const float4*)(A0s + (size_t)r * 4096 + pbase);
        const float4* A1p = (const float4*)(A1s + (size_t)r * 4096 + pbase);
        #pragma unroll
        for (int i = 0; i < 8; ++i) { a0pf[i] = A0p[i]; a1pf[i] = A1p[i]; }
    }
    fwd_s3(data[0], tid);
    fwd_s3(data[1], tid);
    __syncthreads();

    // ---- pointwise (A in regs, used twice) + inverse stage 1 ----
    cx vA[16], vB[16];
    pointwise_read(data[0], tid, a0pf, a1pf, vA);
    pointwise_read(data[1], tid, a0pf, a1pf, vB);
    __syncthreads();                       // all scattered Z reads done
    fft16_dit_inv_r4<false>(vA);
    fft16_dit_inv_r4<false>(vB);
    {
        cx* baseA = data[0] + fpad(pbase);
        cx* baseB = data[1] + fpad(pbase);
        #pragma unroll
        for (int i = 0; i < 16; ++i) baseA[i] = vA[i];
        #pragma unroll
        for (int i = 0; i < 16; ++i) baseB[i] = vB[i];
    }
    __syncthreads();

    // u rows: issue before inv stage 2 so drain overlaps it
    const bf16* u00 = u_t + ((size_t)(b0 * D1 + ch)) * N_SEQ;
    const bf16* u01 = u00 + N_SEQ;
    const bf16* u10 = u_t + ((size_t)(b1 * D1 + ch)) * N_SEQ;
    const bf16* u11 = u10 + N_SEQ;
    bf16x8 ua0 = *(const bf16x8*)(u00 + tid * 8);
    bf16x8 ub0 = *(const bf16x8*)(u01 + tid * 8);
    bf16x8 ua1 = *(const bf16x8*)(u10 + tid * 8);
    bf16x8 ub1 = *(const bf16x8*)(u11 + tid * 8);

    inv_s2(data[0], tid, tw2lds);
    inv_s2(data[1], tid, tw2lds);
    __syncthreads();

    inv_s3_half(data[0], tid, tw);
    inv_s3_half(data[1], tid, tw);
    __syncthreads();

    // ---- gate with u (1/M folded into A spectra) ----
    {
        const int t = tid * 8;
        bf16* g00 = gated_t + ((size_t)(b0 * D1 + ch)) * N_SEQ;
        bf16* g01 = g00 + N_SEQ;
        bf16* g10 = gated_t + ((size_t)(b1 * D1 + ch)) * N_SEQ;
        bf16* g11 = g10 + N_SEQ;
        const cx* baseA = data[0] + fpad(t);
        const cx* baseB = data[1] + fpad(t);
        bf16x8 oa, ob, oc, od;
        #pragma unroll
        for (int i = 0; i < 8; ++i) {
            cx ya = baseA[i];
            cx yb = baseB[i];
            oa[i] = (bf16)(ya.x * (float)ua0[i]);
            ob[i] = (bf16)(ya.y * (float)ub0[i]);
            oc[i] = (bf16)(yb.x * (float)ua1[i]);
            od[i] = (bf16)(yb.y * (float)ub1[i]);
        }
        *(bf16x8*)(g00 + t) = oa;
        *(bf16x8*)(g01 + t) = ob;
        *(bf16x8*)(g10 + t) = oc;
        *(bf16x8*)(g11 + t) = od;
    }
}

// ---------------------------------------------------------------------------
__global__ __launch_bounds__(256) void transpose_cs_kernel(
    const bf16* __restrict__ in, bf16* __restrict__ outp)
{
    __shared__ bf16 tile[64 * 68];
    const int c0 = blockIdx.x * 64;
    const int m0 = blockIdx.y * 64;
    const int b  = m0 >> 11;
    const int s0 = m0 & 2047;
    const int tid = threadIdx.x;
    const int cl = tid >> 4;
    const int sc = (tid & 15) * 4;
    #pragma unroll
    for (int p = 0; p < 4; ++p) {
        int c = p * 16 + cl;
        bf16x4 v = *(const bf16x4*)&in[((size_t)(b * D1 + c0 + c)) * N_SEQ + s0 + sc];
        *(bf16x4*)&tile[c * 68 + sc] = v;
    }
    __syncthreads();
    const int sl = tid >> 4;
    const int cc = (tid & 15) * 4;
    #pragma unroll
    for (int p = 0; p < 4; ++p) {
        int s = p * 16 + sl;
        bf16x4 o;
        #pragma unroll
        for (int j = 0; j < 4; ++j) o[j] = tile[(cc + j) * 68 + s];
        *(bf16x4*)&outp[((size_t)(m0 + s)) * D1 + c0 + cc] = o;
    }
}

// ---------------------------------------------------------------------------
extern "C" void kernel_launch(void* const* d_in, const int* in_sizes, int n_in,
                              void* d_out, int out_size, void* d_ws, size_t ws_size,
                              hipStream_t stream)
{
    const float* x  = (const float*)d_in[0];
    const float* Wu = (const float*)d_in[1];
    const float* bu = (const float*)d_in[2];
    const float* Wv = (const float*)d_in[3];
    const float* bv = (const float*)d_in[4];
    const float* Wo = (const float*)d_in[5];
    const float* bo = (const float*)d_in[6];
    const float* Wp = (const float*)d_in[7];
    const float* bp = (const float*)d_in[8];
    const float* Wl = (const float*)d_in[9];
    const float* bl = (const float*)d_in[10];
    const float* Wr = (const float*)d_in[11];
    const float* br = (const float*)d_in[12];
    float* out = (float*)d_out;

    float* ws      = (float*)d_ws;
    float* a_t     = ws;                       // 1536*4096 fp32; A1spec after fft_a
    float* A0spec  = a_t   + 6291456;          // 768 x 4096 cx
    float* sumsq   = A0spec + 6291456;         // 3 x 4096 fp32
    float* twd     = sumsq + 12288;            // 256 x 16 cx twiddle table
    bf16*  bfws    = (bf16*)(twd + 8192);
    bf16*  x_bf    = bfws;                     // 8192*512
    bf16*  w_bf    = x_bf    + 4194304;        // 5 x 786432: Wu,Wv,Wo,Wl,Wr
    bf16*  Wuv_bf  = w_bf;                     // stacked [Wu;Wv] 3072 x 512
    bf16*  Wo_bf   = w_bf    + 2 * 786432;
    bf16*  Wl_bf   = Wo_bf   + 786432;
    bf16*  Wr_bf   = Wl_bf   + 786432;
    bf16*  gA      = Wr_bf   + 786432;         // 4096*512
    bf16*  gB      = gA      + 2097152;        // 4096*512
    bf16*  u_t     = gB      + 2097152;        // 8192*1536 [b][c][s]
    bf16*  v_t     = u_t     + 12582912;       // 8192*1536 [b][c][s]
    bf16*  gated_t = v_t     + 12582912;       // 8192*1536 [b][c][s]
    bf16*  gated   = gated_t + 12582912;       // 8192*1536 [m][c]

    dim3 blk(256);

    // x/w converts + sumsq zero + rpe input layer + twiddle table
    f2b_all_kernel<<<4096 + 5 * 768 + 12 + 4096 + 16, blk, 0, stream>>>(
        x, Wu, Wv, Wo, Wl, Wr, Wp, bp, x_bf, w_bf, sumsq, gA, twd);

    gemm_bf16<MODE_SILU_UV, 128, bf16><<<dim3(24, 64), blk, 0, stream>>>(
        x_bf, Wuv_bf, bu, bv, u_t, v_t, 8192, 2 * D1, ED, nullptr, nullptr);

    // RPE MLP: srms folded into GEMM epilogues via row-scale commutation.
    // BN=64 -> 256 blocks (1/CU) instead of 128 (half the chip idle).
    bf16* gin = gA;
    bf16* gout = gB;
    for (int i = 0; i < 3; ++i) {
        const float* sin_p = (i == 0) ? nullptr : sumsq + (size_t)(i - 1) * 4096;
        gemm_bf16<MODE_RPE, 64, bf16><<<dim3(8, 32), blk, 0, stream>>>(
            gin, Wl_bf + (size_t)i * ED * ED, bl + (size_t)i * ED, nullptr,
            gout, nullptr, 4096, ED, ED, sin_p, sumsq + (size_t)i * 4096);
        bf16* t = gin; gin = gout; gout = t;
    }
    gemm_bf16<MODE_AT, 64, float><<<dim3(24, 32), blk, 0, stream>>>(
        gin, Wr_bf, br, nullptr, a_t, nullptr, 4096, D1, ED,
        sumsq + 2 * 4096, nullptr);

    fft_a_kernel<<<768, blk, 0, stream>>>(
        a_t, (cx*)A0spec, (cx*)a_t, (const cx*)twd);
    fft_conv_kernel<<<1536, blk, 0, stream>>>(
        v_t, (const cx*)A0spec, (const cx*)a_t, u_t, gated_t, (const cx*)twd);

    transpose_cs_kernel<<<dim3(24, 128), blk, 0, stream>>>(gated_t, gated);

    gemm_bf16<MODE_PLAIN, 64, float><<<dim3(8, 64), blk, 0, stream>>>(
        gated, Wo_bf, bo, nullptr, out, nullptr, 8192, ED, D1,
        nullptr, nullptr);
}

// Round 8
// 331.691 us; speedup vs baseline: 1.2083x; 1.0088x over previous
//
#include <hip/hip_runtime.h>

#define N_SEQ 2048
#define M_FFT 4096
#define D1    1536
#define NH    8
#define HD    192
#define ED    512

typedef __bf16 bf16;
typedef __bf16 bf16x4 __attribute__((ext_vector_type(4)));
typedef __bf16 bf16x8 __attribute__((ext_vector_type(8)));
typedef float  floatx4 __attribute__((ext_vector_type(4)));
typedef float  cx __attribute__((ext_vector_type(2)));   // complex as packed fp32

enum { MODE_PLAIN = 0, MODE_SILU_UV = 1, MODE_AT = 3, MODE_RPE = 4 };

__device__ __forceinline__ void gload16(const void* g, void* l) {
    __builtin_amdgcn_global_load_lds(
        (const __attribute__((address_space(1))) void*)g,
        (__attribute__((address_space(3))) void*)l, 16, 0, 0);
}

// ---------------------------------------------------------------------------
// bf16 MFMA GEMM, depth-4 pipeline with COUNTED vmcnt (T4), BN-templated:
//   BN=128: 4 loads/stage, vmcnt 12/8/4/0   (SILU_UV, big grid)
//   BN=64 : 3 loads/stage, vmcnt  9/6/3/0   (PLAIN/AT/RPE small-N GEMMs)
// ---------------------------------------------------------------------------
template<int MODE, int BN, typename OutT>
__global__ __launch_bounds__(256) void gemm_bf16(
    const bf16* __restrict__ A, const bf16* __restrict__ Bw,
    const float* __restrict__ bias, const float* __restrict__ bias2,
    OutT* __restrict__ C, OutT* __restrict__ C2,
    int M, int Nc, int K,
    const float* __restrict__ scale_in, float* __restrict__ sumsq_out)
{
    constexpr int NJ = BN / 32;            // n-fragments per wave (4 or 2)
    __shared__ __align__(16) bf16 As[4][128 * 32];
    __shared__ __align__(16) bf16 Bs[4][BN * 32];

    const int tid  = threadIdx.x;
    const int row0 = blockIdx.y * 128;
    const int col0 = blockIdx.x * BN;
    const int wid  = tid >> 6;
    const int lane = tid & 63;
    const int lm   = lane & 15;
    const int lk   = lane >> 4;
    const int wm   = wid >> 1;
    const int wn   = wid & 1;
    const int ldrow  = tid >> 2;
    const int ldcol8 = (tid & 3) * 8;

    floatx4 acc[4][NJ] = {};

    const bf16* Ag = A  + ((size_t)(row0 + ldrow)) * K + ldcol8;
    const bf16* Bg = Bw + ((size_t)(col0 + ldrow)) * K + ldcol8;
    const int woff = (wid * 16) * 32;

    auto stage = [&](int t, int buf) {
        const int k0 = t << 5;
        gload16(Ag + k0, &As[buf][woff]);
        gload16(Ag + (size_t)64 * K + k0, &As[buf][woff + 64 * 32]);
        gload16(Bg + k0, &Bs[buf][woff]);
        if constexpr (BN == 128)
            gload16(Bg + (size_t)64 * K + k0, &Bs[buf][woff + 64 * 32]);
    };
    auto compute = [&](int buf) {
        bf16x8 af[4], bfr[NJ];
        #pragma unroll
        for (int mi = 0; mi < 4; ++mi)
            af[mi] = *(const bf16x8*)&As[buf][(wm * 64 + mi * 16 + lm) * 32 + lk * 8];
        #pragma unroll
        for (int nj = 0; nj < NJ; ++nj)
            bfr[nj] = *(const bf16x8*)&Bs[buf][(wn * (BN / 2) + nj * 16 + lm) * 32 + lk * 8];
        #pragma unroll
        for (int mi = 0; mi < 4; ++mi)
            #pragma unroll
            for (int nj = 0; nj < NJ; ++nj)
                acc[mi][nj] = __builtin_amdgcn_mfma_f32_16x16x32_bf16(
                    af[mi], bfr[nj], acc[mi][nj], 0, 0, 0);
    };

#define GEMM_STEP(T, BUF, DOSTAGE, VM)                                  \
    do {                                                                \
        __builtin_amdgcn_s_barrier();          /* A: compute(t-1) done */\
        __builtin_amdgcn_sched_barrier(0);                              \
        if (DOSTAGE) stage((T) + 3, ((T) + 3) & 3);                     \
        asm volatile("s_waitcnt vmcnt(" #VM ")" ::: "memory");          \
        __builtin_amdgcn_s_barrier();          /* B: tile T fully in LDS */\
        __builtin_amdgcn_sched_barrier(0);                              \
        compute(BUF);                                                   \
    } while (0)

    const int nt = K >> 5;           // 16 or 48; nt % 4 == 0
    stage(0, 0);
    stage(1, 1);
    stage(2, 2);
    if constexpr (BN == 128) {
        for (int t4 = 0; t4 < nt - 4; t4 += 4) {
            GEMM_STEP(t4 + 0, 0, true, 12);
            GEMM_STEP(t4 + 1, 1, true, 12);
            GEMM_STEP(t4 + 2, 2, true, 12);
            GEMM_STEP(t4 + 3, 3, true, 12);
        }
        GEMM_STEP(nt - 4, 0, true, 12);
        GEMM_STEP(nt - 3, 1, false, 8);
        GEMM_STEP(nt - 2, 2, false, 4);
        GEMM_STEP(nt - 1, 3, false, 0);
    } else {
        for (int t4 = 0; t4 < nt - 4; t4 += 4) {
            GEMM_STEP(t4 + 0, 0, true, 9);
            GEMM_STEP(t4 + 1, 1, true, 9);
            GEMM_STEP(t4 + 2, 2, true, 9);
            GEMM_STEP(t4 + 3, 3, true, 9);
        }
        GEMM_STEP(nt - 4, 0, true, 9);
        GEMM_STEP(nt - 3, 1, false, 6);
        GEMM_STEP(nt - 2, 2, false, 3);
        GEMM_STEP(nt - 1, 3, false, 0);
    }
#undef GEMM_STEP

    const float* bs = bias;
    OutT* dst = C;
    int cadj = 0;
    if (MODE == MODE_SILU_UV && col0 >= D1) { bs = bias2; dst = C2; cadj = D1; }

    float bcol[NJ];
    #pragma unroll
    for (int nj = 0; nj < NJ; ++nj)
        bcol[nj] = bs[col0 - cadj + wn * (BN / 2) + nj * 16 + lm];

    if (MODE == MODE_RPE) {
        #pragma unroll
        for (int mi = 0; mi < 4; ++mi) {
            #pragma unroll
            for (int r = 0; r < 4; ++r) {
                const int row = row0 + wm * 64 + mi * 16 + lk * 4 + r;
                float sc = 1.0f;
                if (scale_in)
                    sc = 1.0f / (sqrtf(scale_in[row]) * 0.04419417382415922f + 1e-8f);
                float ssq = 0.0f;
                #pragma unroll
                for (int nj = 0; nj < NJ; ++nj) {
                    const int col = col0 + wn * (BN / 2) + nj * 16 + lm;
                    float val = acc[mi][nj][r] * sc + bcol[nj];
                    ssq += val * val;
                    ((bf16*)C)[(size_t)row * Nc + col] = (bf16)fmaxf(val, 0.0f);
                }
                ssq += __shfl_xor(ssq, 1, 64);
                ssq += __shfl_xor(ssq, 2, 64);
                ssq += __shfl_xor(ssq, 4, 64);
                ssq += __shfl_xor(ssq, 8, 64);
                if (lm == 0) atomicAdd(&sumsq_out[row], ssq);
            }
        }
        return;
    }

    #pragma unroll
    for (int mi = 0; mi < 4; ++mi) {
        const int rbase = row0 + wm * 64 + mi * 16 + lk * 4;
        float sc[4];
        #pragma unroll
        for (int r = 0; r < 4; ++r) {
            sc[r] = 1.0f;
            if (MODE == MODE_AT && scale_in)
                sc[r] = 1.0f / (sqrtf(scale_in[rbase + r]) * 0.04419417382415922f + 1e-8f);
        }
        #pragma unroll
        for (int nj = 0; nj < NJ; ++nj) {
            const int col = col0 - cadj + wn * (BN / 2) + nj * 16 + lm;
            float vals[4];
            #pragma unroll
            for (int r = 0; r < 4; ++r) {
                float val = acc[mi][nj][r] * sc[r] + bcol[nj];
                if (MODE == MODE_SILU_UV)
                    val = val * __fdividef(1.0f, 1.0f + __expf(-val));
                vals[r] = val;
            }
            if (MODE == MODE_SILU_UV) {
                int b = rbase >> 11, s = rbase & 2047;
                bf16x4 o;
                #pragma unroll
                for (int r = 0; r < 4; ++r) o[r] = (bf16)vals[r];
                *(bf16x4*)&((bf16*)dst)[((size_t)(b * D1 + col)) * N_SEQ + s] = o;
            } else if (MODE == MODE_AT) {
                float4 o = make_float4(vals[0], vals[1], vals[2], vals[3]);
                *(float4*)&((float*)C)[(size_t)col * M + rbase] = o;
            } else {
                #pragma unroll
                for (int r = 0; r < 4; ++r)
                    C[(size_t)(rbase + r) * Nc + col] = (OutT)vals[r];
            }
        }
    }
}

// ---------------------------------------------------------------------------
// mega-prologue: x convert + 5 weight converts + sumsq zero +
// RPE input layer w/ srms + FFT twiddle table (256 x 16 cx)
// ---------------------------------------------------------------------------
__global__ __launch_bounds__(256) void f2b_all_kernel(
    const float* __restrict__ x,  const float* __restrict__ s0,
    const float* __restrict__ s1, const float* __restrict__ s2,
    const float* __restrict__ s3, const float* __restrict__ s4,
    const float* __restrict__ Wp, const float* __restrict__ bp,
    bf16* __restrict__ x_bf, bf16* __restrict__ w_bf,
    float* __restrict__ sumsq, bf16* __restrict__ g0,
    float* __restrict__ twd)
{
    const int bid = blockIdx.x;
    const int tid = threadIdx.x;
    __shared__ float red[4];

    if (bid < 7936) {
        const float* src;
        bf16* dst;
        size_t off;
        if (bid < 4096) {
            src = x; dst = x_bf; off = (size_t)bid * 1024;
        } else {
            int t = bid - 4096;
            int seg = t / 768;
            src = seg == 0 ? s0 : seg == 1 ? s1 : seg == 2 ? s2
                : seg == 3 ? s3 : s4;
            dst = w_bf + (size_t)seg * 786432;
            off = (size_t)(t % 768) * 1024;
        }
        size_t i = off + (size_t)tid * 4;
        float4 f = *(const float4*)(src + i);
        union { bf16 h[4]; short4 s; } u4;
        u4.h[0] = (bf16)f.x; u4.h[1] = (bf16)f.y;
        u4.h[2] = (bf16)f.z; u4.h[3] = (bf16)f.w;
        *(short4*)(dst + i) = u4.s;
    } else if (bid < 7948) {
        size_t i = (size_t)(bid - 7936) * 1024 + (size_t)tid * 4;
        *(float4*)(sumsq + i) = make_float4(0.f, 0.f, 0.f, 0.f);
    } else if (bid < 12044) {
        const int j = bid - 7948;
        float idxv = (j < N_SEQ) ? (float)j
                                 : (j == N_SEQ ? 0.0f : (float)(j - 2 * N_SEQ));
        float h1 = idxv * Wp[tid] + bp[tid];
        float h2 = idxv * Wp[tid + 256] + bp[tid + 256];
        float ss = h1 * h1 + h2 * h2;
        #pragma unroll
        for (int off = 32; off > 0; off >>= 1) ss += __shfl_down(ss, off, 64);
        if ((tid & 63) == 0) red[tid >> 6] = ss;
        __syncthreads();
        float tot = red[0] + red[1] + red[2] + red[3];
        float scale = 1.0f / (sqrtf(tot) * 0.04419417382415922f + 1e-8f);
        g0[(size_t)j * ED + tid]       = (bf16)fmaxf(h1 * scale, 0.0f);
        g0[(size_t)j * ED + tid + 256] = (bf16)fmaxf(h2 * scale, 0.0f);
    } else {
        const int idx = (bid - 12044) * 256 + tid;    // [0, 4096)
        const int j = idx >> 4, tau = idx & 15;
        float sA, cA;
        __sincosf(-6.283185307179586f * (float)(j * tau) * (1.0f / 4096.0f),
                  &sA, &cA);
        cx w; w.x = cA; w.y = sA;
        ((cx*)twd)[idx] = w;
    }
}

// ---------------------------------------------------------------------------
// Radix-16 FFT, radix-4 butterflies, packed-fp32 complex.
// LDS addressing: fpad(base + s*t) = fpad(base) + s'*t  (256->274, 16->17, 1->1)
// Stage-1/inv-3 twiddle row (tid<<4) in REGISTERS (inverse = conjugate);
// stage-2/inv-2 rows (16 distinct) in a 2 KB LDS broadcast table.
// Register-residency: fwd-s3 output (bins [tid*16,tid*16+16)) stays in regs
// across the barrier -> pointwise reads ONLY the partner block from LDS;
// inv-s3 output (samples tid+256t) gates directly to global (strided
// coalesced), removing the last LDS round-trip + barrier.
// ---------------------------------------------------------------------------
#define FFT_LDS_SZ 4381

__device__ __forceinline__ int fpad(int i) { return i + (i >> 4) + 2 * (i >> 8); }

__device__ __forceinline__ cx mkcx(float a, float b) { cx r; r.x = a; r.y = b; return r; }
__device__ __forceinline__ cx cmul(cx a, cx b) {
    cx br = mkcx(-b.y, b.x);
    return a.xx * b + a.yy * br;
}
__device__ __forceinline__ cx cmul_cj(cx a, cx b) {      // a * conj(b)
    cx bc = mkcx(b.x, -b.y);
    cx br = mkcx(b.y, b.x);
    return a.xx * bc + a.yy * br;
}
__device__ __forceinline__ cx cneg_i(cx a) { return mkcx(a.y, -a.x); }   // a * (-i)
__device__ __forceinline__ cx cpos_i(cx a) { return mkcx(-a.y, a.x); }   // a * (+i)
__host__ __device__ constexpr int brev4(int t) {
    return ((t & 1) << 3) | ((t & 2) << 1) | ((t & 4) >> 1) | ((t & 8) >> 3);
}

#define CC1 0.9238795325112867f
#define SS1 0.3826834323650898f
#define RR2 0.7071067811865476f

template<bool HZ>
__device__ __forceinline__ void fft16_dif_r4(cx x[16]) {
    const cx W1 = mkcx( CC1, -SS1);
    const cx W2 = mkcx( RR2, -RR2);
    const cx W3 = mkcx( SS1, -CC1);
    const cx W6 = mkcx(-RR2, -RR2);
    const cx W9 = mkcx(-CC1,  SS1);
    #pragma unroll
    for (int n = 0; n < 4; ++n) {
        cx A, B, C, D;
        if (HZ) { A = x[n]; C = x[n]; B = x[n + 4]; D = x[n + 4]; }
        else {
            A = x[n] + x[n + 8];      C = x[n] - x[n + 8];
            B = x[n + 4] + x[n + 12]; D = x[n + 4] - x[n + 12];
        }
        cx s = A - B;
        cx nid = cneg_i(D);
        cx m = C + nid;
        cx p = C - nid;
        x[n] = A + B;
        if (n == 0)      { x[4] = s;            x[8]  = m;           x[12] = p; }
        else if (n == 1) { x[5] = cmul(s, W2);  x[9]  = cmul(m, W1); x[13] = cmul(p, W3); }
        else if (n == 2) { x[6] = cneg_i(s);    x[10] = cmul(m, W2); x[14] = cmul(p, W6); }
        else             { x[7] = cmul(s, W6);  x[11] = cmul(m, W3); x[15] = cmul(p, W9); }
    }
    #pragma unroll
    for (int q = 0; q < 16; q += 4) {
        cx a = x[q], b = x[q + 1], c = x[q + 2], d = x[q + 3];
        cx a1 = a + c, c1 = a - c;
        cx b1 = b + d, d1 = cneg_i(b - d);
        x[q]     = a1 + b1;
        x[q + 1] = a1 - b1;
        x[q + 2] = c1 + d1;
        x[q + 3] = c1 - d1;
    }
}

template<bool HALF_OUT>
__device__ __forceinline__ void fft16_dit_inv_r4(cx x[16]) {
    const cx V1 = mkcx( CC1, SS1);
    const cx V2 = mkcx( RR2, RR2);
    const cx V3 = mkcx( SS1, CC1);
    const cx V6 = mkcx(-RR2, RR2);
    #pragma unroll
    for (int q = 0; q < 16; q += 4) {
        cx a = x[q], b = x[q + 1], c = x[q + 2], d = x[q + 3];
        cx a1 = a + b, b1 = a - b;
        cx c1 = c + d, d1 = c - d;
        cx t = cpos_i(d1);
        x[q]     = a1 + c1;
        x[q + 2] = a1 - c1;
        x[q + 1] = b1 + t;
        x[q + 3] = b1 - t;
    }
    #pragma unroll
    for (int n = 0; n < 4; ++n) {
        cx t1, t2;
        if (n == 0)      { t1 = x[4];             t2 = x[12]; }
        else if (n == 1) { t1 = cmul(x[5],  V2);  t2 = cmul(x[13], V2); }
        else if (n == 2) { t1 = cpos_i(x[6]);     t2 = cpos_i(x[14]); }
        else             { t1 = cmul(x[7],  V6);  t2 = cmul(x[15], V6); }
        cx P = x[n] + t1, Q = x[n] - t1;
        cx R = x[n + 8] + t2, S = x[n + 8] - t2;
        cx t, u;
        if (n == 0)      { t = R;            u = S; }
        else if (n == 1) { t = cmul(R, V1);  u = cmul(S, V1); }
        else if (n == 2) { t = cmul(R, V2);  u = cmul(S, V2); }
        else             { t = cmul(R, V3);  u = cmul(S, V3); }
        cx iu = cpos_i(u);
        x[n]     = P + t;
        x[n + 4] = Q + iu;
        if (!HALF_OUT) {
            x[n + 8]  = P - t;
            x[n + 12] = Q - iu;
        }
    }
}

template<bool CONJ>
__device__ __forceinline__ void apply_tw(cx v[16], const cx tw[16]) {
    #pragma unroll
    for (int tau = 1; tau < 16; ++tau) {
        const int q = brev4(tau);
        v[q] = CONJ ? cmul_cj(v[q], tw[tau]) : cmul(v[q], tw[tau]);
    }
}

// twrow points at tw2lds + (tid&15); stride 16 per tau. Broadcast reads.
template<bool CONJ>
__device__ __forceinline__ void apply_tw_lds(cx v[16], const cx* twrow) {
    #pragma unroll
    for (int tau = 1; tau < 16; ++tau) {
        cx w = twrow[tau * 16];
        const int q = brev4(tau);
        v[q] = CONJ ? cmul_cj(v[q], w) : cmul(v[q], w);
    }
}

// ---- per-stage helpers (in-place per-thread; caller places barriers) ------
__device__ __forceinline__ void fwd_s1_store_hz(
    const cx vin[8], const cx tw[16], cx* d, int tid)
{
    cx x[16];
    #pragma unroll
    for (int t = 0; t < 8; ++t) x[t] = vin[t];
    fft16_dif_r4<true>(x);
    apply_tw<false>(x, tw);
    cx* base = d + fpad(tid);
    #pragma unroll
    for (int p = 0; p < 16; ++p) base[274 * p] = x[p];
}

__device__ __forceinline__ void fwd_s2(cx* d, int tid, const cx* tw2lds)
{
    cx v[16];
    cx* base = d + fpad(((tid >> 4) << 8) + (tid & 15));
    #pragma unroll
    for (int t = 0; t < 16; ++t) v[t] = base[17 * t];
    fft16_dif_r4<false>(v);
    apply_tw_lds<false>(v, tw2lds + (tid & 15));
    #pragma unroll
    for (int p = 0; p < 16; ++p) base[17 * p] = v[p];
}

// stage 3: keeps result in v (thread owns bins [tid*16, tid*16+16))
__device__ __forceinline__ void fwd_s3_keep(cx* d, int tid, cx v[16])
{
    cx* base = d + fpad(tid << 4);
    #pragma unroll
    for (int t = 0; t < 16; ++t) v[t] = base[t];
    fft16_dif_r4<false>(v);
    #pragma unroll
    for (int p = 0; p < 16; ++p) base[p] = v[p];
}

__device__ __forceinline__ void inv_s2(cx* d, int tid, const cx* tw2lds)
{
    cx v[16];
    cx* base = d + fpad(((tid >> 4) << 8) + (tid & 15));
    #pragma unroll
    for (int p = 0; p < 16; ++p) v[p] = base[17 * p];
    apply_tw_lds<true>(v, tw2lds + (tid & 15));
    fft16_dit_inv_r4<false>(v);
    #pragma unroll
    for (int t = 0; t < 16; ++t) base[17 * t] = v[t];
}

// inv stage 3 (lower half) fused with the u-gate: output stays in regs and
// goes straight to global at n = tid + 256*t (coalesced strided).
__device__ __forceinline__ void inv_s3_gate(
    const cx* d, int tid, const cx tw[16],
    const bf16 ua[8], const bf16 ub[8],
    bf16* __restrict__ g0, bf16* __restrict__ g1)
{
    cx v[16];
    const cx* base = d + fpad(tid);
    #pragma unroll
    for (int p = 0; p < 16; ++p) v[p] = base[274 * p];
    apply_tw<true>(v, tw);
    fft16_dit_inv_r4<true>(v);
    #pragma unroll
    for (int t = 0; t < 8; ++t) {
        const int n = tid + 256 * t;
        g0[n] = (bf16)(v[t].x * (float)ua[t]);
        g1[n] = (bf16)(v[t].y * (float)ub[t]);
    }
}

// pointwise using own fwd-s3 regs (v in: Z block; v out: Y block).
// Only the conjugate-partner block is read from LDS (thread 0: none).
__device__ __forceinline__ void pointwise_regs(
    const cx* d, int tid, const float4 a0pf[8], const float4 a1pf[8],
    cx v[16])
{
    auto pf = [](const float4* p, int i) -> cx {
        return (i & 1) ? mkcx(p[i >> 1].z, p[i >> 1].w)
                       : mkcx(p[i >> 1].x, p[i >> 1].y);
    };
    const int pbase = tid << 4;
    cx zm[16];
    if (tid == 0) {
        #pragma unroll
        for (int i = 0; i < 16; ++i) {
            const int p2 = (i < 2) ? i : (i ^ ((1 << (31 - __clz(i))) - 1));
            zm[i] = v[p2];                    // compile-time index
        }
    } else {
        const int mask = (1 << (31 - __clz(pbase))) - 1;
        const cx* zb2 = d + fpad((pbase ^ mask) - 15);
        #pragma unroll
        for (int i = 0; i < 16; ++i) zm[i] = zb2[15 - i];
    }
    #pragma unroll
    for (int i = 0; i < 16; ++i) {
        cx Zk = v[i];
        cx cjZm = mkcx(zm[i].x, -zm[i].y);
        cx V0 = Zk + cjZm;
        cx V1 = cneg_i(Zk - cjZm);
        v[i] = cmul(V0, pf(a0pf, i)) + cpos_i(cmul(V1, pf(a1pf, i)));
    }
}

// ---------------------------------------------------------------------------
// Forward FFT of packed (a_ch0, a_ch1) pair, unpack both real spectra in
// DIF order (conjugate-partner: p2 = p ^ (2^floor(log2 p) - 1)).
// A0 = c*(Wk + conj(Wm)), A1 = c*(-i)*(Wk - conj(Wm)), c = 0.25/4096.
// Wk comes from fwd-s3 registers; only Wm is read from LDS.
// ---------------------------------------------------------------------------
__global__ __launch_bounds__(256, 4) void fft_a_kernel(
    const float* a_t, cx* __restrict__ A0s, cx* A1s,
    const cx* __restrict__ Twd)
{
    __shared__ cx data[FFT_LDS_SZ];
    __shared__ cx tw2lds[256];
    const int tid = threadIdx.x;
    const int r = blockIdx.x;                      // pair index, ch = 2r

    cx tw[16];
    {
        const cx* Tr1 = Twd + (tid << 4);
        #pragma unroll
        for (int t = 1; t < 16; ++t) tw[t] = Tr1[t];
        tw2lds[(tid >> 4) * 16 + (tid & 15)] = Twd[(tid & 15) * 256 + (tid >> 4)];
    }

    const float* r0 = a_t + (size_t)(2 * r) * M_FFT;
    const float* r1 = r0 + M_FFT;
    cx v[16];
    #pragma unroll
    for (int t = 0; t < 16; ++t)
        v[t] = mkcx(r0[tid + 256 * t], r1[tid + 256 * t]);

    {   // stage 1 from registers
        fft16_dif_r4<false>(v);
        apply_tw<false>(v, tw);
        cx* base = data + fpad(tid);
        #pragma unroll
        for (int p = 0; p < 16; ++p) base[274 * p] = v[p];
    }
    __syncthreads();
    fwd_s2(data, tid, tw2lds);
    __syncthreads();
    fwd_s3_keep(data, tid, v);
    __syncthreads();

    const float c = 0.25f / 4096.0f;
    const int base_i = tid << 4;
    cx* A0row = A0s + (size_t)r * 4096;
    cx* A1row = A1s + (size_t)r * 4096;
    cx wm[16];
    if (tid == 0) {
        #pragma unroll
        for (int i = 0; i < 16; ++i) {
            const int p2 = (i < 2) ? i : (i ^ ((1 << (31 - __clz(i))) - 1));
            wm[i] = v[p2];
        }
    } else {
        const int mask = (1 << (31 - __clz(base_i))) - 1;
        const cx* zb2 = data + fpad((base_i ^ mask) - 15);
        #pragma unroll
        for (int i = 0; i < 16; ++i) wm[i] = zb2[15 - i];
    }
    #pragma unroll
    for (int i = 0; i < 16; ++i) {
        cx cjWm = mkcx(wm[i].x, -wm[i].y);
        A0row[base_i + i] = c * (v[i] + cjWm);
        A1row[base_i + i] = c * cneg_i(v[i] - cjWm);
    }
}

// ---------------------------------------------------------------------------
// Conv kernel: TWO channel-pairs per block (batches 2bp and 2bp+1 of the
// SAME r) -> 2x work per barrier region, A rows loaded once for both.
// Bijective XCD remap: xcd = r&7; slots pair (r,bp=0),(r,bp=1) adjacent.
// 6 barriers; fwd-s3/pointwise and inv-s3/gate run register-resident.
// ---------------------------------------------------------------------------
__global__ __launch_bounds__(256, 2) void fft_conv_kernel(
    const bf16* __restrict__ v_t, const cx* __restrict__ A0s,
    const cx* __restrict__ A1s, const bf16* __restrict__ u_t,
    bf16* __restrict__ gated_t, const cx* __restrict__ Twd)
{
    __shared__ cx data[2][FFT_LDS_SZ];
    __shared__ cx tw2lds[256];
    const int tid = threadIdx.x;
    const int bx = blockIdx.x;
    const int xcd  = bx & 7;
    const int slot = bx >> 3;                 // [0,192)
    const int bp   = slot & 1;
    const int r    = (slot >> 1) * 8 + xcd;   // [0,768), bijective
    const int ch   = 2 * r;
    const int b0   = 2 * bp;
    const int b1   = 2 * bp + 1;

    cx tw[16];
    {
        const cx* Tr1 = Twd + (tid << 4);
        #pragma unroll
        for (int t = 1; t < 16; ++t) tw[t] = Tr1[t];
        tw2lds[(tid >> 4) * 16 + (tid & 15)] = Twd[(tid & 15) * 256 + (tid >> 4)];
    }

    // ---- forward stage 1: both chunks straight from global ----
    const bf16* z00 = v_t + ((size_t)(b0 * D1 + ch)) * N_SEQ;
    const bf16* z01 = z00 + N_SEQ;
    const bf16* z10 = v_t + ((size_t)(b1 * D1 + ch)) * N_SEQ;
    const bf16* z11 = z10 + N_SEQ;
    {
        cx w0[8], w1[8];
        #pragma unroll
        for (int t = 0; t < 8; ++t)
            w0[t] = mkcx((float)z00[tid + 256 * t], (float)z01[tid + 256 * t]);
        #pragma unroll
        for (int t = 0; t < 8; ++t)
            w1[t] = mkcx((float)z10[tid + 256 * t], (float)z11[tid + 256 * t]);
        fwd_s1_store_hz(w0, tw, data[0], tid);
        fwd_s1_store_hz(w1, tw, data[1], tid);
    }
    __syncthreads();                                              // 1

    fwd_s2(data[0], tid, tw2lds);
    fwd_s2(data[1], tid, tw2lds);
    __syncthreads();                                              // 2

    // A rows (shared by both chunks): issue before stage-3 compute so the
    // pre-barrier vmcnt drain overlaps both chunks' stage 3.
    const int pbase = tid << 4;
    float4 a0pf[8], a1pf[8];
    {
        const float4* A0p = (const float4*)(A0s + (size_t)r * 4096 + pbase);
        const float4* A1p = (const float4*)(A1s + (size_t)r * 4096 + pbase);
        #pragma unroll
        for (int i = 0; i < 8; ++i) { a0pf[i] = A0p[i]; a1pf[i] = A1p[i]; }
    }
    cx vA[16], vB[16];
    fwd_s3_keep(data[0], tid, vA);
    fwd_s3_keep(data[1], tid, vB);
    __syncthreads();                                              // 3

    // ---- pointwise (own Z from regs, partner from LDS; A in regs x2) ----
    pointwise_regs(data[0], tid, a0pf, a1pf, vA);
    pointwise_regs(data[1], tid, a0pf, a1pf, vB);
    __syncthreads();                       // 4: partner reads done
    fft16_dit_inv_r4<false>(vA);
    fft16_dit_inv_r4<false>(vB);
    {
        cx* baseA = data[0] + fpad(pbase);
        cx* baseB = data[1] + fpad(pbase);
        #pragma unroll
        for (int i = 0; i < 16; ++i) baseA[i] = vA[i];
        #pragma unroll
        for (int i = 0; i < 16; ++i) baseB[i] = vB[i];
    }
    __syncthreads();                                              // 5

    // u rows (strided layout matching inv-s3 ownership): issue before inv
    // stage 2 so the latency hides under it.
    const bf16* u00 = u_t + ((size_t)(b0 * D1 + ch)) * N_SEQ;
    const bf16* u01 = u00 + N_SEQ;
    const bf16* u10 = u_t + ((size_t)(b1 * D1 + ch)) * N_SEQ;
    const bf16* u11 = u10 + N_SEQ;
    bf16 ua0[8], ub0[8], ua1[8], ub1[8];
    #pragma unroll
    for (int t = 0; t < 8; ++t) {
        const int n = tid + 256 * t;
        ua0[t] = u00[n]; ub0[t] = u01[n];
        ua1[t] = u10[n]; ub1[t] = u11[n];
    }

    inv_s2(data[0], tid, tw2lds);
    inv_s2(data[1], tid, tw2lds);
    __syncthreads();                                              // 6

    bf16* g00 = gated_t + ((size_t)(b0 * D1 + ch)) * N_SEQ;
    bf16* g01 = g00 + N_SEQ;
    bf16* g10 = gated_t + ((size_t)(b1 * D1 + ch)) * N_SEQ;
    bf16* g11 = g10 + N_SEQ;
    inv_s3_gate(data[0], tid, tw, ua0, ub0, g00, g01);
    inv_s3_gate(data[1], tid, tw, ua1, ub1, g10, g11);
}

// ---------------------------------------------------------------------------
__global__ __launch_bounds__(256) void transpose_cs_kernel(
    const bf16* __restrict__ in, bf16* __restrict__ outp)
{
    __shared__ bf16 tile[64 * 68];
    const int c0 = blockIdx.x * 64;
    const int m0 = blockIdx.y * 64;
    const int b  = m0 >> 11;
    const int s0 = m0 & 2047;
    const int tid = threadIdx.x;
    const int cl = tid >> 4;
    const int sc = (tid & 15) * 4;
    #pragma unroll
    for (int p = 0; p < 4; ++p) {
        int c = p * 16 + cl;
        bf16x4 v = *(const bf16x4*)&in[((size_t)(b * D1 + c0 + c)) * N_SEQ + s0 + sc];
        *(bf16x4*)&tile[c * 68 + sc] = v;
    }
    __syncthreads();
    const int sl = tid >> 4;
    const int cc = (tid & 15) * 4;
    #pragma unroll
    for (int p = 0; p < 4; ++p) {
        int s = p * 16 + sl;
        bf16x4 o;
        #pragma unroll
        for (int j = 0; j < 4; ++j) o[j] = tile[(cc + j) * 68 + s];
        *(bf16x4*)&outp[((size_t)(m0 + s)) * D1 + c0 + cc] = o;
    }
}

// ---------------------------------------------------------------------------
extern "C" void kernel_launch(void* const* d_in, const int* in_sizes, int n_in,
                              void* d_out, int out_size, void* d_ws, size_t ws_size,
                              hipStream_t stream)
{
    const float* x  = (const float*)d_in[0];
    const float* Wu = (const float*)d_in[1];
    const float* bu = (const float*)d_in[2];
    const float* Wv = (const float*)d_in[3];
    const float* bv = (const float*)d_in[4];
    const float* Wo = (const float*)d_in[5];
    const float* bo = (const float*)d_in[6];
    const float* Wp = (const float*)d_in[7];
    const float* bp = (const float*)d_in[8];
    const float* Wl = (const float*)d_in[9];
    const float* bl = (const float*)d_in[10];
    const float* Wr = (const float*)d_in[11];
    const float* br = (const float*)d_in[12];
    float* out = (float*)d_out;

    float* ws      = (float*)d_ws;
    float* a_t     = ws;                       // 1536*4096 fp32; A1spec after fft_a
    float* A0spec  = a_t   + 6291456;          // 768 x 4096 cx
    float* sumsq   = A0spec + 6291456;         // 3 x 4096 fp32
    float* twd     = sumsq + 12288;            // 256 x 16 cx twiddle table
    bf16*  bfws    = (bf16*)(twd + 8192);
    bf16*  x_bf    = bfws;                     // 8192*512
    bf16*  w_bf    = x_bf    + 4194304;        // 5 x 786432: Wu,Wv,Wo,Wl,Wr
    bf16*  Wuv_bf  = w_bf;                     // stacked [Wu;Wv] 3072 x 512
    bf16*  Wo_bf   = w_bf    + 2 * 786432;
    bf16*  Wl_bf   = Wo_bf   + 786432;
    bf16*  Wr_bf   = Wl_bf   + 786432;
    bf16*  gA      = Wr_bf   + 786432;         // 4096*512
    bf16*  gB      = gA      + 2097152;        // 4096*512
    bf16*  u_t     = gB      + 2097152;        // 8192*1536 [b][c][s]
    bf16*  v_t     = u_t     + 12582912;       // 8192*1536 [b][c][s]
    bf16*  gated_t = v_t     + 12582912;       // 8192*1536 [b][c][s]
    bf16*  gated   = gated_t + 12582912;       // 8192*1536 [m][c]

    dim3 blk(256);

    // x/w converts + sumsq zero + rpe input layer + twiddle table
    f2b_all_kernel<<<4096 + 5 * 768 + 12 + 4096 + 16, blk, 0, stream>>>(
        x, Wu, Wv, Wo, Wl, Wr, Wp, bp, x_bf, w_bf, sumsq, gA, twd);

    gemm_bf16<MODE_SILU_UV, 128, bf16><<<dim3(24, 64), blk, 0, stream>>>(
        x_bf, Wuv_bf, bu, bv, u_t, v_t, 8192, 2 * D1, ED, nullptr, nullptr);

    // RPE MLP: srms folded into GEMM epilogues via row-scale commutation.
    bf16* gin = gA;
    bf16* gout = gB;
    for (int i = 0; i < 3; ++i) {
        const float* sin_p = (i == 0) ? nullptr : sumsq + (size_t)(i - 1) * 4096;
        gemm_bf16<MODE_RPE, 64, bf16><<<dim3(8, 32), blk, 0, stream>>>(
            gin, Wl_bf + (size_t)i * ED * ED, bl + (size_t)i * ED, nullptr,
            gout, nullptr, 4096, ED, ED, sin_p, sumsq + (size_t)i * 4096);
        bf16* t = gin; gin = gout; gout = t;
    }
    gemm_bf16<MODE_AT, 64, float><<<dim3(24, 32), blk, 0, stream>>>(
        gin, Wr_bf, br, nullptr, a_t, nullptr, 4096, D1, ED,
        sumsq + 2 * 4096, nullptr);

    fft_a_kernel<<<768, blk, 0, stream>>>(
        a_t, (cx*)A0spec, (cx*)a_t, (const cx*)twd);
    fft_conv_kernel<<<1536, blk, 0, stream>>>(
        v_t, (const cx*)A0spec, (const cx*)a_t, u_t, gated_t, (const cx*)twd);

    transpose_cs_kernel<<<dim3(24, 128), blk, 0, stream>>>(gated_t, gated);

    gemm_bf16<MODE_PLAIN, 64, float><<<dim3(8, 64), blk, 0, stream>>>(
        gated, Wo_bf, bo, nullptr, out, nullptr, 8192, ED, D1,
        nullptr, nullptr);
}

// Round 9
// 330.563 us; speedup vs baseline: 1.2124x; 1.0034x over previous
//
#include <hip/hip_runtime.h>

#define N_SEQ 2048
#define M_FFT 4096
#define D1    1536
#define NH    8
#define HD    192
#define ED    512

typedef __bf16 bf16;
typedef __bf16 bf16x4 __attribute__((ext_vector_type(4)));
typedef __bf16 bf16x8 __attribute__((ext_vector_type(8)));
typedef float  floatx4 __attribute__((ext_vector_type(4)));
typedef float  cx __attribute__((ext_vector_type(2)));   // complex as packed fp32

enum { MODE_PLAIN = 0, MODE_SILU_UV = 1, MODE_AT = 3, MODE_RPE = 4 };

__device__ __forceinline__ void gload16(const void* g, void* l) {
    __builtin_amdgcn_global_load_lds(
        (const __attribute__((address_space(1))) void*)g,
        (__attribute__((address_space(3))) void*)l, 16, 0, 0);
}

// ---------------------------------------------------------------------------
// bf16 MFMA GEMM, depth-4 pipeline with COUNTED vmcnt (T4), BN-templated,
// + T2 granule-XOR LDS swizzle + T5 setprio around the MFMA cluster.
//
// Swizzle (both-sides, rule #21): LDS dest of global_load_lds stays LINEAR;
// the per-lane GLOBAL source col is pre-swizzled so that LDS[row][g] holds
// global granule g ^ ((row>>1)&3); reads apply the same XOR. This turns the
// 8-way ds_read_b128 bank conflict of the row-major [rows][64B] tile into a
// free 2-way (row identity: (r>>1)&3 == (lane>>3)&3 on the write side,
// == (lm>>1)&3 on the read side, independent of mi/nj/wm/wn).
// ---------------------------------------------------------------------------
template<int MODE, int BN, typename OutT>
__global__ __launch_bounds__(256) void gemm_bf16(
    const bf16* __restrict__ A, const bf16* __restrict__ Bw,
    const float* __restrict__ bias, const float* __restrict__ bias2,
    OutT* __restrict__ C, OutT* __restrict__ C2,
    int M, int Nc, int K,
    const float* __restrict__ scale_in, float* __restrict__ sumsq_out)
{
    constexpr int NJ = BN / 32;            // n-fragments per wave (4 or 2)
    __shared__ __align__(16) bf16 As[4][128 * 32];
    __shared__ __align__(16) bf16 Bs[4][BN * 32];

    const int tid  = threadIdx.x;
    const int row0 = blockIdx.y * 128;
    const int col0 = blockIdx.x * BN;
    const int wid  = tid >> 6;
    const int lane = tid & 63;
    const int lm   = lane & 15;
    const int lk   = lane >> 4;
    const int wm   = wid >> 1;
    const int wn   = wid & 1;
    const int ldrow  = tid >> 2;
    // T2 write-side: source granule = (tid&3) ^ ((row>>1)&3), row = tid>>2
    const int ldcol8 = (((tid & 3) ^ ((tid >> 3) & 3))) * 8;
    // T2 read-side: granule = lk ^ ((row>>1)&3) = lk ^ ((lm>>1)&3)
    const int gsw = (lk ^ ((lm >> 1) & 3)) * 8;

    floatx4 acc[4][NJ] = {};

    const bf16* Ag = A  + ((size_t)(row0 + ldrow)) * K + ldcol8;
    const bf16* Bg = Bw + ((size_t)(col0 + ldrow)) * K + ldcol8;
    const int woff = (wid * 16) * 32;

    auto stage = [&](int t, int buf) {
        const int k0 = t << 5;
        gload16(Ag + k0, &As[buf][woff]);
        gload16(Ag + (size_t)64 * K + k0, &As[buf][woff + 64 * 32]);
        gload16(Bg + k0, &Bs[buf][woff]);
        if constexpr (BN == 128)
            gload16(Bg + (size_t)64 * K + k0, &Bs[buf][woff + 64 * 32]);
    };
    auto compute = [&](int buf) {
        bf16x8 af[4], bfr[NJ];
        #pragma unroll
        for (int mi = 0; mi < 4; ++mi)
            af[mi] = *(const bf16x8*)&As[buf][(wm * 64 + mi * 16 + lm) * 32 + gsw];
        #pragma unroll
        for (int nj = 0; nj < NJ; ++nj)
            bfr[nj] = *(const bf16x8*)&Bs[buf][(wn * (BN / 2) + nj * 16 + lm) * 32 + gsw];
        __builtin_amdgcn_s_setprio(1);                 // T5
        #pragma unroll
        for (int mi = 0; mi < 4; ++mi)
            #pragma unroll
            for (int nj = 0; nj < NJ; ++nj)
                acc[mi][nj] = __builtin_amdgcn_mfma_f32_16x16x32_bf16(
                    af[mi], bfr[nj], acc[mi][nj], 0, 0, 0);
        __builtin_amdgcn_s_setprio(0);
    };

#define GEMM_STEP(T, BUF, DOSTAGE, VM)                                  \
    do {                                                                \
        __builtin_amdgcn_s_barrier();          /* A: compute(t-1) done */\
        __builtin_amdgcn_sched_barrier(0);                              \
        if (DOSTAGE) stage((T) + 3, ((T) + 3) & 3);                     \
        asm volatile("s_waitcnt vmcnt(" #VM ")" ::: "memory");          \
        __builtin_amdgcn_s_barrier();          /* B: tile T fully in LDS */\
        __builtin_amdgcn_sched_barrier(0);                              \
        compute(BUF);                                                   \
    } while (0)

    const int nt = K >> 5;           // 16 or 48; nt % 4 == 0
    stage(0, 0);
    stage(1, 1);
    stage(2, 2);
    if constexpr (BN == 128) {
        for (int t4 = 0; t4 < nt - 4; t4 += 4) {
            GEMM_STEP(t4 + 0, 0, true, 12);
            GEMM_STEP(t4 + 1, 1, true, 12);
            GEMM_STEP(t4 + 2, 2, true, 12);
            GEMM_STEP(t4 + 3, 3, true, 12);
        }
        GEMM_STEP(nt - 4, 0, true, 12);
        GEMM_STEP(nt - 3, 1, false, 8);
        GEMM_STEP(nt - 2, 2, false, 4);
        GEMM_STEP(nt - 1, 3, false, 0);
    } else {
        for (int t4 = 0; t4 < nt - 4; t4 += 4) {
            GEMM_STEP(t4 + 0, 0, true, 9);
            GEMM_STEP(t4 + 1, 1, true, 9);
            GEMM_STEP(t4 + 2, 2, true, 9);
            GEMM_STEP(t4 + 3, 3, true, 9);
        }
        GEMM_STEP(nt - 4, 0, true, 9);
        GEMM_STEP(nt - 3, 1, false, 6);
        GEMM_STEP(nt - 2, 2, false, 3);
        GEMM_STEP(nt - 1, 3, false, 0);
    }
#undef GEMM_STEP

    const float* bs = bias;
    OutT* dst = C;
    int cadj = 0;
    if (MODE == MODE_SILU_UV && col0 >= D1) { bs = bias2; dst = C2; cadj = D1; }

    float bcol[NJ];
    #pragma unroll
    for (int nj = 0; nj < NJ; ++nj)
        bcol[nj] = bs[col0 - cadj + wn * (BN / 2) + nj * 16 + lm];

    if (MODE == MODE_RPE) {
        #pragma unroll
        for (int mi = 0; mi < 4; ++mi) {
            #pragma unroll
            for (int r = 0; r < 4; ++r) {
                const int row = row0 + wm * 64 + mi * 16 + lk * 4 + r;
                float sc = 1.0f;
                if (scale_in)
                    sc = 1.0f / (sqrtf(scale_in[row]) * 0.04419417382415922f + 1e-8f);
                float ssq = 0.0f;
                #pragma unroll
                for (int nj = 0; nj < NJ; ++nj) {
                    const int col = col0 + wn * (BN / 2) + nj * 16 + lm;
                    float val = acc[mi][nj][r] * sc + bcol[nj];
                    ssq += val * val;
                    ((bf16*)C)[(size_t)row * Nc + col] = (bf16)fmaxf(val, 0.0f);
                }
                ssq += __shfl_xor(ssq, 1, 64);
                ssq += __shfl_xor(ssq, 2, 64);
                ssq += __shfl_xor(ssq, 4, 64);
                ssq += __shfl_xor(ssq, 8, 64);
                if (lm == 0) atomicAdd(&sumsq_out[row], ssq);
            }
        }
        return;
    }

    #pragma unroll
    for (int mi = 0; mi < 4; ++mi) {
        const int rbase = row0 + wm * 64 + mi * 16 + lk * 4;
        float sc[4];
        #pragma unroll
        for (int r = 0; r < 4; ++r) {
            sc[r] = 1.0f;
            if (MODE == MODE_AT && scale_in)
                sc[r] = 1.0f / (sqrtf(scale_in[rbase + r]) * 0.04419417382415922f + 1e-8f);
        }
        #pragma unroll
        for (int nj = 0; nj < NJ; ++nj) {
            const int col = col0 - cadj + wn * (BN / 2) + nj * 16 + lm;
            float vals[4];
            #pragma unroll
            for (int r = 0; r < 4; ++r) {
                float val = acc[mi][nj][r] * sc[r] + bcol[nj];
                if (MODE == MODE_SILU_UV)
                    val = val * __fdividef(1.0f, 1.0f + __expf(-val));
                vals[r] = val;
            }
            if (MODE == MODE_SILU_UV) {
                int b = rbase >> 11, s = rbase & 2047;
                bf16x4 o;
                #pragma unroll
                for (int r = 0; r < 4; ++r) o[r] = (bf16)vals[r];
                *(bf16x4*)&((bf16*)dst)[((size_t)(b * D1 + col)) * N_SEQ + s] = o;
            } else if (MODE == MODE_AT) {
                float4 o = make_float4(vals[0], vals[1], vals[2], vals[3]);
                *(float4*)&((float*)C)[(size_t)col * M + rbase] = o;
            } else {
                #pragma unroll
                for (int r = 0; r < 4; ++r)
                    C[(size_t)(rbase + r) * Nc + col] = (OutT)vals[r];
            }
        }
    }
}

// ---------------------------------------------------------------------------
// mega-prologue: x convert + 5 weight converts + sumsq zero +
// RPE input layer w/ srms + FFT twiddle table (256 x 16 cx)
// ---------------------------------------------------------------------------
__global__ __launch_bounds__(256) void f2b_all_kernel(
    const float* __restrict__ x,  const float* __restrict__ s0,
    const float* __restrict__ s1, const float* __restrict__ s2,
    const float* __restrict__ s3, const float* __restrict__ s4,
    const float* __restrict__ Wp, const float* __restrict__ bp,
    bf16* __restrict__ x_bf, bf16* __restrict__ w_bf,
    float* __restrict__ sumsq, bf16* __restrict__ g0,
    float* __restrict__ twd)
{
    const int bid = blockIdx.x;
    const int tid = threadIdx.x;
    __shared__ float red[4];

    if (bid < 7936) {
        const float* src;
        bf16* dst;
        size_t off;
        if (bid < 4096) {
            src = x; dst = x_bf; off = (size_t)bid * 1024;
        } else {
            int t = bid - 4096;
            int seg = t / 768;
            src = seg == 0 ? s0 : seg == 1 ? s1 : seg == 2 ? s2
                : seg == 3 ? s3 : s4;
            dst = w_bf + (size_t)seg * 786432;
            off = (size_t)(t % 768) * 1024;
        }
        size_t i = off + (size_t)tid * 4;
        float4 f = *(const float4*)(src + i);
        union { bf16 h[4]; short4 s; } u4;
        u4.h[0] = (bf16)f.x; u4.h[1] = (bf16)f.y;
        u4.h[2] = (bf16)f.z; u4.h[3] = (bf16)f.w;
        *(short4*)(dst + i) = u4.s;
    } else if (bid < 7948) {
        size_t i = (size_t)(bid - 7936) * 1024 + (size_t)tid * 4;
        *(float4*)(sumsq + i) = make_float4(0.f, 0.f, 0.f, 0.f);
    } else if (bid < 12044) {
        const int j = bid - 7948;
        float idxv = (j < N_SEQ) ? (float)j
                                 : (j == N_SEQ ? 0.0f : (float)(j - 2 * N_SEQ));
        float h1 = idxv * Wp[tid] + bp[tid];
        float h2 = idxv * Wp[tid + 256] + bp[tid + 256];
        float ss = h1 * h1 + h2 * h2;
        #pragma unroll
        for (int off = 32; off > 0; off >>= 1) ss += __shfl_down(ss, off, 64);
        if ((tid & 63) == 0) red[tid >> 6] = ss;
        __syncthreads();
        float tot = red[0] + red[1] + red[2] + red[3];
        float scale = 1.0f / (sqrtf(tot) * 0.04419417382415922f + 1e-8f);
        g0[(size_t)j * ED + tid]       = (bf16)fmaxf(h1 * scale, 0.0f);
        g0[(size_t)j * ED + tid + 256] = (bf16)fmaxf(h2 * scale, 0.0f);
    } else {
        const int idx = (bid - 12044) * 256 + tid;    // [0, 4096)
        const int j = idx >> 4, tau = idx & 15;
        float sA, cA;
        __sincosf(-6.283185307179586f * (float)(j * tau) * (1.0f / 4096.0f),
                  &sA, &cA);
        cx w; w.x = cA; w.y = sA;
        ((cx*)twd)[idx] = w;
    }
}

// ---------------------------------------------------------------------------
// Radix-16 FFT, radix-4 butterflies, packed-fp32 complex.
// LDS addressing: fpad(base + s*t) = fpad(base) + s'*t  (256->274, 16->17, 1->1)
// Stage-1/inv-3 twiddle row (tid<<4) in REGISTERS (inverse = conjugate);
// stage-2/inv-2 rows (16 distinct) in a 2 KB LDS broadcast table.
// Register-residency: fwd-s3 output stays in regs across the barrier;
// inv-s3 output gates directly to global (strided coalesced).
// ---------------------------------------------------------------------------
#define FFT_LDS_SZ 4381

__device__ __forceinline__ int fpad(int i) { return i + (i >> 4) + 2 * (i >> 8); }

__device__ __forceinline__ cx mkcx(float a, float b) { cx r; r.x = a; r.y = b; return r; }
__device__ __forceinline__ cx cmul(cx a, cx b) {
    cx br = mkcx(-b.y, b.x);
    return a.xx * b + a.yy * br;
}
__device__ __forceinline__ cx cmul_cj(cx a, cx b) {      // a * conj(b)
    cx bc = mkcx(b.x, -b.y);
    cx br = mkcx(b.y, b.x);
    return a.xx * bc + a.yy * br;
}
__device__ __forceinline__ cx cneg_i(cx a) { return mkcx(a.y, -a.x); }   // a * (-i)
__device__ __forceinline__ cx cpos_i(cx a) { return mkcx(-a.y, a.x); }   // a * (+i)
__host__ __device__ constexpr int brev4(int t) {
    return ((t & 1) << 3) | ((t & 2) << 1) | ((t & 4) >> 1) | ((t & 8) >> 3);
}

#define CC1 0.9238795325112867f
#define SS1 0.3826834323650898f
#define RR2 0.7071067811865476f

template<bool HZ>
__device__ __forceinline__ void fft16_dif_r4(cx x[16]) {
    const cx W1 = mkcx( CC1, -SS1);
    const cx W2 = mkcx( RR2, -RR2);
    const cx W3 = mkcx( SS1, -CC1);
    const cx W6 = mkcx(-RR2, -RR2);
    const cx W9 = mkcx(-CC1,  SS1);
    #pragma unroll
    for (int n = 0; n < 4; ++n) {
        cx A, B, C, D;
        if (HZ) { A = x[n]; C = x[n]; B = x[n + 4]; D = x[n + 4]; }
        else {
            A = x[n] + x[n + 8];      C = x[n] - x[n + 8];
            B = x[n + 4] + x[n + 12]; D = x[n + 4] - x[n + 12];
        }
        cx s = A - B;
        cx nid = cneg_i(D);
        cx m = C + nid;
        cx p = C - nid;
        x[n] = A + B;
        if (n == 0)      { x[4] = s;            x[8]  = m;           x[12] = p; }
        else if (n == 1) { x[5] = cmul(s, W2);  x[9]  = cmul(m, W1); x[13] = cmul(p, W3); }
        else if (n == 2) { x[6] = cneg_i(s);    x[10] = cmul(m, W2); x[14] = cmul(p, W6); }
        else             { x[7] = cmul(s, W6);  x[11] = cmul(m, W3); x[15] = cmul(p, W9); }
    }
    #pragma unroll
    for (int q = 0; q < 16; q += 4) {
        cx a = x[q], b = x[q + 1], c = x[q + 2], d = x[q + 3];
        cx a1 = a + c, c1 = a - c;
        cx b1 = b + d, d1 = cneg_i(b - d);
        x[q]     = a1 + b1;
        x[q + 1] = a1 - b1;
        x[q + 2] = c1 + d1;
        x[q + 3] = c1 - d1;
    }
}

template<bool HALF_OUT>
__device__ __forceinline__ void fft16_dit_inv_r4(cx x[16]) {
    const cx V1 = mkcx( CC1, SS1);
    const cx V2 = mkcx( RR2, RR2);
    const cx V3 = mkcx( SS1, CC1);
    const cx V6 = mkcx(-RR2, RR2);
    #pragma unroll
    for (int q = 0; q < 16; q += 4) {
        cx a = x[q], b = x[q + 1], c = x[q + 2], d = x[q + 3];
        cx a1 = a + b, b1 = a - b;
        cx c1 = c + d, d1 = c - d;
        cx t = cpos_i(d1);
        x[q]     = a1 + c1;
        x[q + 2] = a1 - c1;
        x[q + 1] = b1 + t;
        x[q + 3] = b1 - t;
    }
    #pragma unroll
    for (int n = 0; n < 4; ++n) {
        cx t1, t2;
        if (n == 0)      { t1 = x[4];             t2 = x[12]; }
        else if (n == 1) { t1 = cmul(x[5],  V2);  t2 = cmul(x[13], V2); }
        else if (n == 2) { t1 = cpos_i(x[6]);     t2 = cpos_i(x[14]); }
        else             { t1 = cmul(x[7],  V6);  t2 = cmul(x[15], V6); }
        cx P = x[n] + t1, Q = x[n] - t1;
        cx R = x[n + 8] + t2, S = x[n + 8] - t2;
        cx t, u;
        if (n == 0)      { t = R;            u = S; }
        else if (n == 1) { t = cmul(R, V1);  u = cmul(S, V1); }
        else if (n == 2) { t = cmul(R, V2);  u = cmul(S, V2); }
        else             { t = cmul(R, V3);  u = cmul(S, V3); }
        cx iu = cpos_i(u);
        x[n]     = P + t;
        x[n + 4] = Q + iu;
        if (!HALF_OUT) {
            x[n + 8]  = P - t;
            x[n + 12] = Q - iu;
        }
    }
}

template<bool CONJ>
__device__ __forceinline__ void apply_tw(cx v[16], const cx tw[16]) {
    #pragma unroll
    for (int tau = 1; tau < 16; ++tau) {
        const int q = brev4(tau);
        v[q] = CONJ ? cmul_cj(v[q], tw[tau]) : cmul(v[q], tw[tau]);
    }
}

// twrow points at tw2lds + (tid&15); stride 16 per tau. Broadcast reads.
template<bool CONJ>
__device__ __forceinline__ void apply_tw_lds(cx v[16], const cx* twrow) {
    #pragma unroll
    for (int tau = 1; tau < 16; ++tau) {
        cx w = twrow[tau * 16];
        const int q = brev4(tau);
        v[q] = CONJ ? cmul_cj(v[q], w) : cmul(v[q], w);
    }
}

// ---- per-stage helpers (in-place per-thread; caller places barriers) ------
__device__ __forceinline__ void fwd_s1_store_hz(
    const cx vin[8], const cx tw[16], cx* d, int tid)
{
    cx x[16];
    #pragma unroll
    for (int t = 0; t < 8; ++t) x[t] = vin[t];
    fft16_dif_r4<true>(x);
    apply_tw<false>(x, tw);
    cx* base = d + fpad(tid);
    #pragma unroll
    for (int p = 0; p < 16; ++p) base[274 * p] = x[p];
}

__device__ __forceinline__ void fwd_s2(cx* d, int tid, const cx* tw2lds)
{
    cx v[16];
    cx* base = d + fpad(((tid >> 4) << 8) + (tid & 15));
    #pragma unroll
    for (int t = 0; t < 16; ++t) v[t] = base[17 * t];
    fft16_dif_r4<false>(v);
    apply_tw_lds<false>(v, tw2lds + (tid & 15));
    #pragma unroll
    for (int p = 0; p < 16; ++p) base[17 * p] = v[p];
}

// stage 3: keeps result in v (thread owns bins [tid*16, tid*16+16))
__device__ __forceinline__ void fwd_s3_keep(cx* d, int tid, cx v[16])
{
    cx* base = d + fpad(tid << 4);
    #pragma unroll
    for (int t = 0; t < 16; ++t) v[t] = base[t];
    fft16_dif_r4<false>(v);
    #pragma unroll
    for (int p = 0; p < 16; ++p) base[p] = v[p];
}

__device__ __forceinline__ void inv_s2(cx* d, int tid, const cx* tw2lds)
{
    cx v[16];
    cx* base = d + fpad(((tid >> 4) << 8) + (tid & 15));
    #pragma unroll
    for (int p = 0; p < 16; ++p) v[p] = base[17 * p];
    apply_tw_lds<true>(v, tw2lds + (tid & 15));
    fft16_dit_inv_r4<false>(v);
    #pragma unroll
    for (int t = 0; t < 16; ++t) base[17 * t] = v[t];
}

// inv stage 3 (lower half) fused with the u-gate: output stays in regs and
// goes straight to global at n = tid + 256*t (coalesced strided).
__device__ __forceinline__ void inv_s3_gate(
    const cx* d, int tid, const cx tw[16],
    const bf16 ua[8], const bf16 ub[8],
    bf16* __restrict__ g0, bf16* __restrict__ g1)
{
    cx v[16];
    const cx* base = d + fpad(tid);
    #pragma unroll
    for (int p = 0; p < 16; ++p) v[p] = base[274 * p];
    apply_tw<true>(v, tw);
    fft16_dit_inv_r4<true>(v);
    #pragma unroll
    for (int t = 0; t < 8; ++t) {
        const int n = tid + 256 * t;
        g0[n] = (bf16)(v[t].x * (float)ua[t]);
        g1[n] = (bf16)(v[t].y * (float)ub[t]);
    }
}

// pointwise using own fwd-s3 regs (v in: Z block; v out: Y block).
// Only the conjugate-partner block is read from LDS (thread 0: none).
__device__ __forceinline__ void pointwise_regs(
    const cx* d, int tid, const float4 a0pf[8], const float4 a1pf[8],
    cx v[16])
{
    auto pf = [](const float4* p, int i) -> cx {
        return (i & 1) ? mkcx(p[i >> 1].z, p[i >> 1].w)
                       : mkcx(p[i >> 1].x, p[i >> 1].y);
    };
    const int pbase = tid << 4;
    cx zm[16];
    if (tid == 0) {
        #pragma unroll
        for (int i = 0; i < 16; ++i) {
            const int p2 = (i < 2) ? i : (i ^ ((1 << (31 - __clz(i))) - 1));
            zm[i] = v[p2];                    // compile-time index
        }
    } else {
        const int mask = (1 << (31 - __clz(pbase))) - 1;
        const cx* zb2 = d + fpad((pbase ^ mask) - 15);
        #pragma unroll
        for (int i = 0; i < 16; ++i) zm[i] = zb2[15 - i];
    }
    #pragma unroll
    for (int i = 0; i < 16; ++i) {
        cx Zk = v[i];
        cx cjZm = mkcx(zm[i].x, -zm[i].y);
        cx V0 = Zk + cjZm;
        cx V1 = cneg_i(Zk - cjZm);
        v[i] = cmul(V0, pf(a0pf, i)) + cpos_i(cmul(V1, pf(a1pf, i)));
    }
}

// ---------------------------------------------------------------------------
// Forward FFT of packed (a_ch0, a_ch1) pair, unpack both real spectra in
// DIF order (conjugate-partner: p2 = p ^ (2^floor(log2 p) - 1)).
// A0 = c*(Wk + conj(Wm)), A1 = c*(-i)*(Wk - conj(Wm)), c = 0.25/4096.
// Wk comes from fwd-s3 registers; only Wm is read from LDS.
// ---------------------------------------------------------------------------
__global__ __launch_bounds__(256, 4) void fft_a_kernel(
    const float* a_t, cx* __restrict__ A0s, cx* A1s,
    const cx* __restrict__ Twd)
{
    __shared__ cx data[FFT_LDS_SZ];
    __shared__ cx tw2lds[256];
    const int tid = threadIdx.x;
    const int r = blockIdx.x;                      // pair index, ch = 2r

    cx tw[16];
    {
        const cx* Tr1 = Twd + (tid << 4);
        #pragma unroll
        for (int t = 1; t < 16; ++t) tw[t] = Tr1[t];
        tw2lds[(tid >> 4) * 16 + (tid & 15)] = Twd[(tid & 15) * 256 + (tid >> 4)];
    }

    const float* r0 = a_t + (size_t)(2 * r) * M_FFT;
    const float* r1 = r0 + M_FFT;
    cx v[16];
    #pragma unroll
    for (int t = 0; t < 16; ++t)
        v[t] = mkcx(r0[tid + 256 * t], r1[tid + 256 * t]);

    {   // stage 1 from registers
        fft16_dif_r4<false>(v);
        apply_tw<false>(v, tw);
        cx* base = data + fpad(tid);
        #pragma unroll
        for (int p = 0; p < 16; ++p) base[274 * p] = v[p];
    }
    __syncthreads();
    fwd_s2(data, tid, tw2lds);
    __syncthreads();
    fwd_s3_keep(data, tid, v);
    __syncthreads();

    const float c = 0.25f / 4096.0f;
    const int base_i = tid << 4;
    cx* A0row = A0s + (size_t)r * 4096;
    cx* A1row = A1s + (size_t)r * 4096;
    cx wm[16];
    if (tid == 0) {
        #pragma unroll
        for (int i = 0; i < 16; ++i) {
            const int p2 = (i < 2) ? i : (i ^ ((1 << (31 - __clz(i))) - 1));
            wm[i] = v[p2];
        }
    } else {
        const int mask = (1 << (31 - __clz(base_i))) - 1;
        const cx* zb2 = data + fpad((base_i ^ mask) - 15);
        #pragma unroll
        for (int i = 0; i < 16; ++i) wm[i] = zb2[15 - i];
    }
    #pragma unroll
    for (int i = 0; i < 16; ++i) {
        cx cjWm = mkcx(wm[i].x, -wm[i].y);
        A0row[base_i + i] = c * (v[i] + cjWm);
        A1row[base_i + i] = c * cneg_i(v[i] - cjWm);
    }
}

// ---------------------------------------------------------------------------
// Conv kernel: TWO channel-pairs per block (batches 2bp and 2bp+1 of the
// SAME r) -> 2x work per barrier region, A rows loaded once for both.
// Bijective XCD remap: xcd = r&7; slots pair (r,bp=0),(r,bp=1) adjacent.
// 6 barriers; fwd-s3/pointwise and inv-s3/gate run register-resident.
// ---------------------------------------------------------------------------
__global__ __launch_bounds__(256, 2) void fft_conv_kernel(
    const bf16* __restrict__ v_t, const cx* __restrict__ A0s,
    const cx* __restrict__ A1s, const bf16* __restrict__ u_t,
    bf16* __restrict__ gated_t, const cx* __restrict__ Twd)
{
    __shared__ cx data[2][FFT_LDS_SZ];
    __shared__ cx tw2lds[256];
    const int tid = threadIdx.x;
    const int bx = blockIdx.x;
    const int xcd  = bx & 7;
    const int slot = bx >> 3;                 // [0,192)
    const int bp   = slot & 1;
    const int r    = (slot >> 1) * 8 + xcd;   // [0,768), bijective
    const int ch   = 2 * r;
    const int b0   = 2 * bp;
    const int b1   = 2 * bp + 1;

    cx tw[16];
    {
        const cx* Tr1 = Twd + (tid << 4);
        #pragma unroll
        for (int t = 1; t < 16; ++t) tw[t] = Tr1[t];
        tw2lds[(tid >> 4) * 16 + (tid & 15)] = Twd[(tid & 15) * 256 + (tid >> 4)];
    }

    // ---- forward stage 1: both chunks straight from global ----
    const bf16* z00 = v_t + ((size_t)(b0 * D1 + ch)) * N_SEQ;
    const bf16* z01 = z00 + N_SEQ;
    const bf16* z10 = v_t + ((size_t)(b1 * D1 + ch)) * N_SEQ;
    const bf16* z11 = z10 + N_SEQ;
    {
        cx w0[8], w1[8];
        #pragma unroll
        for (int t = 0; t < 8; ++t)
            w0[t] = mkcx((float)z00[tid + 256 * t], (float)z01[tid + 256 * t]);
        #pragma unroll
        for (int t = 0; t < 8; ++t)
            w1[t] = mkcx((float)z10[tid + 256 * t], (float)z11[tid + 256 * t]);
        fwd_s1_store_hz(w0, tw, data[0], tid);
        fwd_s1_store_hz(w1, tw, data[1], tid);
    }
    __syncthreads();                                              // 1

    fwd_s2(data[0], tid, tw2lds);
    fwd_s2(data[1], tid, tw2lds);
    __syncthreads();                                              // 2

    // A rows (shared by both chunks): issue before stage-3 compute so the
    // pre-barrier vmcnt drain overlaps both chunks' stage 3.
    const int pbase = tid << 4;
    float4 a0pf[8], a1pf[8];
    {
        const float4* A0p = (const float4*)(A0s + (size_t)r * 4096 + pbase);
        const float4* A1p = (const float4*)(A1s + (size_t)r * 4096 + pbase);
        #pragma unroll
        for (int i = 0; i < 8; ++i) { a0pf[i] = A0p[i]; a1pf[i] = A1p[i]; }
    }
    cx vA[16], vB[16];
    fwd_s3_keep(data[0], tid, vA);
    fwd_s3_keep(data[1], tid, vB);
    __syncthreads();                                              // 3

    // ---- pointwise (own Z from regs, partner from LDS; A in regs x2) ----
    pointwise_regs(data[0], tid, a0pf, a1pf, vA);
    pointwise_regs(data[1], tid, a0pf, a1pf, vB);
    __syncthreads();                       // 4: partner reads done
    fft16_dit_inv_r4<false>(vA);
    fft16_dit_inv_r4<false>(vB);
    {
        cx* baseA = data[0] + fpad(pbase);
        cx* baseB = data[1] + fpad(pbase);
        #pragma unroll
        for (int i = 0; i < 16; ++i) baseA[i] = vA[i];
        #pragma unroll
        for (int i = 0; i < 16; ++i) baseB[i] = vB[i];
    }
    __syncthreads();                                              // 5

    // u rows (strided layout matching inv-s3 ownership): issue before inv
    // stage 2 so the latency hides under it.
    const bf16* u00 = u_t + ((size_t)(b0 * D1 + ch)) * N_SEQ;
    const bf16* u01 = u00 + N_SEQ;
    const bf16* u10 = u_t + ((size_t)(b1 * D1 + ch)) * N_SEQ;
    const bf16* u11 = u10 + N_SEQ;
    bf16 ua0[8], ub0[8], ua1[8], ub1[8];
    #pragma unroll
    for (int t = 0; t < 8; ++t) {
        const int n = tid + 256 * t;
        ua0[t] = u00[n]; ub0[t] = u01[n];
        ua1[t] = u10[n]; ub1[t] = u11[n];
    }

    inv_s2(data[0], tid, tw2lds);
    inv_s2(data[1], tid, tw2lds);
    __syncthreads();                                              // 6

    bf16* g00 = gated_t + ((size_t)(b0 * D1 + ch)) * N_SEQ;
    bf16* g01 = g00 + N_SEQ;
    bf16* g10 = gated_t + ((size_t)(b1 * D1 + ch)) * N_SEQ;
    bf16* g11 = g10 + N_SEQ;
    inv_s3_gate(data[0], tid, tw, ua0, ub0, g00, g01);
    inv_s3_gate(data[1], tid, tw, ua1, ub1, g10, g11);
}

// ---------------------------------------------------------------------------
__global__ __launch_bounds__(256) void transpose_cs_kernel(
    const bf16* __restrict__ in, bf16* __restrict__ outp)
{
    __shared__ bf16 tile[64 * 68];
    const int c0 = blockIdx.x * 64;
    const int m0 = blockIdx.y * 64;
    const int b  = m0 >> 11;
    const int s0 = m0 & 2047;
    const int tid = threadIdx.x;
    const int cl = tid >> 4;
    const int sc = (tid & 15) * 4;
    #pragma unroll
    for (int p = 0; p < 4; ++p) {
        int c = p * 16 + cl;
        bf16x4 v = *(const bf16x4*)&in[((size_t)(b * D1 + c0 + c)) * N_SEQ + s0 + sc];
        *(bf16x4*)&tile[c * 68 + sc] = v;
    }
    __syncthreads();
    const int sl = tid >> 4;
    const int cc = (tid & 15) * 4;
    #pragma unroll
    for (int p = 0; p < 4; ++p) {
        int s = p * 16 + sl;
        bf16x4 o;
        #pragma unroll
        for (int j = 0; j < 4; ++j) o[j] = tile[(cc + j) * 68 + s];
        *(bf16x4*)&outp[((size_t)(m0 + s)) * D1 + c0 + cc] = o;
    }
}

// ---------------------------------------------------------------------------
extern "C" void kernel_launch(void* const* d_in, const int* in_sizes, int n_in,
                              void* d_out, int out_size, void* d_ws, size_t ws_size,
                              hipStream_t stream)
{
    const float* x  = (const float*)d_in[0];
    const float* Wu = (const float*)d_in[1];
    const float* bu = (const float*)d_in[2];
    const float* Wv = (const float*)d_in[3];
    const float* bv = (const float*)d_in[4];
    const float* Wo = (const float*)d_in[5];
    const float* bo = (const float*)d_in[6];
    const float* Wp = (const float*)d_in[7];
    const float* bp = (const float*)d_in[8];
    const float* Wl = (const float*)d_in[9];
    const float* bl = (const float*)d_in[10];
    const float* Wr = (const float*)d_in[11];
    const float* br = (const float*)d_in[12];
    float* out = (float*)d_out;

    float* ws      = (float*)d_ws;
    float* a_t     = ws;                       // 1536*4096 fp32; A1spec after fft_a
    float* A0spec  = a_t   + 6291456;          // 768 x 4096 cx
    float* sumsq   = A0spec + 6291456;         // 3 x 4096 fp32
    float* twd     = sumsq + 12288;            // 256 x 16 cx twiddle table
    bf16*  bfws    = (bf16*)(twd + 8192);
    bf16*  x_bf    = bfws;                     // 8192*512
    bf16*  w_bf    = x_bf    + 4194304;        // 5 x 786432: Wu,Wv,Wo,Wl,Wr
    bf16*  Wuv_bf  = w_bf;                     // stacked [Wu;Wv] 3072 x 512
    bf16*  Wo_bf   = w_bf    + 2 * 786432;
    bf16*  Wl_bf   = Wo_bf   + 786432;
    bf16*  Wr_bf   = Wl_bf   + 786432;
    bf16*  gA      = Wr_bf   + 786432;         // 4096*512
    bf16*  gB      = gA      + 2097152;        // 4096*512
    bf16*  u_t     = gB      + 2097152;        // 8192*1536 [b][c][s]
    bf16*  v_t     = u_t     + 12582912;       // 8192*1536 [b][c][s]
    bf16*  gated_t = v_t     + 12582912;       // 8192*1536 [b][c][s]
    bf16*  gated   = gated_t + 12582912;       // 8192*1536 [m][c]

    dim3 blk(256);

    // x/w converts + sumsq zero + rpe input layer + twiddle table
    f2b_all_kernel<<<4096 + 5 * 768 + 12 + 4096 + 16, blk, 0, stream>>>(
        x, Wu, Wv, Wo, Wl, Wr, Wp, bp, x_bf, w_bf, sumsq, gA, twd);

    gemm_bf16<MODE_SILU_UV, 128, bf16><<<dim3(24, 64), blk, 0, stream>>>(
        x_bf, Wuv_bf, bu, bv, u_t, v_t, 8192, 2 * D1, ED, nullptr, nullptr);

    // RPE MLP: srms folded into GEMM epilogues via row-scale commutation.
    bf16* gin = gA;
    bf16* gout = gB;
    for (int i = 0; i < 3; ++i) {
        const float* sin_p = (i == 0) ? nullptr : sumsq + (size_t)(i - 1) * 4096;
        gemm_bf16<MODE_RPE, 64, bf16><<<dim3(8, 32), blk, 0, stream>>>(
            gin, Wl_bf + (size_t)i * ED * ED, bl + (size_t)i * ED, nullptr,
            gout, nullptr, 4096, ED, ED, sin_p, sumsq + (size_t)i * 4096);
        bf16* t = gin; gin = gout; gout = t;
    }
    gemm_bf16<MODE_AT, 64, float><<<dim3(24, 32), blk, 0, stream>>>(
        gin, Wr_bf, br, nullptr, a_t, nullptr, 4096, D1, ED,
        sumsq + 2 * 4096, nullptr);

    fft_a_kernel<<<768, blk, 0, stream>>>(
        a_t, (cx*)A0spec, (cx*)a_t, (const cx*)twd);
    fft_conv_kernel<<<1536, blk, 0, stream>>>(
        v_t, (const cx*)A0spec, (const cx*)a_t, u_t, gated_t, (const cx*)twd);

    transpose_cs_kernel<<<dim3(24, 128), blk, 0, stream>>>(gated_t, gated);

    gemm_bf16<MODE_PLAIN, 64, float><<<dim3(8, 64), blk, 0, stream>>>(
        gated, Wo_bf, bo, nullptr, out, nullptr, 8192, ED, D1,
        nullptr, nullptr);
}

// Round 11
// 329.768 us; speedup vs baseline: 1.2153x; 1.0024x over previous
//
#include <hip/hip_runtime.h>

#define N_SEQ 2048
#define M_FFT 4096
#define D1    1536
#define NH    8
#define HD    192
#define ED    512

typedef __bf16 bf16;
typedef __bf16 bf16x4 __attribute__((ext_vector_type(4)));
typedef __bf16 bf16x8 __attribute__((ext_vector_type(8)));
typedef float  floatx4 __attribute__((ext_vector_type(4)));
typedef float  cx __attribute__((ext_vector_type(2)));   // complex as packed fp32

enum { MODE_PLAIN = 0, MODE_SILU_UV = 1, MODE_AT = 3, MODE_RPE = 4 };

__device__ __forceinline__ void gload16(const void* g, void* l) {
    __builtin_amdgcn_global_load_lds(
        (const __attribute__((address_space(1))) void*)g,
        (__attribute__((address_space(3))) void*)l, 16, 0, 0);
}

// ---------------------------------------------------------------------------
// bf16 MFMA GEMM, depth-3 pipeline with COUNTED vmcnt (T4), BN-templated,
// + T2 granule-XOR LDS swizzle (conflicts measured 0) + T5 setprio.
//
// 3 LDS buffers (not 4): BN=128 -> 48 KB -> 3 blocks/CU (was 2);
// BN=64 -> 36 KB -> 4 blocks/CU. Occupancy was the binding constraint
// (round-9 counters: all pipes <35%, occupancy 18.7% = 75% of the 2-block
// cap). stage(t+2) still lands two steps before use; steady vmcnt(8)/(6)
// keeps the next two tiles in flight, never drains to 0 mid-loop.
// Buffer index rotates at runtime -- LDS address arithmetic, not a
// register array, so rule #20 (scratch) does not apply.
// ---------------------------------------------------------------------------
template<int MODE, int BN, typename OutT>
__global__ __launch_bounds__(256) void gemm_bf16(
    const bf16* __restrict__ A, const bf16* __restrict__ Bw,
    const float* __restrict__ bias, const float* __restrict__ bias2,
    OutT* __restrict__ C, OutT* __restrict__ C2,
    int M, int Nc, int K,
    const float* __restrict__ scale_in, float* __restrict__ sumsq_out)
{
    constexpr int NJ = BN / 32;            // n-fragments per wave (4 or 2)
    __shared__ __align__(16) bf16 As[3][128 * 32];
    __shared__ __align__(16) bf16 Bs[3][BN * 32];

    const int tid  = threadIdx.x;
    const int row0 = blockIdx.y * 128;
    const int col0 = blockIdx.x * BN;
    const int wid  = tid >> 6;
    const int lane = tid & 63;
    const int lm   = lane & 15;
    const int lk   = lane >> 4;
    const int wm   = wid >> 1;
    const int wn   = wid & 1;
    const int ldrow  = tid >> 2;
    // T2 write-side: source granule = (tid&3) ^ ((row>>1)&3), row = tid>>2
    const int ldcol8 = (((tid & 3) ^ ((tid >> 3) & 3))) * 8;
    // T2 read-side: granule = lk ^ ((row>>1)&3) = lk ^ ((lm>>1)&3)
    const int gsw = (lk ^ ((lm >> 1) & 3)) * 8;

    floatx4 acc[4][NJ] = {};

    const bf16* Ag = A  + ((size_t)(row0 + ldrow)) * K + ldcol8;
    const bf16* Bg = Bw + ((size_t)(col0 + ldrow)) * K + ldcol8;
    const int woff = (wid * 16) * 32;

    auto stage = [&](int t, int buf) {
        const int k0 = t << 5;
        gload16(Ag + k0, &As[buf][woff]);
        gload16(Ag + (size_t)64 * K + k0, &As[buf][woff + 64 * 32]);
        gload16(Bg + k0, &Bs[buf][woff]);
        if constexpr (BN == 128)
            gload16(Bg + (size_t)64 * K + k0, &Bs[buf][woff + 64 * 32]);
    };
    auto compute = [&](int buf) {
        bf16x8 af[4], bfr[NJ];
        #pragma unroll
        for (int mi = 0; mi < 4; ++mi)
            af[mi] = *(const bf16x8*)&As[buf][(wm * 64 + mi * 16 + lm) * 32 + gsw];
        #pragma unroll
        for (int nj = 0; nj < NJ; ++nj)
            bfr[nj] = *(const bf16x8*)&Bs[buf][(wn * (BN / 2) + nj * 16 + lm) * 32 + gsw];
        __builtin_amdgcn_s_setprio(1);                 // T5
        #pragma unroll
        for (int mi = 0; mi < 4; ++mi)
            #pragma unroll
            for (int nj = 0; nj < NJ; ++nj)
                acc[mi][nj] = __builtin_amdgcn_mfma_f32_16x16x32_bf16(
                    af[mi], bfr[nj], acc[mi][nj], 0, 0, 0);
        __builtin_amdgcn_s_setprio(0);
    };

    const int nt = K >> 5;           // 16 or 48
    stage(0, 0);
    stage(1, 1);
    int sb = 2, cb = 0;
    for (int t = 0; t < nt; ++t) {
        __builtin_amdgcn_s_barrier();          // A: compute(t-1) done everywhere
        __builtin_amdgcn_sched_barrier(0);
        if (t + 2 < nt) {
            stage(t + 2, sb);
            if (++sb == 3) sb = 0;
        }
        // own tile-t loads complete; next two tiles stay in flight
        if (t < nt - 2) {
            if constexpr (BN == 128) asm volatile("s_waitcnt vmcnt(8)" ::: "memory");
            else                     asm volatile("s_waitcnt vmcnt(6)" ::: "memory");
        } else if (t == nt - 2) {
            if constexpr (BN == 128) asm volatile("s_waitcnt vmcnt(4)" ::: "memory");
            else                     asm volatile("s_waitcnt vmcnt(3)" ::: "memory");
        } else {
            asm volatile("s_waitcnt vmcnt(0)" ::: "memory");
        }
        __builtin_amdgcn_s_barrier();          // B: tile t fully in LDS (all waves)
        __builtin_amdgcn_sched_barrier(0);
        compute(cb);
        if (++cb == 3) cb = 0;
    }

    const float* bs = bias;
    OutT* dst = C;
    int cadj = 0;
    if (MODE == MODE_SILU_UV && col0 >= D1) { bs = bias2; dst = C2; cadj = D1; }

    float bcol[NJ];
    #pragma unroll
    for (int nj = 0; nj < NJ; ++nj)
        bcol[nj] = bs[col0 - cadj + wn * (BN / 2) + nj * 16 + lm];

    if (MODE == MODE_RPE) {
        #pragma unroll
        for (int mi = 0; mi < 4; ++mi) {
            #pragma unroll
            for (int r = 0; r < 4; ++r) {
                const int row = row0 + wm * 64 + mi * 16 + lk * 4 + r;
                float sc = 1.0f;
                if (scale_in)
                    sc = 1.0f / (sqrtf(scale_in[row]) * 0.04419417382415922f + 1e-8f);
                float ssq = 0.0f;
                #pragma unroll
                for (int nj = 0; nj < NJ; ++nj) {
                    const int col = col0 + wn * (BN / 2) + nj * 16 + lm;
                    float val = acc[mi][nj][r] * sc + bcol[nj];
                    ssq += val * val;
                    ((bf16*)C)[(size_t)row * Nc + col] = (bf16)fmaxf(val, 0.0f);
                }
                ssq += __shfl_xor(ssq, 1, 64);
                ssq += __shfl_xor(ssq, 2, 64);
                ssq += __shfl_xor(ssq, 4, 64);
                ssq += __shfl_xor(ssq, 8, 64);
                if (lm == 0) atomicAdd(&sumsq_out[row], ssq);
            }
        }
        return;
    }

    #pragma unroll
    for (int mi = 0; mi < 4; ++mi) {
        const int rbase = row0 + wm * 64 + mi * 16 + lk * 4;
        float sc[4];
        #pragma unroll
        for (int r = 0; r < 4; ++r) {
            sc[r] = 1.0f;
            if (MODE == MODE_AT && scale_in)
                sc[r] = 1.0f / (sqrtf(scale_in[rbase + r]) * 0.04419417382415922f + 1e-8f);
        }
        #pragma unroll
        for (int nj = 0; nj < NJ; ++nj) {
            const int col = col0 - cadj + wn * (BN / 2) + nj * 16 + lm;
            float vals[4];
            #pragma unroll
            for (int r = 0; r < 4; ++r) {
                float val = acc[mi][nj][r] * sc[r] + bcol[nj];
                if (MODE == MODE_SILU_UV)
                    val = val * __fdividef(1.0f, 1.0f + __expf(-val));
                vals[r] = val;
            }
            if (MODE == MODE_SILU_UV) {
                int b = rbase >> 11, s = rbase & 2047;
                bf16x4 o;
                #pragma unroll
                for (int r = 0; r < 4; ++r) o[r] = (bf16)vals[r];
                *(bf16x4*)&((bf16*)dst)[((size_t)(b * D1 + col)) * N_SEQ + s] = o;
            } else if (MODE == MODE_AT) {
                float4 o = make_float4(vals[0], vals[1], vals[2], vals[3]);
                *(float4*)&((float*)C)[(size_t)col * M + rbase] = o;
            } else {
                #pragma unroll
                for (int r = 0; r < 4; ++r)
                    C[(size_t)(rbase + r) * Nc + col] = (OutT)vals[r];
            }
        }
    }
}

// ---------------------------------------------------------------------------
// mega-prologue: x convert + 5 weight converts + sumsq zero +
// RPE input layer w/ srms + FFT twiddle table (256 x 16 cx)
// ---------------------------------------------------------------------------
__global__ __launch_bounds__(256) void f2b_all_kernel(
    const float* __restrict__ x,  const float* __restrict__ s0,
    const float* __restrict__ s1, const float* __restrict__ s2,
    const float* __restrict__ s3, const float* __restrict__ s4,
    const float* __restrict__ Wp, const float* __restrict__ bp,
    bf16* __restrict__ x_bf, bf16* __restrict__ w_bf,
    float* __restrict__ sumsq, bf16* __restrict__ g0,
    float* __restrict__ twd)
{
    const int bid = blockIdx.x;
    const int tid = threadIdx.x;
    __shared__ float red[4];

    if (bid < 7936) {
        const float* src;
        bf16* dst;
        size_t off;
        if (bid < 4096) {
            src = x; dst = x_bf; off = (size_t)bid * 1024;
        } else {
            int t = bid - 4096;
            int seg = t / 768;
            src = seg == 0 ? s0 : seg == 1 ? s1 : seg == 2 ? s2
                : seg == 3 ? s3 : s4;
            dst = w_bf + (size_t)seg * 786432;
            off = (size_t)(t % 768) * 1024;
        }
        size_t i = off + (size_t)tid * 4;
        float4 f = *(const float4*)(src + i);
        union { bf16 h[4]; short4 s; } u4;
        u4.h[0] = (bf16)f.x; u4.h[1] = (bf16)f.y;
        u4.h[2] = (bf16)f.z; u4.h[3] = (bf16)f.w;
        *(short4*)(dst + i) = u4.s;
    } else if (bid < 7948) {
        size_t i = (size_t)(bid - 7936) * 1024 + (size_t)tid * 4;
        *(float4*)(sumsq + i) = make_float4(0.f, 0.f, 0.f, 0.f);
    } else if (bid < 12044) {
        const int j = bid - 7948;
        float idxv = (j < N_SEQ) ? (float)j
                                 : (j == N_SEQ ? 0.0f : (float)(j - 2 * N_SEQ));
        float h1 = idxv * Wp[tid] + bp[tid];
        float h2 = idxv * Wp[tid + 256] + bp[tid + 256];
        float ss = h1 * h1 + h2 * h2;
        #pragma unroll
        for (int off = 32; off > 0; off >>= 1) ss += __shfl_down(ss, off, 64);
        if ((tid & 63) == 0) red[tid >> 6] = ss;
        __syncthreads();
        float tot = red[0] + red[1] + red[2] + red[3];
        float scale = 1.0f / (sqrtf(tot) * 0.04419417382415922f + 1e-8f);
        g0[(size_t)j * ED + tid]       = (bf16)fmaxf(h1 * scale, 0.0f);
        g0[(size_t)j * ED + tid + 256] = (bf16)fmaxf(h2 * scale, 0.0f);
    } else {
        const int idx = (bid - 12044) * 256 + tid;    // [0, 4096)
        const int j = idx >> 4, tau = idx & 15;
        float sA, cA;
        __sincosf(-6.283185307179586f * (float)(j * tau) * (1.0f / 4096.0f),
                  &sA, &cA);
        cx w; w.x = cA; w.y = sA;
        ((cx*)twd)[idx] = w;
    }
}

// ---------------------------------------------------------------------------
// Radix-16 FFT, radix-4 butterflies, packed-fp32 complex.
// LDS addressing: fpad(base + s*t) = fpad(base) + s'*t  (256->274, 16->17, 1->1)
// Stage-1/inv-3 twiddle row (tid<<4) in REGISTERS (inverse = conjugate);
// stage-2/inv-2 rows (16 distinct) in a 2 KB LDS broadcast table.
// Register-residency: fwd-s3 output stays in regs across the barrier;
// inv-s3 output gates directly to global (strided coalesced).
// ---------------------------------------------------------------------------
#define FFT_LDS_SZ 4381

__device__ __forceinline__ int fpad(int i) { return i + (i >> 4) + 2 * (i >> 8); }

__device__ __forceinline__ cx mkcx(float a, float b) { cx r; r.x = a; r.y = b; return r; }
__device__ __forceinline__ cx cmul(cx a, cx b) {
    cx br = mkcx(-b.y, b.x);
    return a.xx * b + a.yy * br;
}
__device__ __forceinline__ cx cmul_cj(cx a, cx b) {      // a * conj(b)
    cx bc = mkcx(b.x, -b.y);
    cx br = mkcx(b.y, b.x);
    return a.xx * bc + a.yy * br;
}
__device__ __forceinline__ cx cneg_i(cx a) { return mkcx(a.y, -a.x); }   // a * (-i)
__device__ __forceinline__ cx cpos_i(cx a) { return mkcx(-a.y, a.x); }   // a * (+i)
__host__ __device__ constexpr int brev4(int t) {
    return ((t & 1) << 3) | ((t & 2) << 1) | ((t & 4) >> 1) | ((t & 8) >> 3);
}

#define CC1 0.9238795325112867f
#define SS1 0.3826834323650898f
#define RR2 0.7071067811865476f

template<bool HZ>
__device__ __forceinline__ void fft16_dif_r4(cx x[16]) {
    const cx W1 = mkcx( CC1, -SS1);
    const cx W2 = mkcx( RR2, -RR2);
    const cx W3 = mkcx( SS1, -CC1);
    const cx W6 = mkcx(-RR2, -RR2);
    const cx W9 = mkcx(-CC1,  SS1);
    #pragma unroll
    for (int n = 0; n < 4; ++n) {
        cx A, B, C, D;
        if (HZ) { A = x[n]; C = x[n]; B = x[n + 4]; D = x[n + 4]; }
        else {
            A = x[n] + x[n + 8];      C = x[n] - x[n + 8];
            B = x[n + 4] + x[n + 12]; D = x[n + 4] - x[n + 12];
        }
        cx s = A - B;
        cx nid = cneg_i(D);
        cx m = C + nid;
        cx p = C - nid;
        x[n] = A + B;
        if (n == 0)      { x[4] = s;            x[8]  = m;           x[12] = p; }
        else if (n == 1) { x[5] = cmul(s, W2);  x[9]  = cmul(m, W1); x[13] = cmul(p, W3); }
        else if (n == 2) { x[6] = cneg_i(s);    x[10] = cmul(m, W2); x[14] = cmul(p, W6); }
        else             { x[7] = cmul(s, W6);  x[11] = cmul(m, W3); x[15] = cmul(p, W9); }
    }
    #pragma unroll
    for (int q = 0; q < 16; q += 4) {
        cx a = x[q], b = x[q + 1], c = x[q + 2], d = x[q + 3];
        cx a1 = a + c, c1 = a - c;
        cx b1 = b + d, d1 = cneg_i(b - d);
        x[q]     = a1 + b1;
        x[q + 1] = a1 - b1;
        x[q + 2] = c1 + d1;
        x[q + 3] = c1 - d1;
    }
}

template<bool HALF_OUT>
__device__ __forceinline__ void fft16_dit_inv_r4(cx x[16]) {
    const cx V1 = mkcx( CC1, SS1);
    const cx V2 = mkcx( RR2, RR2);
    const cx V3 = mkcx( SS1, CC1);
    const cx V6 = mkcx(-RR2, RR2);
    #pragma unroll
    for (int q = 0; q < 16; q += 4) {
        cx a = x[q], b = x[q + 1], c = x[q + 2], d = x[q + 3];
        cx a1 = a + b, b1 = a - b;
        cx c1 = c + d, d1 = c - d;
        cx t = cpos_i(d1);
        x[q]     = a1 + c1;
        x[q + 2] = a1 - c1;
        x[q + 1] = b1 + t;
        x[q + 3] = b1 - t;
    }
    #pragma unroll
    for (int n = 0; n < 4; ++n) {
        cx t1, t2;
        if (n == 0)      { t1 = x[4];             t2 = x[12]; }
        else if (n == 1) { t1 = cmul(x[5],  V2);  t2 = cmul(x[13], V2); }
        else if (n == 2) { t1 = cpos_i(x[6]);     t2 = cpos_i(x[14]); }
        else             { t1 = cmul(x[7],  V6);  t2 = cmul(x[15], V6); }
        cx P = x[n] + t1, Q = x[n] - t1;
        cx R = x[n + 8] + t2, S = x[n + 8] - t2;
        cx t, u;
        if (n == 0)      { t = R;            u = S; }
        else if (n == 1) { t = cmul(R, V1);  u = cmul(S, V1); }
        else if (n == 2) { t = cmul(R, V2);  u = cmul(S, V2); }
        else             { t = cmul(R, V3);  u = cmul(S, V3); }
        cx iu = cpos_i(u);
        x[n]     = P + t;
        x[n + 4] = Q + iu;
        if (!HALF_OUT) {
            x[n + 8]  = P - t;
            x[n + 12] = Q - iu;
        }
    }
}

template<bool CONJ>
__device__ __forceinline__ void apply_tw(cx v[16], const cx tw[16]) {
    #pragma unroll
    for (int tau = 1; tau < 16; ++tau) {
        const int q = brev4(tau);
        v[q] = CONJ ? cmul_cj(v[q], tw[tau]) : cmul(v[q], tw[tau]);
    }
}

// twrow points at tw2lds + (tid&15); stride 16 per tau. Broadcast reads.
template<bool CONJ>
__device__ __forceinline__ void apply_tw_lds(cx v[16], const cx* twrow) {
    #pragma unroll
    for (int tau = 1; tau < 16; ++tau) {
        cx w = twrow[tau * 16];
        const int q = brev4(tau);
        v[q] = CONJ ? cmul_cj(v[q], w) : cmul(v[q], w);
    }
}

// ---- per-stage helpers (in-place per-thread; caller places barriers) ------
__device__ __forceinline__ void fwd_s1_store_hz(
    const cx vin[8], const cx tw[16], cx* d, int tid)
{
    cx x[16];
    #pragma unroll
    for (int t = 0; t < 8; ++t) x[t] = vin[t];
    fft16_dif_r4<true>(x);
    apply_tw<false>(x, tw);
    cx* base = d + fpad(tid);
    #pragma unroll
    for (int p = 0; p < 16; ++p) base[274 * p] = x[p];
}

__device__ __forceinline__ void fwd_s2(cx* d, int tid, const cx* tw2lds)
{
    cx v[16];
    cx* base = d + fpad(((tid >> 4) << 8) + (tid & 15));
    #pragma unroll
    for (int t = 0; t < 16; ++t) v[t] = base[17 * t];
    fft16_dif_r4<false>(v);
    apply_tw_lds<false>(v, tw2lds + (tid & 15));
    #pragma unroll
    for (int p = 0; p < 16; ++p) base[17 * p] = v[p];
}

// stage 3: keeps result in v (thread owns bins [tid*16, tid*16+16))
__device__ __forceinline__ void fwd_s3_keep(cx* d, int tid, cx v[16])
{
    cx* base = d + fpad(tid << 4);
    #pragma unroll
    for (int t = 0; t < 16; ++t) v[t] = base[t];
    fft16_dif_r4<false>(v);
    #pragma unroll
    for (int p = 0; p < 16; ++p) base[p] = v[p];
}

__device__ __forceinline__ void inv_s2(cx* d, int tid, const cx* tw2lds)
{
    cx v[16];
    cx* base = d + fpad(((tid >> 4) << 8) + (tid & 15));
    #pragma unroll
    for (int p = 0; p < 16; ++p) v[p] = base[17 * p];
    apply_tw_lds<true>(v, tw2lds + (tid & 15));
    fft16_dit_inv_r4<false>(v);
    #pragma unroll
    for (int t = 0; t < 16; ++t) base[17 * t] = v[t];
}

// inv stage 3 (lower half) fused with the u-gate: output stays in regs and
// goes straight to global at n = tid + 256*t (coalesced strided).
__device__ __forceinline__ void inv_s3_gate(
    const cx* d, int tid, const cx tw[16],
    const bf16 ua[8], const bf16 ub[8],
    bf16* __restrict__ g0, bf16* __restrict__ g1)
{
    cx v[16];
    const cx* base = d + fpad(tid);
    #pragma unroll
    for (int p = 0; p < 16; ++p) v[p] = base[274 * p];
    apply_tw<true>(v, tw);
    fft16_dit_inv_r4<true>(v);
    #pragma unroll
    for (int t = 0; t < 8; ++t) {
        const int n = tid + 256 * t;
        g0[n] = (bf16)(v[t].x * (float)ua[t]);
        g1[n] = (bf16)(v[t].y * (float)ub[t]);
    }
}

// pointwise using own fwd-s3 regs (v in: Z block; v out: Y block).
// Only the conjugate-partner block is read from LDS (thread 0: none).
__device__ __forceinline__ void pointwise_regs(
    const cx* d, int tid, const float4 a0pf[8], const float4 a1pf[8],
    cx v[16])
{
    auto pf = [](const float4* p, int i) -> cx {
        return (i & 1) ? mkcx(p[i >> 1].z, p[i >> 1].w)
                       : mkcx(p[i >> 1].x, p[i >> 1].y);
    };
    const int pbase = tid << 4;
    cx zm[16];
    if (tid == 0) {
        #pragma unroll
        for (int i = 0; i < 16; ++i) {
            const int p2 = (i < 2) ? i : (i ^ ((1 << (31 - __clz(i))) - 1));
            zm[i] = v[p2];                    // compile-time index
        }
    } else {
        const int mask = (1 << (31 - __clz(pbase))) - 1;
        const cx* zb2 = d + fpad((pbase ^ mask) - 15);
        #pragma unroll
        for (int i = 0; i < 16; ++i) zm[i] = zb2[15 - i];
    }
    #pragma unroll
    for (int i = 0; i < 16; ++i) {
        cx Zk = v[i];
        cx cjZm = mkcx(zm[i].x, -zm[i].y);
        cx V0 = Zk + cjZm;
        cx V1 = cneg_i(Zk - cjZm);
        v[i] = cmul(V0, pf(a0pf, i)) + cpos_i(cmul(V1, pf(a1pf, i)));
    }
}

// ---------------------------------------------------------------------------
// Forward FFT of packed (a_ch0, a_ch1) pair, unpack both real spectra in
// DIF order (conjugate-partner: p2 = p ^ (2^floor(log2 p) - 1)).
// A0 = c*(Wk + conj(Wm)), A1 = c*(-i)*(Wk - conj(Wm)), c = 0.25/4096.
// Wk comes from fwd-s3 registers; only Wm is read from LDS.
// ---------------------------------------------------------------------------
__global__ __launch_bounds__(256, 4) void fft_a_kernel(
    const float* a_t, cx* __restrict__ A0s, cx* A1s,
    const cx* __restrict__ Twd)
{
    __shared__ cx data[FFT_LDS_SZ];
    __shared__ cx tw2lds[256];
    const int tid = threadIdx.x;
    const int r = blockIdx.x;                      // pair index, ch = 2r

    cx tw[16];
    {
        const cx* Tr1 = Twd + (tid << 4);
        #pragma unroll
        for (int t = 1; t < 16; ++t) tw[t] = Tr1[t];
        tw2lds[(tid >> 4) * 16 + (tid & 15)] = Twd[(tid & 15) * 256 + (tid >> 4)];
    }

    const float* r0 = a_t + (size_t)(2 * r) * M_FFT;
    const float* r1 = r0 + M_FFT;
    cx v[16];
    #pragma unroll
    for (int t = 0; t < 16; ++t)
        v[t] = mkcx(r0[tid + 256 * t], r1[tid + 256 * t]);

    {   // stage 1 from registers
        fft16_dif_r4<false>(v);
        apply_tw<false>(v, tw);
        cx* base = data + fpad(tid);
        #pragma unroll
        for (int p = 0; p < 16; ++p) base[274 * p] = v[p];
    }
    __syncthreads();
    fwd_s2(data, tid, tw2lds);
    __syncthreads();
    fwd_s3_keep(data, tid, v);
    __syncthreads();

    const float c = 0.25f / 4096.0f;
    const int base_i = tid << 4;
    cx* A0row = A0s + (size_t)r * 4096;
    cx* A1row = A1s + (size_t)r * 4096;
    cx wm[16];
    if (tid == 0) {
        #pragma unroll
        for (int i = 0; i < 16; ++i) {
            const int p2 = (i < 2) ? i : (i ^ ((1 << (31 - __clz(i))) - 1));
            wm[i] = v[p2];
        }
    } else {
        const int mask = (1 << (31 - __clz(base_i))) - 1;
        const cx* zb2 = data + fpad((base_i ^ mask) - 15);
        #pragma unroll
        for (int i = 0; i < 16; ++i) wm[i] = zb2[15 - i];
    }
    #pragma unroll
    for (int i = 0; i < 16; ++i) {
        cx cjWm = mkcx(wm[i].x, -wm[i].y);
        A0row[base_i + i] = c * (v[i] + cjWm);
        A1row[base_i + i] = c * cneg_i(v[i] - cjWm);
    }
}

// ---------------------------------------------------------------------------
// Conv kernel: TWO channel-pairs per block (batches 2bp and 2bp+1 of the
// SAME r) -> 2x work per barrier region, A rows loaded once for both.
// Bijective XCD remap: xcd = r&7; slots pair (r,bp=0),(r,bp=1) adjacent.
// 6 barriers; fwd-s3/pointwise and inv-s3/gate run register-resident.
// ---------------------------------------------------------------------------
__global__ __launch_bounds__(256, 2) void fft_conv_kernel(
    const bf16* __restrict__ v_t, const cx* __restrict__ A0s,
    const cx* __restrict__ A1s, const bf16* __restrict__ u_t,
    bf16* __restrict__ gated_t, const cx* __restrict__ Twd)
{
    __shared__ cx data[2][FFT_LDS_SZ];
    __shared__ cx tw2lds[256];
    const int tid = threadIdx.x;
    const int bx = blockIdx.x;
    const int xcd  = bx & 7;
    const int slot = bx >> 3;                 // [0,192)
    const int bp   = slot & 1;
    const int r    = (slot >> 1) * 8 + xcd;   // [0,768), bijective
    const int ch   = 2 * r;
    const int b0   = 2 * bp;
    const int b1   = 2 * bp + 1;

    cx tw[16];
    {
        const cx* Tr1 = Twd + (tid << 4);
        #pragma unroll
        for (int t = 1; t < 16; ++t) tw[t] = Tr1[t];
        tw2lds[(tid >> 4) * 16 + (tid & 15)] = Twd[(tid & 15) * 256 + (tid >> 4)];
    }

    // ---- forward stage 1: both chunks straight from global ----
    const bf16* z00 = v_t + ((size_t)(b0 * D1 + ch)) * N_SEQ;
    const bf16* z01 = z00 + N_SEQ;
    const bf16* z10 = v_t + ((size_t)(b1 * D1 + ch)) * N_SEQ;
    const bf16* z11 = z10 + N_SEQ;
    {
        cx w0[8], w1[8];
        #pragma unroll
        for (int t = 0; t < 8; ++t)
            w0[t] = mkcx((float)z00[tid + 256 * t], (float)z01[tid + 256 * t]);
        #pragma unroll
        for (int t = 0; t < 8; ++t)
            w1[t] = mkcx((float)z10[tid + 256 * t], (float)z11[tid + 256 * t]);
        fwd_s1_store_hz(w0, tw, data[0], tid);
        fwd_s1_store_hz(w1, tw, data[1], tid);
    }
    __syncthreads();                                              // 1

    fwd_s2(data[0], tid, tw2lds);
    fwd_s2(data[1], tid, tw2lds);
    __syncthreads();                                              // 2

    // A rows (shared by both chunks): issue before stage-3 compute so the
    // pre-barrier vmcnt drain overlaps both chunks' stage 3.
    const int pbase = tid << 4;
    float4 a0pf[8], a1pf[8];
    {
        const float4* A0p = (const float4*)(A0s + (size_t)r * 4096 + pbase);
        const float4* A1p = (const float4*)(A1s + (size_t)r * 4096 + pbase);
        #pragma unroll
        for (int i = 0; i < 8; ++i) { a0pf[i] = A0p[i]; a1pf[i] = A1p[i]; }
    }
    cx vA[16], vB[16];
    fwd_s3_keep(data[0], tid, vA);
    fwd_s3_keep(data[1], tid, vB);
    __syncthreads();                                              // 3

    // ---- pointwise (own Z from regs, partner from LDS; A in regs x2) ----
    pointwise_regs(data[0], tid, a0pf, a1pf, vA);
    pointwise_regs(data[1], tid, a0pf, a1pf, vB);
    __syncthreads();                       // 4: partner reads done
    fft16_dit_inv_r4<false>(vA);
    fft16_dit_inv_r4<false>(vB);
    {
        cx* baseA = data[0] + fpad(pbase);
        cx* baseB = data[1] + fpad(pbase);
        #pragma unroll
        for (int i = 0; i < 16; ++i) baseA[i] = vA[i];
        #pragma unroll
        for (int i = 0; i < 16; ++i) baseB[i] = vB[i];
    }
    __syncthreads();                                              // 5

    // u rows (strided layout matching inv-s3 ownership): issue before inv
    // stage 2 so the latency hides under it.
    const bf16* u00 = u_t + ((size_t)(b0 * D1 + ch)) * N_SEQ;
    const bf16* u01 = u00 + N_SEQ;
    const bf16* u10 = u_t + ((size_t)(b1 * D1 + ch)) * N_SEQ;
    const bf16* u11 = u10 + N_SEQ;
    bf16 ua0[8], ub0[8], ua1[8], ub1[8];
    #pragma unroll
    for (int t = 0; t < 8; ++t) {
        const int n = tid + 256 * t;
        ua0[t] = u00[n]; ub0[t] = u01[n];
        ua1[t] = u10[n]; ub1[t] = u11[n];
    }

    inv_s2(data[0], tid, tw2lds);
    inv_s2(data[1], tid, tw2lds);
    __syncthreads();                                              // 6

    bf16* g00 = gated_t + ((size_t)(b0 * D1 + ch)) * N_SEQ;
    bf16* g01 = g00 + N_SEQ;
    bf16* g10 = gated_t + ((size_t)(b1 * D1 + ch)) * N_SEQ;
    bf16* g11 = g10 + N_SEQ;
    inv_s3_gate(data[0], tid, tw, ua0, ub0, g00, g01);
    inv_s3_gate(data[1], tid, tw, ua1, ub1, g10, g11);
}

// ---------------------------------------------------------------------------
__global__ __launch_bounds__(256) void transpose_cs_kernel(
    const bf16* __restrict__ in, bf16* __restrict__ outp)
{
    __shared__ bf16 tile[64 * 68];
    const int c0 = blockIdx.x * 64;
    const int m0 = blockIdx.y * 64;
    const int b  = m0 >> 11;
    const int s0 = m0 & 2047;
    const int tid = threadIdx.x;
    const int cl = tid >> 4;
    const int sc = (tid & 15) * 4;
    #pragma unroll
    for (int p = 0; p < 4; ++p) {
        int c = p * 16 + cl;
        bf16x4 v = *(const bf16x4*)&in[((size_t)(b * D1 + c0 + c)) * N_SEQ + s0 + sc];
        *(bf16x4*)&tile[c * 68 + sc] = v;
    }
    __syncthreads();
    const int sl = tid >> 4;
    const int cc = (tid & 15) * 4;
    #pragma unroll
    for (int p = 0; p < 4; ++p) {
        int s = p * 16 + sl;
        bf16x4 o;
        #pragma unroll
        for (int j = 0; j < 4; ++j) o[j] = tile[(cc + j) * 68 + s];
        *(bf16x4*)&outp[((size_t)(m0 + s)) * D1 + c0 + cc] = o;
    }
}

// ---------------------------------------------------------------------------
extern "C" void kernel_launch(void* const* d_in, const int* in_sizes, int n_in,
                              void* d_out, int out_size, void* d_ws, size_t ws_size,
                              hipStream_t stream)
{
    const float* x  = (const float*)d_in[0];
    const float* Wu = (const float*)d_in[1];
    const float* bu = (const float*)d_in[2];
    const float* Wv = (const float*)d_in[3];
    const float* bv = (const float*)d_in[4];
    const float* Wo = (const float*)d_in[5];
    const float* bo = (const float*)d_in[6];
    const float* Wp = (const float*)d_in[7];
    const float* bp = (const float*)d_in[8];
    const float* Wl = (const float*)d_in[9];
    const float* bl = (const float*)d_in[10];
    const float* Wr = (const float*)d_in[11];
    const float* br = (const float*)d_in[12];
    float* out = (float*)d_out;

    float* ws      = (float*)d_ws;
    float* a_t     = ws;                       // 1536*4096 fp32; A1spec after fft_a
    float* A0spec  = a_t   + 6291456;          // 768 x 4096 cx
    float* sumsq   = A0spec + 6291456;         // 3 x 4096 fp32
    float* twd     = sumsq + 12288;            // 256 x 16 cx twiddle table
    bf16*  bfws    = (bf16*)(twd + 8192);
    bf16*  x_bf    = bfws;                     // 8192*512
    bf16*  w_bf    = x_bf    + 4194304;        // 5 x 786432: Wu,Wv,Wo,Wl,Wr
    bf16*  Wuv_bf  = w_bf;                     // stacked [Wu;Wv] 3072 x 512
    bf16*  Wo_bf   = w_bf    + 2 * 786432;
    bf16*  Wl_bf   = Wo_bf   + 786432;
    bf16*  Wr_bf   = Wl_bf   + 786432;
    bf16*  gA      = Wr_bf   + 786432;         // 4096*512
    bf16*  gB      = gA      + 2097152;        // 4096*512
    bf16*  u_t     = gB      + 2097152;        // 8192*1536 [b][c][s]
    bf16*  v_t     = u_t     + 12582912;       // 8192*1536 [b][c][s]
    bf16*  gated_t = v_t     + 12582912;       // 8192*1536 [b][c][s]
    bf16*  gated   = gated_t + 12582912;       // 8192*1536 [m][c]

    dim3 blk(256);

    // x/w converts + sumsq zero + rpe input layer + twiddle table
    f2b_all_kernel<<<4096 + 5 * 768 + 12 + 4096 + 16, blk, 0, stream>>>(
        x, Wu, Wv, Wo, Wl, Wr, Wp, bp, x_bf, w_bf, sumsq, gA, twd);

    gemm_bf16<MODE_SILU_UV, 128, bf16><<<dim3(24, 64), blk, 0, stream>>>(
        x_bf, Wuv_bf, bu, bv, u_t, v_t, 8192, 2 * D1, ED, nullptr, nullptr);

    // RPE MLP: srms folded into GEMM epilogues via row-scale commutation.
    bf16* gin = gA;
    bf16* gout = gB;
    for (int i = 0; i < 3; ++i) {
        const float* sin_p = (i == 0) ? nullptr : sumsq + (size_t)(i - 1) * 4096;
        gemm_bf16<MODE_RPE, 64, bf16><<<dim3(8, 32), blk, 0, stream>>>(
            gin, Wl_bf + (size_t)i * ED * ED, bl + (size_t)i * ED, nullptr,
            gout, nullptr, 4096, ED, ED, sin_p, sumsq + (size_t)i * 4096);
        bf16* t = gin; gin = gout; gout = t;
    }
    gemm_bf16<MODE_AT, 64, float><<<dim3(24, 32), blk, 0, stream>>>(
        gin, Wr_bf, br, nullptr, a_t, nullptr, 4096, D1, ED,
        sumsq + 2 * 4096, nullptr);

    fft_a_kernel<<<768, blk, 0, stream>>>(
        a_t, (cx*)A0spec, (cx*)a_t, (const cx*)twd);
    fft_conv_kernel<<<1536, blk, 0, stream>>>(
        v_t, (const cx*)A0spec, (const cx*)a_t, u_t, gated_t, (const cx*)twd);

    transpose_cs_kernel<<<dim3(24, 128), blk, 0, stream>>>(gated_t, gated);

    gemm_bf16<MODE_PLAIN, 64, float><<<dim3(8, 64), blk, 0, stream>>>(
        gated, Wo_bf, bo, nullptr, out, nullptr, 8192, ED, D1,
        nullptr, nullptr);
}

// Round 12
// 316.724 us; speedup vs baseline: 1.2654x; 1.0412x over previous
//
#include <hip/hip_runtime.h>

#define N_SEQ 2048
#define M_FFT 4096
#define D1    1536
#define NH    8
#define HD    192
#define ED    512

typedef __bf16 bf16;
typedef __bf16 bf16x4 __attribute__((ext_vector_type(4)));
typedef __bf16 bf16x8 __attribute__((ext_vector_type(8)));
typedef float  floatx4 __attribute__((ext_vector_type(4)));
typedef float  cx __attribute__((ext_vector_type(2)));   // complex as packed fp32

enum { MODE_PLAIN = 0, MODE_SILU_UV = 1, MODE_AT = 3, MODE_RPE = 4 };

__device__ __forceinline__ void gload16(const void* g, void* l) {
    __builtin_amdgcn_global_load_lds(
        (const __attribute__((address_space(1))) void*)g,
        (__attribute__((address_space(3))) void*)l, 16, 0, 0);
}

// ---------------------------------------------------------------------------
// bf16 MFMA GEMM, depth-3 pipeline with COUNTED vmcnt (T4), BN-templated,
// + T2 granule-XOR LDS swizzle + T5 setprio.
// NEW: SILU_UV / AT epilogues transpose through LDS (reusing the dead
// staging buffers) so the [channel][seq]-layout stores become 256-512 B
// contiguous segments instead of 4-16 KB/lane scatter (store-issue
// serialization was the residual after conflicts+occupancy were fixed).
// ---------------------------------------------------------------------------
template<int MODE, int BN, typename OutT>
__global__ __launch_bounds__(256) void gemm_bf16(
    const bf16* __restrict__ A, const bf16* __restrict__ Bw,
    const float* __restrict__ bias, const float* __restrict__ bias2,
    OutT* __restrict__ C, OutT* __restrict__ C2,
    int M, int Nc, int K,
    const float* __restrict__ scale_in, float* __restrict__ sumsq_out)
{
    constexpr int NJ  = BN / 32;           // n-fragments per wave (4 or 2)
    constexpr int ASZ = 3 * 128 * 32;
    constexpr int BSZ = 3 * BN * 32;
    __shared__ __align__(16) bf16 smem[ASZ + BSZ];
    bf16* As = smem;
    bf16* Bs = smem + ASZ;

    const int tid  = threadIdx.x;
    const int row0 = blockIdx.y * 128;
    const int col0 = blockIdx.x * BN;
    const int wid  = tid >> 6;
    const int lane = tid & 63;
    const int lm   = lane & 15;
    const int lk   = lane >> 4;
    const int wm   = wid >> 1;
    const int wn   = wid & 1;
    const int ldrow  = tid >> 2;
    // T2 write-side: source granule = (tid&3) ^ ((row>>1)&3), row = tid>>2
    const int ldcol8 = (((tid & 3) ^ ((tid >> 3) & 3))) * 8;
    // T2 read-side: granule = lk ^ ((row>>1)&3) = lk ^ ((lm>>1)&3)
    const int gsw = (lk ^ ((lm >> 1) & 3)) * 8;

    floatx4 acc[4][NJ] = {};

    const bf16* Ag = A  + ((size_t)(row0 + ldrow)) * K + ldcol8;
    const bf16* Bg = Bw + ((size_t)(col0 + ldrow)) * K + ldcol8;
    const int woff = (wid * 16) * 32;

    auto stage = [&](int t, int buf) {
        const int k0 = t << 5;
        gload16(Ag + k0, &As[buf * (128 * 32) + woff]);
        gload16(Ag + (size_t)64 * K + k0, &As[buf * (128 * 32) + woff + 64 * 32]);
        gload16(Bg + k0, &Bs[buf * (BN * 32) + woff]);
        if constexpr (BN == 128)
            gload16(Bg + (size_t)64 * K + k0, &Bs[buf * (BN * 32) + woff + 64 * 32]);
    };
    auto compute = [&](int buf) {
        bf16x8 af[4], bfr[NJ];
        #pragma unroll
        for (int mi = 0; mi < 4; ++mi)
            af[mi] = *(const bf16x8*)&As[buf * (128 * 32) + (wm * 64 + mi * 16 + lm) * 32 + gsw];
        #pragma unroll
        for (int nj = 0; nj < NJ; ++nj)
            bfr[nj] = *(const bf16x8*)&Bs[buf * (BN * 32) + (wn * (BN / 2) + nj * 16 + lm) * 32 + gsw];
        __builtin_amdgcn_s_setprio(1);                 // T5
        #pragma unroll
        for (int mi = 0; mi < 4; ++mi)
            #pragma unroll
            for (int nj = 0; nj < NJ; ++nj)
                acc[mi][nj] = __builtin_amdgcn_mfma_f32_16x16x32_bf16(
                    af[mi], bfr[nj], acc[mi][nj], 0, 0, 0);
        __builtin_amdgcn_s_setprio(0);
    };

    const int nt = K >> 5;           // 16 or 48
    stage(0, 0);
    stage(1, 1);
    int sb = 2, cb = 0;
    for (int t = 0; t < nt; ++t) {
        __builtin_amdgcn_s_barrier();          // A: compute(t-1) done everywhere
        __builtin_amdgcn_sched_barrier(0);
        if (t + 2 < nt) {
            stage(t + 2, sb);
            if (++sb == 3) sb = 0;
        }
        // own tile-t loads complete; next two tiles stay in flight
        if (t < nt - 2) {
            if constexpr (BN == 128) asm volatile("s_waitcnt vmcnt(8)" ::: "memory");
            else                     asm volatile("s_waitcnt vmcnt(6)" ::: "memory");
        } else if (t == nt - 2) {
            if constexpr (BN == 128) asm volatile("s_waitcnt vmcnt(4)" ::: "memory");
            else                     asm volatile("s_waitcnt vmcnt(3)" ::: "memory");
        } else {
            asm volatile("s_waitcnt vmcnt(0)" ::: "memory");
        }
        __builtin_amdgcn_s_barrier();          // B: tile t fully in LDS (all waves)
        __builtin_amdgcn_sched_barrier(0);
        compute(cb);
        if (++cb == 3) cb = 0;
    }

    const float* bs = bias;
    OutT* dst = C;
    int cadj = 0;
    if (MODE == MODE_SILU_UV && col0 >= D1) { bs = bias2; dst = C2; cadj = D1; }

    float bcol[NJ];
    #pragma unroll
    for (int nj = 0; nj < NJ; ++nj)
        bcol[nj] = bs[col0 - cadj + wn * (BN / 2) + nj * 16 + lm];

    if (MODE == MODE_RPE) {
        #pragma unroll
        for (int mi = 0; mi < 4; ++mi) {
            #pragma unroll
            for (int r = 0; r < 4; ++r) {
                const int row = row0 + wm * 64 + mi * 16 + lk * 4 + r;
                float sc = 1.0f;
                if (scale_in)
                    sc = 1.0f / (sqrtf(scale_in[row]) * 0.04419417382415922f + 1e-8f);
                float ssq = 0.0f;
                #pragma unroll
                for (int nj = 0; nj < NJ; ++nj) {
                    const int col = col0 + wn * (BN / 2) + nj * 16 + lm;
                    float val = acc[mi][nj][r] * sc + bcol[nj];
                    ssq += val * val;
                    ((bf16*)C)[(size_t)row * Nc + col] = (bf16)fmaxf(val, 0.0f);
                }
                ssq += __shfl_xor(ssq, 1, 64);
                ssq += __shfl_xor(ssq, 2, 64);
                ssq += __shfl_xor(ssq, 4, 64);
                ssq += __shfl_xor(ssq, 8, 64);
                if (lm == 0) atomicAdd(&sumsq_out[row], ssq);
            }
        }
        return;
    }

    if (MODE == MODE_SILU_UV) {
        // ---- transpose-through-LDS coalesced store (128 x 128 tile) ----
        constexpr int TP = 136;                 // row pad: 16B-aligned rows
        bf16* T = smem;                         // 128*136*2 = 34816 B <= 48K
        __syncthreads();                        // K-loop LDS reads done
        #pragma unroll
        for (int mi = 0; mi < 4; ++mi) {
            const int rl = wm * 64 + mi * 16 + lk * 4;
            #pragma unroll
            for (int nj = 0; nj < NJ; ++nj) {
                const int cl = wn * 64 + nj * 16 + lm;
                bf16x4 o;
                #pragma unroll
                for (int r = 0; r < 4; ++r) {
                    float val = acc[mi][nj][r] + bcol[nj];
                    val = val * __fdividef(1.0f, 1.0f + __expf(-val));
                    o[r] = (bf16)val;
                }
                *(bf16x4*)&T[cl * TP + rl] = o;
            }
        }
        __syncthreads();
        const int b  = row0 >> 11;
        const int s0 = row0 & 2047;
        #pragma unroll
        for (int j = 0; j < 8; ++j) {
            const int idx = j * 256 + tid;      // [0, 2048)
            const int sc  = (idx & 15) * 8;     // s-chunk (16 consecutive tids)
            const int c   = idx >> 4;           // column 0..127
            bf16x8 o = *(const bf16x8*)&T[c * TP + sc];
            *(bf16x8*)&((bf16*)dst)[((size_t)(b * D1 + col0 - cadj + c)) * N_SEQ + s0 + sc] = o;
        }
        return;
    }

    if (MODE == MODE_AT) {
        // ---- transpose-through-LDS coalesced fp32 store (64 x 128 tile) ----
        constexpr int TP = 132;                 // fp32 row pad (16B-aligned)
        float* Tf = (float*)smem;               // 64*132*4 = 33792 B <= 36864
        __syncthreads();
        #pragma unroll
        for (int mi = 0; mi < 4; ++mi) {
            const int rbase = row0 + wm * 64 + mi * 16 + lk * 4;
            const int rl    = wm * 64 + mi * 16 + lk * 4;
            float sc[4];
            #pragma unroll
            for (int r = 0; r < 4; ++r)
                sc[r] = scale_in
                    ? 1.0f / (sqrtf(scale_in[rbase + r]) * 0.04419417382415922f + 1e-8f)
                    : 1.0f;
            #pragma unroll
            for (int nj = 0; nj < NJ; ++nj) {
                const int cl = wn * (BN / 2) + nj * 16 + lm;
                float4 o;
                o.x = acc[mi][nj][0] * sc[0] + bcol[nj];
                o.y = acc[mi][nj][1] * sc[1] + bcol[nj];
                o.z = acc[mi][nj][2] * sc[2] + bcol[nj];
                o.w = acc[mi][nj][3] * sc[3] + bcol[nj];
                *(float4*)&Tf[cl * TP + rl] = o;
            }
        }
        __syncthreads();
        #pragma unroll
        for (int j = 0; j < 8; ++j) {
            const int idx = j * 256 + tid;      // [0, 2048)
            const int rc  = (idx & 31) * 4;     // row-chunk (32 consecutive tids)
            const int c   = idx >> 5;           // column 0..63
            float4 o = *(const float4*)&Tf[c * TP + rc];
            *(float4*)&((float*)C)[(size_t)(col0 + c) * M + row0 + rc] = o;
        }
        return;
    }

    // MODE_PLAIN: row-major contiguous store (already coalesced enough)
    #pragma unroll
    for (int mi = 0; mi < 4; ++mi) {
        const int rbase = row0 + wm * 64 + mi * 16 + lk * 4;
        #pragma unroll
        for (int nj = 0; nj < NJ; ++nj) {
            const int col = col0 + wn * (BN / 2) + nj * 16 + lm;
            #pragma unroll
            for (int r = 0; r < 4; ++r) {
                float val = acc[mi][nj][r] + bcol[nj];
                C[(size_t)(rbase + r) * Nc + col] = (OutT)val;
            }
        }
    }
}

// ---------------------------------------------------------------------------
// mega-prologue: x convert + 5 weight converts + sumsq zero +
// RPE input layer w/ srms + FFT twiddle table (256 x 16 cx)
// ---------------------------------------------------------------------------
__global__ __launch_bounds__(256) void f2b_all_kernel(
    const float* __restrict__ x,  const float* __restrict__ s0,
    const float* __restrict__ s1, const float* __restrict__ s2,
    const float* __restrict__ s3, const float* __restrict__ s4,
    const float* __restrict__ Wp, const float* __restrict__ bp,
    bf16* __restrict__ x_bf, bf16* __restrict__ w_bf,
    float* __restrict__ sumsq, bf16* __restrict__ g0,
    float* __restrict__ twd)
{
    const int bid = blockIdx.x;
    const int tid = threadIdx.x;
    __shared__ float red[4];

    if (bid < 7936) {
        const float* src;
        bf16* dst;
        size_t off;
        if (bid < 4096) {
            src = x; dst = x_bf; off = (size_t)bid * 1024;
        } else {
            int t = bid - 4096;
            int seg = t / 768;
            src = seg == 0 ? s0 : seg == 1 ? s1 : seg == 2 ? s2
                : seg == 3 ? s3 : s4;
            dst = w_bf + (size_t)seg * 786432;
            off = (size_t)(t % 768) * 1024;
        }
        size_t i = off + (size_t)tid * 4;
        float4 f = *(const float4*)(src + i);
        union { bf16 h[4]; short4 s; } u4;
        u4.h[0] = (bf16)f.x; u4.h[1] = (bf16)f.y;
        u4.h[2] = (bf16)f.z; u4.h[3] = (bf16)f.w;
        *(short4*)(dst + i) = u4.s;
    } else if (bid < 7948) {
        size_t i = (size_t)(bid - 7936) * 1024 + (size_t)tid * 4;
        *(float4*)(sumsq + i) = make_float4(0.f, 0.f, 0.f, 0.f);
    } else if (bid < 12044) {
        const int j = bid - 7948;
        float idxv = (j < N_SEQ) ? (float)j
                                 : (j == N_SEQ ? 0.0f : (float)(j - 2 * N_SEQ));
        float h1 = idxv * Wp[tid] + bp[tid];
        float h2 = idxv * Wp[tid + 256] + bp[tid + 256];
        float ss = h1 * h1 + h2 * h2;
        #pragma unroll
        for (int off = 32; off > 0; off >>= 1) ss += __shfl_down(ss, off, 64);
        if ((tid & 63) == 0) red[tid >> 6] = ss;
        __syncthreads();
        float tot = red[0] + red[1] + red[2] + red[3];
        float scale = 1.0f / (sqrtf(tot) * 0.04419417382415922f + 1e-8f);
        g0[(size_t)j * ED + tid]       = (bf16)fmaxf(h1 * scale, 0.0f);
        g0[(size_t)j * ED + tid + 256] = (bf16)fmaxf(h2 * scale, 0.0f);
    } else {
        const int idx = (bid - 12044) * 256 + tid;    // [0, 4096)
        const int j = idx >> 4, tau = idx & 15;
        float sA, cA;
        __sincosf(-6.283185307179586f * (float)(j * tau) * (1.0f / 4096.0f),
                  &sA, &cA);
        cx w; w.x = cA; w.y = sA;
        ((cx*)twd)[idx] = w;
    }
}

// ---------------------------------------------------------------------------
// Radix-16 FFT, radix-4 butterflies, packed-fp32 complex.
// LDS addressing: fpad(base + s*t) = fpad(base) + s'*t  (256->274, 16->17, 1->1)
// Stage-1/inv-3 twiddle row (tid<<4) in REGISTERS (inverse = conjugate);
// stage-2/inv-2 rows (16 distinct) in a 2 KB LDS broadcast table.
// Register-residency: fwd-s3 output stays in regs across the barrier;
// inv-s3 output gates directly to global (strided coalesced).
// ---------------------------------------------------------------------------
#define FFT_LDS_SZ 4381

__device__ __forceinline__ int fpad(int i) { return i + (i >> 4) + 2 * (i >> 8); }

__device__ __forceinline__ cx mkcx(float a, float b) { cx r; r.x = a; r.y = b; return r; }
__device__ __forceinline__ cx cmul(cx a, cx b) {
    cx br = mkcx(-b.y, b.x);
    return a.xx * b + a.yy * br;
}
__device__ __forceinline__ cx cmul_cj(cx a, cx b) {      // a * conj(b)
    cx bc = mkcx(b.x, -b.y);
    cx br = mkcx(b.y, b.x);
    return a.xx * bc + a.yy * br;
}
__device__ __forceinline__ cx cneg_i(cx a) { return mkcx(a.y, -a.x); }   // a * (-i)
__device__ __forceinline__ cx cpos_i(cx a) { return mkcx(-a.y, a.x); }   // a * (+i)
__host__ __device__ constexpr int brev4(int t) {
    return ((t & 1) << 3) | ((t & 2) << 1) | ((t & 4) >> 1) | ((t & 8) >> 3);
}

#define CC1 0.9238795325112867f
#define SS1 0.3826834323650898f
#define RR2 0.7071067811865476f

template<bool HZ>
__device__ __forceinline__ void fft16_dif_r4(cx x[16]) {
    const cx W1 = mkcx( CC1, -SS1);
    const cx W2 = mkcx( RR2, -RR2);
    const cx W3 = mkcx( SS1, -CC1);
    const cx W6 = mkcx(-RR2, -RR2);
    const cx W9 = mkcx(-CC1,  SS1);
    #pragma unroll
    for (int n = 0; n < 4; ++n) {
        cx A, B, C, D;
        if (HZ) { A = x[n]; C = x[n]; B = x[n + 4]; D = x[n + 4]; }
        else {
            A = x[n] + x[n + 8];      C = x[n] - x[n + 8];
            B = x[n + 4] + x[n + 12]; D = x[n + 4] - x[n + 12];
        }
        cx s = A - B;
        cx nid = cneg_i(D);
        cx m = C + nid;
        cx p = C - nid;
        x[n] = A + B;
        if (n == 0)      { x[4] = s;            x[8]  = m;           x[12] = p; }
        else if (n == 1) { x[5] = cmul(s, W2);  x[9]  = cmul(m, W1); x[13] = cmul(p, W3); }
        else if (n == 2) { x[6] = cneg_i(s);    x[10] = cmul(m, W2); x[14] = cmul(p, W6); }
        else             { x[7] = cmul(s, W6);  x[11] = cmul(m, W3); x[15] = cmul(p, W9); }
    }
    #pragma unroll
    for (int q = 0; q < 16; q += 4) {
        cx a = x[q], b = x[q + 1], c = x[q + 2], d = x[q + 3];
        cx a1 = a + c, c1 = a - c;
        cx b1 = b + d, d1 = cneg_i(b - d);
        x[q]     = a1 + b1;
        x[q + 1] = a1 - b1;
        x[q + 2] = c1 + d1;
        x[q + 3] = c1 - d1;
    }
}

template<bool HALF_OUT>
__device__ __forceinline__ void fft16_dit_inv_r4(cx x[16]) {
    const cx V1 = mkcx( CC1, SS1);
    const cx V2 = mkcx( RR2, RR2);
    const cx V3 = mkcx( SS1, CC1);
    const cx V6 = mkcx(-RR2, RR2);
    #pragma unroll
    for (int q = 0; q < 16; q += 4) {
        cx a = x[q], b = x[q + 1], c = x[q + 2], d = x[q + 3];
        cx a1 = a + b, b1 = a - b;
        cx c1 = c + d, d1 = c - d;
        cx t = cpos_i(d1);
        x[q]     = a1 + c1;
        x[q + 2] = a1 - c1;
        x[q + 1] = b1 + t;
        x[q + 3] = b1 - t;
    }
    #pragma unroll
    for (int n = 0; n < 4; ++n) {
        cx t1, t2;
        if (n == 0)      { t1 = x[4];             t2 = x[12]; }
        else if (n == 1) { t1 = cmul(x[5],  V2);  t2 = cmul(x[13], V2); }
        else if (n == 2) { t1 = cpos_i(x[6]);     t2 = cpos_i(x[14]); }
        else             { t1 = cmul(x[7],  V6);  t2 = cmul(x[15], V6); }
        cx P = x[n] + t1, Q = x[n] - t1;
        cx R = x[n + 8] + t2, S = x[n + 8] - t2;
        cx t, u;
        if (n == 0)      { t = R;            u = S; }
        else if (n == 1) { t = cmul(R, V1);  u = cmul(S, V1); }
        else if (n == 2) { t = cmul(R, V2);  u = cmul(S, V2); }
        else             { t = cmul(R, V3);  u = cmul(S, V3); }
        cx iu = cpos_i(u);
        x[n]     = P + t;
        x[n + 4] = Q + iu;
        if (!HALF_OUT) {
            x[n + 8]  = P - t;
            x[n + 12] = Q - iu;
        }
    }
}

template<bool CONJ>
__device__ __forceinline__ void apply_tw(cx v[16], const cx tw[16]) {
    #pragma unroll
    for (int tau = 1; tau < 16; ++tau) {
        const int q = brev4(tau);
        v[q] = CONJ ? cmul_cj(v[q], tw[tau]) : cmul(v[q], tw[tau]);
    }
}

// twrow points at tw2lds + (tid&15); stride 16 per tau. Broadcast reads.
template<bool CONJ>
__device__ __forceinline__ void apply_tw_lds(cx v[16], const cx* twrow) {
    #pragma unroll
    for (int tau = 1; tau < 16; ++tau) {
        cx w = twrow[tau * 16];
        const int q = brev4(tau);
        v[q] = CONJ ? cmul_cj(v[q], w) : cmul(v[q], w);
    }
}

// ---- per-stage helpers (in-place per-thread; caller places barriers) ------
__device__ __forceinline__ void fwd_s1_store_hz(
    const cx vin[8], const cx tw[16], cx* d, int tid)
{
    cx x[16];
    #pragma unroll
    for (int t = 0; t < 8; ++t) x[t] = vin[t];
    fft16_dif_r4<true>(x);
    apply_tw<false>(x, tw);
    cx* base = d + fpad(tid);
    #pragma unroll
    for (int p = 0; p < 16; ++p) base[274 * p] = x[p];
}

__device__ __forceinline__ void fwd_s2(cx* d, int tid, const cx* tw2lds)
{
    cx v[16];
    cx* base = d + fpad(((tid >> 4) << 8) + (tid & 15));
    #pragma unroll
    for (int t = 0; t < 16; ++t) v[t] = base[17 * t];
    fft16_dif_r4<false>(v);
    apply_tw_lds<false>(v, tw2lds + (tid & 15));
    #pragma unroll
    for (int p = 0; p < 16; ++p) base[17 * p] = v[p];
}

// stage 3: keeps result in v (thread owns bins [tid*16, tid*16+16))
__device__ __forceinline__ void fwd_s3_keep(cx* d, int tid, cx v[16])
{
    cx* base = d + fpad(tid << 4);
    #pragma unroll
    for (int t = 0; t < 16; ++t) v[t] = base[t];
    fft16_dif_r4<false>(v);
    #pragma unroll
    for (int p = 0; p < 16; ++p) base[p] = v[p];
}

__device__ __forceinline__ void inv_s2(cx* d, int tid, const cx* tw2lds)
{
    cx v[16];
    cx* base = d + fpad(((tid >> 4) << 8) + (tid & 15));
    #pragma unroll
    for (int p = 0; p < 16; ++p) v[p] = base[17 * p];
    apply_tw_lds<true>(v, tw2lds + (tid & 15));
    fft16_dit_inv_r4<false>(v);
    #pragma unroll
    for (int t = 0; t < 16; ++t) base[17 * t] = v[t];
}

// inv stage 3 (lower half) fused with the u-gate: output stays in regs and
// goes straight to global at n = tid + 256*t (coalesced strided).
__device__ __forceinline__ void inv_s3_gate(
    const cx* d, int tid, const cx tw[16],
    const bf16 ua[8], const bf16 ub[8],
    bf16* __restrict__ g0, bf16* __restrict__ g1)
{
    cx v[16];
    const cx* base = d + fpad(tid);
    #pragma unroll
    for (int p = 0; p < 16; ++p) v[p] = base[274 * p];
    apply_tw<true>(v, tw);
    fft16_dit_inv_r4<true>(v);
    #pragma unroll
    for (int t = 0; t < 8; ++t) {
        const int n = tid + 256 * t;
        g0[n] = (bf16)(v[t].x * (float)ua[t]);
        g1[n] = (bf16)(v[t].y * (float)ub[t]);
    }
}

// pointwise using own fwd-s3 regs (v in: Z block; v out: Y block).
// Only the conjugate-partner block is read from LDS (thread 0: none).
__device__ __forceinline__ void pointwise_regs(
    const cx* d, int tid, const float4 a0pf[8], const float4 a1pf[8],
    cx v[16])
{
    auto pf = [](const float4* p, int i) -> cx {
        return (i & 1) ? mkcx(p[i >> 1].z, p[i >> 1].w)
                       : mkcx(p[i >> 1].x, p[i >> 1].y);
    };
    const int pbase = tid << 4;
    cx zm[16];
    if (tid == 0) {
        #pragma unroll
        for (int i = 0; i < 16; ++i) {
            const int p2 = (i < 2) ? i : (i ^ ((1 << (31 - __clz(i))) - 1));
            zm[i] = v[p2];                    // compile-time index
        }
    } else {
        const int mask = (1 << (31 - __clz(pbase))) - 1;
        const cx* zb2 = d + fpad((pbase ^ mask) - 15);
        #pragma unroll
        for (int i = 0; i < 16; ++i) zm[i] = zb2[15 - i];
    }
    #pragma unroll
    for (int i = 0; i < 16; ++i) {
        cx Zk = v[i];
        cx cjZm = mkcx(zm[i].x, -zm[i].y);
        cx V0 = Zk + cjZm;
        cx V1 = cneg_i(Zk - cjZm);
        v[i] = cmul(V0, pf(a0pf, i)) + cpos_i(cmul(V1, pf(a1pf, i)));
    }
}

// ---------------------------------------------------------------------------
// Forward FFT of packed (a_ch0, a_ch1) pair, unpack both real spectra in
// DIF order (conjugate-partner: p2 = p ^ (2^floor(log2 p) - 1)).
// A0 = c*(Wk + conj(Wm)), A1 = c*(-i)*(Wk - conj(Wm)), c = 0.25/4096.
// Wk comes from fwd-s3 registers; only Wm is read from LDS.
// ---------------------------------------------------------------------------
__global__ __launch_bounds__(256, 4) void fft_a_kernel(
    const float* a_t, cx* __restrict__ A0s, cx* A1s,
    const cx* __restrict__ Twd)
{
    __shared__ cx data[FFT_LDS_SZ];
    __shared__ cx tw2lds[256];
    const int tid = threadIdx.x;
    const int r = blockIdx.x;                      // pair index, ch = 2r

    cx tw[16];
    {
        const cx* Tr1 = Twd + (tid << 4);
        #pragma unroll
        for (int t = 1; t < 16; ++t) tw[t] = Tr1[t];
        tw2lds[(tid >> 4) * 16 + (tid & 15)] = Twd[(tid & 15) * 256 + (tid >> 4)];
    }

    const float* r0 = a_t + (size_t)(2 * r) * M_FFT;
    const float* r1 = r0 + M_FFT;
    cx v[16];
    #pragma unroll
    for (int t = 0; t < 16; ++t)
        v[t] = mkcx(r0[tid + 256 * t], r1[tid + 256 * t]);

    {   // stage 1 from registers
        fft16_dif_r4<false>(v);
        apply_tw<false>(v, tw);
        cx* base = data + fpad(tid);
        #pragma unroll
        for (int p = 0; p < 16; ++p) base[274 * p] = v[p];
    }
    __syncthreads();
    fwd_s2(data, tid, tw2lds);
    __syncthreads();
    fwd_s3_keep(data, tid, v);
    __syncthreads();

    const float c = 0.25f / 4096.0f;
    const int base_i = tid << 4;
    cx* A0row = A0s + (size_t)r * 4096;
    cx* A1row = A1s + (size_t)r * 4096;
    cx wm[16];
    if (tid == 0) {
        #pragma unroll
        for (int i = 0; i < 16; ++i) {
            const int p2 = (i < 2) ? i : (i ^ ((1 << (31 - __clz(i))) - 1));
            wm[i] = v[p2];
        }
    } else {
        const int mask = (1 << (31 - __clz(base_i))) - 1;
        const cx* zb2 = data + fpad((base_i ^ mask) - 15);
        #pragma unroll
        for (int i = 0; i < 16; ++i) wm[i] = zb2[15 - i];
    }
    #pragma unroll
    for (int i = 0; i < 16; ++i) {
        cx cjWm = mkcx(wm[i].x, -wm[i].y);
        A0row[base_i + i] = c * (v[i] + cjWm);
        A1row[base_i + i] = c * cneg_i(v[i] - cjWm);
    }
}

// ---------------------------------------------------------------------------
// Conv kernel: TWO channel-pairs per block (batches 2bp and 2bp+1 of the
// SAME r) -> 2x work per barrier region, A rows loaded once for both.
// Bijective XCD remap: xcd = r&7; slots pair (r,bp=0),(r,bp=1) adjacent.
// 6 barriers; fwd-s3/pointwise and inv-s3/gate run register-resident.
// ---------------------------------------------------------------------------
__global__ __launch_bounds__(256, 2) void fft_conv_kernel(
    const bf16* __restrict__ v_t, const cx* __restrict__ A0s,
    const cx* __restrict__ A1s, const bf16* __restrict__ u_t,
    bf16* __restrict__ gated_t, const cx* __restrict__ Twd)
{
    __shared__ cx data[2][FFT_LDS_SZ];
    __shared__ cx tw2lds[256];
    const int tid = threadIdx.x;
    const int bx = blockIdx.x;
    const int xcd  = bx & 7;
    const int slot = bx >> 3;                 // [0,192)
    const int bp   = slot & 1;
    const int r    = (slot >> 1) * 8 + xcd;   // [0,768), bijective
    const int ch   = 2 * r;
    const int b0   = 2 * bp;
    const int b1   = 2 * bp + 1;

    cx tw[16];
    {
        const cx* Tr1 = Twd + (tid << 4);
        #pragma unroll
        for (int t = 1; t < 16; ++t) tw[t] = Tr1[t];
        tw2lds[(tid >> 4) * 16 + (tid & 15)] = Twd[(tid & 15) * 256 + (tid >> 4)];
    }

    // ---- forward stage 1: both chunks straight from global ----
    const bf16* z00 = v_t + ((size_t)(b0 * D1 + ch)) * N_SEQ;
    const bf16* z01 = z00 + N_SEQ;
    const bf16* z10 = v_t + ((size_t)(b1 * D1 + ch)) * N_SEQ;
    const bf16* z11 = z10 + N_SEQ;
    {
        cx w0[8], w1[8];
        #pragma unroll
        for (int t = 0; t < 8; ++t)
            w0[t] = mkcx((float)z00[tid + 256 * t], (float)z01[tid + 256 * t]);
        #pragma unroll
        for (int t = 0; t < 8; ++t)
            w1[t] = mkcx((float)z10[tid + 256 * t], (float)z11[tid + 256 * t]);
        fwd_s1_store_hz(w0, tw, data[0], tid);
        fwd_s1_store_hz(w1, tw, data[1], tid);
    }
    __syncthreads();                                              // 1

    fwd_s2(data[0], tid, tw2lds);
    fwd_s2(data[1], tid, tw2lds);
    __syncthreads();                                              // 2

    // A rows (shared by both chunks): issue before stage-3 compute so the
    // pre-barrier vmcnt drain overlaps both chunks' stage 3.
    const int pbase = tid << 4;
    float4 a0pf[8], a1pf[8];
    {
        const float4* A0p = (const float4*)(A0s + (size_t)r * 4096 + pbase);
        const float4* A1p = (const float4*)(A1s + (size_t)r * 4096 + pbase);
        #pragma unroll
        for (int i = 0; i < 8; ++i) { a0pf[i] = A0p[i]; a1pf[i] = A1p[i]; }
    }
    cx vA[16], vB[16];
    fwd_s3_keep(data[0], tid, vA);
    fwd_s3_keep(data[1], tid, vB);
    __syncthreads();                                              // 3

    // ---- pointwise (own Z from regs, partner from LDS; A in regs x2) ----
    pointwise_regs(data[0], tid, a0pf, a1pf, vA);
    pointwise_regs(data[1], tid, a0pf, a1pf, vB);
    __syncthreads();                       // 4: partner reads done
    fft16_dit_inv_r4<false>(vA);
    fft16_dit_inv_r4<false>(vB);
    {
        cx* baseA = data[0] + fpad(pbase);
        cx* baseB = data[1] + fpad(pbase);
        #pragma unroll
        for (int i = 0; i < 16; ++i) baseA[i] = vA[i];
        #pragma unroll
        for (int i = 0; i < 16; ++i) baseB[i] = vB[i];
    }
    __syncthreads();                                              // 5

    // u rows (strided layout matching inv-s3 ownership): issue before inv
    // stage 2 so the latency hides under it.
    const bf16* u00 = u_t + ((size_t)(b0 * D1 + ch)) * N_SEQ;
    const bf16* u01 = u00 + N_SEQ;
    const bf16* u10 = u_t + ((size_t)(b1 * D1 + ch)) * N_SEQ;
    const bf16* u11 = u10 + N_SEQ;
    bf16 ua0[8], ub0[8], ua1[8], ub1[8];
    #pragma unroll
    for (int t = 0; t < 8; ++t) {
        const int n = tid + 256 * t;
        ua0[t] = u00[n]; ub0[t] = u01[n];
        ua1[t] = u10[n]; ub1[t] = u11[n];
    }

    inv_s2(data[0], tid, tw2lds);
    inv_s2(data[1], tid, tw2lds);
    __syncthreads();                                              // 6

    bf16* g00 = gated_t + ((size_t)(b0 * D1 + ch)) * N_SEQ;
    bf16* g01 = g00 + N_SEQ;
    bf16* g10 = gated_t + ((size_t)(b1 * D1 + ch)) * N_SEQ;
    bf16* g11 = g10 + N_SEQ;
    inv_s3_gate(data[0], tid, tw, ua0, ub0, g00, g01);
    inv_s3_gate(data[1], tid, tw, ua1, ub1, g10, g11);
}

// ---------------------------------------------------------------------------
__global__ __launch_bounds__(256) void transpose_cs_kernel(
    const bf16* __restrict__ in, bf16* __restrict__ outp)
{
    __shared__ bf16 tile[64 * 68];
    const int c0 = blockIdx.x * 64;
    const int m0 = blockIdx.y * 64;
    const int b  = m0 >> 11;
    const int s0 = m0 & 2047;
    const int tid = threadIdx.x;
    const int cl = tid >> 4;
    const int sc = (tid & 15) * 4;
    #pragma unroll
    for (int p = 0; p < 4; ++p) {
        int c = p * 16 + cl;
        bf16x4 v = *(const bf16x4*)&in[((size_t)(b * D1 + c0 + c)) * N_SEQ + s0 + sc];
        *(bf16x4*)&tile[c * 68 + sc] = v;
    }
    __syncthreads();
    const int sl = tid >> 4;
    const int cc = (tid & 15) * 4;
    #pragma unroll
    for (int p = 0; p < 4; ++p) {
        int s = p * 16 + sl;
        bf16x4 o;
        #pragma unroll
        for (int j = 0; j < 4; ++j) o[j] = tile[(cc + j) * 68 + s];
        *(bf16x4*)&outp[((size_t)(m0 + s)) * D1 + c0 + cc] = o;
    }
}

// ---------------------------------------------------------------------------
extern "C" void kernel_launch(void* const* d_in, const int* in_sizes, int n_in,
                              void* d_out, int out_size, void* d_ws, size_t ws_size,
                              hipStream_t stream)
{
    const float* x  = (const float*)d_in[0];
    const float* Wu = (const float*)d_in[1];
    const float* bu = (const float*)d_in[2];
    const float* Wv = (const float*)d_in[3];
    const float* bv = (const float*)d_in[4];
    const float* Wo = (const float*)d_in[5];
    const float* bo = (const float*)d_in[6];
    const float* Wp = (const float*)d_in[7];
    const float* bp = (const float*)d_in[8];
    const float* Wl = (const float*)d_in[9];
    const float* bl = (const float*)d_in[10];
    const float* Wr = (const float*)d_in[11];
    const float* br = (const float*)d_in[12];
    float* out = (float*)d_out;

    float* ws      = (float*)d_ws;
    float* a_t     = ws;                       // 1536*4096 fp32; A1spec after fft_a
    float* A0spec  = a_t   + 6291456;          // 768 x 4096 cx
    float* sumsq   = A0spec + 6291456;         // 3 x 4096 fp32
    float* twd     = sumsq + 12288;            // 256 x 16 cx twiddle table
    bf16*  bfws    = (bf16*)(twd + 8192);
    bf16*  x_bf    = bfws;                     // 8192*512
    bf16*  w_bf    = x_bf    + 4194304;        // 5 x 786432: Wu,Wv,Wo,Wl,Wr
    bf16*  Wuv_bf  = w_bf;                     // stacked [Wu;Wv] 3072 x 512
    bf16*  Wo_bf   = w_bf    + 2 * 786432;
    bf16*  Wl_bf   = Wo_bf   + 786432;
    bf16*  Wr_bf   = Wl_bf   + 786432;
    bf16*  gA      = Wr_bf   + 786432;         // 4096*512
    bf16*  gB      = gA      + 2097152;        // 4096*512
    bf16*  u_t     = gB      + 2097152;        // 8192*1536 [b][c][s]
    bf16*  v_t     = u_t     + 12582912;       // 8192*1536 [b][c][s]
    bf16*  gated_t = v_t     + 12582912;       // 8192*1536 [b][c][s]
    bf16*  gated   = gated_t + 12582912;       // 8192*1536 [m][c]

    dim3 blk(256);

    // x/w converts + sumsq zero + rpe input layer + twiddle table
    f2b_all_kernel<<<4096 + 5 * 768 + 12 + 4096 + 16, blk, 0, stream>>>(
        x, Wu, Wv, Wo, Wl, Wr, Wp, bp, x_bf, w_bf, sumsq, gA, twd);

    gemm_bf16<MODE_SILU_UV, 128, bf16><<<dim3(24, 64), blk, 0, stream>>>(
        x_bf, Wuv_bf, bu, bv, u_t, v_t, 8192, 2 * D1, ED, nullptr, nullptr);

    // RPE MLP: srms folded into GEMM epilogues via row-scale commutation.
    bf16* gin = gA;
    bf16* gout = gB;
    for (int i = 0; i < 3; ++i) {
        const float* sin_p = (i == 0) ? nullptr : sumsq + (size_t)(i - 1) * 4096;
        gemm_bf16<MODE_RPE, 64, bf16><<<dim3(8, 32), blk, 0, stream>>>(
            gin, Wl_bf + (size_t)i * ED * ED, bl + (size_t)i * ED, nullptr,
            gout, nullptr, 4096, ED, ED, sin_p, sumsq + (size_t)i * 4096);
        bf16* t = gin; gin = gout; gout = t;
    }
    gemm_bf16<MODE_AT, 64, float><<<dim3(24, 32), blk, 0, stream>>>(
        gin, Wr_bf, br, nullptr, a_t, nullptr, 4096, D1, ED,
        sumsq + 2 * 4096, nullptr);

    fft_a_kernel<<<768, blk, 0, stream>>>(
        a_t, (cx*)A0spec, (cx*)a_t, (const cx*)twd);
    fft_conv_kernel<<<1536, blk, 0, stream>>>(
        v_t, (const cx*)A0spec, (const cx*)a_t, u_t, gated_t, (const cx*)twd);

    transpose_cs_kernel<<<dim3(24, 128), blk, 0, stream>>>(gated_t, gated);

    gemm_bf16<MODE_PLAIN, 64, float><<<dim3(8, 64), blk, 0, stream>>>(
        gated, Wo_bf, bo, nullptr, out, nullptr, 8192, ED, D1,
        nullptr, nullptr);
}

// Round 13
// 315.070 us; speedup vs baseline: 1.2720x; 1.0052x over previous
//
#include <hip/hip_runtime.h>

#define N_SEQ 2048
#define M_FFT 4096
#define D1    1536
#define NH    8
#define HD    192
#define ED    512

typedef __bf16 bf16;
typedef __bf16 bf16x4 __attribute__((ext_vector_type(4)));
typedef __bf16 bf16x8 __attribute__((ext_vector_type(8)));
typedef float  floatx4 __attribute__((ext_vector_type(4)));
typedef float  cx __attribute__((ext_vector_type(2)));   // complex as packed fp32

enum { MODE_PLAIN = 0, MODE_SILU_UV = 1, MODE_AT = 3, MODE_RPE = 4 };

__device__ __forceinline__ void gload16(const void* g, void* l) {
    __builtin_amdgcn_global_load_lds(
        (const __attribute__((address_space(1))) void*)g,
        (__attribute__((address_space(3))) void*)l, 16, 0, 0);
}

// same-wave LDS hand-off: commit prior ds_writes + compiler fence.
// Valid only when producer and consumer threads are in the same wave
// (DS ops of a wave execute in order).
#define WAVE_LDS_FENCE() asm volatile("s_waitcnt lgkmcnt(0)" ::: "memory")

// ---------------------------------------------------------------------------
// bf16 MFMA GEMM, depth-3 pipeline with COUNTED vmcnt (T4), BN-templated,
// + T2 granule-XOR LDS swizzle + T5 setprio.
// SILU_UV / AT epilogues transpose through LDS (reusing dead staging bufs).
// ---------------------------------------------------------------------------
template<int MODE, int BN, typename OutT>
__global__ __launch_bounds__(256) void gemm_bf16(
    const bf16* __restrict__ A, const bf16* __restrict__ Bw,
    const float* __restrict__ bias, const float* __restrict__ bias2,
    OutT* __restrict__ C, OutT* __restrict__ C2,
    int M, int Nc, int K,
    const float* __restrict__ scale_in, float* __restrict__ sumsq_out)
{
    constexpr int NJ  = BN / 32;           // n-fragments per wave (4 or 2)
    constexpr int ASZ = 3 * 128 * 32;
    constexpr int BSZ = 3 * BN * 32;
    __shared__ __align__(16) bf16 smem[ASZ + BSZ];
    bf16* As = smem;
    bf16* Bs = smem + ASZ;

    const int tid  = threadIdx.x;
    const int row0 = blockIdx.y * 128;
    const int col0 = blockIdx.x * BN;
    const int wid  = tid >> 6;
    const int lane = tid & 63;
    const int lm   = lane & 15;
    const int lk   = lane >> 4;
    const int wm   = wid >> 1;
    const int wn   = wid & 1;
    const int ldrow  = tid >> 2;
    // T2 write-side: source granule = (tid&3) ^ ((row>>1)&3), row = tid>>2
    const int ldcol8 = (((tid & 3) ^ ((tid >> 3) & 3))) * 8;
    // T2 read-side: granule = lk ^ ((row>>1)&3) = lk ^ ((lm>>1)&3)
    const int gsw = (lk ^ ((lm >> 1) & 3)) * 8;

    floatx4 acc[4][NJ] = {};

    const bf16* Ag = A  + ((size_t)(row0 + ldrow)) * K + ldcol8;
    const bf16* Bg = Bw + ((size_t)(col0 + ldrow)) * K + ldcol8;
    const int woff = (wid * 16) * 32;

    auto stage = [&](int t, int buf) {
        const int k0 = t << 5;
        gload16(Ag + k0, &As[buf * (128 * 32) + woff]);
        gload16(Ag + (size_t)64 * K + k0, &As[buf * (128 * 32) + woff + 64 * 32]);
        gload16(Bg + k0, &Bs[buf * (BN * 32) + woff]);
        if constexpr (BN == 128)
            gload16(Bg + (size_t)64 * K + k0, &Bs[buf * (BN * 32) + woff + 64 * 32]);
    };
    auto compute = [&](int buf) {
        bf16x8 af[4], bfr[NJ];
        #pragma unroll
        for (int mi = 0; mi < 4; ++mi)
            af[mi] = *(const bf16x8*)&As[buf * (128 * 32) + (wm * 64 + mi * 16 + lm) * 32 + gsw];
        #pragma unroll
        for (int nj = 0; nj < NJ; ++nj)
            bfr[nj] = *(const bf16x8*)&Bs[buf * (BN * 32) + (wn * (BN / 2) + nj * 16 + lm) * 32 + gsw];
        __builtin_amdgcn_s_setprio(1);                 // T5
        #pragma unroll
        for (int mi = 0; mi < 4; ++mi)
            #pragma unroll
            for (int nj = 0; nj < NJ; ++nj)
                acc[mi][nj] = __builtin_amdgcn_mfma_f32_16x16x32_bf16(
                    af[mi], bfr[nj], acc[mi][nj], 0, 0, 0);
        __builtin_amdgcn_s_setprio(0);
    };

    const int nt = K >> 5;           // 16 or 48
    stage(0, 0);
    stage(1, 1);
    int sb = 2, cb = 0;
    for (int t = 0; t < nt; ++t) {
        __builtin_amdgcn_s_barrier();          // A: compute(t-1) done everywhere
        __builtin_amdgcn_sched_barrier(0);
        if (t + 2 < nt) {
            stage(t + 2, sb);
            if (++sb == 3) sb = 0;
        }
        // own tile-t loads complete; next two tiles stay in flight
        if (t < nt - 2) {
            if constexpr (BN == 128) asm volatile("s_waitcnt vmcnt(8)" ::: "memory");
            else                     asm volatile("s_waitcnt vmcnt(6)" ::: "memory");
        } else if (t == nt - 2) {
            if constexpr (BN == 128) asm volatile("s_waitcnt vmcnt(4)" ::: "memory");
            else                     asm volatile("s_waitcnt vmcnt(3)" ::: "memory");
        } else {
            asm volatile("s_waitcnt vmcnt(0)" ::: "memory");
        }
        __builtin_amdgcn_s_barrier();          // B: tile t fully in LDS (all waves)
        __builtin_amdgcn_sched_barrier(0);
        compute(cb);
        if (++cb == 3) cb = 0;
    }

    const float* bs = bias;
    OutT* dst = C;
    int cadj = 0;
    if (MODE == MODE_SILU_UV && col0 >= D1) { bs = bias2; dst = C2; cadj = D1; }

    float bcol[NJ];
    #pragma unroll
    for (int nj = 0; nj < NJ; ++nj)
        bcol[nj] = bs[col0 - cadj + wn * (BN / 2) + nj * 16 + lm];

    if (MODE == MODE_RPE) {
        #pragma unroll
        for (int mi = 0; mi < 4; ++mi) {
            #pragma unroll
            for (int r = 0; r < 4; ++r) {
                const int row = row0 + wm * 64 + mi * 16 + lk * 4 + r;
                float sc = 1.0f;
                if (scale_in)
                    sc = 1.0f / (sqrtf(scale_in[row]) * 0.04419417382415922f + 1e-8f);
                float ssq = 0.0f;
                #pragma unroll
                for (int nj = 0; nj < NJ; ++nj) {
                    const int col = col0 + wn * (BN / 2) + nj * 16 + lm;
                    float val = acc[mi][nj][r] * sc + bcol[nj];
                    ssq += val * val;
                    ((bf16*)C)[(size_t)row * Nc + col] = (bf16)fmaxf(val, 0.0f);
                }
                ssq += __shfl_xor(ssq, 1, 64);
                ssq += __shfl_xor(ssq, 2, 64);
                ssq += __shfl_xor(ssq, 4, 64);
                ssq += __shfl_xor(ssq, 8, 64);
                if (lm == 0) atomicAdd(&sumsq_out[row], ssq);
            }
        }
        return;
    }

    if (MODE == MODE_SILU_UV) {
        // ---- transpose-through-LDS coalesced store (128 x 128 tile) ----
        constexpr int TP = 136;                 // row pad: 16B-aligned rows
        bf16* T = smem;                         // 128*136*2 = 34816 B <= 48K
        __syncthreads();                        // K-loop LDS reads done
        #pragma unroll
        for (int mi = 0; mi < 4; ++mi) {
            const int rl = wm * 64 + mi * 16 + lk * 4;
            #pragma unroll
            for (int nj = 0; nj < NJ; ++nj) {
                const int cl = wn * 64 + nj * 16 + lm;
                bf16x4 o;
                #pragma unroll
                for (int r = 0; r < 4; ++r) {
                    float val = acc[mi][nj][r] + bcol[nj];
                    val = val * __fdividef(1.0f, 1.0f + __expf(-val));
                    o[r] = (bf16)val;
                }
                *(bf16x4*)&T[cl * TP + rl] = o;
            }
        }
        __syncthreads();
        const int b  = row0 >> 11;
        const int s0 = row0 & 2047;
        #pragma unroll
        for (int j = 0; j < 8; ++j) {
            const int idx = j * 256 + tid;      // [0, 2048)
            const int sc  = (idx & 15) * 8;     // s-chunk (16 consecutive tids)
            const int c   = idx >> 4;           // column 0..127
            bf16x8 o = *(const bf16x8*)&T[c * TP + sc];
            *(bf16x8*)&((bf16*)dst)[((size_t)(b * D1 + col0 - cadj + c)) * N_SEQ + s0 + sc] = o;
        }
        return;
    }

    if (MODE == MODE_AT) {
        // ---- transpose-through-LDS coalesced fp32 store (64 x 128 tile) ----
        constexpr int TP = 132;                 // fp32 row pad (16B-aligned)
        float* Tf = (float*)smem;               // 64*132*4 = 33792 B <= 36864
        __syncthreads();
        #pragma unroll
        for (int mi = 0; mi < 4; ++mi) {
            const int rbase = row0 + wm * 64 + mi * 16 + lk * 4;
            const int rl    = wm * 64 + mi * 16 + lk * 4;
            float sc[4];
            #pragma unroll
            for (int r = 0; r < 4; ++r)
                sc[r] = scale_in
                    ? 1.0f / (sqrtf(scale_in[rbase + r]) * 0.04419417382415922f + 1e-8f)
                    : 1.0f;
            #pragma unroll
            for (int nj = 0; nj < NJ; ++nj) {
                const int cl = wn * (BN / 2) + nj * 16 + lm;
                float4 o;
                o.x = acc[mi][nj][0] * sc[0] + bcol[nj];
                o.y = acc[mi][nj][1] * sc[1] + bcol[nj];
                o.z = acc[mi][nj][2] * sc[2] + bcol[nj];
                o.w = acc[mi][nj][3] * sc[3] + bcol[nj];
                *(float4*)&Tf[cl * TP + rl] = o;
            }
        }
        __syncthreads();
        #pragma unroll
        for (int j = 0; j < 8; ++j) {
            const int idx = j * 256 + tid;      // [0, 2048)
            const int rc  = (idx & 31) * 4;     // row-chunk (32 consecutive tids)
            const int c   = idx >> 5;           // column 0..63
            float4 o = *(const float4*)&Tf[c * TP + rc];
            *(float4*)&((float*)C)[(size_t)(col0 + c) * M + row0 + rc] = o;
        }
        return;
    }

    // MODE_PLAIN: row-major contiguous store (already coalesced enough)
    #pragma unroll
    for (int mi = 0; mi < 4; ++mi) {
        const int rbase = row0 + wm * 64 + mi * 16 + lk * 4;
        #pragma unroll
        for (int nj = 0; nj < NJ; ++nj) {
            const int col = col0 + wn * (BN / 2) + nj * 16 + lm;
            #pragma unroll
            for (int r = 0; r < 4; ++r) {
                float val = acc[mi][nj][r] + bcol[nj];
                C[(size_t)(rbase + r) * Nc + col] = (OutT)val;
            }
        }
    }
}

// ---------------------------------------------------------------------------
// mega-prologue: x convert + 5 weight converts + sumsq zero +
// RPE input layer w/ srms + FFT twiddle table (256 x 16 cx)
// ---------------------------------------------------------------------------
__global__ __launch_bounds__(256) void f2b_all_kernel(
    const float* __restrict__ x,  const float* __restrict__ s0,
    const float* __restrict__ s1, const float* __restrict__ s2,
    const float* __restrict__ s3, const float* __restrict__ s4,
    const float* __restrict__ Wp, const float* __restrict__ bp,
    bf16* __restrict__ x_bf, bf16* __restrict__ w_bf,
    float* __restrict__ sumsq, bf16* __restrict__ g0,
    float* __restrict__ twd)
{
    const int bid = blockIdx.x;
    const int tid = threadIdx.x;
    __shared__ float red[4];

    if (bid < 7936) {
        const float* src;
        bf16* dst;
        size_t off;
        if (bid < 4096) {
            src = x; dst = x_bf; off = (size_t)bid * 1024;
        } else {
            int t = bid - 4096;
            int seg = t / 768;
            src = seg == 0 ? s0 : seg == 1 ? s1 : seg == 2 ? s2
                : seg == 3 ? s3 : s4;
            dst = w_bf + (size_t)seg * 786432;
            off = (size_t)(t % 768) * 1024;
        }
        size_t i = off + (size_t)tid * 4;
        float4 f = *(const float4*)(src + i);
        union { bf16 h[4]; short4 s; } u4;
        u4.h[0] = (bf16)f.x; u4.h[1] = (bf16)f.y;
        u4.h[2] = (bf16)f.z; u4.h[3] = (bf16)f.w;
        *(short4*)(dst + i) = u4.s;
    } else if (bid < 7948) {
        size_t i = (size_t)(bid - 7936) * 1024 + (size_t)tid * 4;
        *(float4*)(sumsq + i) = make_float4(0.f, 0.f, 0.f, 0.f);
    } else if (bid < 12044) {
        const int j = bid - 7948;
        float idxv = (j < N_SEQ) ? (float)j
                                 : (j == N_SEQ ? 0.0f : (float)(j - 2 * N_SEQ));
        float h1 = idxv * Wp[tid] + bp[tid];
        float h2 = idxv * Wp[tid + 256] + bp[tid + 256];
        float ss = h1 * h1 + h2 * h2;
        #pragma unroll
        for (int off = 32; off > 0; off >>= 1) ss += __shfl_down(ss, off, 64);
        if ((tid & 63) == 0) red[tid >> 6] = ss;
        __syncthreads();
        float tot = red[0] + red[1] + red[2] + red[3];
        float scale = 1.0f / (sqrtf(tot) * 0.04419417382415922f + 1e-8f);
        g0[(size_t)j * ED + tid]       = (bf16)fmaxf(h1 * scale, 0.0f);
        g0[(size_t)j * ED + tid + 256] = (bf16)fmaxf(h2 * scale, 0.0f);
    } else {
        const int idx = (bid - 12044) * 256 + tid;    // [0, 4096)
        const int j = idx >> 4, tau = idx & 15;
        float sA, cA;
        __sincosf(-6.283185307179586f * (float)(j * tau) * (1.0f / 4096.0f),
                  &sA, &cA);
        cx w; w.x = cA; w.y = sA;
        ((cx*)twd)[idx] = w;
    }
}

// ---------------------------------------------------------------------------
// Radix-16 FFT, radix-4 butterflies, packed-fp32 complex.
// LDS addressing: fpad(base + s*t) = fpad(base) + s'*t  (256->274, 16->17, 1->1)
// Stage-1/inv-3 twiddle row (tid<<4) in REGISTERS (inverse = conjugate);
// stage-2/inv-2 rows (16 distinct) in a 2 KB LDS broadcast table.
// SYNC STRUCTURE: stages 2 and 3 (and inv-1 -> inv-2) operate within
// 256-element groups owned by the SAME 16 threads, and 16 | 64 -> same
// wave. Those hand-offs use WAVE_LDS_FENCE (in-order DS per wave), not
// s_barrier. Barriers remain only at cross-group transitions.
// ---------------------------------------------------------------------------
#define FFT_LDS_SZ 4381

__device__ __forceinline__ int fpad(int i) { return i + (i >> 4) + 2 * (i >> 8); }

__device__ __forceinline__ cx mkcx(float a, float b) { cx r; r.x = a; r.y = b; return r; }
__device__ __forceinline__ cx cmul(cx a, cx b) {
    cx br = mkcx(-b.y, b.x);
    return a.xx * b + a.yy * br;
}
__device__ __forceinline__ cx cmul_cj(cx a, cx b) {      // a * conj(b)
    cx bc = mkcx(b.x, -b.y);
    cx br = mkcx(b.y, b.x);
    return a.xx * bc + a.yy * br;
}
__device__ __forceinline__ cx cneg_i(cx a) { return mkcx(a.y, -a.x); }   // a * (-i)
__device__ __forceinline__ cx cpos_i(cx a) { return mkcx(-a.y, a.x); }   // a * (+i)
__host__ __device__ constexpr int brev4(int t) {
    return ((t & 1) << 3) | ((t & 2) << 1) | ((t & 4) >> 1) | ((t & 8) >> 3);
}

#define CC1 0.9238795325112867f
#define SS1 0.3826834323650898f
#define RR2 0.7071067811865476f

template<bool HZ>
__device__ __forceinline__ void fft16_dif_r4(cx x[16]) {
    const cx W1 = mkcx( CC1, -SS1);
    const cx W2 = mkcx( RR2, -RR2);
    const cx W3 = mkcx( SS1, -CC1);
    const cx W6 = mkcx(-RR2, -RR2);
    const cx W9 = mkcx(-CC1,  SS1);
    #pragma unroll
    for (int n = 0; n < 4; ++n) {
        cx A, B, C, D;
        if (HZ) { A = x[n]; C = x[n]; B = x[n + 4]; D = x[n + 4]; }
        else {
            A = x[n] + x[n + 8];      C = x[n] - x[n + 8];
            B = x[n + 4] + x[n + 12]; D = x[n + 4] - x[n + 12];
        }
        cx s = A - B;
        cx nid = cneg_i(D);
        cx m = C + nid;
        cx p = C - nid;
        x[n] = A + B;
        if (n == 0)      { x[4] = s;            x[8]  = m;           x[12] = p; }
        else if (n == 1) { x[5] = cmul(s, W2);  x[9]  = cmul(m, W1); x[13] = cmul(p, W3); }
        else if (n == 2) { x[6] = cneg_i(s);    x[10] = cmul(m, W2); x[14] = cmul(p, W6); }
        else             { x[7] = cmul(s, W6);  x[11] = cmul(m, W3); x[15] = cmul(p, W9); }
    }
    #pragma unroll
    for (int q = 0; q < 16; q += 4) {
        cx a = x[q], b = x[q + 1], c = x[q + 2], d = x[q + 3];
        cx a1 = a + c, c1 = a - c;
        cx b1 = b + d, d1 = cneg_i(b - d);
        x[q]     = a1 + b1;
        x[q + 1] = a1 - b1;
        x[q + 2] = c1 + d1;
        x[q + 3] = c1 - d1;
    }
}

template<bool HALF_OUT>
__device__ __forceinline__ void fft16_dit_inv_r4(cx x[16]) {
    const cx V1 = mkcx( CC1, SS1);
    const cx V2 = mkcx( RR2, RR2);
    const cx V3 = mkcx( SS1, CC1);
    const cx V6 = mkcx(-RR2, RR2);
    #pragma unroll
    for (int q = 0; q < 16; q += 4) {
        cx a = x[q], b = x[q + 1], c = x[q + 2], d = x[q + 3];
        cx a1 = a + b, b1 = a - b;
        cx c1 = c + d, d1 = c - d;
        cx t = cpos_i(d1);
        x[q]     = a1 + c1;
        x[q + 2] = a1 - c1;
        x[q + 1] = b1 + t;
        x[q + 3] = b1 - t;
    }
    #pragma unroll
    for (int n = 0; n < 4; ++n) {
        cx t1, t2;
        if (n == 0)      { t1 = x[4];             t2 = x[12]; }
        else if (n == 1) { t1 = cmul(x[5],  V2);  t2 = cmul(x[13], V2); }
        else if (n == 2) { t1 = cpos_i(x[6]);     t2 = cpos_i(x[14]); }
        else             { t1 = cmul(x[7],  V6);  t2 = cmul(x[15], V6); }
        cx P = x[n] + t1, Q = x[n] - t1;
        cx R = x[n + 8] + t2, S = x[n + 8] - t2;
        cx t, u;
        if (n == 0)      { t = R;            u = S; }
        else if (n == 1) { t = cmul(R, V1);  u = cmul(S, V1); }
        else if (n == 2) { t = cmul(R, V2);  u = cmul(S, V2); }
        else             { t = cmul(R, V3);  u = cmul(S, V3); }
        cx iu = cpos_i(u);
        x[n]     = P + t;
        x[n + 4] = Q + iu;
        if (!HALF_OUT) {
            x[n + 8]  = P - t;
            x[n + 12] = Q - iu;
        }
    }
}

template<bool CONJ>
__device__ __forceinline__ void apply_tw(cx v[16], const cx tw[16]) {
    #pragma unroll
    for (int tau = 1; tau < 16; ++tau) {
        const int q = brev4(tau);
        v[q] = CONJ ? cmul_cj(v[q], tw[tau]) : cmul(v[q], tw[tau]);
    }
}

// twrow points at tw2lds + (tid&15); stride 16 per tau. Broadcast reads.
template<bool CONJ>
__device__ __forceinline__ void apply_tw_lds(cx v[16], const cx* twrow) {
    #pragma unroll
    for (int tau = 1; tau < 16; ++tau) {
        cx w = twrow[tau * 16];
        const int q = brev4(tau);
        v[q] = CONJ ? cmul_cj(v[q], w) : cmul(v[q], w);
    }
}

// ---- per-stage helpers (in-place per-thread; caller places sync) ----------
__device__ __forceinline__ void fwd_s1_store_hz(
    const cx vin[8], const cx tw[16], cx* d, int tid)
{
    cx x[16];
    #pragma unroll
    for (int t = 0; t < 8; ++t) x[t] = vin[t];
    fft16_dif_r4<true>(x);
    apply_tw<false>(x, tw);
    cx* base = d + fpad(tid);
    #pragma unroll
    for (int p = 0; p < 16; ++p) base[274 * p] = x[p];
}

__device__ __forceinline__ void fwd_s2(cx* d, int tid, const cx* tw2lds)
{
    cx v[16];
    cx* base = d + fpad(((tid >> 4) << 8) + (tid & 15));
    #pragma unroll
    for (int t = 0; t < 16; ++t) v[t] = base[17 * t];
    fft16_dif_r4<false>(v);
    apply_tw_lds<false>(v, tw2lds + (tid & 15));
    #pragma unroll
    for (int p = 0; p < 16; ++p) base[17 * p] = v[p];
}

// stage 3: keeps result in v (thread owns bins [tid*16, tid*16+16))
__device__ __forceinline__ void fwd_s3_keep(cx* d, int tid, cx v[16])
{
    cx* base = d + fpad(tid << 4);
    #pragma unroll
    for (int t = 0; t < 16; ++t) v[t] = base[t];
    fft16_dif_r4<false>(v);
    #pragma unroll
    for (int p = 0; p < 16; ++p) base[p] = v[p];
}

__device__ __forceinline__ void inv_s2(cx* d, int tid, const cx* tw2lds)
{
    cx v[16];
    cx* base = d + fpad(((tid >> 4) << 8) + (tid & 15));
    #pragma unroll
    for (int p = 0; p < 16; ++p) v[p] = base[17 * p];
    apply_tw_lds<true>(v, tw2lds + (tid & 15));
    fft16_dit_inv_r4<false>(v);
    #pragma unroll
    for (int t = 0; t < 16; ++t) base[17 * t] = v[t];
}

// inv stage 3 (lower half) fused with the u-gate: output stays in regs and
// goes straight to global at n = tid + 256*t (coalesced strided).
__device__ __forceinline__ void inv_s3_gate(
    const cx* d, int tid, const cx tw[16],
    const bf16 ua[8], const bf16 ub[8],
    bf16* __restrict__ g0, bf16* __restrict__ g1)
{
    cx v[16];
    const cx* base = d + fpad(tid);
    #pragma unroll
    for (int p = 0; p < 16; ++p) v[p] = base[274 * p];
    apply_tw<true>(v, tw);
    fft16_dit_inv_r4<true>(v);
    #pragma unroll
    for (int t = 0; t < 8; ++t) {
        const int n = tid + 256 * t;
        g0[n] = (bf16)(v[t].x * (float)ua[t]);
        g1[n] = (bf16)(v[t].y * (float)ub[t]);
    }
}

// pointwise using own fwd-s3 regs (v in: Z block; v out: Y block).
// Only the conjugate-partner block is read from LDS (thread 0: none).
__device__ __forceinline__ void pointwise_regs(
    const cx* d, int tid, const float4 a0pf[8], const float4 a1pf[8],
    cx v[16])
{
    auto pf = [](const float4* p, int i) -> cx {
        return (i & 1) ? mkcx(p[i >> 1].z, p[i >> 1].w)
                       : mkcx(p[i >> 1].x, p[i >> 1].y);
    };
    const int pbase = tid << 4;
    cx zm[16];
    if (tid == 0) {
        #pragma unroll
        for (int i = 0; i < 16; ++i) {
            const int p2 = (i < 2) ? i : (i ^ ((1 << (31 - __clz(i))) - 1));
            zm[i] = v[p2];                    // compile-time index
        }
    } else {
        const int mask = (1 << (31 - __clz(pbase))) - 1;
        const cx* zb2 = d + fpad((pbase ^ mask) - 15);
        #pragma unroll
        for (int i = 0; i < 16; ++i) zm[i] = zb2[15 - i];
    }
    #pragma unroll
    for (int i = 0; i < 16; ++i) {
        cx Zk = v[i];
        cx cjZm = mkcx(zm[i].x, -zm[i].y);
        cx V0 = Zk + cjZm;
        cx V1 = cneg_i(Zk - cjZm);
        v[i] = cmul(V0, pf(a0pf, i)) + cpos_i(cmul(V1, pf(a1pf, i)));
    }
}

// ---------------------------------------------------------------------------
// Forward FFT of packed (a_ch0, a_ch1) pair, unpack both real spectra in
// DIF order (conjugate-partner: p2 = p ^ (2^floor(log2 p) - 1)).
// A0 = c*(Wk + conj(Wm)), A1 = c*(-i)*(Wk - conj(Wm)), c = 0.25/4096.
// Wk comes from fwd-s3 registers; only Wm is read from LDS.
// ---------------------------------------------------------------------------
__global__ __launch_bounds__(256, 4) void fft_a_kernel(
    const float* a_t, cx* __restrict__ A0s, cx* A1s,
    const cx* __restrict__ Twd)
{
    __shared__ cx data[FFT_LDS_SZ];
    __shared__ cx tw2lds[256];
    const int tid = threadIdx.x;
    const int r = blockIdx.x;                      // pair index, ch = 2r

    cx tw[16];
    {
        const cx* Tr1 = Twd + (tid << 4);
        #pragma unroll
        for (int t = 1; t < 16; ++t) tw[t] = Tr1[t];
        tw2lds[(tid >> 4) * 16 + (tid & 15)] = Twd[(tid & 15) * 256 + (tid >> 4)];
    }

    const float* r0 = a_t + (size_t)(2 * r) * M_FFT;
    const float* r1 = r0 + M_FFT;
    cx v[16];
    #pragma unroll
    for (int t = 0; t < 16; ++t)
        v[t] = mkcx(r0[tid + 256 * t], r1[tid + 256 * t]);

    {   // stage 1 from registers
        fft16_dif_r4<false>(v);
        apply_tw<false>(v, tw);
        cx* base = data + fpad(tid);
        #pragma unroll
        for (int p = 0; p < 16; ++p) base[274 * p] = v[p];
    }
    __syncthreads();                      // cross-group: s1 -> s2
    fwd_s2(data, tid, tw2lds);
    WAVE_LDS_FENCE();                     // same-wave: s2 -> s3
    fwd_s3_keep(data, tid, v);
    __syncthreads();                      // cross-group: s3 -> partner unpack

    const float c = 0.25f / 4096.0f;
    const int base_i = tid << 4;
    cx* A0row = A0s + (size_t)r * 4096;
    cx* A1row = A1s + (size_t)r * 4096;
    cx wm[16];
    if (tid == 0) {
        #pragma unroll
        for (int i = 0; i < 16; ++i) {
            const int p2 = (i < 2) ? i : (i ^ ((1 << (31 - __clz(i))) - 1));
            wm[i] = v[p2];
        }
    } else {
        const int mask = (1 << (31 - __clz(base_i))) - 1;
        const cx* zb2 = data + fpad((base_i ^ mask) - 15);
        #pragma unroll
        for (int i = 0; i < 16; ++i) wm[i] = zb2[15 - i];
    }
    #pragma unroll
    for (int i = 0; i < 16; ++i) {
        cx cjWm = mkcx(wm[i].x, -wm[i].y);
        A0row[base_i + i] = c * (v[i] + cjWm);
        A1row[base_i + i] = c * cneg_i(v[i] - cjWm);
    }
}

// ---------------------------------------------------------------------------
// Conv kernel: TWO channel-pairs per block (batches 2bp and 2bp+1 of the
// SAME r) -> 2x work per barrier region, A rows loaded once for both.
// Bijective XCD remap: xcd = r&7; slots pair (r,bp=0),(r,bp=1) adjacent.
// 4 barriers (was 6): s2->s3 and inv1->inv2 are same-wave hand-offs.
// ---------------------------------------------------------------------------
__global__ __launch_bounds__(256, 2) void fft_conv_kernel(
    const bf16* __restrict__ v_t, const cx* __restrict__ A0s,
    const cx* __restrict__ A1s, const bf16* __restrict__ u_t,
    bf16* __restrict__ gated_t, const cx* __restrict__ Twd)
{
    __shared__ cx data[2][FFT_LDS_SZ];
    __shared__ cx tw2lds[256];
    const int tid = threadIdx.x;
    const int bx = blockIdx.x;
    const int xcd  = bx & 7;
    const int slot = bx >> 3;                 // [0,192)
    const int bp   = slot & 1;
    const int r    = (slot >> 1) * 8 + xcd;   // [0,768), bijective
    const int ch   = 2 * r;
    const int b0   = 2 * bp;
    const int b1   = 2 * bp + 1;

    cx tw[16];
    {
        const cx* Tr1 = Twd + (tid << 4);
        #pragma unroll
        for (int t = 1; t < 16; ++t) tw[t] = Tr1[t];
        tw2lds[(tid >> 4) * 16 + (tid & 15)] = Twd[(tid & 15) * 256 + (tid >> 4)];
    }

    // ---- forward stage 1: both chunks straight from global ----
    const bf16* z00 = v_t + ((size_t)(b0 * D1 + ch)) * N_SEQ;
    const bf16* z01 = z00 + N_SEQ;
    const bf16* z10 = v_t + ((size_t)(b1 * D1 + ch)) * N_SEQ;
    const bf16* z11 = z10 + N_SEQ;
    {
        cx w0[8], w1[8];
        #pragma unroll
        for (int t = 0; t < 8; ++t)
            w0[t] = mkcx((float)z00[tid + 256 * t], (float)z01[tid + 256 * t]);
        #pragma unroll
        for (int t = 0; t < 8; ++t)
            w1[t] = mkcx((float)z10[tid + 256 * t], (float)z11[tid + 256 * t]);
        fwd_s1_store_hz(w0, tw, data[0], tid);
        fwd_s1_store_hz(w1, tw, data[1], tid);
    }
    __syncthreads();                      // 1: cross-group s1 -> s2

    fwd_s2(data[0], tid, tw2lds);
    fwd_s2(data[1], tid, tw2lds);
    WAVE_LDS_FENCE();                     // same-wave s2 -> s3

    // A rows (shared by both chunks): issue before stage-3 compute so the
    // latency overlaps both chunks' stage 3.
    const int pbase = tid << 4;
    float4 a0pf[8], a1pf[8];
    {
        const float4* A0p = (const float4*)(A0s + (size_t)r * 4096 + pbase);
        const float4* A1p = (const float4*)(A1s + (size_t)r * 4096 + pbase);
        #pragma unroll
        for (int i = 0; i < 8; ++i) { a0pf[i] = A0p[i]; a1pf[i] = A1p[i]; }
    }
    cx vA[16], vB[16];
    fwd_s3_keep(data[0], tid, vA);
    fwd_s3_keep(data[1], tid, vB);
    __syncthreads();                      // 2: cross-group s3 -> pointwise

    // ---- pointwise (own Z from regs, partner from LDS; A in regs x2) ----
    pointwise_regs(data[0], tid, a0pf, a1pf, vA);
    pointwise_regs(data[1], tid, a0pf, a1pf, vB);
    __syncthreads();                      // 3: partner reads done (cross-wave)
    fft16_dit_inv_r4<false>(vA);
    fft16_dit_inv_r4<false>(vB);
    {
        cx* baseA = data[0] + fpad(pbase);
        cx* baseB = data[1] + fpad(pbase);
        #pragma unroll
        for (int i = 0; i < 16; ++i) baseA[i] = vA[i];
        #pragma unroll
        for (int i = 0; i < 16; ++i) baseB[i] = vB[i];
    }
    WAVE_LDS_FENCE();                     // same-wave inv1 -> inv2

    // u rows (strided layout matching inv-s3 ownership): issue before inv
    // stage 2 so the latency hides under it.
    const bf16* u00 = u_t + ((size_t)(b0 * D1 + ch)) * N_SEQ;
    const bf16* u01 = u00 + N_SEQ;
    const bf16* u10 = u_t + ((size_t)(b1 * D1 + ch)) * N_SEQ;
    const bf16* u11 = u10 + N_SEQ;
    bf16 ua0[8], ub0[8], ua1[8], ub1[8];
    #pragma unroll
    for (int t = 0; t < 8; ++t) {
        const int n = tid + 256 * t;
        ua0[t] = u00[n]; ub0[t] = u01[n];
        ua1[t] = u10[n]; ub1[t] = u11[n];
    }

    inv_s2(data[0], tid, tw2lds);
    inv_s2(data[1], tid, tw2lds);
    __syncthreads();                      // 4: cross-group inv2 -> inv3

    bf16* g00 = gated_t + ((size_t)(b0 * D1 + ch)) * N_SEQ;
    bf16* g01 = g00 + N_SEQ;
    bf16* g10 = gated_t + ((size_t)(b1 * D1 + ch)) * N_SEQ;
    bf16* g11 = g10 + N_SEQ;
    inv_s3_gate(data[0], tid, tw, ua0, ub0, g00, g01);
    inv_s3_gate(data[1], tid, tw, ua1, ub1, g10, g11);
}

// ---------------------------------------------------------------------------
__global__ __launch_bounds__(256) void transpose_cs_kernel(
    const bf16* __restrict__ in, bf16* __restrict__ outp)
{
    __shared__ bf16 tile[64 * 68];
    const int c0 = blockIdx.x * 64;
    const int m0 = blockIdx.y * 64;
    const int b  = m0 >> 11;
    const int s0 = m0 & 2047;
    const int tid = threadIdx.x;
    const int cl = tid >> 4;
    const int sc = (tid & 15) * 4;
    #pragma unroll
    for (int p = 0; p < 4; ++p) {
        int c = p * 16 + cl;
        bf16x4 v = *(const bf16x4*)&in[((size_t)(b * D1 + c0 + c)) * N_SEQ + s0 + sc];
        *(bf16x4*)&tile[c * 68 + sc] = v;
    }
    __syncthreads();
    const int sl = tid >> 4;
    const int cc = (tid & 15) * 4;
    #pragma unroll
    for (int p = 0; p < 4; ++p) {
        int s = p * 16 + sl;
        bf16x4 o;
        #pragma unroll
        for (int j = 0; j < 4; ++j) o[j] = tile[(cc + j) * 68 + s];
        *(bf16x4*)&outp[((size_t)(m0 + s)) * D1 + c0 + cc] = o;
    }
}

// ---------------------------------------------------------------------------
extern "C" void kernel_launch(void* const* d_in, const int* in_sizes, int n_in,
                              void* d_out, int out_size, void* d_ws, size_t ws_size,
                              hipStream_t stream)
{
    const float* x  = (const float*)d_in[0];
    const float* Wu = (const float*)d_in[1];
    const float* bu = (const float*)d_in[2];
    const float* Wv = (const float*)d_in[3];
    const float* bv = (const float*)d_in[4];
    const float* Wo = (const float*)d_in[5];
    const float* bo = (const float*)d_in[6];
    const float* Wp = (const float*)d_in[7];
    const float* bp = (const float*)d_in[8];
    const float* Wl = (const float*)d_in[9];
    const float* bl = (const float*)d_in[10];
    const float* Wr = (const float*)d_in[11];
    const float* br = (const float*)d_in[12];
    float* out = (float*)d_out;

    float* ws      = (float*)d_ws;
    float* a_t     = ws;                       // 1536*4096 fp32; A1spec after fft_a
    float* A0spec  = a_t   + 6291456;          // 768 x 4096 cx
    float* sumsq   = A0spec + 6291456;         // 3 x 4096 fp32
    float* twd     = sumsq + 12288;            // 256 x 16 cx twiddle table
    bf16*  bfws    = (bf16*)(twd + 8192);
    bf16*  x_bf    = bfws;                     // 8192*512
    bf16*  w_bf    = x_bf    + 4194304;        // 5 x 786432: Wu,Wv,Wo,Wl,Wr
    bf16*  Wuv_bf  = w_bf;                     // stacked [Wu;Wv] 3072 x 512
    bf16*  Wo_bf   = w_bf    + 2 * 786432;
    bf16*  Wl_bf   = Wo_bf   + 786432;
    bf16*  Wr_bf   = Wl_bf   + 786432;
    bf16*  gA      = Wr_bf   + 786432;         // 4096*512
    bf16*  gB      = gA      + 2097152;        // 4096*512
    bf16*  u_t     = gB      + 2097152;        // 8192*1536 [b][c][s]
    bf16*  v_t     = u_t     + 12582912;       // 8192*1536 [b][c][s]
    bf16*  gated_t = v_t     + 12582912;       // 8192*1536 [b][c][s]
    bf16*  gated   = gated_t + 12582912;       // 8192*1536 [m][c]

    dim3 blk(256);

    // x/w converts + sumsq zero + rpe input layer + twiddle table
    f2b_all_kernel<<<4096 + 5 * 768 + 12 + 4096 + 16, blk, 0, stream>>>(
        x, Wu, Wv, Wo, Wl, Wr, Wp, bp, x_bf, w_bf, sumsq, gA, twd);

    gemm_bf16<MODE_SILU_UV, 128, bf16><<<dim3(24, 64), blk, 0, stream>>>(
        x_bf, Wuv_bf, bu, bv, u_t, v_t, 8192, 2 * D1, ED, nullptr, nullptr);

    // RPE MLP: srms folded into GEMM epilogues via row-scale commutation.
    bf16* gin = gA;
    bf16* gout = gB;
    for (int i = 0; i < 3; ++i) {
        const float* sin_p = (i == 0) ? nullptr : sumsq + (size_t)(i - 1) * 4096;
        gemm_bf16<MODE_RPE, 64, bf16><<<dim3(8, 32), blk, 0, stream>>>(
            gin, Wl_bf + (size_t)i * ED * ED, bl + (size_t)i * ED, nullptr,
            gout, nullptr, 4096, ED, ED, sin_p, sumsq + (size_t)i * 4096);
        bf16* t = gin; gin = gout; gout = t;
    }
    gemm_bf16<MODE_AT, 64, float><<<dim3(24, 32), blk, 0, stream>>>(
        gin, Wr_bf, br, nullptr, a_t, nullptr, 4096, D1, ED,
        sumsq + 2 * 4096, nullptr);

    fft_a_kernel<<<768, blk, 0, stream>>>(
        a_t, (cx*)A0spec, (cx*)a_t, (const cx*)twd);
    fft_conv_kernel<<<1536, blk, 0, stream>>>(
        v_t, (const cx*)A0spec, (const cx*)a_t, u_t, gated_t, (const cx*)twd);

    transpose_cs_kernel<<<dim3(24, 128), blk, 0, stream>>>(gated_t, gated);

    gemm_bf16<MODE_PLAIN, 64, float><<<dim3(8, 64), blk, 0, stream>>>(
        gated, Wo_bf, bo, nullptr, out, nullptr, 8192, ED, D1,
        nullptr, nullptr);
}